// Round 6
// baseline (998.517 us; speedup 1.0000x reference)
//
#include <hip/hip_runtime.h>
#include <hip/hip_bf16.h>
#include <stdint.h>

namespace {

constexpr int Z0 = 41, Y0 = 256, X0 = 256;
constexpr int Z2 = 21, Y2 = 128, X2 = 128;
constexpr int Z3 = 11, Y3 = 64,  X3 = 64;
constexpr int Z4 = 21, Y4 = 127, X4 = 127;
constexpr int NV0 = Z0 * Y0 * X0;
constexpr int NV2 = Z2 * Y2 * X2;
constexpr int NV3 = Z3 * Y3 * X3;
constexpr int NV4 = Z4 * Y4 * X4;

constexpr int ZP0 = 43, YP0 = 258, XP0 = 258; constexpr int NP0 = ZP0 * YP0 * XP0;
constexpr int ZP2 = 23, YP2 = 130, XP2 = 130; constexpr int NP2 = ZP2 * YP2 * XP2;
constexpr int ZP3 = 13, YP3 = 66,  XP3 = 66;  constexpr int NP3 = ZP3 * YP3 * XP3;
constexpr int ZP4 = 23, YP4 = 129, XP4 = 129; constexpr int NP4 = ZP4 * YP4 * XP4;

using bf16 = __hip_bfloat16;
typedef __attribute__((ext_vector_type(8))) short s16x8;
typedef __attribute__((ext_vector_type(4))) float f32x4;

__device__ inline float bflo(unsigned u) { return __builtin_bit_cast(float, u << 16); }
__device__ inline float bfhi(unsigned u) { return __builtin_bit_cast(float, u & 0xffff0000u); }
__device__ inline unsigned f2b(float f) {
    return (unsigned)__builtin_bit_cast(unsigned short, __float2bfloat16(f));
}

__device__ inline int xcd_swz(int bid, int nwg) {
    int q = nwg >> 3, r = nwg & 7;
    int x = bid & 7, j = bid >> 3;
    return (x < r ? x * (q + 1) : r * (q + 1) + (x - r) * q) + j;
}

__device__ inline void glds16(const bf16* g, void* l) {
    __builtin_amdgcn_global_load_lds(
        (const __attribute__((address_space(1))) void*)g,
        (__attribute__((address_space(3))) void*)l, 16, 0, 0);
}

__global__ __launch_bounds__(256) void sentinel_k(float* out) { out[0] = 12345.0f; }

__global__ __launch_bounds__(256) void scatter_k(const float* __restrict__ feats,
                                                 const int* __restrict__ coords,
                                                 bf16* __restrict__ dense,
                                                 uint8_t* __restrict__ m0, int n) {
    int v = blockIdx.x * 256 + threadIdx.x;
    if (v >= n) return;
    int z = coords[v * 4 + 1], y = coords[v * 4 + 2], x = coords[v * 4 + 3];
    m0[(z * Y0 + y) * X0 + x] = 1;
    int pp = ((z + 1) * YP0 + (y + 1)) * XP0 + (x + 1);
    uint2 u;
    u.x = f2b(feats[v * 4 + 0]) | (f2b(feats[v * 4 + 1]) << 16);
    u.y = f2b(feats[v * 4 + 2]) | (f2b(feats[v * 4 + 3]) << 16);
    *(uint2*)(dense + (size_t)pp * 4) = u;
}

template <int C>
__global__ __launch_bounds__(256) void halo_zero_k(bf16* __restrict__ buf,
                                                   int Zi, int Yi, int Xi,
                                                   int Zp, int Yp, int Xp) {
    int i = blockIdx.x * 256 + threadIdx.x;
    int tot = Zp * Yp * Xp;
    if (i >= tot) return;
    int x = i % Xp; int t = i / Xp; int y = t % Yp; int z = t / Yp;
    bool halo = (z < 1) | (z > Zi) | (y < 1) | (y > Yi) | (x < 1) | (x > Xi);
    if (!halo) return;
    uint4 zz = make_uint4(0, 0, 0, 0);
    uint4* p = (uint4*)(buf + (size_t)i * C);
#pragma unroll
    for (int j = 0; j < C / 8; ++j) p[j] = zz;
}

__global__ __launch_bounds__(256) void repack_frag_k(const float* __restrict__ w,
                                                     bf16* __restrict__ wf,
                                                     int CIN, int COUT, int TRANS) {
    int NT = COUT / 16, KT = CIN / 32;
    int i = blockIdx.x * 256 + threadIdx.x;
    int total = 27 * NT * KT * 64;
    if (i >= total) return;
    int lane = i & 63; int t = i >> 6;
    int kt = t % KT; t /= KT; int nt = t % NT; int tap = t / NT;
    int co = nt * 16 + (lane & 15);
    int ci0 = kt * 32 + (lane >> 4) * 8;
    unsigned e[8];
#pragma unroll
    for (int j = 0; j < 8; ++j) {
        int ci = ci0 + j;
        int src = TRANS ? ((ci * COUT + co) * 27 + tap) : ((co * CIN + ci) * 27 + tap);
        e[j] = f2b(w[src]);
    }
    uint4 u;
    u.x = e[0] | (e[1] << 16); u.y = e[2] | (e[3] << 16);
    u.z = e[4] | (e[5] << 16); u.w = e[6] | (e[7] << 16);
    ((uint4*)wf)[i] = u;
}

// CIN=16 stride-2 frag: K = 2 taps x 16ch, 14 pairs (tap 27 zero)
__global__ __launch_bounds__(256) void repack_frag_c16_k(const float* __restrict__ w,
                                                         bf16* __restrict__ wf) {
    int i = blockIdx.x * 256 + threadIdx.x;
    int total = 14 * 2 * 64;
    if (i >= total) return;
    int lane = i & 63; int t = i >> 6;
    int nt = t & 1; int p = t >> 1;
    int lg = lane >> 4, lr = lane & 15;
    int co = nt * 16 + lr;
    unsigned e[8];
#pragma unroll
    for (int j = 0; j < 8; ++j) {
        int tap = 2 * p + (lg >> 1);
        int ci = (lg & 1) * 8 + j;
        e[j] = (tap < 27) ? f2b(w[(co * 16 + ci) * 27 + tap]) : 0u;
    }
    uint4 u;
    u.x = e[0] | (e[1] << 16); u.y = e[2] | (e[3] << 16);
    u.z = e[4] | (e[5] << 16); u.w = e[6] | (e[7] << 16);
    ((uint4*)wf)[i] = u;
}

__global__ __launch_bounds__(256) void repack_frag_l1_k(const float* __restrict__ w,
                                                        bf16* __restrict__ wf) {
    int i = blockIdx.x * 256 + threadIdx.x;
    if (i >= 256) return;
    int lane = i & 63, kb = i >> 6;
    int lg = lane >> 4, lr = lane & 15;
    unsigned e[8];
#pragma unroll
    for (int j = 0; j < 8; ++j) {
        int tap = kb * 8 + lg * 2 + (j >> 2);
        int ci = j & 3;
        e[j] = (tap < 27) ? f2b(w[(lr * 4 + ci) * 27 + tap]) : 0u;
    }
    uint4 u;
    u.x = e[0] | (e[1] << 16); u.y = e[2] | (e[3] << 16);
    u.z = e[4] | (e[5] << 16); u.w = e[6] | (e[7] << 16);
    ((uint4*)wf)[i] = u;
}

__global__ __launch_bounds__(256) void dilate_k(const uint8_t* __restrict__ in,
                                                uint8_t* __restrict__ out,
                                                int Zi, int Yi, int Xi,
                                                int Zo, int Yo, int Xo, int stride) {
    int idx = blockIdx.x * 256 + threadIdx.x;
    int total = Zo * Yo * Xo;
    if (idx >= total) return;
    int x = idx % Xo; int t = idx / Xo; int y = t % Yo; int z = t / Yo;
    int YX = Yi * Xi;
    uint8_t r = 0;
    for (int kz = 0; kz < 3; ++kz) {
        int zi = z * stride + kz - 1;
        if ((unsigned)zi >= (unsigned)Zi) continue;
        for (int ky = 0; ky < 3; ++ky) {
            int yi = y * stride + ky - 1;
            if ((unsigned)yi >= (unsigned)Yi) continue;
            for (int kx = 0; kx < 3; ++kx) {
                int xi = x * stride + kx - 1;
                if ((unsigned)xi >= (unsigned)Xi) continue;
                r |= in[zi * YX + yi * Xi + xi];
            }
        }
    }
    out[idx] = r ? 1 : 0;
}

__global__ __launch_bounds__(256) void dilate4_k(const uint8_t* __restrict__ in,
                                                 uint8_t* __restrict__ out,
                                                 int Z, int Y, int X) {
    int ngx = X >> 2;
    int g = blockIdx.x * 256 + threadIdx.x;
    int total = Z * Y * ngx;
    if (g >= total) return;
    int gx = g % ngx; int t = g / ngx; int y = t % Y; int z = t / Y;
    const int YX = Y * X;
    unsigned r = 0;
    for (int kz = 0; kz < 3; ++kz) {
        int zi = z + kz - 1;
        if ((unsigned)zi >= (unsigned)Z) continue;
        for (int ky = 0; ky < 3; ++ky) {
            int yi = y + ky - 1;
            if ((unsigned)yi >= (unsigned)Y) continue;
            const unsigned* rw = (const unsigned*)(in + zi * YX + yi * X);
            unsigned u1 = rw[gx];
            unsigned u0 = gx ? rw[gx - 1] : 0u;
            unsigned u2 = (gx + 1 < ngx) ? rw[gx + 1] : 0u;
            r |= u1 | ((u1 << 8) | (u0 >> 24)) | ((u1 >> 8) | (u2 << 24));
        }
    }
    r |= r >> 4; r |= r >> 2; r |= r >> 1; r &= 0x01010101u;
    ((unsigned*)out)[g] = r;
}

__global__ __launch_bounds__(256) void tdilate_k(const uint8_t* __restrict__ in,
                                                 uint8_t* __restrict__ out,
                                                 int Zi, int Yi, int Xi,
                                                 int Zo, int Yo, int Xo) {
    int idx = blockIdx.x * 256 + threadIdx.x;
    int total = Zo * Yo * Xo;
    if (idx >= total) return;
    int x = idx % Xo; int t = idx / Xo; int y = t % Yo; int z = t / Yo;
    int YX = Yi * Xi;
    uint8_t r = 0;
    for (int kz = 0; kz < 3; ++kz) {
        int tz = z + 1 - kz;
        if (tz & 1) continue;
        int zi = tz >> 1;
        if ((unsigned)zi >= (unsigned)Zi) continue;
        for (int ky = 0; ky < 3; ++ky) {
            int ty = y + 1 - ky;
            if (ty & 1) continue;
            int yi = ty >> 1;
            if ((unsigned)yi >= (unsigned)Yi) continue;
            for (int kx = 0; kx < 3; ++kx) {
                int tx = x + 1 - kx;
                if (tx & 1) continue;
                int xi = tx >> 1;
                if ((unsigned)xi >= (unsigned)Xi) continue;
                r |= in[zi * YX + yi * Xi + xi];
            }
        }
    }
    out[idx] = r ? 1 : 0;
}

// vectorized transposed dilation, 4 outputs/thread (Xo % 4 == 0)
__global__ __launch_bounds__(256) void tdilate4_k(const uint8_t* __restrict__ in,
                                                  uint8_t* __restrict__ out,
                                                  int Zi, int Yi, int Xi,
                                                  int Zo, int Yo, int Xo) {
    int ngx = Xo >> 2;
    int g = blockIdx.x * 256 + threadIdx.x;
    int total = Zo * Yo * ngx;
    if (g >= total) return;
    int gx = g % ngx; int t = g / ngx; int y = t % Yo; int z = t / Yo;
    int YX = Yi * Xi;
    int j0 = gx * 2;
    unsigned r0 = 0, r1 = 0, r2 = 0, r3 = 0;
    for (int kz = 0; kz < 3; ++kz) {
        int tz = z + 1 - kz;
        if (tz & 1) continue;
        int zi = tz >> 1;
        if ((unsigned)zi >= (unsigned)Zi) continue;
        for (int ky = 0; ky < 3; ++ky) {
            int ty = y + 1 - ky;
            if (ty & 1) continue;
            int yi = ty >> 1;
            if ((unsigned)yi >= (unsigned)Yi) continue;
            const uint8_t* rp = in + zi * YX + yi * Xi;
            unsigned b0 = (j0 < Xi) ? rp[j0] : 0u;
            unsigned b1 = (j0 + 1 < Xi) ? rp[j0 + 1] : 0u;
            unsigned b2 = (j0 + 2 < Xi) ? rp[j0 + 2] : 0u;
            r0 |= b0; r1 |= b0 | b1; r2 |= b1; r3 |= b1 | b2;
        }
    }
    unsigned rr = (r0 ? 1u : 0u) | (r1 ? 0x100u : 0u) | (r2 ? 0x10000u : 0u) | (r3 ? 0x1000000u : 0u);
    ((unsigned*)out)[g] = rr;
}

// ---- rolling-z pipelined LDS MFMA conv: 32->32, full 4y x 32x columns, f32 out ----
// block 256 thr = 4 waves, wave w owns y-row y0+w; loops all Zo planes with a
// 4-slab LDS ring; stage(z+3) issued before compute(z); counted vmcnt so stage
// loads drain under the compute phase, stores stay in flight.
__global__ __launch_bounds__(256, 3) void conv_roll_k(
    const bf16* __restrict__ in, const bf16* __restrict__ wfrag,
    const float* __restrict__ scale, const float* __restrict__ shift,
    const uint8_t* __restrict__ mask, float* __restrict__ outf,
    int Zo, int Yo, int Xo, int Ypi, int Xpi, int nx) {
    constexpr int ROWB = 34 * 64;     // 2176 B per halo row
    constexpr int SLABB = 6 * ROWB;   // 13056 B per z-plane slab
    constexpr int NLD = 6 * 136;      // 816 x 16B loads per slab
    __shared__ uint4 ring4[4 * SLABB / 16];
    char* ring = (char*)ring4;

    const int No = Zo * Yo * Xo;
    const int bid = xcd_swz(blockIdx.x, gridDim.x);
    const int tx = bid % nx, ty = bid / nx;
    const int y0 = ty * 4, x0 = tx * 32;

    const int tid = threadIdx.x;
    const int w = tid >> 6, lane = tid & 63, lg = lane >> 4, lr = lane & 15;

    auto stage = [&](int zp) {
        char* slab = ring + (zp & 3) * SLABB;
        const bf16* pb = in + ((size_t)zp * Ypi + y0) * Xpi * 32 + x0 * 32;
        for (int i = tid; i < NLD; i += 256) {
            int row = i / 136, u = i - row * 136;
            int usw = u ^ ((u >> 3) & 7);   // involution; read side applies same XOR
            glds16(pb + row * Xpi * 32 + usw * 8, slab + i * 16);
        }
    };

    stage(0); stage(1); stage(2);

    // swizzled read byte-offsets: frag xh in {0,1}, tap dx in {0,1,2}
    int bsw[2][3];
#pragma unroll
    for (int xh = 0; xh < 2; ++xh)
#pragma unroll
        for (int dx = 0; dx < 3; ++dx) {
            int b = (xh * 16 + lr + dx) * 64 + lg * 16;
            bsw[xh][dx] = b ^ (((b >> 7) & 7) << 4);
        }

    const float sc0 = scale[lr], sc1 = scale[16 + lr];
    const float sh0 = shift[lr], sh1 = shift[16 + lr];
    const uint4* gw = (const uint4*)wfrag;

    asm volatile("s_waitcnt vmcnt(0)" ::: "memory");
    __syncthreads();

    for (int z = 0; z < Zo; ++z) {
        if (z + 3 <= Zo + 1) stage(z + 3);

        f32x4 acc00 = (f32x4){0,0,0,0}, acc01 = (f32x4){0,0,0,0};
        f32x4 acc10 = (f32x4){0,0,0,0}, acc11 = (f32x4){0,0,0,0};

#pragma unroll 1
        for (int dz = 0; dz < 3; ++dz) {
            const char* slab = ring + ((z + dz) & 3) * SLABB;
#pragma unroll
            for (int dy = 0; dy < 3; ++dy) {
                const char* rowp = slab + (w + dy) * ROWB;
#pragma unroll
                for (int dx = 0; dx < 3; ++dx) {
                    const int tap = dz * 9 + dy * 3 + dx;
                    uint4 b0 = gw[(tap * 2 + 0) * 64 + lane];
                    uint4 b1 = gw[(tap * 2 + 1) * 64 + lane];
                    uint4 a0 = *(const uint4*)(rowp + bsw[0][dx]);
                    uint4 a1 = *(const uint4*)(rowp + bsw[1][dx]);
                    acc00 = __builtin_amdgcn_mfma_f32_16x16x32_bf16(
                        __builtin_bit_cast(s16x8, a0), __builtin_bit_cast(s16x8, b0), acc00, 0, 0, 0);
                    acc01 = __builtin_amdgcn_mfma_f32_16x16x32_bf16(
                        __builtin_bit_cast(s16x8, a0), __builtin_bit_cast(s16x8, b1), acc01, 0, 0, 0);
                    acc10 = __builtin_amdgcn_mfma_f32_16x16x32_bf16(
                        __builtin_bit_cast(s16x8, a1), __builtin_bit_cast(s16x8, b0), acc10, 0, 0, 0);
                    acc11 = __builtin_amdgcn_mfma_f32_16x16x32_bf16(
                        __builtin_bit_cast(s16x8, a1), __builtin_bit_cast(s16x8, b1), acc11, 0, 0, 0);
                }
            }
        }

        // epilogue: full tile (Xo%32==0, Yo%4==0 by construction), f32 vec stores
        {
            const size_t rowidx = ((size_t)z * Yo + (y0 + w)) * Xo;
#pragma unroll
            for (int xh = 0; xh < 2; ++xh) {
                const int xv = x0 + xh * 16 + lg * 4;
                const size_t idx0 = rowidx + xv;
                uchar4 mk = *(const uchar4*)(mask + idx0);
                float mm[4] = {mk.x ? 1.f : 0.f, mk.y ? 1.f : 0.f,
                               mk.z ? 1.f : 0.f, mk.w ? 1.f : 0.f};
                f32x4 aN0 = xh ? acc10 : acc00;
                f32x4 aN1 = xh ? acc11 : acc01;
                f32x4 o0, o1;
#pragma unroll
                for (int r = 0; r < 4; ++r) {
                    o0[r] = fmaxf(fmaf(aN0[r], sc0, sh0), 0.f) * mm[r];
                    o1[r] = fmaxf(fmaf(aN1[r], sc1, sh1), 0.f) * mm[r];
                }
                *(f32x4*)(outf + (size_t)lr * No + idx0) = o0;
                *(f32x4*)(outf + (size_t)(16 + lr) * No + idx0) = o1;
            }
        }
        // drain stage loads (oldest); leave the 4 stores in flight
        asm volatile("s_waitcnt vmcnt(4)" ::: "memory");
        __syncthreads();
    }
}

// LDS-tiled MFMA stride-1 conv, CIN=COUT=32, XOR-swizzled LDS (L2b, L4b)
template <bool FINAL>
__global__ __launch_bounds__(512, 4) void conv_lds_k(
    const bf16* __restrict__ in, const bf16* __restrict__ wfrag,
    const float* __restrict__ scale, const float* __restrict__ shift,
    const uint8_t* __restrict__ mask, bf16* __restrict__ out, float* __restrict__ outf,
    int Zo, int Yo, int Xo, int Ypi, int Xpi, int Ypo, int Xpo, int nx, int ny) {
    constexpr int ROWB = 34 * 64;
    __shared__ uint4 tile4[36 * ROWB / 16];
    char* tile = (char*)tile4;

    const int No = Zo * Yo * Xo;
    const int bid = xcd_swz(blockIdx.x, gridDim.x);
    int tx = bid % nx; int tt = bid / nx; int ty = tt % ny; int tz = tt / ny;
    const int z0 = tz * 4, y0 = ty * 4, x0 = tx * 32;

    const int tid = threadIdx.x;
    const int w = tid >> 6, lane = tid & 63, lg = lane >> 4, lr = lane & 15;

    int anywork;
    {
        int row = tid >> 5, xl = tid & 31;
        int zz = z0 + (row >> 2), yy = y0 + (row & 3), xx = x0 + xl;
        int ok = (zz < Zo) && (yy < Yo) && (xx < Xo) && mask[((size_t)zz * Yo + yy) * Xo + xx];
        anywork = __syncthreads_or(ok);
    }

    f32x4 acc[4][2];
#pragma unroll
    for (int s = 0; s < 4; ++s) { acc[s][0] = (f32x4){0,0,0,0}; acc[s][1] = (f32x4){0,0,0,0}; }

    if (anywork) {
        const int lsw = (lane ^ ((lane >> 3) & 7)) * 8;
        for (int rr = w; rr < 36; rr += 8) {
            int dz = rr / 6, dy = rr % 6;
            const bf16* g = in + ((size_t)(z0 + dz) * Ypi + (y0 + dy)) * Xpi * 32 + (size_t)x0 * 32;
            char* l = tile + rr * ROWB;
            glds16(g + lsw, l);
            glds16(g + 512 + lsw, l + 1024);
            if (lane < 8) glds16(g + 1024 + lane * 8, l + 2048);
        }
        asm volatile("s_waitcnt vmcnt(0)" ::: "memory");
        __syncthreads();

        int rbB[4], bsw[4][3];
#pragma unroll
        for (int s = 0; s < 4; ++s) {
            int lrow = 2 * w + (s >> 1);
            rbB[s] = ((lrow >> 2) * 6 + (lrow & 3)) * ROWB;
            int xpart = (s & 1) * 16 + lr;
#pragma unroll
            for (int dx = 0; dx < 3; ++dx) {
                int b = (xpart + dx) * 64 + lg * 16;
                bsw[s][dx] = b ^ (((b >> 7) & 7) << 4);
            }
        }

        const uint4* gw = (const uint4*)wfrag;
#pragma unroll 1
        for (int dz = 0; dz < 3; ++dz) {
#pragma unroll
            for (int dy = 0; dy < 3; ++dy) {
                const int rowoff = (dz * 6 + dy) * ROWB;
#pragma unroll
                for (int dx = 0; dx < 3; ++dx) {
                    const int tap = dz * 9 + dy * 3 + dx;
                    uint4 b0 = gw[(tap * 2 + 0) * 64 + lane];
                    uint4 b1 = gw[(tap * 2 + 1) * 64 + lane];
                    uint4 ua[4];
#pragma unroll
                    for (int s = 0; s < 4; ++s)
                        ua[s] = *(const uint4*)(tile + rbB[s] + rowoff + bsw[s][dx]);
#pragma unroll
                    for (int s = 0; s < 4; ++s) {
                        acc[s][0] = __builtin_amdgcn_mfma_f32_16x16x32_bf16(
                            __builtin_bit_cast(s16x8, ua[s]),
                            __builtin_bit_cast(s16x8, b0), acc[s][0], 0, 0, 0);
                        acc[s][1] = __builtin_amdgcn_mfma_f32_16x16x32_bf16(
                            __builtin_bit_cast(s16x8, ua[s]),
                            __builtin_bit_cast(s16x8, b1), acc[s][1], 0, 0, 0);
                    }
                }
            }
        }
    }

#pragma unroll
    for (int s = 0; s < 4; ++s) {
        int lrow = 2 * w + (s >> 1);
        int zz = z0 + (lrow >> 2), yy = y0 + (lrow & 3);
        int xv = x0 + (s & 1) * 16 + lg * 4;
        bool rowok = (zz < Zo) && (yy < Yo);
        if (!rowok) continue;
        size_t idx0 = ((size_t)zz * Yo + yy) * Xo + xv;
        float mm[4];
#pragma unroll
        for (int r = 0; r < 4; ++r)
            mm[r] = (xv + r < Xo && mask[idx0 + r]) ? 1.f : 0.f;
        if constexpr (FINAL) {
#pragma unroll
            for (int nt = 0; nt < 2; ++nt) {
                int co = nt * 16 + lr;
                float sc = scale[co], sh = shift[co];
                f32x4 o;
#pragma unroll
                for (int r = 0; r < 4; ++r)
                    o[r] = fmaxf(fmaf(acc[s][nt][r], sc, sh), 0.f) * mm[r];
                if (xv + 3 < Xo) {
                    *(f32x4*)(outf + (size_t)co * No + idx0) = o;
                } else {
#pragma unroll
                    for (int r = 0; r < 4; ++r)
                        if (xv + r < Xo) outf[(size_t)co * No + idx0 + r] = o[r];
                }
            }
        } else {
            int opd = ((zz + 1) * Ypo + (yy + 1)) * Xpo + (xv + 1);
#pragma unroll
            for (int nt = 0; nt < 2; ++nt) {
                int co = nt * 16 + lr;
                float sc = scale[co], sh = shift[co];
#pragma unroll
                for (int r = 0; r < 4; ++r) {
                    if (xv + r >= Xo) continue;
                    float yv = fmaxf(fmaf(acc[s][nt][r], sc, sh), 0.f) * mm[r];
                    out[(size_t)(opd + r) * 32 + co] = __float2bfloat16(yv);
                }
            }
        }
    }
}

// global-load MFMA conv, generic stride & block size
template <int CIN, int COUT, int STRIDE, int BLK, bool FINAL>
__global__ __launch_bounds__(BLK, ((CIN <= 32 && COUT <= 32) ? 4 : 2)) void conv_mfma_k(
    const bf16* __restrict__ in, const bf16* __restrict__ wfrag,
    const float* __restrict__ scale, const float* __restrict__ shift,
    const uint8_t* __restrict__ mask, bf16* __restrict__ out, float* __restrict__ outf,
    int Zo, int Yo, int Xo, int Ypi, int Xpi, int Ypo, int Xpo) {
    constexpr int NT = COUT / 16;
    constexpr int KT = CIN / 32;
    const int No = Zo * Yo * Xo;
    const int bid = xcd_swz(blockIdx.x, gridDim.x);
    const int tid = threadIdx.x;
    const int wv = tid >> 6, lane = tid & 63;
    const int lg = lane >> 4, lr = lane & 15;
    const int v0 = bid * BLK + wv * 64;
    if (v0 >= No) return;

    int vm = v0 + lane;
    bool mw = (vm < No) && (mask[vm] != 0);
    const bool anywork = (__ballot(mw) != 0ull);

    f32x4 acc[4][NT];
#pragma unroll
    for (int s = 0; s < 4; ++s)
#pragma unroll
        for (int nt = 0; nt < NT; ++nt) acc[s][nt] = (f32x4){0.f, 0.f, 0.f, 0.f};

    const uint4* gw = (const uint4*)wfrag;

    if (anywork) {
        int pA[4];
#pragma unroll
        for (int s = 0; s < 4; ++s) {
            int vr = v0 + s * 16 + lr;
            if (vr >= No) vr = 0;
            int zz = vr / (Yo * Xo); int rr = vr - zz * (Yo * Xo);
            int yy = rr / Xo; int xx = rr - yy * Xo;
            pA[s] = (((zz * STRIDE + 1) * Ypi + (yy * STRIDE + 1)) * Xpi + (xx * STRIDE + 1)) * CIN + lg * 8;
        }
#pragma unroll
        for (int tap = 0; tap < 27; ++tap) {
            const int kz = tap / 9, r9 = tap - kz * 9, ky = r9 / 3, kx = r9 - ky * 3;
            const int toff = (((kz - 1) * Ypi + (ky - 1)) * Xpi + (kx - 1)) * CIN;
            uint4 ub[NT][KT];
#pragma unroll
            for (int nt = 0; nt < NT; ++nt)
#pragma unroll
                for (int kt = 0; kt < KT; ++kt)
                    ub[nt][kt] = gw[((tap * NT + nt) * KT + kt) * 64 + lane];
            uint4 ua[4][KT];
#pragma unroll
            for (int s = 0; s < 4; ++s)
#pragma unroll
                for (int kt = 0; kt < KT; ++kt)
                    ua[s][kt] = *(const uint4*)(in + pA[s] + toff + kt * 32);
#pragma unroll
            for (int s = 0; s < 4; ++s)
#pragma unroll
                for (int kt = 0; kt < KT; ++kt)
#pragma unroll
                    for (int nt = 0; nt < NT; ++nt)
                        acc[s][nt] = __builtin_amdgcn_mfma_f32_16x16x32_bf16(
                            __builtin_bit_cast(s16x8, ua[s][kt]),
                            __builtin_bit_cast(s16x8, ub[nt][kt]), acc[s][nt], 0, 0, 0);
        }
    }

#pragma unroll
    for (int s = 0; s < 4; ++s) {
        const int vb = v0 + s * 16 + lg * 4;
        int opd[4]; float mm[4]; bool ok[4];
#pragma unroll
        for (int r = 0; r < 4; ++r) {
            int v = vb + r;
            ok[r] = v < No;
            int vc = ok[r] ? v : 0;
            mm[r] = (ok[r] && mask[vc]) ? 1.f : 0.f;
            int zz = vc / (Yo * Xo); int rr = vc - zz * (Yo * Xo);
            int yy = rr / Xo; int xx = rr - yy * Xo;
            opd[r] = FINAL ? vc : ((zz + 1) * Ypo + (yy + 1)) * Xpo + (xx + 1);
        }
#pragma unroll
        for (int nt = 0; nt < NT; ++nt) {
            int co = nt * 16 + lr;
            float sc = scale[co], sh = shift[co];
#pragma unroll
            for (int r = 0; r < 4; ++r) {
                if (!ok[r]) continue;
                float yv = fmaxf(fmaf(acc[s][nt][r], sc, sh), 0.f) * mm[r];
                if constexpr (FINAL) outf[(size_t)co * No + opd[r]] = yv;
                else out[(size_t)opd[r] * COUT + co] = __float2bfloat16(yv);
            }
        }
    }
}

// stride-2 CIN=16 MFMA conv (L2a): K = 2 taps x 16 ch, 14 pairs
__global__ __launch_bounds__(256, 4) void conv_s2c16_k(
    const bf16* __restrict__ in, const bf16* __restrict__ wfrag,
    const float* __restrict__ scale, const float* __restrict__ shift,
    const uint8_t* __restrict__ mask, bf16* __restrict__ out,
    int Zo, int Yo, int Xo, int Ypi, int Xpi, int Ypo, int Xpo) {
    const int No = Zo * Yo * Xo;
    const int bid = xcd_swz(blockIdx.x, gridDim.x);
    const int tid = threadIdx.x;
    const int wv = tid >> 6, lane = tid & 63;
    const int lg = lane >> 4, lr = lane & 15;
    const int v0 = bid * 256 + wv * 64;
    if (v0 >= No) return;

    int vm = v0 + lane;
    bool mw = (vm < No) && (mask[vm] != 0);
    const bool anywork = (__ballot(mw) != 0ull);

    f32x4 acc[4][2];
#pragma unroll
    for (int s = 0; s < 4; ++s) { acc[s][0] = (f32x4){0,0,0,0}; acc[s][1] = (f32x4){0,0,0,0}; }

    if (anywork) {
        const uint4* gw = (const uint4*)wfrag;
        const int choff = (lg & 1) * 8;
        const int tb = lg >> 1;
        int toffl[14];
#pragma unroll
        for (int p = 0; p < 14; ++p) {
            int tp = 2 * p + tb;
            if (tp >= 27) tp = 0;
            int kz = tp / 9, r9 = tp - kz * 9, ky = r9 / 3, kx = r9 - ky * 3;
            toffl[p] = ((kz * Ypi + ky) * Xpi + kx) * 16;
        }
        int pA[4];
#pragma unroll
        for (int s = 0; s < 4; ++s) {
            int vr = v0 + s * 16 + lr;
            if (vr >= No) vr = 0;
            int zz = vr / (Yo * Xo); int rr = vr - zz * (Yo * Xo);
            int yy = rr / Xo; int xx = rr - yy * Xo;
            pA[s] = (((zz * 2) * Ypi + (yy * 2)) * Xpi + (xx * 2)) * 16 + choff;
        }
#pragma unroll
        for (int p = 0; p < 14; ++p) {
            uint4 b0 = gw[(p * 2 + 0) * 64 + lane];
            uint4 b1 = gw[(p * 2 + 1) * 64 + lane];
            uint4 ua[4];
#pragma unroll
            for (int s = 0; s < 4; ++s)
                ua[s] = *(const uint4*)(in + pA[s] + toffl[p]);
#pragma unroll
            for (int s = 0; s < 4; ++s) {
                acc[s][0] = __builtin_amdgcn_mfma_f32_16x16x32_bf16(
                    __builtin_bit_cast(s16x8, ua[s]),
                    __builtin_bit_cast(s16x8, b0), acc[s][0], 0, 0, 0);
                acc[s][1] = __builtin_amdgcn_mfma_f32_16x16x32_bf16(
                    __builtin_bit_cast(s16x8, ua[s]),
                    __builtin_bit_cast(s16x8, b1), acc[s][1], 0, 0, 0);
            }
        }
    }

#pragma unroll
    for (int s = 0; s < 4; ++s) {
        const int vb = v0 + s * 16 + lg * 4;
        int opd[4]; float mm[4]; bool ok[4];
#pragma unroll
        for (int r = 0; r < 4; ++r) {
            int v = vb + r;
            ok[r] = v < No;
            int vc = ok[r] ? v : 0;
            mm[r] = (ok[r] && mask[vc]) ? 1.f : 0.f;
            int zz = vc / (Yo * Xo); int rr = vc - zz * (Yo * Xo);
            int yy = rr / Xo; int xx = rr - yy * Xo;
            opd[r] = ((zz + 1) * Ypo + (yy + 1)) * Xpo + (xx + 1);
        }
#pragma unroll
        for (int nt = 0; nt < 2; ++nt) {
            int co = nt * 16 + lr;
            float sc = scale[co], sh = shift[co];
#pragma unroll
            for (int r = 0; r < 4; ++r) {
                if (!ok[r]) continue;
                float yv = fmaxf(fmaf(acc[s][nt][r], sc, sh), 0.f) * mm[r];
                out[(size_t)opd[r] * 32 + co] = __float2bfloat16(yv);
            }
        }
    }
}

// MFMA transposed conv (stride 2) via parity octants; blockIdx.y = octant
template <int CIN, int COUT>
__global__ __launch_bounds__(256, 4) void tconv_mfma_k(
    const bf16* __restrict__ in, const bf16* __restrict__ wfrag,
    const float* __restrict__ scale, const float* __restrict__ shift,
    const uint8_t* __restrict__ mask, bf16* __restrict__ out,
    int Zo, int Yo, int Xo, int Ypi, int Xpi, int Ypo, int Xpo) {
    constexpr int NT = COUT / 16;
    constexpr int KT = CIN / 32;
    const int oct = blockIdx.y;
    const int pz = oct >> 2, py = (oct >> 1) & 1, px = oct & 1;
    const int Zq = (Zo - pz + 1) >> 1, Yq = (Yo - py + 1) >> 1, Xq = (Xo - px + 1) >> 1;
    const int Nq = Zq * Yq * Xq;
    const int YXq = Yq * Xq;
    const int bid = xcd_swz(blockIdx.x, gridDim.x);
    const int tid = threadIdx.x;
    const int wv = tid >> 6, lane = tid & 63;
    const int lg = lane >> 4, lr = lane & 15;
    const int v0 = bid * 256 + wv * 64;
    if (v0 >= Nq) return;

    bool mw = false;
    {
        int q = v0 + lane;
        if (q < Nq) {
            int zq = q / YXq; int rr = q - zq * YXq; int yq = rr / Xq; int xq = rr - yq * Xq;
            int zz = 2 * zq + pz, yy = 2 * yq + py, xx = 2 * xq + px;
            mw = mask[(zz * Yo + yy) * Xo + xx] != 0;
        }
    }
    const bool anywork = (__ballot(mw) != 0ull);

    f32x4 acc[4][NT];
#pragma unroll
    for (int s = 0; s < 4; ++s)
#pragma unroll
        for (int nt = 0; nt < NT; ++nt) acc[s][nt] = (f32x4){0.f, 0.f, 0.f, 0.f};

    const uint4* gw = (const uint4*)wfrag;

    if (anywork) {
        int pA[4];
#pragma unroll
        for (int s = 0; s < 4; ++s) {
            int q = v0 + s * 16 + lr;
            if (q >= Nq) q = 0;
            int zq = q / YXq; int rr = q - zq * YXq; int yq = rr / Xq; int xq = rr - yq * Xq;
            pA[s] = (((zq + 1) * Ypi + (yq + 1)) * Xpi + (xq + 1)) * CIN + lg * 8;
        }
        const int nkz = 1 + pz, nky = 1 + py, nkx = 1 + px;
        for (int iz = 0; iz < nkz; ++iz) {
            const int kz = pz ? (iz ? 2 : 0) : 1;
            const int dz = (pz && !iz) ? 1 : 0;
            for (int iy = 0; iy < nky; ++iy) {
                const int ky = py ? (iy ? 2 : 0) : 1;
                const int dy = (py && !iy) ? 1 : 0;
                for (int ix = 0; ix < nkx; ++ix) {
                    const int kx = px ? (ix ? 2 : 0) : 1;
                    const int dx = (px && !ix) ? 1 : 0;
                    const int tap = kz * 9 + ky * 3 + kx;
                    const int toff = ((dz * Ypi + dy) * Xpi + dx) * CIN;
                    uint4 ub[NT][KT];
#pragma unroll
                    for (int nt = 0; nt < NT; ++nt)
#pragma unroll
                        for (int kt = 0; kt < KT; ++kt)
                            ub[nt][kt] = gw[((tap * NT + nt) * KT + kt) * 64 + lane];
                    uint4 ua[4][KT];
#pragma unroll
                    for (int s = 0; s < 4; ++s)
#pragma unroll
                        for (int kt = 0; kt < KT; ++kt)
                            ua[s][kt] = *(const uint4*)(in + pA[s] + toff + kt * 32);
#pragma unroll
                    for (int s = 0; s < 4; ++s)
#pragma unroll
                        for (int kt = 0; kt < KT; ++kt)
#pragma unroll
                            for (int nt = 0; nt < NT; ++nt)
                                acc[s][nt] = __builtin_amdgcn_mfma_f32_16x16x32_bf16(
                                    __builtin_bit_cast(s16x8, ua[s][kt]),
                                    __builtin_bit_cast(s16x8, ub[nt][kt]), acc[s][nt], 0, 0, 0);
                }
            }
        }
    }

#pragma unroll
    for (int s = 0; s < 4; ++s) {
        const int vb = v0 + s * 16 + lg * 4;
        int opd[4]; float mm[4]; bool ok[4];
#pragma unroll
        for (int r = 0; r < 4; ++r) {
            int q = vb + r;
            ok[r] = q < Nq;
            int qc = ok[r] ? q : 0;
            int zq = qc / YXq; int rr = qc - zq * YXq; int yq = rr / Xq; int xq = rr - yq * Xq;
            int zz = 2 * zq + pz, yy = 2 * yq + py, xx = 2 * xq + px;
            mm[r] = (ok[r] && mask[(zz * Yo + yy) * Xo + xx]) ? 1.f : 0.f;
            opd[r] = ((zz + 1) * Ypo + (yy + 1)) * Xpo + (xx + 1);
        }
#pragma unroll
        for (int nt = 0; nt < NT; ++nt) {
            int co = nt * 16 + lr;
            float sc = scale[co], sh = shift[co];
#pragma unroll
            for (int r = 0; r < 4; ++r) {
                if (!ok[r]) continue;
                float yv = fmaxf(fmaf(acc[s][nt][r], sc, sh), 0.f) * mm[r];
                out[(size_t)opd[r] * COUT + co] = __float2bfloat16(yv);
            }
        }
    }
}

__global__ __launch_bounds__(256, 4) void conv_l1_mfma_k(
    const bf16* __restrict__ in, const bf16* __restrict__ wfrag,
    const float* __restrict__ scale, const float* __restrict__ shift,
    const uint8_t* __restrict__ mask, bf16* __restrict__ out,
    int Zo, int Yo, int Xo, int Ypi, int Xpi, int Ypo, int Xpo) {
    const int No = Zo * Yo * Xo;
    const int bid = xcd_swz(blockIdx.x, gridDim.x);
    const int tid = threadIdx.x;
    const int wv = tid >> 6, lane = tid & 63;
    const int lg = lane >> 4, lr = lane & 15;
    const int v0 = bid * 256 + wv * 64;
    if (v0 >= No) return;

    int vm = v0 + lane;
    bool mw = (vm < No) && (mask[vm] != 0);
    const bool anywork = (__ballot(mw) != 0ull);

    f32x4 acc[4];
#pragma unroll
    for (int s = 0; s < 4; ++s) acc[s] = (f32x4){0.f, 0.f, 0.f, 0.f};

    if (anywork) {
        const uint4* gw = (const uint4*)wfrag;
        uint4 bu[4];
#pragma unroll
        for (int kb = 0; kb < 4; ++kb) bu[kb] = gw[kb * 64 + lane];

        int vtf[4][2];
#pragma unroll
        for (int kb = 0; kb < 4; ++kb)
#pragma unroll
            for (int u = 0; u < 2; ++u) {
                int tp = kb * 8 + lg * 2 + u;
                int kz = tp / 9, r9 = tp - kz * 9, ky = r9 / 3, kx = r9 - ky * 3;
                vtf[kb][u] = (tp < 27) ? (((kz - 1) * Ypi + (ky - 1)) * Xpi + (kx - 1)) : 0;
            }

        int pV[4];
#pragma unroll
        for (int s = 0; s < 4; ++s) {
            int vr = v0 + s * 16 + lr;
            if (vr >= No) vr = 0;
            int zz = vr / (Yo * Xo); int rr = vr - zz * (Yo * Xo);
            int yy = rr / Xo; int xx = rr - yy * Xo;
            pV[s] = ((zz + 1) * Ypi + (yy + 1)) * Xpi + (xx + 1);
        }

#pragma unroll
        for (int kb = 0; kb < 4; ++kb) {
#pragma unroll
            for (int s = 0; s < 4; ++s) {
                uint2 a0 = *(const uint2*)(in + (size_t)(pV[s] + vtf[kb][0]) * 4);
                uint2 a1 = *(const uint2*)(in + (size_t)(pV[s] + vtf[kb][1]) * 4);
                int4 ai; ai.x = a0.x; ai.y = a0.y; ai.z = a1.x; ai.w = a1.y;
                acc[s] = __builtin_amdgcn_mfma_f32_16x16x32_bf16(
                    __builtin_bit_cast(s16x8, ai),
                    __builtin_bit_cast(s16x8, bu[kb]), acc[s], 0, 0, 0);
            }
        }
    }

#pragma unroll
    for (int s = 0; s < 4; ++s) {
        const int vb = v0 + s * 16 + lg * 4;
        int co = lr;
        float sc = scale[co], sh = shift[co];
#pragma unroll
        for (int r = 0; r < 4; ++r) {
            int v = vb + r;
            if (v >= No) continue;
            float mm = mask[v] ? 1.f : 0.f;
            int zz = v / (Yo * Xo); int rr = v - zz * (Yo * Xo);
            int yy = rr / Xo; int xx = rr - yy * Xo;
            int opd = ((zz + 1) * Ypo + (yy + 1)) * Xpo + (xx + 1);
            float yv = fmaxf(fmaf(acc[s][r], sc, sh), 0.f) * mm;
            out[(size_t)opd * 16 + co] = __float2bfloat16(yv);
        }
    }
}

inline int nblk(int n) { return (n + 255) / 256; }
inline int cdiv(int a, int b) { return (a + b - 1) / b; }

}  // namespace

extern "C" void kernel_launch(void* const* d_in, const int* in_sizes, int n_in,
                              void* d_out, int out_size, void* d_ws, size_t ws_size,
                              hipStream_t stream) {
    const float* feats = (const float*)d_in[0];
    const int* coords = (const int*)d_in[1];
    const int NVOX = in_sizes[0] / 4;

    const float *w1 = (const float*)d_in[3], *s1 = (const float*)d_in[4], *b1 = (const float*)d_in[5];
    const float *w2a = (const float*)d_in[6], *s2a = (const float*)d_in[7], *b2a = (const float*)d_in[8];
    const float *w2b = (const float*)d_in[9], *s2b = (const float*)d_in[10], *b2b = (const float*)d_in[11];
    const float *w3a = (const float*)d_in[12], *s3a = (const float*)d_in[13], *b3a = (const float*)d_in[14];
    const float *w3b = (const float*)d_in[15], *s3b = (const float*)d_in[16], *b3b = (const float*)d_in[17];
    const float *w4a = (const float*)d_in[18], *s4a = (const float*)d_in[19], *b4a = (const float*)d_in[20];
    const float *w4b = (const float*)d_in[21], *s4b = (const float*)d_in[22], *b4b = (const float*)d_in[23];
    const float *w5a = (const float*)d_in[24], *s5a = (const float*)d_in[25], *b5a = (const float*)d_in[26];
    const float *w5b = (const float*)d_in[27], *s5b = (const float*)d_in[28], *b5b = (const float*)d_in[29];

    char* ws = (char*)d_ws;
    size_t off = 0;
    auto alloc = [&](size_t bytes) -> void* {
        void* p = ws + off;
        off = (off + bytes + 255) & ~(size_t)255;
        return p;
    };

    uint8_t* m0 = (uint8_t*)alloc(NV0);
    uint8_t* m1 = (uint8_t*)alloc(NV0);
    uint8_t* m2 = (uint8_t*)alloc(NV2);
    uint8_t* m3 = (uint8_t*)alloc(NV3);
    uint8_t* m4 = (uint8_t*)alloc(NV4);
    uint8_t* m5 = (uint8_t*)alloc(NV0);

    bf16* slot0 = (bf16*)alloc((size_t)NP0 * 32 * 2);
    bf16* slot1 = (bf16*)alloc((size_t)NP0 * 16 * 2);

    bf16* dense0 = slot0;  // 4ch  @P0
    bf16* x1     = slot1;  // 16ch @P0
    bf16* x2a    = slot0;  // 32ch @P2
    bf16* x2b    = slot1;  // 32ch @P2
    bf16* x3a    = slot0;  // 64ch @P3
    bf16* x3b    = slot1;  // 64ch @P3
    bf16* x4a    = slot0;  // 32ch @P4
    bf16* x4b    = slot1;  // 32ch @(23,130,130)
    bf16* x5a    = slot0;  // 32ch @P0

    bf16* wfL1 = (bf16*)alloc(4 * 64 * 8 * 2);
    bf16* wf2a = (bf16*)alloc((size_t)14 * 2 * 64 * 16);
    bf16* wf2b = (bf16*)alloc((size_t)27 * 2 * 1 * 64 * 16);
    bf16* wf3a = (bf16*)alloc((size_t)27 * 4 * 1 * 64 * 16);
    bf16* wf3b = (bf16*)alloc((size_t)27 * 4 * 2 * 64 * 16);
    bf16* wf4a = (bf16*)alloc((size_t)27 * 2 * 2 * 64 * 16);
    bf16* wf4b = (bf16*)alloc((size_t)27 * 2 * 1 * 64 * 16);
    bf16* wf5a = (bf16*)alloc((size_t)27 * 2 * 1 * 64 * 16);
    bf16* wf5b = (bf16*)alloc((size_t)27 * 2 * 1 * 64 * 16);
    alloc(20u << 20);  // slack for OOB halo reads of partial tiles

    if (off > ws_size) {
        sentinel_k<<<1, 256, 0, stream>>>((float*)d_out);
        return;
    }

    // stage 0
    hipMemsetAsync(dense0, 0, (size_t)NP0 * 4 * 2, stream);
    hipMemsetAsync(m0, 0, NV0, stream);
    repack_frag_l1_k<<<1, 256, 0, stream>>>(w1, wfL1);
    repack_frag_c16_k<<<nblk(14 * 2 * 64), 256, 0, stream>>>(w2a, wf2a);
    repack_frag_k<<<nblk(27 * 2 * 64), 256, 0, stream>>>(w2b, wf2b, 32, 32, 0);
    repack_frag_k<<<nblk(27 * 4 * 64), 256, 0, stream>>>(w3a, wf3a, 32, 64, 0);
    repack_frag_k<<<nblk(27 * 8 * 64), 256, 0, stream>>>(w3b, wf3b, 64, 64, 0);
    repack_frag_k<<<nblk(27 * 4 * 64), 256, 0, stream>>>(w4a, wf4a, 64, 32, 1);
    repack_frag_k<<<nblk(27 * 2 * 64), 256, 0, stream>>>(w4b, wf4b, 32, 32, 0);
    repack_frag_k<<<nblk(27 * 2 * 64), 256, 0, stream>>>(w5a, wf5a, 32, 32, 1);
    repack_frag_k<<<nblk(27 * 2 * 64), 256, 0, stream>>>(w5b, wf5b, 32, 32, 0);

    scatter_k<<<nblk(NVOX), 256, 0, stream>>>(feats, coords, dense0, m0, NVOX);

    // level 1
    dilate4_k<<<nblk(NV0 / 4), 256, 0, stream>>>(m0, m1, Z0, Y0, X0);
    halo_zero_k<16><<<nblk(NP0), 256, 0, stream>>>(x1, Z0, Y0, X0, ZP0, YP0, XP0);
    conv_l1_mfma_k<<<nblk(NV0), 256, 0, stream>>>(
        dense0, wfL1, s1, b1, m1, x1, Z0, Y0, X0, YP0, XP0, YP0, XP0);

    // level 2
    dilate_k<<<nblk(NV2), 256, 0, stream>>>(m1, m2, Z0, Y0, X0, Z2, Y2, X2, 2);
    halo_zero_k<32><<<nblk(NP2), 256, 0, stream>>>(x2a, Z2, Y2, X2, ZP2, YP2, XP2);
    conv_s2c16_k<<<nblk(NV2), 256, 0, stream>>>(
        x1, wf2a, s2a, b2a, m2, x2a, Z2, Y2, X2, YP0, XP0, YP2, XP2);
    halo_zero_k<32><<<nblk(NP2), 256, 0, stream>>>(x2b, Z2, Y2, X2, ZP2, YP2, XP2);
    {
        int nx = cdiv(X2, 32), ny = cdiv(Y2, 4), nz = cdiv(Z2, 4);
        conv_lds_k<false><<<nx * ny * nz, 512, 0, stream>>>(
            x2a, wf2b, s2b, b2b, m2, x2b, nullptr, Z2, Y2, X2, YP2, XP2, YP2, XP2, nx, ny);
    }

    // level 3 (both convs MFMA, 64-thread blocks for grid spread)
    dilate_k<<<nblk(NV3), 256, 0, stream>>>(m2, m3, Z2, Y2, X2, Z3, Y3, X3, 2);
    halo_zero_k<64><<<nblk(NP3), 256, 0, stream>>>(x3a, Z3, Y3, X3, ZP3, YP3, XP3);
    conv_mfma_k<32, 64, 2, 64, false><<<cdiv(NV3, 64), 64, 0, stream>>>(
        x2b, wf3a, s3a, b3a, m3, x3a, nullptr, Z3, Y3, X3, YP2, XP2, YP3, XP3);
    halo_zero_k<64><<<nblk(NP3), 256, 0, stream>>>(x3b, Z3, Y3, X3, ZP3, YP3, XP3);
    conv_mfma_k<64, 64, 1, 64, false><<<cdiv(NV3, 64), 64, 0, stream>>>(
        x3a, wf3b, s3b, b3b, m3, x3b, nullptr, Z3, Y3, X3, YP3, XP3, YP3, XP3);

    // level 4 (tconv up via parity octants)
    tdilate_k<<<nblk(NV4), 256, 0, stream>>>(m3, m4, Z3, Y3, X3, Z4, Y4, X4);
    halo_zero_k<32><<<nblk(NP4), 256, 0, stream>>>(x4a, Z4, Y4, X4, ZP4, YP4, XP4);
    {
        int maxNq = ((Z4 + 1) >> 1) * ((Y4 + 1) >> 1) * ((X4 + 1) >> 1);
        dim3 g(nblk(maxNq), 8);
        tconv_mfma_k<64, 32><<<g, 256, 0, stream>>>(
            x3b, wf4a, s4a, b4a, m4, x4a, Z4, Y4, X4, YP3, XP3, YP4, XP4);
    }
    halo_zero_k<32><<<nblk(NP2), 256, 0, stream>>>(x4b, Z4, Y4, X4, ZP2, YP2, XP2);
    {
        int nx = cdiv(X4, 32), ny = cdiv(Y4, 4), nz = cdiv(Z4, 4);
        conv_lds_k<false><<<nx * ny * nz, 512, 0, stream>>>(
            x4a, wf4b, s4b, b4b, m4, x4b, nullptr, Z4, Y4, X4, YP4, XP4, YP2, XP2, nx, ny);
    }

    // level 5 (tconv up, outpad (0,3,3))
    tdilate4_k<<<nblk(NV0 / 4), 256, 0, stream>>>(m4, m5, Z4, Y4, X4, Z0, Y0, X0);
    halo_zero_k<32><<<nblk(NP0), 256, 0, stream>>>(x5a, Z0, Y0, X0, ZP0, YP0, XP0);
    {
        int maxNq = ((Z0 + 1) >> 1) * (Y0 >> 1) * (X0 >> 1);
        dim3 g(nblk(maxNq), 8);
        tconv_mfma_k<32, 32><<<g, 256, 0, stream>>>(
            x4b, wf5a, s5a, b5a, m5, x5a, Z0, Y0, X0, YP2, XP2, YP0, XP0);
    }
    {
        int nx = X0 / 32, ny = Y0 / 4;  // full tiles by construction
        conv_roll_k<<<nx * ny, 256, 0, stream>>>(
            x5a, wf5b, s5b, b5b, m5, (float*)d_out, Z0, Y0, X0, YP0, XP0, nx);
    }
}

// Round 7
// 974.315 us; speedup vs baseline: 1.0248x; 1.0248x over previous
//
#include <hip/hip_runtime.h>
#include <hip/hip_bf16.h>
#include <stdint.h>

namespace {

constexpr int Z0 = 41, Y0 = 256, X0 = 256;
constexpr int Z2 = 21, Y2 = 128, X2 = 128;
constexpr int Z3 = 11, Y3 = 64,  X3 = 64;
constexpr int Z4 = 21, Y4 = 127, X4 = 127;
constexpr int NV0 = Z0 * Y0 * X0;
constexpr int NV2 = Z2 * Y2 * X2;
constexpr int NV3 = Z3 * Y3 * X3;
constexpr int NV4 = Z4 * Y4 * X4;

constexpr int ZP0 = 43, YP0 = 258, XP0 = 258; constexpr int NP0 = ZP0 * YP0 * XP0;
constexpr int ZP2 = 23, YP2 = 130, XP2 = 130; constexpr int NP2 = ZP2 * YP2 * XP2;
constexpr int ZP3 = 13, YP3 = 66,  XP3 = 66;  constexpr int NP3 = ZP3 * YP3 * XP3;
constexpr int ZP4 = 23, YP4 = 129, XP4 = 129; constexpr int NP4 = ZP4 * YP4 * XP4;

using bf16 = __hip_bfloat16;
typedef __attribute__((ext_vector_type(8))) short s16x8;
typedef __attribute__((ext_vector_type(4))) float f32x4;

__device__ inline unsigned f2b(float f) {
    return (unsigned)__builtin_bit_cast(unsigned short, __float2bfloat16(f));
}

__device__ inline int xcd_swz(int bid, int nwg) {
    int q = nwg >> 3, r = nwg & 7;
    int x = bid & 7, j = bid >> 3;
    return (x < r ? x * (q + 1) : r * (q + 1) + (x - r) * q) + j;
}

__device__ inline void glds16(const bf16* g, void* l) {
    __builtin_amdgcn_global_load_lds(
        (const __attribute__((address_space(1))) void*)g,
        (__attribute__((address_space(3))) void*)l, 16, 0, 0);
}

__global__ __launch_bounds__(256) void sentinel_k(float* out) { out[0] = 12345.0f; }

__global__ __launch_bounds__(256) void scatter_k(const float* __restrict__ feats,
                                                 const int* __restrict__ coords,
                                                 bf16* __restrict__ dense,
                                                 uint8_t* __restrict__ m0, int n) {
    int v = blockIdx.x * 256 + threadIdx.x;
    if (v >= n) return;
    int z = coords[v * 4 + 1], y = coords[v * 4 + 2], x = coords[v * 4 + 3];
    m0[(z * Y0 + y) * X0 + x] = 1;
    int pp = ((z + 1) * YP0 + (y + 1)) * XP0 + (x + 1);
    uint2 u;
    u.x = f2b(feats[v * 4 + 0]) | (f2b(feats[v * 4 + 1]) << 16);
    u.y = f2b(feats[v * 4 + 2]) | (f2b(feats[v * 4 + 3]) << 16);
    *(uint2*)(dense + (size_t)pp * 4) = u;
}

template <int C>
__global__ __launch_bounds__(256) void halo_zero_k(bf16* __restrict__ buf,
                                                   int Zi, int Yi, int Xi,
                                                   int Zp, int Yp, int Xp) {
    int i = blockIdx.x * 256 + threadIdx.x;
    int tot = Zp * Yp * Xp;
    if (i >= tot) return;
    int x = i % Xp; int t = i / Xp; int y = t % Yp; int z = t / Yp;
    bool halo = (z < 1) | (z > Zi) | (y < 1) | (y > Yi) | (x < 1) | (x > Xi);
    if (!halo) return;
    uint4 zz = make_uint4(0, 0, 0, 0);
    uint4* p = (uint4*)(buf + (size_t)i * C);
#pragma unroll
    for (int j = 0; j < C / 8; ++j) p[j] = zz;
}

__global__ __launch_bounds__(256) void repack_frag_k(const float* __restrict__ w,
                                                     bf16* __restrict__ wf,
                                                     int CIN, int COUT, int TRANS) {
    int NT = COUT / 16, KT = CIN / 32;
    int i = blockIdx.x * 256 + threadIdx.x;
    int total = 27 * NT * KT * 64;
    if (i >= total) return;
    int lane = i & 63; int t = i >> 6;
    int kt = t % KT; t /= KT; int nt = t % NT; int tap = t / NT;
    int co = nt * 16 + (lane & 15);
    int ci0 = kt * 32 + (lane >> 4) * 8;
    unsigned e[8];
#pragma unroll
    for (int j = 0; j < 8; ++j) {
        int ci = ci0 + j;
        int src = TRANS ? ((ci * COUT + co) * 27 + tap) : ((co * CIN + ci) * 27 + tap);
        e[j] = f2b(w[src]);
    }
    uint4 u;
    u.x = e[0] | (e[1] << 16); u.y = e[2] | (e[3] << 16);
    u.z = e[4] | (e[5] << 16); u.w = e[6] | (e[7] << 16);
    ((uint4*)wf)[i] = u;
}

// CIN=16 stride-2 frag: K = 2 taps x 16ch, 14 pairs (tap 27 zero)
__global__ __launch_bounds__(256) void repack_frag_c16_k(const float* __restrict__ w,
                                                         bf16* __restrict__ wf) {
    int i = blockIdx.x * 256 + threadIdx.x;
    int total = 14 * 2 * 64;
    if (i >= total) return;
    int lane = i & 63; int t = i >> 6;
    int nt = t & 1; int p = t >> 1;
    int lg = lane >> 4, lr = lane & 15;
    int co = nt * 16 + lr;
    unsigned e[8];
#pragma unroll
    for (int j = 0; j < 8; ++j) {
        int tap = 2 * p + (lg >> 1);
        int ci = (lg & 1) * 8 + j;
        e[j] = (tap < 27) ? f2b(w[(co * 16 + ci) * 27 + tap]) : 0u;
    }
    uint4 u;
    u.x = e[0] | (e[1] << 16); u.y = e[2] | (e[3] << 16);
    u.z = e[4] | (e[5] << 16); u.w = e[6] | (e[7] << 16);
    ((uint4*)wf)[i] = u;
}

__global__ __launch_bounds__(256) void repack_frag_l1_k(const float* __restrict__ w,
                                                        bf16* __restrict__ wf) {
    int i = blockIdx.x * 256 + threadIdx.x;
    if (i >= 256) return;
    int lane = i & 63, kb = i >> 6;
    int lg = lane >> 4, lr = lane & 15;
    unsigned e[8];
#pragma unroll
    for (int j = 0; j < 8; ++j) {
        int tap = kb * 8 + lg * 2 + (j >> 2);
        int ci = j & 3;
        e[j] = (tap < 27) ? f2b(w[(lr * 4 + ci) * 27 + tap]) : 0u;
    }
    uint4 u;
    u.x = e[0] | (e[1] << 16); u.y = e[2] | (e[3] << 16);
    u.z = e[4] | (e[5] << 16); u.w = e[6] | (e[7] << 16);
    ((uint4*)wf)[i] = u;
}

__global__ __launch_bounds__(256) void dilate_k(const uint8_t* __restrict__ in,
                                                uint8_t* __restrict__ out,
                                                int Zi, int Yi, int Xi,
                                                int Zo, int Yo, int Xo, int stride) {
    int idx = blockIdx.x * 256 + threadIdx.x;
    int total = Zo * Yo * Xo;
    if (idx >= total) return;
    int x = idx % Xo; int t = idx / Xo; int y = t % Yo; int z = t / Yo;
    int YX = Yi * Xi;
    uint8_t r = 0;
    for (int kz = 0; kz < 3; ++kz) {
        int zi = z * stride + kz - 1;
        if ((unsigned)zi >= (unsigned)Zi) continue;
        for (int ky = 0; ky < 3; ++ky) {
            int yi = y * stride + ky - 1;
            if ((unsigned)yi >= (unsigned)Yi) continue;
            for (int kx = 0; kx < 3; ++kx) {
                int xi = x * stride + kx - 1;
                if ((unsigned)xi >= (unsigned)Xi) continue;
                r |= in[zi * YX + yi * Xi + xi];
            }
        }
    }
    out[idx] = r ? 1 : 0;
}

__global__ __launch_bounds__(256) void dilate4_k(const uint8_t* __restrict__ in,
                                                 uint8_t* __restrict__ out,
                                                 int Z, int Y, int X) {
    int ngx = X >> 2;
    int g = blockIdx.x * 256 + threadIdx.x;
    int total = Z * Y * ngx;
    if (g >= total) return;
    int gx = g % ngx; int t = g / ngx; int y = t % Y; int z = t / Y;
    const int YX = Y * X;
    unsigned r = 0;
    for (int kz = 0; kz < 3; ++kz) {
        int zi = z + kz - 1;
        if ((unsigned)zi >= (unsigned)Z) continue;
        for (int ky = 0; ky < 3; ++ky) {
            int yi = y + ky - 1;
            if ((unsigned)yi >= (unsigned)Y) continue;
            const unsigned* rw = (const unsigned*)(in + zi * YX + yi * X);
            unsigned u1 = rw[gx];
            unsigned u0 = gx ? rw[gx - 1] : 0u;
            unsigned u2 = (gx + 1 < ngx) ? rw[gx + 1] : 0u;
            r |= u1 | ((u1 << 8) | (u0 >> 24)) | ((u1 >> 8) | (u2 << 24));
        }
    }
    r |= r >> 4; r |= r >> 2; r |= r >> 1; r &= 0x01010101u;
    ((unsigned*)out)[g] = r;
}

__global__ __launch_bounds__(256) void tdilate_k(const uint8_t* __restrict__ in,
                                                 uint8_t* __restrict__ out,
                                                 int Zi, int Yi, int Xi,
                                                 int Zo, int Yo, int Xo) {
    int idx = blockIdx.x * 256 + threadIdx.x;
    int total = Zo * Yo * Xo;
    if (idx >= total) return;
    int x = idx % Xo; int t = idx / Xo; int y = t % Yo; int z = t / Yo;
    int YX = Yi * Xi;
    uint8_t r = 0;
    for (int kz = 0; kz < 3; ++kz) {
        int tz = z + 1 - kz;
        if (tz & 1) continue;
        int zi = tz >> 1;
        if ((unsigned)zi >= (unsigned)Zi) continue;
        for (int ky = 0; ky < 3; ++ky) {
            int ty = y + 1 - ky;
            if (ty & 1) continue;
            int yi = ty >> 1;
            if ((unsigned)yi >= (unsigned)Yi) continue;
            for (int kx = 0; kx < 3; ++kx) {
                int tx = x + 1 - kx;
                if (tx & 1) continue;
                int xi = tx >> 1;
                if ((unsigned)xi >= (unsigned)Xi) continue;
                r |= in[zi * YX + yi * Xi + xi];
            }
        }
    }
    out[idx] = r ? 1 : 0;
}

__global__ __launch_bounds__(256) void tdilate4_k(const uint8_t* __restrict__ in,
                                                  uint8_t* __restrict__ out,
                                                  int Zi, int Yi, int Xi,
                                                  int Zo, int Yo, int Xo) {
    int ngx = Xo >> 2;
    int g = blockIdx.x * 256 + threadIdx.x;
    int total = Zo * Yo * ngx;
    if (g >= total) return;
    int gx = g % ngx; int t = g / ngx; int y = t % Yo; int z = t / Yo;
    int YX = Yi * Xi;
    int j0 = gx * 2;
    unsigned r0 = 0, r1 = 0, r2 = 0, r3 = 0;
    for (int kz = 0; kz < 3; ++kz) {
        int tz = z + 1 - kz;
        if (tz & 1) continue;
        int zi = tz >> 1;
        if ((unsigned)zi >= (unsigned)Zi) continue;
        for (int ky = 0; ky < 3; ++ky) {
            int ty = y + 1 - ky;
            if (ty & 1) continue;
            int yi = ty >> 1;
            if ((unsigned)yi >= (unsigned)Yi) continue;
            const uint8_t* rp = in + zi * YX + yi * Xi;
            unsigned b0 = (j0 < Xi) ? rp[j0] : 0u;
            unsigned b1 = (j0 + 1 < Xi) ? rp[j0 + 1] : 0u;
            unsigned b2 = (j0 + 2 < Xi) ? rp[j0 + 2] : 0u;
            r0 |= b0; r1 |= b0 | b1; r2 |= b1; r3 |= b1 | b2;
        }
    }
    unsigned rr = (r0 ? 1u : 0u) | (r1 ? 0x100u : 0u) | (r2 ? 0x10000u : 0u) | (r3 ? 0x1000000u : 0u);
    ((unsigned*)out)[g] = rr;
}

// ---- rolling-z pipelined conv 32->32, B in VGPRs, raw barrier + counted vmcnt ----
// block 256 = 4 waves: wave = (y-row yr = w>>1, cout-half ch = w&1); tile 2y x 32x.
// 4-slab LDS ring (4 halo rows each); stage(z+3) at iter top; only stores left
// in flight across the barrier (vmcnt(2)). No global loads during compute.
__global__ __launch_bounds__(256, 3) void conv_roll_k(
    const bf16* __restrict__ in, const bf16* __restrict__ wfrag,
    const float* __restrict__ scale, const float* __restrict__ shift,
    const uint8_t* __restrict__ mask, float* __restrict__ outf,
    int Zo, int Yo, int Xo, int Ypi, int Xpi, int nx) {
    constexpr int ROWB = 34 * 64;      // 2176 B per halo row
    constexpr int SLABB = 4 * ROWB;    // 8704 B per z-plane slab (4 rows)
    __shared__ uint4 ring4[4 * SLABB / 16];
    char* ring = (char*)ring4;

    const int No = Zo * Yo * Xo;
    const int bid = xcd_swz(blockIdx.x, gridDim.x);
    const int tx = bid % nx, ty = bid / nx;
    const int y0 = ty * 2, x0 = tx * 32;

    const int tid = threadIdx.x;
    const int w = tid >> 6, lane = tid & 63;
    const int lg = lane >> 4, lr = lane & 15;
    const int yr = w >> 1, ch = w & 1;

    // stage padded plane zp: wave w stages halo row w (136 x 16B chunks)
    auto stage = [&](int zp) {
        int zs = zp <= Zo + 1 ? zp : Zo + 1;  // clamp; keeps instr count uniform
        char* slab = ring + (zp & 3) * SLABB + w * ROWB;
        const bf16* pb = in + ((size_t)zs * Ypi + (y0 + w)) * (size_t)Xpi * 32 + (size_t)x0 * 32;
#pragma unroll
        for (int k = 0; k < 3; ++k) {
            int u = k * 64 + lane;
            if (k < 2 || lane < 8) {
                int usw = u ^ ((u >> 3) & 7);
                glds16(pb + usw * 8, slab + u * 16);
            }
        }
    };

    // B fragments for this wave's cout-half: 27 taps x 16B = 108 VGPRs
    const uint4* gw = (const uint4*)wfrag;
    uint4 breg[27];
#pragma unroll
    for (int t = 0; t < 27; ++t) breg[t] = gw[(t * 2 + ch) * 64 + lane];

    stage(0); stage(1); stage(2);

    // swizzled A read offsets: frag xh in {0,1}, tap dx in {0,1,2}
    int asw[2][3];
#pragma unroll
    for (int xh = 0; xh < 2; ++xh)
#pragma unroll
        for (int dx = 0; dx < 3; ++dx) {
            int b = (xh * 16 + lr + dx) * 64 + lg * 16;
            asw[xh][dx] = b ^ (((b >> 7) & 7) << 4);
        }

    const int co = ch * 16 + lr;
    const float sc = scale[co], sh = shift[co];

    asm volatile("s_waitcnt vmcnt(0)" ::: "memory");
    __builtin_amdgcn_s_barrier();

    for (int z = 0; z < Zo; ++z) {
        stage(z + 3);  // 3 glds, drained at end of this iter (covered by compute)

        f32x4 acc0 = (f32x4){0, 0, 0, 0}, acc1 = (f32x4){0, 0, 0, 0};
#pragma unroll
        for (int dz = 0; dz < 3; ++dz) {
            const char* slab = ring + ((z + dz) & 3) * SLABB;
#pragma unroll
            for (int dy = 0; dy < 3; ++dy) {
                const char* rowp = slab + (yr + dy) * ROWB;
#pragma unroll
                for (int dx = 0; dx < 3; ++dx) {
                    const int tap = dz * 9 + dy * 3 + dx;
                    uint4 a0 = *(const uint4*)(rowp + asw[0][dx]);
                    uint4 a1 = *(const uint4*)(rowp + asw[1][dx]);
                    acc0 = __builtin_amdgcn_mfma_f32_16x16x32_bf16(
                        __builtin_bit_cast(s16x8, a0), __builtin_bit_cast(s16x8, breg[tap]),
                        acc0, 0, 0, 0);
                    acc1 = __builtin_amdgcn_mfma_f32_16x16x32_bf16(
                        __builtin_bit_cast(s16x8, a1), __builtin_bit_cast(s16x8, breg[tap]),
                        acc1, 0, 0, 0);
                }
            }
        }

        // epilogue: C row = lg*4+r (voxel), col = lr (cout within half)
        const size_t rowbase = ((size_t)z * Yo + (y0 + yr)) * Xo + x0;
#pragma unroll
        for (int xh = 0; xh < 2; ++xh) {
            const size_t idx0 = rowbase + xh * 16 + lg * 4;
            uchar4 mk = *(const uchar4*)(mask + idx0);
            float mm[4] = {mk.x ? 1.f : 0.f, mk.y ? 1.f : 0.f,
                           mk.z ? 1.f : 0.f, mk.w ? 1.f : 0.f};
            f32x4 a = xh ? acc1 : acc0;
            f32x4 o;
#pragma unroll
            for (int r = 0; r < 4; ++r)
                o[r] = fmaxf(fmaf(a[r], sc, sh), 0.f) * mm[r];
            *(f32x4*)(outf + (size_t)co * No + idx0) = o;
        }

        // drain stage+mask (in-order), leave the 2 stores in flight; raw barrier
        asm volatile("s_waitcnt vmcnt(2)" ::: "memory");
        __builtin_amdgcn_s_barrier();
    }
}

// LDS-tiled MFMA stride-1 conv, CIN=COUT=32 (L2b, L4b)
template <bool FINAL>
__global__ __launch_bounds__(512, 4) void conv_lds_k(
    const bf16* __restrict__ in, const bf16* __restrict__ wfrag,
    const float* __restrict__ scale, const float* __restrict__ shift,
    const uint8_t* __restrict__ mask, bf16* __restrict__ out, float* __restrict__ outf,
    int Zo, int Yo, int Xo, int Ypi, int Xpi, int Ypo, int Xpo, int nx, int ny) {
    constexpr int ROWB = 34 * 64;
    __shared__ uint4 tile4[36 * ROWB / 16];
    char* tile = (char*)tile4;

    const int No = Zo * Yo * Xo;
    const int bid = xcd_swz(blockIdx.x, gridDim.x);
    int tx = bid % nx; int tt = bid / nx; int ty = tt % ny; int tz = tt / ny;
    const int z0 = tz * 4, y0 = ty * 4, x0 = tx * 32;

    const int tid = threadIdx.x;
    const int w = tid >> 6, lane = tid & 63, lg = lane >> 4, lr = lane & 15;

    int anywork;
    {
        int row = tid >> 5, xl = tid & 31;
        int zz = z0 + (row >> 2), yy = y0 + (row & 3), xx = x0 + xl;
        int ok = (zz < Zo) && (yy < Yo) && (xx < Xo) && mask[((size_t)zz * Yo + yy) * Xo + xx];
        anywork = __syncthreads_or(ok);
    }

    f32x4 acc[4][2];
#pragma unroll
    for (int s = 0; s < 4; ++s) { acc[s][0] = (f32x4){0,0,0,0}; acc[s][1] = (f32x4){0,0,0,0}; }

    if (anywork) {
        const int lsw = (lane ^ ((lane >> 3) & 7)) * 8;
        for (int rr = w; rr < 36; rr += 8) {
            int dz = rr / 6, dy = rr % 6;
            const bf16* g = in + ((size_t)(z0 + dz) * Ypi + (y0 + dy)) * Xpi * 32 + (size_t)x0 * 32;
            char* l = tile + rr * ROWB;
            glds16(g + lsw, l);
            glds16(g + 512 + lsw, l + 1024);
            if (lane < 8) glds16(g + 1024 + lane * 8, l + 2048);
        }
        asm volatile("s_waitcnt vmcnt(0)" ::: "memory");
        __syncthreads();

        int rbB[4], bsw[4][3];
#pragma unroll
        for (int s = 0; s < 4; ++s) {
            int lrow = 2 * w + (s >> 1);
            rbB[s] = ((lrow >> 2) * 6 + (lrow & 3)) * ROWB;
            int xpart = (s & 1) * 16 + lr;
#pragma unroll
            for (int dx = 0; dx < 3; ++dx) {
                int b = (xpart + dx) * 64 + lg * 16;
                bsw[s][dx] = b ^ (((b >> 7) & 7) << 4);
            }
        }

        const uint4* gw = (const uint4*)wfrag;
#pragma unroll 1
        for (int dz = 0; dz < 3; ++dz) {
#pragma unroll
            for (int dy = 0; dy < 3; ++dy) {
                const int rowoff = (dz * 6 + dy) * ROWB;
#pragma unroll
                for (int dx = 0; dx < 3; ++dx) {
                    const int tap = dz * 9 + dy * 3 + dx;
                    uint4 b0 = gw[(tap * 2 + 0) * 64 + lane];
                    uint4 b1 = gw[(tap * 2 + 1) * 64 + lane];
                    uint4 ua[4];
#pragma unroll
                    for (int s = 0; s < 4; ++s)
                        ua[s] = *(const uint4*)(tile + rbB[s] + rowoff + bsw[s][dx]);
#pragma unroll
                    for (int s = 0; s < 4; ++s) {
                        acc[s][0] = __builtin_amdgcn_mfma_f32_16x16x32_bf16(
                            __builtin_bit_cast(s16x8, ua[s]),
                            __builtin_bit_cast(s16x8, b0), acc[s][0], 0, 0, 0);
                        acc[s][1] = __builtin_amdgcn_mfma_f32_16x16x32_bf16(
                            __builtin_bit_cast(s16x8, ua[s]),
                            __builtin_bit_cast(s16x8, b1), acc[s][1], 0, 0, 0);
                    }
                }
            }
        }
    }

#pragma unroll
    for (int s = 0; s < 4; ++s) {
        int lrow = 2 * w + (s >> 1);
        int zz = z0 + (lrow >> 2), yy = y0 + (lrow & 3);
        int xv = x0 + (s & 1) * 16 + lg * 4;
        bool rowok = (zz < Zo) && (yy < Yo);
        if (!rowok) continue;
        size_t idx0 = ((size_t)zz * Yo + yy) * Xo + xv;
        float mm[4];
#pragma unroll
        for (int r = 0; r < 4; ++r)
            mm[r] = (xv + r < Xo && mask[idx0 + r]) ? 1.f : 0.f;
        if constexpr (FINAL) {
#pragma unroll
            for (int nt = 0; nt < 2; ++nt) {
                int co = nt * 16 + lr;
                float sc = scale[co], sh = shift[co];
                f32x4 o;
#pragma unroll
                for (int r = 0; r < 4; ++r)
                    o[r] = fmaxf(fmaf(acc[s][nt][r], sc, sh), 0.f) * mm[r];
                if (xv + 3 < Xo) {
                    *(f32x4*)(outf + (size_t)co * No + idx0) = o;
                } else {
#pragma unroll
                    for (int r = 0; r < 4; ++r)
                        if (xv + r < Xo) outf[(size_t)co * No + idx0 + r] = o[r];
                }
            }
        } else {
            int opd = ((zz + 1) * Ypo + (yy + 1)) * Xpo + (xv + 1);
#pragma unroll
            for (int nt = 0; nt < 2; ++nt) {
                int co = nt * 16 + lr;
                float sc = scale[co], sh = shift[co];
#pragma unroll
                for (int r = 0; r < 4; ++r) {
                    if (xv + r >= Xo) continue;
                    float yv = fmaxf(fmaf(acc[s][nt][r], sc, sh), 0.f) * mm[r];
                    out[(size_t)(opd + r) * 32 + co] = __float2bfloat16(yv);
                }
            }
        }
    }
}

// global-load MFMA conv, generic stride & block size
template <int CIN, int COUT, int STRIDE, int BLK, bool FINAL>
__global__ __launch_bounds__(BLK, ((CIN <= 32 && COUT <= 32) ? 4 : 2)) void conv_mfma_k(
    const bf16* __restrict__ in, const bf16* __restrict__ wfrag,
    const float* __restrict__ scale, const float* __restrict__ shift,
    const uint8_t* __restrict__ mask, bf16* __restrict__ out, float* __restrict__ outf,
    int Zo, int Yo, int Xo, int Ypi, int Xpi, int Ypo, int Xpo) {
    constexpr int NT = COUT / 16;
    constexpr int KT = CIN / 32;
    const int No = Zo * Yo * Xo;
    const int bid = xcd_swz(blockIdx.x, gridDim.x);
    const int tid = threadIdx.x;
    const int wv = tid >> 6, lane = tid & 63;
    const int lg = lane >> 4, lr = lane & 15;
    const int v0 = bid * BLK + wv * 64;
    if (v0 >= No) return;

    int vm = v0 + lane;
    bool mw = (vm < No) && (mask[vm] != 0);
    const bool anywork = (__ballot(mw) != 0ull);

    f32x4 acc[4][NT];
#pragma unroll
    for (int s = 0; s < 4; ++s)
#pragma unroll
        for (int nt = 0; nt < NT; ++nt) acc[s][nt] = (f32x4){0.f, 0.f, 0.f, 0.f};

    const uint4* gw = (const uint4*)wfrag;

    if (anywork) {
        int pA[4];
#pragma unroll
        for (int s = 0; s < 4; ++s) {
            int vr = v0 + s * 16 + lr;
            if (vr >= No) vr = 0;
            int zz = vr / (Yo * Xo); int rr = vr - zz * (Yo * Xo);
            int yy = rr / Xo; int xx = rr - yy * Xo;
            pA[s] = (((zz * STRIDE + 1) * Ypi + (yy * STRIDE + 1)) * Xpi + (xx * STRIDE + 1)) * CIN + lg * 8;
        }
#pragma unroll
        for (int tap = 0; tap < 27; ++tap) {
            const int kz = tap / 9, r9 = tap - kz * 9, ky = r9 / 3, kx = r9 - ky * 3;
            const int toff = (((kz - 1) * Ypi + (ky - 1)) * Xpi + (kx - 1)) * CIN;
            uint4 ub[NT][KT];
#pragma unroll
            for (int nt = 0; nt < NT; ++nt)
#pragma unroll
                for (int kt = 0; kt < KT; ++kt)
                    ub[nt][kt] = gw[((tap * NT + nt) * KT + kt) * 64 + lane];
            uint4 ua[4][KT];
#pragma unroll
            for (int s = 0; s < 4; ++s)
#pragma unroll
                for (int kt = 0; kt < KT; ++kt)
                    ua[s][kt] = *(const uint4*)(in + pA[s] + toff + kt * 32);
#pragma unroll
            for (int s = 0; s < 4; ++s)
#pragma unroll
                for (int kt = 0; kt < KT; ++kt)
#pragma unroll
                    for (int nt = 0; nt < NT; ++nt)
                        acc[s][nt] = __builtin_amdgcn_mfma_f32_16x16x32_bf16(
                            __builtin_bit_cast(s16x8, ua[s][kt]),
                            __builtin_bit_cast(s16x8, ub[nt][kt]), acc[s][nt], 0, 0, 0);
        }
    }

#pragma unroll
    for (int s = 0; s < 4; ++s) {
        const int vb = v0 + s * 16 + lg * 4;
        int opd[4]; float mm[4]; bool ok[4];
#pragma unroll
        for (int r = 0; r < 4; ++r) {
            int v = vb + r;
            ok[r] = v < No;
            int vc = ok[r] ? v : 0;
            mm[r] = (ok[r] && mask[vc]) ? 1.f : 0.f;
            int zz = vc / (Yo * Xo); int rr = vc - zz * (Yo * Xo);
            int yy = rr / Xo; int xx = rr - yy * Xo;
            opd[r] = FINAL ? vc : ((zz + 1) * Ypo + (yy + 1)) * Xpo + (xx + 1);
        }
#pragma unroll
        for (int nt = 0; nt < NT; ++nt) {
            int co = nt * 16 + lr;
            float sc = scale[co], sh = shift[co];
#pragma unroll
            for (int r = 0; r < 4; ++r) {
                if (!ok[r]) continue;
                float yv = fmaxf(fmaf(acc[s][nt][r], sc, sh), 0.f) * mm[r];
                if constexpr (FINAL) outf[(size_t)co * No + opd[r]] = yv;
                else out[(size_t)opd[r] * COUT + co] = __float2bfloat16(yv);
            }
        }
    }
}

// stride-2 CIN=16 MFMA conv (L2a)
__global__ __launch_bounds__(256, 4) void conv_s2c16_k(
    const bf16* __restrict__ in, const bf16* __restrict__ wfrag,
    const float* __restrict__ scale, const float* __restrict__ shift,
    const uint8_t* __restrict__ mask, bf16* __restrict__ out,
    int Zo, int Yo, int Xo, int Ypi, int Xpi, int Ypo, int Xpo) {
    const int No = Zo * Yo * Xo;
    const int bid = xcd_swz(blockIdx.x, gridDim.x);
    const int tid = threadIdx.x;
    const int wv = tid >> 6, lane = tid & 63;
    const int lg = lane >> 4, lr = lane & 15;
    const int v0 = bid * 256 + wv * 64;
    if (v0 >= No) return;

    int vm = v0 + lane;
    bool mw = (vm < No) && (mask[vm] != 0);
    const bool anywork = (__ballot(mw) != 0ull);

    f32x4 acc[4][2];
#pragma unroll
    for (int s = 0; s < 4; ++s) { acc[s][0] = (f32x4){0,0,0,0}; acc[s][1] = (f32x4){0,0,0,0}; }

    if (anywork) {
        const uint4* gw = (const uint4*)wfrag;
        const int choff = (lg & 1) * 8;
        const int tb = lg >> 1;
        int toffl[14];
#pragma unroll
        for (int p = 0; p < 14; ++p) {
            int tp = 2 * p + tb;
            if (tp >= 27) tp = 0;
            int kz = tp / 9, r9 = tp - kz * 9, ky = r9 / 3, kx = r9 - ky * 3;
            toffl[p] = ((kz * Ypi + ky) * Xpi + kx) * 16;
        }
        int pA[4];
#pragma unroll
        for (int s = 0; s < 4; ++s) {
            int vr = v0 + s * 16 + lr;
            if (vr >= No) vr = 0;
            int zz = vr / (Yo * Xo); int rr = vr - zz * (Yo * Xo);
            int yy = rr / Xo; int xx = rr - yy * Xo;
            pA[s] = (((zz * 2) * Ypi + (yy * 2)) * Xpi + (xx * 2)) * 16 + choff;
        }
#pragma unroll
        for (int p = 0; p < 14; ++p) {
            uint4 b0 = gw[(p * 2 + 0) * 64 + lane];
            uint4 b1 = gw[(p * 2 + 1) * 64 + lane];
            uint4 ua[4];
#pragma unroll
            for (int s = 0; s < 4; ++s)
                ua[s] = *(const uint4*)(in + pA[s] + toffl[p]);
#pragma unroll
            for (int s = 0; s < 4; ++s) {
                acc[s][0] = __builtin_amdgcn_mfma_f32_16x16x32_bf16(
                    __builtin_bit_cast(s16x8, ua[s]),
                    __builtin_bit_cast(s16x8, b0), acc[s][0], 0, 0, 0);
                acc[s][1] = __builtin_amdgcn_mfma_f32_16x16x32_bf16(
                    __builtin_bit_cast(s16x8, ua[s]),
                    __builtin_bit_cast(s16x8, b1), acc[s][1], 0, 0, 0);
            }
        }
    }

#pragma unroll
    for (int s = 0; s < 4; ++s) {
        const int vb = v0 + s * 16 + lg * 4;
        int opd[4]; float mm[4]; bool ok[4];
#pragma unroll
        for (int r = 0; r < 4; ++r) {
            int v = vb + r;
            ok[r] = v < No;
            int vc = ok[r] ? v : 0;
            mm[r] = (ok[r] && mask[vc]) ? 1.f : 0.f;
            int zz = vc / (Yo * Xo); int rr = vc - zz * (Yo * Xo);
            int yy = rr / Xo; int xx = rr - yy * Xo;
            opd[r] = ((zz + 1) * Ypo + (yy + 1)) * Xpo + (xx + 1);
        }
#pragma unroll
        for (int nt = 0; nt < 2; ++nt) {
            int co = nt * 16 + lr;
            float sc = scale[co], sh = shift[co];
#pragma unroll
            for (int r = 0; r < 4; ++r) {
                if (!ok[r]) continue;
                float yv = fmaxf(fmaf(acc[s][nt][r], sc, sh), 0.f) * mm[r];
                out[(size_t)opd[r] * 32 + co] = __float2bfloat16(yv);
            }
        }
    }
}

// MFMA transposed conv (stride 2) via parity octants
template <int CIN, int COUT>
__global__ __launch_bounds__(256, 4) void tconv_mfma_k(
    const bf16* __restrict__ in, const bf16* __restrict__ wfrag,
    const float* __restrict__ scale, const float* __restrict__ shift,
    const uint8_t* __restrict__ mask, bf16* __restrict__ out,
    int Zo, int Yo, int Xo, int Ypi, int Xpi, int Ypo, int Xpo) {
    constexpr int NT = COUT / 16;
    constexpr int KT = CIN / 32;
    const int oct = blockIdx.y;
    const int pz = oct >> 2, py = (oct >> 1) & 1, px = oct & 1;
    const int Zq = (Zo - pz + 1) >> 1, Yq = (Yo - py + 1) >> 1, Xq = (Xo - px + 1) >> 1;
    const int Nq = Zq * Yq * Xq;
    const int YXq = Yq * Xq;
    const int bid = xcd_swz(blockIdx.x, gridDim.x);
    const int tid = threadIdx.x;
    const int wv = tid >> 6, lane = tid & 63;
    const int lg = lane >> 4, lr = lane & 15;
    const int v0 = bid * 256 + wv * 64;
    if (v0 >= Nq) return;

    bool mw = false;
    {
        int q = v0 + lane;
        if (q < Nq) {
            int zq = q / YXq; int rr = q - zq * YXq; int yq = rr / Xq; int xq = rr - yq * Xq;
            int zz = 2 * zq + pz, yy = 2 * yq + py, xx = 2 * xq + px;
            mw = mask[(zz * Yo + yy) * Xo + xx] != 0;
        }
    }
    const bool anywork = (__ballot(mw) != 0ull);

    f32x4 acc[4][NT];
#pragma unroll
    for (int s = 0; s < 4; ++s)
#pragma unroll
        for (int nt = 0; nt < NT; ++nt) acc[s][nt] = (f32x4){0.f, 0.f, 0.f, 0.f};

    const uint4* gw = (const uint4*)wfrag;

    if (anywork) {
        int pA[4];
#pragma unroll
        for (int s = 0; s < 4; ++s) {
            int q = v0 + s * 16 + lr;
            if (q >= Nq) q = 0;
            int zq = q / YXq; int rr = q - zq * YXq; int yq = rr / Xq; int xq = rr - yq * Xq;
            pA[s] = (((zq + 1) * Ypi + (yq + 1)) * Xpi + (xq + 1)) * CIN + lg * 8;
        }
        const int nkz = 1 + pz, nky = 1 + py, nkx = 1 + px;
        for (int iz = 0; iz < nkz; ++iz) {
            const int kz = pz ? (iz ? 2 : 0) : 1;
            const int dz = (pz && !iz) ? 1 : 0;
            for (int iy = 0; iy < nky; ++iy) {
                const int ky = py ? (iy ? 2 : 0) : 1;
                const int dy = (py && !iy) ? 1 : 0;
                for (int ix = 0; ix < nkx; ++ix) {
                    const int kx = px ? (ix ? 2 : 0) : 1;
                    const int dx = (px && !ix) ? 1 : 0;
                    const int tap = kz * 9 + ky * 3 + kx;
                    const int toff = ((dz * Ypi + dy) * Xpi + dx) * CIN;
                    uint4 ub[NT][KT];
#pragma unroll
                    for (int nt = 0; nt < NT; ++nt)
#pragma unroll
                        for (int kt = 0; kt < KT; ++kt)
                            ub[nt][kt] = gw[((tap * NT + nt) * KT + kt) * 64 + lane];
                    uint4 ua[4][KT];
#pragma unroll
                    for (int s = 0; s < 4; ++s)
#pragma unroll
                        for (int kt = 0; kt < KT; ++kt)
                            ua[s][kt] = *(const uint4*)(in + pA[s] + toff + kt * 32);
#pragma unroll
                    for (int s = 0; s < 4; ++s)
#pragma unroll
                        for (int kt = 0; kt < KT; ++kt)
#pragma unroll
                            for (int nt = 0; nt < NT; ++nt)
                                acc[s][nt] = __builtin_amdgcn_mfma_f32_16x16x32_bf16(
                                    __builtin_bit_cast(s16x8, ua[s][kt]),
                                    __builtin_bit_cast(s16x8, ub[nt][kt]), acc[s][nt], 0, 0, 0);
                }
            }
        }
    }

#pragma unroll
    for (int s = 0; s < 4; ++s) {
        const int vb = v0 + s * 16 + lg * 4;
        int opd[4]; float mm[4]; bool ok[4];
#pragma unroll
        for (int r = 0; r < 4; ++r) {
            int q = vb + r;
            ok[r] = q < Nq;
            int qc = ok[r] ? q : 0;
            int zq = qc / YXq; int rr = qc - zq * YXq; int yq = rr / Xq; int xq = rr - yq * Xq;
            int zz = 2 * zq + pz, yy = 2 * yq + py, xx = 2 * xq + px;
            mm[r] = (ok[r] && mask[(zz * Yo + yy) * Xo + xx]) ? 1.f : 0.f;
            opd[r] = ((zz + 1) * Ypo + (yy + 1)) * Xpo + (xx + 1);
        }
#pragma unroll
        for (int nt = 0; nt < NT; ++nt) {
            int co = nt * 16 + lr;
            float sc = scale[co], sh = shift[co];
#pragma unroll
            for (int r = 0; r < 4; ++r) {
                if (!ok[r]) continue;
                float yv = fmaxf(fmaf(acc[s][nt][r], sc, sh), 0.f) * mm[r];
                out[(size_t)opd[r] * COUT + co] = __float2bfloat16(yv);
            }
        }
    }
}

__global__ __launch_bounds__(256, 4) void conv_l1_mfma_k(
    const bf16* __restrict__ in, const bf16* __restrict__ wfrag,
    const float* __restrict__ scale, const float* __restrict__ shift,
    const uint8_t* __restrict__ mask, bf16* __restrict__ out,
    int Zo, int Yo, int Xo, int Ypi, int Xpi, int Ypo, int Xpo) {
    const int No = Zo * Yo * Xo;
    const int bid = xcd_swz(blockIdx.x, gridDim.x);
    const int tid = threadIdx.x;
    const int wv = tid >> 6, lane = tid & 63;
    const int lg = lane >> 4, lr = lane & 15;
    const int v0 = bid * 256 + wv * 64;
    if (v0 >= No) return;

    int vm = v0 + lane;
    bool mw = (vm < No) && (mask[vm] != 0);
    const bool anywork = (__ballot(mw) != 0ull);

    f32x4 acc[4];
#pragma unroll
    for (int s = 0; s < 4; ++s) acc[s] = (f32x4){0.f, 0.f, 0.f, 0.f};

    if (anywork) {
        const uint4* gw = (const uint4*)wfrag;
        uint4 bu[4];
#pragma unroll
        for (int kb = 0; kb < 4; ++kb) bu[kb] = gw[kb * 64 + lane];

        int vtf[4][2];
#pragma unroll
        for (int kb = 0; kb < 4; ++kb)
#pragma unroll
            for (int u = 0; u < 2; ++u) {
                int tp = kb * 8 + lg * 2 + u;
                int kz = tp / 9, r9 = tp - kz * 9, ky = r9 / 3, kx = r9 - ky * 3;
                vtf[kb][u] = (tp < 27) ? (((kz - 1) * Ypi + (ky - 1)) * Xpi + (kx - 1)) : 0;
            }

        int pV[4];
#pragma unroll
        for (int s = 0; s < 4; ++s) {
            int vr = v0 + s * 16 + lr;
            if (vr >= No) vr = 0;
            int zz = vr / (Yo * Xo); int rr = vr - zz * (Yo * Xo);
            int yy = rr / Xo; int xx = rr - yy * Xo;
            pV[s] = ((zz + 1) * Ypi + (yy + 1)) * Xpi + (xx + 1);
        }

#pragma unroll
        for (int kb = 0; kb < 4; ++kb) {
#pragma unroll
            for (int s = 0; s < 4; ++s) {
                uint2 a0 = *(const uint2*)(in + (size_t)(pV[s] + vtf[kb][0]) * 4);
                uint2 a1 = *(const uint2*)(in + (size_t)(pV[s] + vtf[kb][1]) * 4);
                int4 ai; ai.x = a0.x; ai.y = a0.y; ai.z = a1.x; ai.w = a1.y;
                acc[s] = __builtin_amdgcn_mfma_f32_16x16x32_bf16(
                    __builtin_bit_cast(s16x8, ai),
                    __builtin_bit_cast(s16x8, bu[kb]), acc[s], 0, 0, 0);
            }
        }
    }

#pragma unroll
    for (int s = 0; s < 4; ++s) {
        const int vb = v0 + s * 16 + lg * 4;
        int co = lr;
        float sc = scale[co], sh = shift[co];
#pragma unroll
        for (int r = 0; r < 4; ++r) {
            int v = vb + r;
            if (v >= No) continue;
            float mm = mask[v] ? 1.f : 0.f;
            int zz = v / (Yo * Xo); int rr = v - zz * (Yo * Xo);
            int yy = rr / Xo; int xx = rr - yy * Xo;
            int opd = ((zz + 1) * Ypo + (yy + 1)) * Xpo + (xx + 1);
            float yv = fmaxf(fmaf(acc[s][r], sc, sh), 0.f) * mm;
            out[(size_t)opd * 16 + co] = __float2bfloat16(yv);
        }
    }
}

inline int nblk(int n) { return (n + 255) / 256; }
inline int cdiv(int a, int b) { return (a + b - 1) / b; }

}  // namespace

extern "C" void kernel_launch(void* const* d_in, const int* in_sizes, int n_in,
                              void* d_out, int out_size, void* d_ws, size_t ws_size,
                              hipStream_t stream) {
    const float* feats = (const float*)d_in[0];
    const int* coords = (const int*)d_in[1];
    const int NVOX = in_sizes[0] / 4;

    const float *w1 = (const float*)d_in[3], *s1 = (const float*)d_in[4], *b1 = (const float*)d_in[5];
    const float *w2a = (const float*)d_in[6], *s2a = (const float*)d_in[7], *b2a = (const float*)d_in[8];
    const float *w2b = (const float*)d_in[9], *s2b = (const float*)d_in[10], *b2b = (const float*)d_in[11];
    const float *w3a = (const float*)d_in[12], *s3a = (const float*)d_in[13], *b3a = (const float*)d_in[14];
    const float *w3b = (const float*)d_in[15], *s3b = (const float*)d_in[16], *b3b = (const float*)d_in[17];
    const float *w4a = (const float*)d_in[18], *s4a = (const float*)d_in[19], *b4a = (const float*)d_in[20];
    const float *w4b = (const float*)d_in[21], *s4b = (const float*)d_in[22], *b4b = (const float*)d_in[23];
    const float *w5a = (const float*)d_in[24], *s5a = (const float*)d_in[25], *b5a = (const float*)d_in[26];
    const float *w5b = (const float*)d_in[27], *s5b = (const float*)d_in[28], *b5b = (const float*)d_in[29];

    char* ws = (char*)d_ws;
    size_t off = 0;
    auto alloc = [&](size_t bytes) -> void* {
        void* p = ws + off;
        off = (off + bytes + 255) & ~(size_t)255;
        return p;
    };

    uint8_t* m0 = (uint8_t*)alloc(NV0);
    uint8_t* m1 = (uint8_t*)alloc(NV0);
    uint8_t* m2 = (uint8_t*)alloc(NV2);
    uint8_t* m3 = (uint8_t*)alloc(NV3);
    uint8_t* m4 = (uint8_t*)alloc(NV4);
    uint8_t* m5 = (uint8_t*)alloc(NV0);

    bf16* slot0 = (bf16*)alloc((size_t)NP0 * 32 * 2);
    bf16* slot1 = (bf16*)alloc((size_t)NP0 * 16 * 2);

    bf16* dense0 = slot0;  // 4ch  @P0
    bf16* x1     = slot1;  // 16ch @P0
    bf16* x2a    = slot0;  // 32ch @P2
    bf16* x2b    = slot1;  // 32ch @P2
    bf16* x3a    = slot0;  // 64ch @P3
    bf16* x3b    = slot1;  // 64ch @P3
    bf16* x4a    = slot0;  // 32ch @P4
    bf16* x4b    = slot1;  // 32ch @(23,130,130)
    bf16* x5a    = slot0;  // 32ch @P0

    bf16* wfL1 = (bf16*)alloc(4 * 64 * 8 * 2);
    bf16* wf2a = (bf16*)alloc((size_t)14 * 2 * 64 * 16);
    bf16* wf2b = (bf16*)alloc((size_t)27 * 2 * 1 * 64 * 16);
    bf16* wf3a = (bf16*)alloc((size_t)27 * 4 * 1 * 64 * 16);
    bf16* wf3b = (bf16*)alloc((size_t)27 * 4 * 2 * 64 * 16);
    bf16* wf4a = (bf16*)alloc((size_t)27 * 2 * 2 * 64 * 16);
    bf16* wf4b = (bf16*)alloc((size_t)27 * 2 * 1 * 64 * 16);
    bf16* wf5a = (bf16*)alloc((size_t)27 * 2 * 1 * 64 * 16);
    bf16* wf5b = (bf16*)alloc((size_t)27 * 2 * 1 * 64 * 16);
    alloc(20u << 20);  // slack for OOB halo reads of partial tiles

    if (off > ws_size) {
        sentinel_k<<<1, 256, 0, stream>>>((float*)d_out);
        return;
    }

    // stage 0
    hipMemsetAsync(dense0, 0, (size_t)NP0 * 4 * 2, stream);
    hipMemsetAsync(m0, 0, NV0, stream);
    repack_frag_l1_k<<<1, 256, 0, stream>>>(w1, wfL1);
    repack_frag_c16_k<<<nblk(14 * 2 * 64), 256, 0, stream>>>(w2a, wf2a);
    repack_frag_k<<<nblk(27 * 2 * 64), 256, 0, stream>>>(w2b, wf2b, 32, 32, 0);
    repack_frag_k<<<nblk(27 * 4 * 64), 256, 0, stream>>>(w3a, wf3a, 32, 64, 0);
    repack_frag_k<<<nblk(27 * 8 * 64), 256, 0, stream>>>(w3b, wf3b, 64, 64, 0);
    repack_frag_k<<<nblk(27 * 4 * 64), 256, 0, stream>>>(w4a, wf4a, 64, 32, 1);
    repack_frag_k<<<nblk(27 * 2 * 64), 256, 0, stream>>>(w4b, wf4b, 32, 32, 0);
    repack_frag_k<<<nblk(27 * 2 * 64), 256, 0, stream>>>(w5a, wf5a, 32, 32, 1);
    repack_frag_k<<<nblk(27 * 2 * 64), 256, 0, stream>>>(w5b, wf5b, 32, 32, 0);

    scatter_k<<<nblk(NVOX), 256, 0, stream>>>(feats, coords, dense0, m0, NVOX);

    // level 1
    dilate4_k<<<nblk(NV0 / 4), 256, 0, stream>>>(m0, m1, Z0, Y0, X0);
    halo_zero_k<16><<<nblk(NP0), 256, 0, stream>>>(x1, Z0, Y0, X0, ZP0, YP0, XP0);
    conv_l1_mfma_k<<<nblk(NV0), 256, 0, stream>>>(
        dense0, wfL1, s1, b1, m1, x1, Z0, Y0, X0, YP0, XP0, YP0, XP0);

    // level 2
    dilate_k<<<nblk(NV2), 256, 0, stream>>>(m1, m2, Z0, Y0, X0, Z2, Y2, X2, 2);
    halo_zero_k<32><<<nblk(NP2), 256, 0, stream>>>(x2a, Z2, Y2, X2, ZP2, YP2, XP2);
    conv_s2c16_k<<<nblk(NV2), 256, 0, stream>>>(
        x1, wf2a, s2a, b2a, m2, x2a, Z2, Y2, X2, YP0, XP0, YP2, XP2);
    halo_zero_k<32><<<nblk(NP2), 256, 0, stream>>>(x2b, Z2, Y2, X2, ZP2, YP2, XP2);
    {
        int nx = cdiv(X2, 32), ny = cdiv(Y2, 4), nz = cdiv(Z2, 4);
        conv_lds_k<false><<<nx * ny * nz, 512, 0, stream>>>(
            x2a, wf2b, s2b, b2b, m2, x2b, nullptr, Z2, Y2, X2, YP2, XP2, YP2, XP2, nx, ny);
    }

    // level 3
    dilate_k<<<nblk(NV3), 256, 0, stream>>>(m2, m3, Z2, Y2, X2, Z3, Y3, X3, 2);
    halo_zero_k<64><<<nblk(NP3), 256, 0, stream>>>(x3a, Z3, Y3, X3, ZP3, YP3, XP3);
    conv_mfma_k<32, 64, 2, 64, false><<<cdiv(NV3, 64), 64, 0, stream>>>(
        x2b, wf3a, s3a, b3a, m3, x3a, nullptr, Z3, Y3, X3, YP2, XP2, YP3, XP3);
    halo_zero_k<64><<<nblk(NP3), 256, 0, stream>>>(x3b, Z3, Y3, X3, ZP3, YP3, XP3);
    conv_mfma_k<64, 64, 1, 64, false><<<cdiv(NV3, 64), 64, 0, stream>>>(
        x3a, wf3b, s3b, b3b, m3, x3b, nullptr, Z3, Y3, X3, YP3, XP3, YP3, XP3);

    // level 4 (tconv up via parity octants)
    tdilate_k<<<nblk(NV4), 256, 0, stream>>>(m3, m4, Z3, Y3, X3, Z4, Y4, X4);
    halo_zero_k<32><<<nblk(NP4), 256, 0, stream>>>(x4a, Z4, Y4, X4, ZP4, YP4, XP4);
    {
        int maxNq = ((Z4 + 1) >> 1) * ((Y4 + 1) >> 1) * ((X4 + 1) >> 1);
        dim3 g(nblk(maxNq), 8);
        tconv_mfma_k<64, 32><<<g, 256, 0, stream>>>(
            x3b, wf4a, s4a, b4a, m4, x4a, Z4, Y4, X4, YP3, XP3, YP4, XP4);
    }
    halo_zero_k<32><<<nblk(NP2), 256, 0, stream>>>(x4b, Z4, Y4, X4, ZP2, YP2, XP2);
    {
        int nx = cdiv(X4, 32), ny = cdiv(Y4, 4), nz = cdiv(Z4, 4);
        conv_lds_k<false><<<nx * ny * nz, 512, 0, stream>>>(
            x4a, wf4b, s4b, b4b, m4, x4b, nullptr, Z4, Y4, X4, YP4, XP4, YP2, XP2, nx, ny);
    }

    // level 5 (tconv up, outpad (0,3,3))
    tdilate4_k<<<nblk(NV0 / 4), 256, 0, stream>>>(m4, m5, Z4, Y4, X4, Z0, Y0, X0);
    halo_zero_k<32><<<nblk(NP0), 256, 0, stream>>>(x5a, Z0, Y0, X0, ZP0, YP0, XP0);
    {
        int maxNq = ((Z0 + 1) >> 1) * (Y0 >> 1) * (X0 >> 1);
        dim3 g(nblk(maxNq), 8);
        tconv_mfma_k<32, 32><<<g, 256, 0, stream>>>(
            x4b, wf5a, s5a, b5a, m5, x5a, Z0, Y0, X0, YP2, XP2, YP0, XP0);
    }
    {
        int nx = X0 / 32, ny = Y0 / 2;  // 8 x 128 = 1024 blocks, full tiles
        conv_roll_k<<<nx * ny, 256, 0, stream>>>(
            x5a, wf5b, s5b, b5b, m5, (float*)d_out, Z0, Y0, X0, YP0, XP0, nx);
    }
}

// Round 8
// 866.074 us; speedup vs baseline: 1.1529x; 1.1250x over previous
//
#include <hip/hip_runtime.h>
#include <hip/hip_bf16.h>
#include <stdint.h>

namespace {

constexpr int Z0 = 41, Y0 = 256, X0 = 256;
constexpr int Z2 = 21, Y2 = 128, X2 = 128;
constexpr int Z3 = 11, Y3 = 64,  X3 = 64;
constexpr int Z4 = 21, Y4 = 127, X4 = 127;
constexpr int NV0 = Z0 * Y0 * X0;
constexpr int NV2 = Z2 * Y2 * X2;
constexpr int NV3 = Z3 * Y3 * X3;
constexpr int NV4 = Z4 * Y4 * X4;

constexpr int ZP0 = 43, YP0 = 258, XP0 = 258; constexpr int NP0 = ZP0 * YP0 * XP0;
constexpr int ZP2 = 23, YP2 = 130, XP2 = 130; constexpr int NP2 = ZP2 * YP2 * XP2;
constexpr int ZP3 = 13, YP3 = 66,  XP3 = 66;  constexpr int NP3 = ZP3 * YP3 * XP3;
constexpr int ZP4 = 23, YP4 = 129, XP4 = 129; constexpr int NP4 = ZP4 * YP4 * XP4;

using bf16 = __hip_bfloat16;
typedef __attribute__((ext_vector_type(8))) short s16x8;
typedef __attribute__((ext_vector_type(4))) float f32x4;

__device__ inline unsigned f2b(float f) {
    return (unsigned)__builtin_bit_cast(unsigned short, __float2bfloat16(f));
}

__device__ inline int xcd_swz(int bid, int nwg) {
    int q = nwg >> 3, r = nwg & 7;
    int x = bid & 7, j = bid >> 3;
    return (x < r ? x * (q + 1) : r * (q + 1) + (x - r) * q) + j;
}

__device__ inline void glds16(const bf16* g, void* l) {
    __builtin_amdgcn_global_load_lds(
        (const __attribute__((address_space(1))) void*)g,
        (__attribute__((address_space(3))) void*)l, 16, 0, 0);
}

__global__ __launch_bounds__(256) void sentinel_k(float* out) { out[0] = 12345.0f; }

__global__ __launch_bounds__(256) void scatter_k(const float* __restrict__ feats,
                                                 const int* __restrict__ coords,
                                                 bf16* __restrict__ dense,
                                                 uint8_t* __restrict__ m0, int n) {
    int v = blockIdx.x * 256 + threadIdx.x;
    if (v >= n) return;
    int z = coords[v * 4 + 1], y = coords[v * 4 + 2], x = coords[v * 4 + 3];
    m0[(z * Y0 + y) * X0 + x] = 1;
    int pp = ((z + 1) * YP0 + (y + 1)) * XP0 + (x + 1);
    uint2 u;
    u.x = f2b(feats[v * 4 + 0]) | (f2b(feats[v * 4 + 1]) << 16);
    u.y = f2b(feats[v * 4 + 2]) | (f2b(feats[v * 4 + 3]) << 16);
    *(uint2*)(dense + (size_t)pp * 4) = u;
}

template <int C>
__global__ __launch_bounds__(256) void halo_zero_k(bf16* __restrict__ buf,
                                                   int Zi, int Yi, int Xi,
                                                   int Zp, int Yp, int Xp) {
    int i = blockIdx.x * 256 + threadIdx.x;
    int tot = Zp * Yp * Xp;
    if (i >= tot) return;
    int x = i % Xp; int t = i / Xp; int y = t % Yp; int z = t / Yp;
    bool halo = (z < 1) | (z > Zi) | (y < 1) | (y > Yi) | (x < 1) | (x > Xi);
    if (!halo) return;
    uint4 zz = make_uint4(0, 0, 0, 0);
    uint4* p = (uint4*)(buf + (size_t)i * C);
#pragma unroll
    for (int j = 0; j < C / 8; ++j) p[j] = zz;
}

__global__ __launch_bounds__(256) void repack_frag_k(const float* __restrict__ w,
                                                     bf16* __restrict__ wf,
                                                     int CIN, int COUT, int TRANS) {
    int NT = COUT / 16, KT = CIN / 32;
    int i = blockIdx.x * 256 + threadIdx.x;
    int total = 27 * NT * KT * 64;
    if (i >= total) return;
    int lane = i & 63; int t = i >> 6;
    int kt = t % KT; t /= KT; int nt = t % NT; int tap = t / NT;
    int co = nt * 16 + (lane & 15);
    int ci0 = kt * 32 + (lane >> 4) * 8;
    unsigned e[8];
#pragma unroll
    for (int j = 0; j < 8; ++j) {
        int ci = ci0 + j;
        int src = TRANS ? ((ci * COUT + co) * 27 + tap) : ((co * CIN + ci) * 27 + tap);
        e[j] = f2b(w[src]);
    }
    uint4 u;
    u.x = e[0] | (e[1] << 16); u.y = e[2] | (e[3] << 16);
    u.z = e[4] | (e[5] << 16); u.w = e[6] | (e[7] << 16);
    ((uint4*)wf)[i] = u;
}

// CIN=16 stride-2 frag: K = 2 taps x 16ch, 14 pairs (tap 27 zero)
__global__ __launch_bounds__(256) void repack_frag_c16_k(const float* __restrict__ w,
                                                         bf16* __restrict__ wf) {
    int i = blockIdx.x * 256 + threadIdx.x;
    int total = 14 * 2 * 64;
    if (i >= total) return;
    int lane = i & 63; int t = i >> 6;
    int nt = t & 1; int p = t >> 1;
    int lg = lane >> 4, lr = lane & 15;
    int co = nt * 16 + lr;
    unsigned e[8];
#pragma unroll
    for (int j = 0; j < 8; ++j) {
        int tap = 2 * p + (lg >> 1);
        int ci = (lg & 1) * 8 + j;
        e[j] = (tap < 27) ? f2b(w[(co * 16 + ci) * 27 + tap]) : 0u;
    }
    uint4 u;
    u.x = e[0] | (e[1] << 16); u.y = e[2] | (e[3] << 16);
    u.z = e[4] | (e[5] << 16); u.w = e[6] | (e[7] << 16);
    ((uint4*)wf)[i] = u;
}

__global__ __launch_bounds__(256) void repack_frag_l1_k(const float* __restrict__ w,
                                                        bf16* __restrict__ wf) {
    int i = blockIdx.x * 256 + threadIdx.x;
    if (i >= 256) return;
    int lane = i & 63, kb = i >> 6;
    int lg = lane >> 4, lr = lane & 15;
    unsigned e[8];
#pragma unroll
    for (int j = 0; j < 8; ++j) {
        int tap = kb * 8 + lg * 2 + (j >> 2);
        int ci = j & 3;
        e[j] = (tap < 27) ? f2b(w[(lr * 4 + ci) * 27 + tap]) : 0u;
    }
    uint4 u;
    u.x = e[0] | (e[1] << 16); u.y = e[2] | (e[3] << 16);
    u.z = e[4] | (e[5] << 16); u.w = e[6] | (e[7] << 16);
    ((uint4*)wf)[i] = u;
}

__global__ __launch_bounds__(256) void dilate_k(const uint8_t* __restrict__ in,
                                                uint8_t* __restrict__ out,
                                                int Zi, int Yi, int Xi,
                                                int Zo, int Yo, int Xo, int stride) {
    int idx = blockIdx.x * 256 + threadIdx.x;
    int total = Zo * Yo * Xo;
    if (idx >= total) return;
    int x = idx % Xo; int t = idx / Xo; int y = t % Yo; int z = t / Yo;
    int YX = Yi * Xi;
    uint8_t r = 0;
    for (int kz = 0; kz < 3; ++kz) {
        int zi = z * stride + kz - 1;
        if ((unsigned)zi >= (unsigned)Zi) continue;
        for (int ky = 0; ky < 3; ++ky) {
            int yi = y * stride + ky - 1;
            if ((unsigned)yi >= (unsigned)Yi) continue;
            for (int kx = 0; kx < 3; ++kx) {
                int xi = x * stride + kx - 1;
                if ((unsigned)xi >= (unsigned)Xi) continue;
                r |= in[zi * YX + yi * Xi + xi];
            }
        }
    }
    out[idx] = r ? 1 : 0;
}

__global__ __launch_bounds__(256) void dilate4_k(const uint8_t* __restrict__ in,
                                                 uint8_t* __restrict__ out,
                                                 int Z, int Y, int X) {
    int ngx = X >> 2;
    int g = blockIdx.x * 256 + threadIdx.x;
    int total = Z * Y * ngx;
    if (g >= total) return;
    int gx = g % ngx; int t = g / ngx; int y = t % Y; int z = t / Y;
    const int YX = Y * X;
    unsigned r = 0;
    for (int kz = 0; kz < 3; ++kz) {
        int zi = z + kz - 1;
        if ((unsigned)zi >= (unsigned)Z) continue;
        for (int ky = 0; ky < 3; ++ky) {
            int yi = y + ky - 1;
            if ((unsigned)yi >= (unsigned)Y) continue;
            const unsigned* rw = (const unsigned*)(in + zi * YX + yi * X);
            unsigned u1 = rw[gx];
            unsigned u0 = gx ? rw[gx - 1] : 0u;
            unsigned u2 = (gx + 1 < ngx) ? rw[gx + 1] : 0u;
            r |= u1 | ((u1 << 8) | (u0 >> 24)) | ((u1 >> 8) | (u2 << 24));
        }
    }
    r |= r >> 4; r |= r >> 2; r |= r >> 1; r &= 0x01010101u;
    ((unsigned*)out)[g] = r;
}

__global__ __launch_bounds__(256) void tdilate_k(const uint8_t* __restrict__ in,
                                                 uint8_t* __restrict__ out,
                                                 int Zi, int Yi, int Xi,
                                                 int Zo, int Yo, int Xo) {
    int idx = blockIdx.x * 256 + threadIdx.x;
    int total = Zo * Yo * Xo;
    if (idx >= total) return;
    int x = idx % Xo; int t = idx / Xo; int y = t % Yo; int z = t / Yo;
    int YX = Yi * Xi;
    uint8_t r = 0;
    for (int kz = 0; kz < 3; ++kz) {
        int tz = z + 1 - kz;
        if (tz & 1) continue;
        int zi = tz >> 1;
        if ((unsigned)zi >= (unsigned)Zi) continue;
        for (int ky = 0; ky < 3; ++ky) {
            int ty = y + 1 - ky;
            if (ty & 1) continue;
            int yi = ty >> 1;
            if ((unsigned)yi >= (unsigned)Yi) continue;
            for (int kx = 0; kx < 3; ++kx) {
                int tx = x + 1 - kx;
                if (tx & 1) continue;
                int xi = tx >> 1;
                if ((unsigned)xi >= (unsigned)Xi) continue;
                r |= in[zi * YX + yi * Xi + xi];
            }
        }
    }
    out[idx] = r ? 1 : 0;
}

__global__ __launch_bounds__(256) void tdilate4_k(const uint8_t* __restrict__ in,
                                                  uint8_t* __restrict__ out,
                                                  int Zi, int Yi, int Xi,
                                                  int Zo, int Yo, int Xo) {
    int ngx = Xo >> 2;
    int g = blockIdx.x * 256 + threadIdx.x;
    int total = Zo * Yo * ngx;
    if (g >= total) return;
    int gx = g % ngx; int t = g / ngx; int y = t % Yo; int z = t / Yo;
    int YX = Yi * Xi;
    int j0 = gx * 2;
    unsigned r0 = 0, r1 = 0, r2 = 0, r3 = 0;
    for (int kz = 0; kz < 3; ++kz) {
        int tz = z + 1 - kz;
        if (tz & 1) continue;
        int zi = tz >> 1;
        if ((unsigned)zi >= (unsigned)Zi) continue;
        for (int ky = 0; ky < 3; ++ky) {
            int ty = y + 1 - ky;
            if (ty & 1) continue;
            int yi = ty >> 1;
            if ((unsigned)yi >= (unsigned)Yi) continue;
            const uint8_t* rp = in + zi * YX + yi * Xi;
            unsigned b0 = (j0 < Xi) ? rp[j0] : 0u;
            unsigned b1 = (j0 + 1 < Xi) ? rp[j0 + 1] : 0u;
            unsigned b2 = (j0 + 2 < Xi) ? rp[j0 + 2] : 0u;
            r0 |= b0; r1 |= b0 | b1; r2 |= b1; r3 |= b1 | b2;
        }
    }
    unsigned rr = (r0 ? 1u : 0u) | (r1 ? 0x100u : 0u) | (r2 ? 0x10000u : 0u) | (r3 ? 0x1000000u : 0u);
    ((unsigned*)out)[g] = rr;
}

// ---- rolling-z pipelined conv 32->32 (L5b), deep prefetch, B resident ----
// 4 waves = (2 y-rows) x (2 cout halves). 5-slab ring: stage(z+4) at iter z,
// drained at end of iter z+1 (2 compute phases > HBM latency). Masks
// prefetched one plane ahead into registers -> NO loads consumed in-iter.
__global__ __launch_bounds__(256, 2) void conv_roll_k(
    const bf16* __restrict__ in, const bf16* __restrict__ wfrag,
    const float* __restrict__ scale, const float* __restrict__ shift,
    const uint8_t* __restrict__ mask, float* __restrict__ outf,
    int Zo, int Yo, int Xo, int Ypi, int Xpi, int nx) {
    constexpr int ROWB = 34 * 64;     // 2176 B per halo row
    constexpr int SLABB = 4 * ROWB;   // 4 halo rows per plane slab
    __shared__ uint4 ring4[5 * SLABB / 16];
    char* ring = (char*)ring4;

    const int No = Zo * Yo * Xo;
    const int bid = xcd_swz(blockIdx.x, gridDim.x);
    const int tx = bid % nx, ty = bid / nx;
    const int y0 = ty * 2, x0 = tx * 32;

    const int tid = threadIdx.x;
    const int w = tid >> 6, lane = tid & 63;
    const int lg = lane >> 4, lr = lane & 15;
    const int yr = w >> 1, ch = w & 1;

    auto stagefn = [&](int zp, int slot) {
        int zs = zp <= Zo + 1 ? zp : Zo + 1;
        char* slab = ring + slot * SLABB + w * ROWB;
        const bf16* pb = in + ((size_t)zs * Ypi + (y0 + w)) * (size_t)Xpi * 32 + (size_t)x0 * 32;
        int u0 = lane;      glds16(pb + (u0 ^ ((u0 >> 3) & 7)) * 8, slab + u0 * 16);
        int u1 = 64 + lane; glds16(pb + (u1 ^ ((u1 >> 3) & 7)) * 8, slab + u1 * 16);
        if (lane < 8) { int u2 = 128 + lane; glds16(pb + u2 * 8, slab + u2 * 16); }
    };

    // B fragments for this wave's cout-half: 27 x 16B = 108 VGPRs (resident @ 2 waves/SIMD)
    const uint4* gw = (const uint4*)wfrag;
    uint4 breg[27];
#pragma unroll
    for (int t = 0; t < 27; ++t) breg[t] = gw[(t * 2 + ch) * 64 + lane];

    int asw0[3], asw1[3];
#pragma unroll
    for (int dx = 0; dx < 3; ++dx) {
        int b0 = (lr + dx) * 64 + lg * 16;       asw0[dx] = b0 ^ (((b0 >> 7) & 7) << 4);
        int b1 = (16 + lr + dx) * 64 + lg * 16;  asw1[dx] = b1 ^ (((b1 >> 7) & 7) << 4);
    }

    const int co = ch * 16 + lr;
    const float sc = scale[co], sh = shift[co];

    stagefn(0, 0); stagefn(1, 1); stagefn(2, 2); stagefn(3, 3);
    uint mk0, mk1;
    {
        const uint8_t* mrow = mask + (size_t)(y0 + yr) * Xo + x0;
        mk0 = *(const uint*)(mrow + lg * 4);
        mk1 = *(const uint*)(mrow + 16 + lg * 4);
    }
    asm volatile("s_waitcnt vmcnt(0)" ::: "memory");
    __builtin_amdgcn_s_barrier();

    int rs0 = 0, wslot = 4;
    for (int z = 0; z < Zo; ++z) {
        // mask prefetch (plane z+1) FIRST, then stage(z+4)
        uint nk0, nk1;
        {
            int zn = (z + 1 < Zo) ? z + 1 : Zo - 1;
            const uint8_t* mrow = mask + ((size_t)zn * Yo + (y0 + yr)) * Xo + x0;
            nk0 = *(const uint*)(mrow + lg * 4);
            nk1 = *(const uint*)(mrow + 16 + lg * 4);
        }
        stagefn(z + 4, wslot);

        int rs1 = rs0 + 1 < 5 ? rs0 + 1 : 0;
        int rs2 = rs1 + 1 < 5 ? rs1 + 1 : 0;
        const char* sl_0 = ring + rs0 * SLABB;
        const char* sl_1 = ring + rs1 * SLABB;
        const char* sl_2 = ring + rs2 * SLABB;

        f32x4 acc0 = (f32x4){0, 0, 0, 0}, acc1 = (f32x4){0, 0, 0, 0};
#pragma unroll
        for (int dz = 0; dz < 3; ++dz) {
            const char* slab = dz == 0 ? sl_0 : (dz == 1 ? sl_1 : sl_2);
#pragma unroll
            for (int dy = 0; dy < 3; ++dy) {
                const char* rowp = slab + (yr + dy) * ROWB;
#pragma unroll
                for (int dx = 0; dx < 3; ++dx) {
                    const int tap = dz * 9 + dy * 3 + dx;
                    uint4 a0 = *(const uint4*)(rowp + asw0[dx]);
                    uint4 a1 = *(const uint4*)(rowp + asw1[dx]);
                    acc0 = __builtin_amdgcn_mfma_f32_16x16x32_bf16(
                        __builtin_bit_cast(s16x8, a0), __builtin_bit_cast(s16x8, breg[tap]),
                        acc0, 0, 0, 0);
                    acc1 = __builtin_amdgcn_mfma_f32_16x16x32_bf16(
                        __builtin_bit_cast(s16x8, a1), __builtin_bit_cast(s16x8, breg[tap]),
                        acc1, 0, 0, 0);
                }
            }
        }

        const size_t rowbase = ((size_t)z * Yo + (y0 + yr)) * Xo + x0;
        {
            f32x4 o0, o1;
#pragma unroll
            for (int r = 0; r < 4; ++r) {
                float m0f = (float)((mk0 >> (8 * r)) & 1);
                float m1f = (float)((mk1 >> (8 * r)) & 1);
                o0[r] = fmaxf(fmaf(acc0[r], sc, sh), 0.f) * m0f;
                o1[r] = fmaxf(fmaf(acc1[r], sc, sh), 0.f) * m1f;
            }
            *(f32x4*)(outf + (size_t)co * No + rowbase + lg * 4)      = o0;
            *(f32x4*)(outf + (size_t)co * No + rowbase + 16 + lg * 4) = o1;
        }

        // drain stage(z+3) (3 oldest); keep iter-z's 7 ops + old stores in flight
        asm volatile("s_waitcnt vmcnt(9)" ::: "memory");
        __builtin_amdgcn_s_barrier();
        rs0 = rs1;
        wslot = wslot + 1 < 5 ? wslot + 1 : 0;
        mk0 = nk0; mk1 = nk1;
    }
}

// ---- rolling-z pipelined transposed conv 32->32 (L5a) via parity octants ----
// blockIdx.y = octant (pz,py,px): fixed tap set (<=8 taps), nt=2 per wave.
// 4 waves = (2 yq-rows) x (2 x-halves). 4-slab ring of x4b planes.
__global__ __launch_bounds__(256, 3) void tconv_roll_k(
    const bf16* __restrict__ in, const bf16* __restrict__ wfrag,
    const float* __restrict__ scale, const float* __restrict__ shift,
    const uint8_t* __restrict__ mask, bf16* __restrict__ out,
    int Zo, int Yo, int Xo, int Zi, int Ypi, int Xpi, int Ypo, int Xpo, int nx) {
    constexpr int ROWB = 34 * 64;
    constexpr int SLABB = 3 * ROWB;   // 3 halo rows per input plane
    __shared__ uint4 ring4[4 * SLABB / 16];
    char* ring = (char*)ring4;

    const int oct = blockIdx.y;
    const int pz = oct >> 2, py = (oct >> 1) & 1, px = oct & 1;
    const int Zq = (Zo - pz + 1) >> 1;

    const int bid = xcd_swz(blockIdx.x, gridDim.x);
    const int tx = bid % nx, ty = bid / nx;
    const int yq0 = ty * 2, xq0 = tx * 32;

    const int tid = threadIdx.x;
    const int w = tid >> 6, lane = tid & 63;
    const int lg = lane >> 4, lr = lane & 15;
    const int yr = w >> 1, xh = w & 1;

    // tap index 0: k = p?0:1, input offset d = p?1:0 ; tap index 1 (p only): k=2, d=0
    const int kz0 = pz ? 0 : 1, dzo0 = pz ? 1 : 0;
    const int ky0 = py ? 0 : 1, dyo0 = py ? 1 : 0;
    const int kx0 = px ? 0 : 1, dxo0 = px ? 1 : 0;

    auto stagefn = [&](int p, int slot) {
        if (w < 3) {
            int zs = p < Zi ? p : Zi - 1;
            char* slab = ring + slot * SLABB + w * ROWB;
            const bf16* pb = in + ((size_t)(zs + 1) * Ypi + (yq0 + 1 + w)) * (size_t)Xpi * 32
                                + (size_t)(xq0 + 1) * 32;
            int u0 = lane;      glds16(pb + (u0 ^ ((u0 >> 3) & 7)) * 8, slab + u0 * 16);
            int u1 = 64 + lane; glds16(pb + (u1 ^ ((u1 >> 3) & 7)) * 8, slab + u1 * 16);
            if (lane < 8) { int u2 = 128 + lane; glds16(pb + u2 * 8, slab + u2 * 16); }
        }
    };

    // B fragments breg[iz][iy][ix][nt] (static indexing via unrolled loops)
    const uint4* gw = (const uint4*)wfrag;
    uint4 breg[2][2][2][2];
#pragma unroll
    for (int iz = 0; iz < 2; ++iz) {
        int kz = iz ? 2 : kz0;
#pragma unroll
        for (int iy = 0; iy < 2; ++iy) {
            int ky = iy ? 2 : ky0;
#pragma unroll
            for (int ix = 0; ix < 2; ++ix) {
                int kx = ix ? 2 : kx0;
                int tap = kz * 9 + ky * 3 + kx;
                breg[iz][iy][ix][0] = gw[(tap * 2 + 0) * 64 + lane];
                breg[iz][iy][ix][1] = gw[(tap * 2 + 1) * 64 + lane];
            }
        }
    }

    // swizzled A byte offsets: ix=0 -> col+dxo0, ix=1 -> col+0
    int b0 = (xh * 16 + lr + dxo0) * 64 + lg * 16;
    int b1 = (xh * 16 + lr) * 64 + lg * 16;
    const int aswA = b0 ^ (((b0 >> 7) & 7) << 4);
    const int aswB = b1 ^ (((b1 >> 7) & 7) << 4);
    const int rowA = (yr + dyo0) * ROWB;  // iy=0
    const int rowB = yr * ROWB;           // iy=1

    const float sc0 = scale[lr], sh0 = shift[lr];
    const float sc1 = scale[16 + lr], sh1 = shift[16 + lr];

    const int yout = 2 * (yq0 + yr) + py;
    const int xb = 2 * (xq0 + xh * 16 + lg * 4) + px;  // xb - px is 8-aligned

    stagefn(0, 0); stagefn(1, 1); stagefn(2, 2);
    uint2 mv;
    mv = *(const uint2*)(mask + ((size_t)pz * Yo + yout) * Xo + (xb - px));
    asm volatile("s_waitcnt vmcnt(0)" ::: "memory");
    __builtin_amdgcn_s_barrier();

    int rs0 = 0, wslot = 3;
    for (int zq = 0; zq < Zq; ++zq) {
        uint2 nv;
        {
            int zqn = (zq + 1 < Zq) ? zq + 1 : Zq - 1;
            nv = *(const uint2*)(mask + ((size_t)(2 * zqn + pz) * Yo + yout) * Xo + (xb - px));
        }
        stagefn(zq + 3, wslot);

        int rs1 = rs0 + 1 < 4 ? rs0 + 1 : 0;
        const char* sl_0 = ring + rs0 * SLABB;
        const char* sl_1 = ring + rs1 * SLABB;
        const char* slz0 = pz ? sl_1 : sl_0;  // iz=0 plane: zq + dzo0
        const char* slz1 = sl_0;              // iz=1 plane: zq

        f32x4 acc0 = (f32x4){0, 0, 0, 0}, acc1 = (f32x4){0, 0, 0, 0};
#pragma unroll
        for (int iz = 0; iz < 2; ++iz) {
            if (iz > pz) continue;
            const char* slab = iz ? slz1 : slz0;
#pragma unroll
            for (int iy = 0; iy < 2; ++iy) {
                if (iy > py) continue;
                const char* rowp = slab + (iy ? rowB : rowA);
#pragma unroll
                for (int ix = 0; ix < 2; ++ix) {
                    if (ix > px) continue;
                    uint4 a = *(const uint4*)(rowp + (ix ? aswB : aswA));
                    acc0 = __builtin_amdgcn_mfma_f32_16x16x32_bf16(
                        __builtin_bit_cast(s16x8, a),
                        __builtin_bit_cast(s16x8, breg[iz][iy][ix][0]), acc0, 0, 0, 0);
                    acc1 = __builtin_amdgcn_mfma_f32_16x16x32_bf16(
                        __builtin_bit_cast(s16x8, a),
                        __builtin_bit_cast(s16x8, breg[iz][iy][ix][1]), acc1, 0, 0, 0);
                }
            }
        }

        const int zout = 2 * zq + pz;
        const size_t opdbase = ((size_t)(zout + 1) * Ypo + (yout + 1)) * Xpo;
#pragma unroll
        for (int r = 0; r < 4; ++r) {
            unsigned word = (r < 2) ? mv.x : mv.y;
            float m = (float)((word >> (px * 8 + (r & 1) * 16)) & 1);
            float v0 = fmaxf(fmaf(acc0[r], sc0, sh0), 0.f) * m;
            float v1 = fmaxf(fmaf(acc1[r], sc1, sh1), 0.f) * m;
            size_t opd = opdbase + (size_t)(xb + 2 * r + 1);
            out[opd * 32 + lr]      = __float2bfloat16(v0);
            out[opd * 32 + 16 + lr] = __float2bfloat16(v1);
        }

        asm volatile("s_waitcnt vmcnt(20)" ::: "memory");
        __builtin_amdgcn_s_barrier();
        rs0 = rs1;
        wslot = wslot + 1 < 4 ? wslot + 1 : 0;
        mv = nv;
    }
}

// LDS-tiled MFMA stride-1 conv, CIN=COUT=32 (L2b, L4b)
template <bool FINAL>
__global__ __launch_bounds__(512, 4) void conv_lds_k(
    const bf16* __restrict__ in, const bf16* __restrict__ wfrag,
    const float* __restrict__ scale, const float* __restrict__ shift,
    const uint8_t* __restrict__ mask, bf16* __restrict__ out, float* __restrict__ outf,
    int Zo, int Yo, int Xo, int Ypi, int Xpi, int Ypo, int Xpo, int nx, int ny) {
    constexpr int ROWB = 34 * 64;
    __shared__ uint4 tile4[36 * ROWB / 16];
    char* tile = (char*)tile4;

    const int No = Zo * Yo * Xo;
    const int bid = xcd_swz(blockIdx.x, gridDim.x);
    int tx = bid % nx; int tt = bid / nx; int ty = tt % ny; int tz = tt / ny;
    const int z0 = tz * 4, y0 = ty * 4, x0 = tx * 32;

    const int tid = threadIdx.x;
    const int w = tid >> 6, lane = tid & 63, lg = lane >> 4, lr = lane & 15;

    int anywork;
    {
        int row = tid >> 5, xl = tid & 31;
        int zz = z0 + (row >> 2), yy = y0 + (row & 3), xx = x0 + xl;
        int ok = (zz < Zo) && (yy < Yo) && (xx < Xo) && mask[((size_t)zz * Yo + yy) * Xo + xx];
        anywork = __syncthreads_or(ok);
    }

    f32x4 acc[4][2];
#pragma unroll
    for (int s = 0; s < 4; ++s) { acc[s][0] = (f32x4){0,0,0,0}; acc[s][1] = (f32x4){0,0,0,0}; }

    if (anywork) {
        const int lsw = (lane ^ ((lane >> 3) & 7)) * 8;
        for (int rr = w; rr < 36; rr += 8) {
            int dz = rr / 6, dy = rr % 6;
            const bf16* g = in + ((size_t)(z0 + dz) * Ypi + (y0 + dy)) * Xpi * 32 + (size_t)x0 * 32;
            char* l = tile + rr * ROWB;
            glds16(g + lsw, l);
            glds16(g + 512 + lsw, l + 1024);
            if (lane < 8) glds16(g + 1024 + lane * 8, l + 2048);
        }
        asm volatile("s_waitcnt vmcnt(0)" ::: "memory");
        __syncthreads();

        int rbB[4], bsw[4][3];
#pragma unroll
        for (int s = 0; s < 4; ++s) {
            int lrow = 2 * w + (s >> 1);
            rbB[s] = ((lrow >> 2) * 6 + (lrow & 3)) * ROWB;
            int xpart = (s & 1) * 16 + lr;
#pragma unroll
            for (int dx = 0; dx < 3; ++dx) {
                int b = (xpart + dx) * 64 + lg * 16;
                bsw[s][dx] = b ^ (((b >> 7) & 7) << 4);
            }
        }

        const uint4* gw = (const uint4*)wfrag;
#pragma unroll 1
        for (int dz = 0; dz < 3; ++dz) {
#pragma unroll
            for (int dy = 0; dy < 3; ++dy) {
                const int rowoff = (dz * 6 + dy) * ROWB;
#pragma unroll
                for (int dx = 0; dx < 3; ++dx) {
                    const int tap = dz * 9 + dy * 3 + dx;
                    uint4 b0 = gw[(tap * 2 + 0) * 64 + lane];
                    uint4 b1 = gw[(tap * 2 + 1) * 64 + lane];
                    uint4 ua[4];
#pragma unroll
                    for (int s = 0; s < 4; ++s)
                        ua[s] = *(const uint4*)(tile + rbB[s] + rowoff + bsw[s][dx]);
#pragma unroll
                    for (int s = 0; s < 4; ++s) {
                        acc[s][0] = __builtin_amdgcn_mfma_f32_16x16x32_bf16(
                            __builtin_bit_cast(s16x8, ua[s]),
                            __builtin_bit_cast(s16x8, b0), acc[s][0], 0, 0, 0);
                        acc[s][1] = __builtin_amdgcn_mfma_f32_16x16x32_bf16(
                            __builtin_bit_cast(s16x8, ua[s]),
                            __builtin_bit_cast(s16x8, b1), acc[s][1], 0, 0, 0);
                    }
                }
            }
        }
    }

#pragma unroll
    for (int s = 0; s < 4; ++s) {
        int lrow = 2 * w + (s >> 1);
        int zz = z0 + (lrow >> 2), yy = y0 + (lrow & 3);
        int xv = x0 + (s & 1) * 16 + lg * 4;
        bool rowok = (zz < Zo) && (yy < Yo);
        if (!rowok) continue;
        size_t idx0 = ((size_t)zz * Yo + yy) * Xo + xv;
        float mm[4];
#pragma unroll
        for (int r = 0; r < 4; ++r)
            mm[r] = (xv + r < Xo && mask[idx0 + r]) ? 1.f : 0.f;
        if constexpr (FINAL) {
#pragma unroll
            for (int nt = 0; nt < 2; ++nt) {
                int co = nt * 16 + lr;
                float sc = scale[co], sh = shift[co];
                f32x4 o;
#pragma unroll
                for (int r = 0; r < 4; ++r)
                    o[r] = fmaxf(fmaf(acc[s][nt][r], sc, sh), 0.f) * mm[r];
                if (xv + 3 < Xo) {
                    *(f32x4*)(outf + (size_t)co * No + idx0) = o;
                } else {
#pragma unroll
                    for (int r = 0; r < 4; ++r)
                        if (xv + r < Xo) outf[(size_t)co * No + idx0 + r] = o[r];
                }
            }
        } else {
            int opd = ((zz + 1) * Ypo + (yy + 1)) * Xpo + (xv + 1);
#pragma unroll
            for (int nt = 0; nt < 2; ++nt) {
                int co = nt * 16 + lr;
                float sc = scale[co], sh = shift[co];
#pragma unroll
                for (int r = 0; r < 4; ++r) {
                    if (xv + r >= Xo) continue;
                    float yv = fmaxf(fmaf(acc[s][nt][r], sc, sh), 0.f) * mm[r];
                    out[(size_t)(opd + r) * 32 + co] = __float2bfloat16(yv);
                }
            }
        }
    }
}

// global-load MFMA conv, generic stride & block size (L3a, L3b)
template <int CIN, int COUT, int STRIDE, int BLK, bool FINAL>
__global__ __launch_bounds__(BLK, ((CIN <= 32 && COUT <= 32) ? 4 : 2)) void conv_mfma_k(
    const bf16* __restrict__ in, const bf16* __restrict__ wfrag,
    const float* __restrict__ scale, const float* __restrict__ shift,
    const uint8_t* __restrict__ mask, bf16* __restrict__ out, float* __restrict__ outf,
    int Zo, int Yo, int Xo, int Ypi, int Xpi, int Ypo, int Xpo) {
    constexpr int NT = COUT / 16;
    constexpr int KT = CIN / 32;
    const int No = Zo * Yo * Xo;
    const int bid = xcd_swz(blockIdx.x, gridDim.x);
    const int tid = threadIdx.x;
    const int wv = tid >> 6, lane = tid & 63;
    const int lg = lane >> 4, lr = lane & 15;
    const int v0 = bid * BLK + wv * 64;
    if (v0 >= No) return;

    int vm = v0 + lane;
    bool mw = (vm < No) && (mask[vm] != 0);
    const bool anywork = (__ballot(mw) != 0ull);

    f32x4 acc[4][NT];
#pragma unroll
    for (int s = 0; s < 4; ++s)
#pragma unroll
        for (int nt = 0; nt < NT; ++nt) acc[s][nt] = (f32x4){0.f, 0.f, 0.f, 0.f};

    const uint4* gw = (const uint4*)wfrag;

    if (anywork) {
        int pA[4];
#pragma unroll
        for (int s = 0; s < 4; ++s) {
            int vr = v0 + s * 16 + lr;
            if (vr >= No) vr = 0;
            int zz = vr / (Yo * Xo); int rr = vr - zz * (Yo * Xo);
            int yy = rr / Xo; int xx = rr - yy * Xo;
            pA[s] = (((zz * STRIDE + 1) * Ypi + (yy * STRIDE + 1)) * Xpi + (xx * STRIDE + 1)) * CIN + lg * 8;
        }
#pragma unroll
        for (int tap = 0; tap < 27; ++tap) {
            const int kz = tap / 9, r9 = tap - kz * 9, ky = r9 / 3, kx = r9 - ky * 3;
            const int toff = (((kz - 1) * Ypi + (ky - 1)) * Xpi + (kx - 1)) * CIN;
            uint4 ub[NT][KT];
#pragma unroll
            for (int nt = 0; nt < NT; ++nt)
#pragma unroll
                for (int kt = 0; kt < KT; ++kt)
                    ub[nt][kt] = gw[((tap * NT + nt) * KT + kt) * 64 + lane];
            uint4 ua[4][KT];
#pragma unroll
            for (int s = 0; s < 4; ++s)
#pragma unroll
                for (int kt = 0; kt < KT; ++kt)
                    ua[s][kt] = *(const uint4*)(in + pA[s] + toff + kt * 32);
#pragma unroll
            for (int s = 0; s < 4; ++s)
#pragma unroll
                for (int kt = 0; kt < KT; ++kt)
#pragma unroll
                    for (int nt = 0; nt < NT; ++nt)
                        acc[s][nt] = __builtin_amdgcn_mfma_f32_16x16x32_bf16(
                            __builtin_bit_cast(s16x8, ua[s][kt]),
                            __builtin_bit_cast(s16x8, ub[nt][kt]), acc[s][nt], 0, 0, 0);
        }
    }

#pragma unroll
    for (int s = 0; s < 4; ++s) {
        const int vb = v0 + s * 16 + lg * 4;
        int opd[4]; float mm[4]; bool ok[4];
#pragma unroll
        for (int r = 0; r < 4; ++r) {
            int v = vb + r;
            ok[r] = v < No;
            int vc = ok[r] ? v : 0;
            mm[r] = (ok[r] && mask[vc]) ? 1.f : 0.f;
            int zz = vc / (Yo * Xo); int rr = vc - zz * (Yo * Xo);
            int yy = rr / Xo; int xx = rr - yy * Xo;
            opd[r] = FINAL ? vc : ((zz + 1) * Ypo + (yy + 1)) * Xpo + (xx + 1);
        }
#pragma unroll
        for (int nt = 0; nt < NT; ++nt) {
            int co = nt * 16 + lr;
            float sc = scale[co], sh = shift[co];
#pragma unroll
            for (int r = 0; r < 4; ++r) {
                if (!ok[r]) continue;
                float yv = fmaxf(fmaf(acc[s][nt][r], sc, sh), 0.f) * mm[r];
                if constexpr (FINAL) outf[(size_t)co * No + opd[r]] = yv;
                else out[(size_t)opd[r] * COUT + co] = __float2bfloat16(yv);
            }
        }
    }
}

// stride-2 CIN=16 MFMA conv (L2a)
__global__ __launch_bounds__(256, 4) void conv_s2c16_k(
    const bf16* __restrict__ in, const bf16* __restrict__ wfrag,
    const float* __restrict__ scale, const float* __restrict__ shift,
    const uint8_t* __restrict__ mask, bf16* __restrict__ out,
    int Zo, int Yo, int Xo, int Ypi, int Xpi, int Ypo, int Xpo) {
    const int No = Zo * Yo * Xo;
    const int bid = xcd_swz(blockIdx.x, gridDim.x);
    const int tid = threadIdx.x;
    const int wv = tid >> 6, lane = tid & 63;
    const int lg = lane >> 4, lr = lane & 15;
    const int v0 = bid * 256 + wv * 64;
    if (v0 >= No) return;

    int vm = v0 + lane;
    bool mw = (vm < No) && (mask[vm] != 0);
    const bool anywork = (__ballot(mw) != 0ull);

    f32x4 acc[4][2];
#pragma unroll
    for (int s = 0; s < 4; ++s) { acc[s][0] = (f32x4){0,0,0,0}; acc[s][1] = (f32x4){0,0,0,0}; }

    if (anywork) {
        const uint4* gw = (const uint4*)wfrag;
        const int choff = (lg & 1) * 8;
        const int tb = lg >> 1;
        int toffl[14];
#pragma unroll
        for (int p = 0; p < 14; ++p) {
            int tp = 2 * p + tb;
            if (tp >= 27) tp = 0;
            int kz = tp / 9, r9 = tp - kz * 9, ky = r9 / 3, kx = r9 - ky * 3;
            toffl[p] = ((kz * Ypi + ky) * Xpi + kx) * 16;
        }
        int pA[4];
#pragma unroll
        for (int s = 0; s < 4; ++s) {
            int vr = v0 + s * 16 + lr;
            if (vr >= No) vr = 0;
            int zz = vr / (Yo * Xo); int rr = vr - zz * (Yo * Xo);
            int yy = rr / Xo; int xx = rr - yy * Xo;
            pA[s] = (((zz * 2) * Ypi + (yy * 2)) * Xpi + (xx * 2)) * 16 + choff;
        }
#pragma unroll
        for (int p = 0; p < 14; ++p) {
            uint4 b0 = gw[(p * 2 + 0) * 64 + lane];
            uint4 b1 = gw[(p * 2 + 1) * 64 + lane];
            uint4 ua[4];
#pragma unroll
            for (int s = 0; s < 4; ++s)
                ua[s] = *(const uint4*)(in + pA[s] + toffl[p]);
#pragma unroll
            for (int s = 0; s < 4; ++s) {
                acc[s][0] = __builtin_amdgcn_mfma_f32_16x16x32_bf16(
                    __builtin_bit_cast(s16x8, ua[s]),
                    __builtin_bit_cast(s16x8, b0), acc[s][0], 0, 0, 0);
                acc[s][1] = __builtin_amdgcn_mfma_f32_16x16x32_bf16(
                    __builtin_bit_cast(s16x8, ua[s]),
                    __builtin_bit_cast(s16x8, b1), acc[s][1], 0, 0, 0);
            }
        }
    }

#pragma unroll
    for (int s = 0; s < 4; ++s) {
        const int vb = v0 + s * 16 + lg * 4;
        int opd[4]; float mm[4]; bool ok[4];
#pragma unroll
        for (int r = 0; r < 4; ++r) {
            int v = vb + r;
            ok[r] = v < No;
            int vc = ok[r] ? v : 0;
            mm[r] = (ok[r] && mask[vc]) ? 1.f : 0.f;
            int zz = vc / (Yo * Xo); int rr = vc - zz * (Yo * Xo);
            int yy = rr / Xo; int xx = rr - yy * Xo;
            opd[r] = ((zz + 1) * Ypo + (yy + 1)) * Xpo + (xx + 1);
        }
#pragma unroll
        for (int nt = 0; nt < 2; ++nt) {
            int co = nt * 16 + lr;
            float sc = scale[co], sh = shift[co];
#pragma unroll
            for (int r = 0; r < 4; ++r) {
                if (!ok[r]) continue;
                float yv = fmaxf(fmaf(acc[s][nt][r], sc, sh), 0.f) * mm[r];
                out[(size_t)opd[r] * 32 + co] = __float2bfloat16(yv);
            }
        }
    }
}

// MFMA transposed conv (stride 2) via parity octants (L4a)
template <int CIN, int COUT>
__global__ __launch_bounds__(256, 4) void tconv_mfma_k(
    const bf16* __restrict__ in, const bf16* __restrict__ wfrag,
    const float* __restrict__ scale, const float* __restrict__ shift,
    const uint8_t* __restrict__ mask, bf16* __restrict__ out,
    int Zo, int Yo, int Xo, int Ypi, int Xpi, int Ypo, int Xpo) {
    constexpr int NT = COUT / 16;
    constexpr int KT = CIN / 32;
    const int oct = blockIdx.y;
    const int pz = oct >> 2, py = (oct >> 1) & 1, px = oct & 1;
    const int Zq = (Zo - pz + 1) >> 1, Yq = (Yo - py + 1) >> 1, Xq = (Xo - px + 1) >> 1;
    const int Nq = Zq * Yq * Xq;
    const int YXq = Yq * Xq;
    const int bid = xcd_swz(blockIdx.x, gridDim.x);
    const int tid = threadIdx.x;
    const int wv = tid >> 6, lane = tid & 63;
    const int lg = lane >> 4, lr = lane & 15;
    const int v0 = bid * 256 + wv * 64;
    if (v0 >= Nq) return;

    bool mw = false;
    {
        int q = v0 + lane;
        if (q < Nq) {
            int zq = q / YXq; int rr = q - zq * YXq; int yq = rr / Xq; int xq = rr - yq * Xq;
            int zz = 2 * zq + pz, yy = 2 * yq + py, xx = 2 * xq + px;
            mw = mask[(zz * Yo + yy) * Xo + xx] != 0;
        }
    }
    const bool anywork = (__ballot(mw) != 0ull);

    f32x4 acc[4][NT];
#pragma unroll
    for (int s = 0; s < 4; ++s)
#pragma unroll
        for (int nt = 0; nt < NT; ++nt) acc[s][nt] = (f32x4){0.f, 0.f, 0.f, 0.f};

    const uint4* gw = (const uint4*)wfrag;

    if (anywork) {
        int pA[4];
#pragma unroll
        for (int s = 0; s < 4; ++s) {
            int q = v0 + s * 16 + lr;
            if (q >= Nq) q = 0;
            int zq = q / YXq; int rr = q - zq * YXq; int yq = rr / Xq; int xq = rr - yq * Xq;
            pA[s] = (((zq + 1) * Ypi + (yq + 1)) * Xpi + (xq + 1)) * CIN + lg * 8;
        }
        const int nkz = 1 + pz, nky = 1 + py, nkx = 1 + px;
        for (int iz = 0; iz < nkz; ++iz) {
            const int kz = pz ? (iz ? 2 : 0) : 1;
            const int dz = (pz && !iz) ? 1 : 0;
            for (int iy = 0; iy < nky; ++iy) {
                const int ky = py ? (iy ? 2 : 0) : 1;
                const int dy = (py && !iy) ? 1 : 0;
                for (int ix = 0; ix < nkx; ++ix) {
                    const int kx = px ? (ix ? 2 : 0) : 1;
                    const int dx = (px && !ix) ? 1 : 0;
                    const int tap = kz * 9 + ky * 3 + kx;
                    const int toff = ((dz * Ypi + dy) * Xpi + dx) * CIN;
                    uint4 ub[NT][KT];
#pragma unroll
                    for (int nt = 0; nt < NT; ++nt)
#pragma unroll
                        for (int kt = 0; kt < KT; ++kt)
                            ub[nt][kt] = gw[((tap * NT + nt) * KT + kt) * 64 + lane];
                    uint4 ua[4][KT];
#pragma unroll
                    for (int s = 0; s < 4; ++s)
#pragma unroll
                        for (int kt = 0; kt < KT; ++kt)
                            ua[s][kt] = *(const uint4*)(in + pA[s] + toff + kt * 32);
#pragma unroll
                    for (int s = 0; s < 4; ++s)
#pragma unroll
                        for (int kt = 0; kt < KT; ++kt)
#pragma unroll
                            for (int nt = 0; nt < NT; ++nt)
                                acc[s][nt] = __builtin_amdgcn_mfma_f32_16x16x32_bf16(
                                    __builtin_bit_cast(s16x8, ua[s][kt]),
                                    __builtin_bit_cast(s16x8, ub[nt][kt]), acc[s][nt], 0, 0, 0);
                }
            }
        }
    }

#pragma unroll
    for (int s = 0; s < 4; ++s) {
        const int vb = v0 + s * 16 + lg * 4;
        int opd[4]; float mm[4]; bool ok[4];
#pragma unroll
        for (int r = 0; r < 4; ++r) {
            int q = vb + r;
            ok[r] = q < Nq;
            int qc = ok[r] ? q : 0;
            int zq = qc / YXq; int rr = qc - zq * YXq; int yq = rr / Xq; int xq = rr - yq * Xq;
            int zz = 2 * zq + pz, yy = 2 * yq + py, xx = 2 * xq + px;
            mm[r] = (ok[r] && mask[(zz * Yo + yy) * Xo + xx]) ? 1.f : 0.f;
            opd[r] = ((zz + 1) * Ypo + (yy + 1)) * Xpo + (xx + 1);
        }
#pragma unroll
        for (int nt = 0; nt < NT; ++nt) {
            int co = nt * 16 + lr;
            float sc = scale[co], sh = shift[co];
#pragma unroll
            for (int r = 0; r < 4; ++r) {
                if (!ok[r]) continue;
                float yv = fmaxf(fmaf(acc[s][nt][r], sc, sh), 0.f) * mm[r];
                out[(size_t)opd[r] * COUT + co] = __float2bfloat16(yv);
            }
        }
    }
}

__global__ __launch_bounds__(256, 4) void conv_l1_mfma_k(
    const bf16* __restrict__ in, const bf16* __restrict__ wfrag,
    const float* __restrict__ scale, const float* __restrict__ shift,
    const uint8_t* __restrict__ mask, bf16* __restrict__ out,
    int Zo, int Yo, int Xo, int Ypi, int Xpi, int Ypo, int Xpo) {
    const int No = Zo * Yo * Xo;
    const int bid = xcd_swz(blockIdx.x, gridDim.x);
    const int tid = threadIdx.x;
    const int wv = tid >> 6, lane = tid & 63;
    const int lg = lane >> 4, lr = lane & 15;
    const int v0 = bid * 256 + wv * 64;
    if (v0 >= No) return;

    int vm = v0 + lane;
    bool mw = (vm < No) && (mask[vm] != 0);
    const bool anywork = (__ballot(mw) != 0ull);

    f32x4 acc[4];
#pragma unroll
    for (int s = 0; s < 4; ++s) acc[s] = (f32x4){0.f, 0.f, 0.f, 0.f};

    if (anywork) {
        const uint4* gw = (const uint4*)wfrag;
        uint4 bu[4];
#pragma unroll
        for (int kb = 0; kb < 4; ++kb) bu[kb] = gw[kb * 64 + lane];

        int vtf[4][2];
#pragma unroll
        for (int kb = 0; kb < 4; ++kb)
#pragma unroll
            for (int u = 0; u < 2; ++u) {
                int tp = kb * 8 + lg * 2 + u;
                int kz = tp / 9, r9 = tp - kz * 9, ky = r9 / 3, kx = r9 - ky * 3;
                vtf[kb][u] = (tp < 27) ? (((kz - 1) * Ypi + (ky - 1)) * Xpi + (kx - 1)) : 0;
            }

        int pV[4];
#pragma unroll
        for (int s = 0; s < 4; ++s) {
            int vr = v0 + s * 16 + lr;
            if (vr >= No) vr = 0;
            int zz = vr / (Yo * Xo); int rr = vr - zz * (Yo * Xo);
            int yy = rr / Xo; int xx = rr - yy * Xo;
            pV[s] = ((zz + 1) * Ypi + (yy + 1)) * Xpi + (xx + 1);
        }

#pragma unroll
        for (int kb = 0; kb < 4; ++kb) {
#pragma unroll
            for (int s = 0; s < 4; ++s) {
                uint2 a0 = *(const uint2*)(in + (size_t)(pV[s] + vtf[kb][0]) * 4);
                uint2 a1 = *(const uint2*)(in + (size_t)(pV[s] + vtf[kb][1]) * 4);
                int4 ai; ai.x = a0.x; ai.y = a0.y; ai.z = a1.x; ai.w = a1.y;
                acc[s] = __builtin_amdgcn_mfma_f32_16x16x32_bf16(
                    __builtin_bit_cast(s16x8, ai),
                    __builtin_bit_cast(s16x8, bu[kb]), acc[s], 0, 0, 0);
            }
        }
    }

#pragma unroll
    for (int s = 0; s < 4; ++s) {
        const int vb = v0 + s * 16 + lg * 4;
        int co = lr;
        float sc = scale[co], sh = shift[co];
#pragma unroll
        for (int r = 0; r < 4; ++r) {
            int v = vb + r;
            if (v >= No) continue;
            float mm = mask[v] ? 1.f : 0.f;
            int zz = v / (Yo * Xo); int rr = v - zz * (Yo * Xo);
            int yy = rr / Xo; int xx = rr - yy * Xo;
            int opd = ((zz + 1) * Ypo + (yy + 1)) * Xpo + (xx + 1);
            float yv = fmaxf(fmaf(acc[s][r], sc, sh), 0.f) * mm;
            out[(size_t)opd * 16 + co] = __float2bfloat16(yv);
        }
    }
}

inline int nblk(int n) { return (n + 255) / 256; }
inline int cdiv(int a, int b) { return (a + b - 1) / b; }

}  // namespace

extern "C" void kernel_launch(void* const* d_in, const int* in_sizes, int n_in,
                              void* d_out, int out_size, void* d_ws, size_t ws_size,
                              hipStream_t stream) {
    const float* feats = (const float*)d_in[0];
    const int* coords = (const int*)d_in[1];
    const int NVOX = in_sizes[0] / 4;

    const float *w1 = (const float*)d_in[3], *s1 = (const float*)d_in[4], *b1 = (const float*)d_in[5];
    const float *w2a = (const float*)d_in[6], *s2a = (const float*)d_in[7], *b2a = (const float*)d_in[8];
    const float *w2b = (const float*)d_in[9], *s2b = (const float*)d_in[10], *b2b = (const float*)d_in[11];
    const float *w3a = (const float*)d_in[12], *s3a = (const float*)d_in[13], *b3a = (const float*)d_in[14];
    const float *w3b = (const float*)d_in[15], *s3b = (const float*)d_in[16], *b3b = (const float*)d_in[17];
    const float *w4a = (const float*)d_in[18], *s4a = (const float*)d_in[19], *b4a = (const float*)d_in[20];
    const float *w4b = (const float*)d_in[21], *s4b = (const float*)d_in[22], *b4b = (const float*)d_in[23];
    const float *w5a = (const float*)d_in[24], *s5a = (const float*)d_in[25], *b5a = (const float*)d_in[26];
    const float *w5b = (const float*)d_in[27], *s5b = (const float*)d_in[28], *b5b = (const float*)d_in[29];

    char* ws = (char*)d_ws;
    size_t off = 0;
    auto alloc = [&](size_t bytes) -> void* {
        void* p = ws + off;
        off = (off + bytes + 255) & ~(size_t)255;
        return p;
    };

    uint8_t* m0 = (uint8_t*)alloc(NV0);
    uint8_t* m1 = (uint8_t*)alloc(NV0);
    uint8_t* m2 = (uint8_t*)alloc(NV2);
    uint8_t* m3 = (uint8_t*)alloc(NV3);
    uint8_t* m4 = (uint8_t*)alloc(NV4);
    uint8_t* m5 = (uint8_t*)alloc(NV0);

    bf16* slot0 = (bf16*)alloc((size_t)NP0 * 32 * 2);
    bf16* slot1 = (bf16*)alloc((size_t)NP0 * 16 * 2);

    bf16* dense0 = slot0;  // 4ch  @P0
    bf16* x1     = slot1;  // 16ch @P0
    bf16* x2a    = slot0;  // 32ch @P2
    bf16* x2b    = slot1;  // 32ch @P2
    bf16* x3a    = slot0;  // 64ch @P3
    bf16* x3b    = slot1;  // 64ch @P3
    bf16* x4a    = slot0;  // 32ch @P4
    bf16* x4b    = slot1;  // 32ch @(23,130,130)
    bf16* x5a    = slot0;  // 32ch @P0

    bf16* wfL1 = (bf16*)alloc(4 * 64 * 8 * 2);
    bf16* wf2a = (bf16*)alloc((size_t)14 * 2 * 64 * 16);
    bf16* wf2b = (bf16*)alloc((size_t)27 * 2 * 1 * 64 * 16);
    bf16* wf3a = (bf16*)alloc((size_t)27 * 4 * 1 * 64 * 16);
    bf16* wf3b = (bf16*)alloc((size_t)27 * 4 * 2 * 64 * 16);
    bf16* wf4a = (bf16*)alloc((size_t)27 * 2 * 2 * 64 * 16);
    bf16* wf4b = (bf16*)alloc((size_t)27 * 2 * 1 * 64 * 16);
    bf16* wf5a = (bf16*)alloc((size_t)27 * 2 * 1 * 64 * 16);
    bf16* wf5b = (bf16*)alloc((size_t)27 * 2 * 1 * 64 * 16);
    alloc(20u << 20);  // slack for OOB halo reads of partial tiles

    if (off > ws_size) {
        sentinel_k<<<1, 256, 0, stream>>>((float*)d_out);
        return;
    }

    // stage 0
    hipMemsetAsync(dense0, 0, (size_t)NP0 * 4 * 2, stream);
    hipMemsetAsync(m0, 0, NV0, stream);
    repack_frag_l1_k<<<1, 256, 0, stream>>>(w1, wfL1);
    repack_frag_c16_k<<<nblk(14 * 2 * 64), 256, 0, stream>>>(w2a, wf2a);
    repack_frag_k<<<nblk(27 * 2 * 64), 256, 0, stream>>>(w2b, wf2b, 32, 32, 0);
    repack_frag_k<<<nblk(27 * 4 * 64), 256, 0, stream>>>(w3a, wf3a, 32, 64, 0);
    repack_frag_k<<<nblk(27 * 8 * 64), 256, 0, stream>>>(w3b, wf3b, 64, 64, 0);
    repack_frag_k<<<nblk(27 * 4 * 64), 256, 0, stream>>>(w4a, wf4a, 64, 32, 1);
    repack_frag_k<<<nblk(27 * 2 * 64), 256, 0, stream>>>(w4b, wf4b, 32, 32, 0);
    repack_frag_k<<<nblk(27 * 2 * 64), 256, 0, stream>>>(w5a, wf5a, 32, 32, 1);
    repack_frag_k<<<nblk(27 * 2 * 64), 256, 0, stream>>>(w5b, wf5b, 32, 32, 0);

    scatter_k<<<nblk(NVOX), 256, 0, stream>>>(feats, coords, dense0, m0, NVOX);

    // level 1
    dilate4_k<<<nblk(NV0 / 4), 256, 0, stream>>>(m0, m1, Z0, Y0, X0);
    halo_zero_k<16><<<nblk(NP0), 256, 0, stream>>>(x1, Z0, Y0, X0, ZP0, YP0, XP0);
    conv_l1_mfma_k<<<nblk(NV0), 256, 0, stream>>>(
        dense0, wfL1, s1, b1, m1, x1, Z0, Y0, X0, YP0, XP0, YP0, XP0);

    // level 2
    dilate_k<<<nblk(NV2), 256, 0, stream>>>(m1, m2, Z0, Y0, X0, Z2, Y2, X2, 2);
    halo_zero_k<32><<<nblk(NP2), 256, 0, stream>>>(x2a, Z2, Y2, X2, ZP2, YP2, XP2);
    conv_s2c16_k<<<nblk(NV2), 256, 0, stream>>>(
        x1, wf2a, s2a, b2a, m2, x2a, Z2, Y2, X2, YP0, XP0, YP2, XP2);
    halo_zero_k<32><<<nblk(NP2), 256, 0, stream>>>(x2b, Z2, Y2, X2, ZP2, YP2, XP2);
    {
        int nx = cdiv(X2, 32), ny = cdiv(Y2, 4), nz = cdiv(Z2, 4);
        conv_lds_k<false><<<nx * ny * nz, 512, 0, stream>>>(
            x2a, wf2b, s2b, b2b, m2, x2b, nullptr, Z2, Y2, X2, YP2, XP2, YP2, XP2, nx, ny);
    }

    // level 3
    dilate_k<<<nblk(NV3), 256, 0, stream>>>(m2, m3, Z2, Y2, X2, Z3, Y3, X3, 2);
    halo_zero_k<64><<<nblk(NP3), 256, 0, stream>>>(x3a, Z3, Y3, X3, ZP3, YP3, XP3);
    conv_mfma_k<32, 64, 2, 64, false><<<cdiv(NV3, 64), 64, 0, stream>>>(
        x2b, wf3a, s3a, b3a, m3, x3a, nullptr, Z3, Y3, X3, YP2, XP2, YP3, XP3);
    halo_zero_k<64><<<nblk(NP3), 256, 0, stream>>>(x3b, Z3, Y3, X3, ZP3, YP3, XP3);
    conv_mfma_k<64, 64, 1, 64, false><<<cdiv(NV3, 64), 64, 0, stream>>>(
        x3a, wf3b, s3b, b3b, m3, x3b, nullptr, Z3, Y3, X3, YP3, XP3, YP3, XP3);

    // level 4 (tconv up via parity octants)
    tdilate_k<<<nblk(NV4), 256, 0, stream>>>(m3, m4, Z3, Y3, X3, Z4, Y4, X4);
    halo_zero_k<32><<<nblk(NP4), 256, 0, stream>>>(x4a, Z4, Y4, X4, ZP4, YP4, XP4);
    {
        int maxNq = ((Z4 + 1) >> 1) * ((Y4 + 1) >> 1) * ((X4 + 1) >> 1);
        dim3 g(nblk(maxNq), 8);
        tconv_mfma_k<64, 32><<<g, 256, 0, stream>>>(
            x3b, wf4a, s4a, b4a, m4, x4a, Z4, Y4, X4, YP3, XP3, YP4, XP4);
    }
    halo_zero_k<32><<<nblk(NP2), 256, 0, stream>>>(x4b, Z4, Y4, X4, ZP2, YP2, XP2);
    {
        int nx = cdiv(X4, 32), ny = cdiv(Y4, 4), nz = cdiv(Z4, 4);
        conv_lds_k<false><<<nx * ny * nz, 512, 0, stream>>>(
            x4a, wf4b, s4b, b4b, m4, x4b, nullptr, Z4, Y4, X4, YP4, XP4, YP2, XP2, nx, ny);
    }

    // level 5 (tconv up, outpad (0,3,3)) — both kernels rolling-z pipelined
    tdilate4_k<<<nblk(NV0 / 4), 256, 0, stream>>>(m4, m5, Z4, Y4, X4, Z0, Y0, X0);
    halo_zero_k<32><<<nblk(NP0), 256, 0, stream>>>(x5a, Z0, Y0, X0, ZP0, YP0, XP0);
    {
        dim3 g((Y0 / 2 / 2) * (X0 / 2 / 32), 8);  // 256 blocks x 8 octants
        tconv_roll_k<<<g, 256, 0, stream>>>(
            x4b, wf5a, s5a, b5a, m5, x5a, Z0, Y0, X0, Z4, YP2, XP2, YP0, XP0, X0 / 2 / 32);
    }
    {
        int nx = X0 / 32, ny = Y0 / 2;  // 1024 blocks, full tiles
        conv_roll_k<<<nx * ny, 256, 0, stream>>>(
            x5a, wf5b, s5b, b5b, m5, (float*)d_out, Z0, Y0, X0, YP0, XP0, nx);
    }
}

// Round 10
// 864.721 us; speedup vs baseline: 1.1547x; 1.0016x over previous
//
#include <hip/hip_runtime.h>
#include <hip/hip_bf16.h>
#include <stdint.h>

namespace {

constexpr int Z0 = 41, Y0 = 256, X0 = 256;
constexpr int Z2 = 21, Y2 = 128, X2 = 128;
constexpr int Z3 = 11, Y3 = 64,  X3 = 64;
constexpr int Z4 = 21, Y4 = 127, X4 = 127;
constexpr int NV0 = Z0 * Y0 * X0;
constexpr int NV2 = Z2 * Y2 * X2;
constexpr int NV3 = Z3 * Y3 * X3;
constexpr int NV4 = Z4 * Y4 * X4;

constexpr int ZP0 = 43, YP0 = 258, XP0 = 258; constexpr int NP0 = ZP0 * YP0 * XP0;
constexpr int ZP2 = 23, YP2 = 130, XP2 = 130; constexpr int NP2 = ZP2 * YP2 * XP2;
constexpr int ZP3 = 13, YP3 = 66,  XP3 = 66;  constexpr int NP3 = ZP3 * YP3 * XP3;
constexpr int ZP4 = 23, YP4 = 129, XP4 = 129; constexpr int NP4 = ZP4 * YP4 * XP4;

using bf16 = __hip_bfloat16;
typedef __attribute__((ext_vector_type(8))) short s16x8;
typedef __attribute__((ext_vector_type(4))) float f32x4;
typedef __attribute__((ext_vector_type(16))) float f32x16;
typedef __attribute__((ext_vector_type(4))) unsigned u32x4;

__device__ inline unsigned f2b(float f) {
    return (unsigned)__builtin_bit_cast(unsigned short, __float2bfloat16(f));
}

__device__ inline int xcd_swz(int bid, int nwg) {
    int q = nwg >> 3, r = nwg & 7;
    int x = bid & 7, j = bid >> 3;
    return (x < r ? x * (q + 1) : r * (q + 1) + (x - r) * q) + j;
}

__device__ inline void glds16(const bf16* g, void* l) {
    __builtin_amdgcn_global_load_lds(
        (const __attribute__((address_space(1))) void*)g,
        (__attribute__((address_space(3))) void*)l, 16, 0, 0);
}

__global__ __launch_bounds__(256) void sentinel_k(float* out) { out[0] = 12345.0f; }

__global__ __launch_bounds__(256) void scatter_k(const float* __restrict__ feats,
                                                 const int* __restrict__ coords,
                                                 bf16* __restrict__ dense,
                                                 uint8_t* __restrict__ m0, int n) {
    int v = blockIdx.x * 256 + threadIdx.x;
    if (v >= n) return;
    int z = coords[v * 4 + 1], y = coords[v * 4 + 2], x = coords[v * 4 + 3];
    m0[(z * Y0 + y) * X0 + x] = 1;
    int pp = ((z + 1) * YP0 + (y + 1)) * XP0 + (x + 1);
    uint2 u;
    u.x = f2b(feats[v * 4 + 0]) | (f2b(feats[v * 4 + 1]) << 16);
    u.y = f2b(feats[v * 4 + 2]) | (f2b(feats[v * 4 + 3]) << 16);
    *(uint2*)(dense + (size_t)pp * 4) = u;
}

template <int C>
__global__ __launch_bounds__(256) void halo_zero_k(bf16* __restrict__ buf,
                                                   int Zi, int Yi, int Xi,
                                                   int Zp, int Yp, int Xp) {
    int i = blockIdx.x * 256 + threadIdx.x;
    int tot = Zp * Yp * Xp;
    if (i >= tot) return;
    int x = i % Xp; int t = i / Xp; int y = t % Yp; int z = t / Yp;
    bool halo = (z < 1) | (z > Zi) | (y < 1) | (y > Yi) | (x < 1) | (x > Xi);
    if (!halo) return;
    uint4 zz = make_uint4(0, 0, 0, 0);
    uint4* p = (uint4*)(buf + (size_t)i * C);
#pragma unroll
    for (int j = 0; j < C / 8; ++j) p[j] = zz;
}

__global__ __launch_bounds__(256) void repack_frag_k(const float* __restrict__ w,
                                                     bf16* __restrict__ wf,
                                                     int CIN, int COUT, int TRANS) {
    int NT = COUT / 16, KT = CIN / 32;
    int i = blockIdx.x * 256 + threadIdx.x;
    int total = 27 * NT * KT * 64;
    if (i >= total) return;
    int lane = i & 63; int t = i >> 6;
    int kt = t % KT; t /= KT; int nt = t % NT; int tap = t / NT;
    int co = nt * 16 + (lane & 15);
    int ci0 = kt * 32 + (lane >> 4) * 8;
    unsigned e[8];
#pragma unroll
    for (int j = 0; j < 8; ++j) {
        int ci = ci0 + j;
        int src = TRANS ? ((ci * COUT + co) * 27 + tap) : ((co * CIN + ci) * 27 + tap);
        e[j] = f2b(w[src]);
    }
    uint4 u;
    u.x = e[0] | (e[1] << 16); u.y = e[2] | (e[3] << 16);
    u.z = e[4] | (e[5] << 16); u.w = e[6] | (e[7] << 16);
    ((uint4*)wf)[i] = u;
}

// 32x32x16 B-frag repack: wf[(tap*2+ks)*64+lane], elem j: B[k=(lane>>5)*8+j][col=lane&31]
// with weight channel cin = ks*16 + k
__global__ __launch_bounds__(256) void repack_frag32_k(const float* __restrict__ w,
                                                       bf16* __restrict__ wf) {
    int i = blockIdx.x * 256 + threadIdx.x;
    if (i >= 27 * 2 * 64) return;
    int lane = i & 63; int t2 = i >> 6;
    int ks = t2 & 1; int tap = t2 >> 1;
    int co = lane & 31; int h = lane >> 5;
    unsigned e[8];
#pragma unroll
    for (int j = 0; j < 8; ++j) {
        int cin = ks * 16 + h * 8 + j;
        e[j] = f2b(w[(co * 32 + cin) * 27 + tap]);
    }
    uint4 u;
    u.x = e[0] | (e[1] << 16); u.y = e[2] | (e[3] << 16);
    u.z = e[4] | (e[5] << 16); u.w = e[6] | (e[7] << 16);
    ((uint4*)wf)[i] = u;
}

// CIN=16 stride-2 frag: K = 2 taps x 16ch, 14 pairs (tap 27 zero)
__global__ __launch_bounds__(256) void repack_frag_c16_k(const float* __restrict__ w,
                                                         bf16* __restrict__ wf) {
    int i = blockIdx.x * 256 + threadIdx.x;
    int total = 14 * 2 * 64;
    if (i >= total) return;
    int lane = i & 63; int t = i >> 6;
    int nt = t & 1; int p = t >> 1;
    int lg = lane >> 4, lr = lane & 15;
    int co = nt * 16 + lr;
    unsigned e[8];
#pragma unroll
    for (int j = 0; j < 8; ++j) {
        int tap = 2 * p + (lg >> 1);
        int ci = (lg & 1) * 8 + j;
        e[j] = (tap < 27) ? f2b(w[(co * 16 + ci) * 27 + tap]) : 0u;
    }
    uint4 u;
    u.x = e[0] | (e[1] << 16); u.y = e[2] | (e[3] << 16);
    u.z = e[4] | (e[5] << 16); u.w = e[6] | (e[7] << 16);
    ((uint4*)wf)[i] = u;
}

__global__ __launch_bounds__(256) void repack_frag_l1_k(const float* __restrict__ w,
                                                        bf16* __restrict__ wf) {
    int i = blockIdx.x * 256 + threadIdx.x;
    if (i >= 256) return;
    int lane = i & 63, kb = i >> 6;
    int lg = lane >> 4, lr = lane & 15;
    unsigned e[8];
#pragma unroll
    for (int j = 0; j < 8; ++j) {
        int tap = kb * 8 + lg * 2 + (j >> 2);
        int ci = j & 3;
        e[j] = (tap < 27) ? f2b(w[(lr * 4 + ci) * 27 + tap]) : 0u;
    }
    uint4 u;
    u.x = e[0] | (e[1] << 16); u.y = e[2] | (e[3] << 16);
    u.z = e[4] | (e[5] << 16); u.w = e[6] | (e[7] << 16);
    ((uint4*)wf)[i] = u;
}

__global__ __launch_bounds__(256) void dilate_k(const uint8_t* __restrict__ in,
                                                uint8_t* __restrict__ out,
                                                int Zi, int Yi, int Xi,
                                                int Zo, int Yo, int Xo, int stride) {
    int idx = blockIdx.x * 256 + threadIdx.x;
    int total = Zo * Yo * Xo;
    if (idx >= total) return;
    int x = idx % Xo; int t = idx / Xo; int y = t % Yo; int z = t / Yo;
    int YX = Yi * Xi;
    uint8_t r = 0;
    for (int kz = 0; kz < 3; ++kz) {
        int zi = z * stride + kz - 1;
        if ((unsigned)zi >= (unsigned)Zi) continue;
        for (int ky = 0; ky < 3; ++ky) {
            int yi = y * stride + ky - 1;
            if ((unsigned)yi >= (unsigned)Yi) continue;
            for (int kx = 0; kx < 3; ++kx) {
                int xi = x * stride + kx - 1;
                if ((unsigned)xi >= (unsigned)Xi) continue;
                r |= in[zi * YX + yi * Xi + xi];
            }
        }
    }
    out[idx] = r ? 1 : 0;
}

__global__ __launch_bounds__(256) void dilate4_k(const uint8_t* __restrict__ in,
                                                 uint8_t* __restrict__ out,
                                                 int Z, int Y, int X) {
    int ngx = X >> 2;
    int g = blockIdx.x * 256 + threadIdx.x;
    int total = Z * Y * ngx;
    if (g >= total) return;
    int gx = g % ngx; int t = g / ngx; int y = t % Y; int z = t / Y;
    const int YX = Y * X;
    unsigned r = 0;
    for (int kz = 0; kz < 3; ++kz) {
        int zi = z + kz - 1;
        if ((unsigned)zi >= (unsigned)Z) continue;
        for (int ky = 0; ky < 3; ++ky) {
            int yi = y + ky - 1;
            if ((unsigned)yi >= (unsigned)Y) continue;
            const unsigned* rw = (const unsigned*)(in + zi * YX + yi * X);
            unsigned u1 = rw[gx];
            unsigned u0 = gx ? rw[gx - 1] : 0u;
            unsigned u2 = (gx + 1 < ngx) ? rw[gx + 1] : 0u;
            r |= u1 | ((u1 << 8) | (u0 >> 24)) | ((u1 >> 8) | (u2 << 24));
        }
    }
    r |= r >> 4; r |= r >> 2; r |= r >> 1; r &= 0x01010101u;
    ((unsigned*)out)[g] = r;
}

__global__ __launch_bounds__(256) void tdilate_k(const uint8_t* __restrict__ in,
                                                 uint8_t* __restrict__ out,
                                                 int Zi, int Yi, int Xi,
                                                 int Zo, int Yo, int Xo) {
    int idx = blockIdx.x * 256 + threadIdx.x;
    int total = Zo * Yo * Xo;
    if (idx >= total) return;
    int x = idx % Xo; int t = idx / Xo; int y = t % Yo; int z = t / Yo;
    int YX = Yi * Xi;
    uint8_t r = 0;
    for (int kz = 0; kz < 3; ++kz) {
        int tz = z + 1 - kz;
        if (tz & 1) continue;
        int zi = tz >> 1;
        if ((unsigned)zi >= (unsigned)Zi) continue;
        for (int ky = 0; ky < 3; ++ky) {
            int ty = y + 1 - ky;
            if (ty & 1) continue;
            int yi = ty >> 1;
            if ((unsigned)yi >= (unsigned)Yi) continue;
            for (int kx = 0; kx < 3; ++kx) {
                int tx = x + 1 - kx;
                if (tx & 1) continue;
                int xi = tx >> 1;
                if ((unsigned)xi >= (unsigned)Xi) continue;
                r |= in[zi * YX + yi * Xi + xi];
            }
        }
    }
    out[idx] = r ? 1 : 0;
}

__global__ __launch_bounds__(256) void tdilate4_k(const uint8_t* __restrict__ in,
                                                  uint8_t* __restrict__ out,
                                                  int Zi, int Yi, int Xi,
                                                  int Zo, int Yo, int Xo) {
    int ngx = Xo >> 2;
    int g = blockIdx.x * 256 + threadIdx.x;
    int total = Zo * Yo * ngx;
    if (g >= total) return;
    int gx = g % ngx; int t = g / ngx; int y = t % Yo; int z = t / Yo;
    int YX = Yi * Xi;
    int j0 = gx * 2;
    unsigned r0 = 0, r1 = 0, r2 = 0, r3 = 0;
    for (int kz = 0; kz < 3; ++kz) {
        int tz = z + 1 - kz;
        if (tz & 1) continue;
        int zi = tz >> 1;
        if ((unsigned)zi >= (unsigned)Zi) continue;
        for (int ky = 0; ky < 3; ++ky) {
            int ty = y + 1 - ky;
            if (ty & 1) continue;
            int yi = ty >> 1;
            if ((unsigned)yi >= (unsigned)Yi) continue;
            const uint8_t* rp = in + zi * YX + yi * Xi;
            unsigned b0 = (j0 < Xi) ? rp[j0] : 0u;
            unsigned b1 = (j0 + 1 < Xi) ? rp[j0 + 1] : 0u;
            unsigned b2 = (j0 + 2 < Xi) ? rp[j0 + 2] : 0u;
            r0 |= b0; r1 |= b0 | b1; r2 |= b1; r3 |= b1 | b2;
        }
    }
    unsigned rr = (r0 ? 1u : 0u) | (r1 ? 0x100u : 0u) | (r2 ? 0x10000u : 0u) | (r3 ? 0x1000000u : 0u);
    ((unsigned*)out)[g] = rr;
}

// ---- rolling-z pipelined conv 32->32 (L5b) with 32x32x16 MFMA ----
// 512 thr = 8 waves, wave = 1 y-row of 32 x-voxels, FULL cout per wave.
// B pinned in VGPRs (216). 5-slab LDS ring, slab stride padded to 24576 B so
// staging-tail lanes land in pad (glds dest = WAVE-UNIFORM base + lane*16).
// LDS layout: row*2176 + ks*1088 + swz(v)*32 + h*16, swz(v)=v^((v>>2)&3).
__global__ __launch_bounds__(512, 2) void conv_roll_k(
    const bf16* __restrict__ in, const bf16* __restrict__ wfrag,
    const float* __restrict__ scale, const float* __restrict__ shift,
    const uint8_t* __restrict__ mask, float* __restrict__ outf) {
    constexpr int ROWB = 2176;           // 34 voxels * 64B (2 ks halves of 1088)
    constexpr int SLABB = 24576;         // padded stride (1536 chunk slots; 1360 used)
    __shared__ uint4 ring4[5 * SLABB / 16];
    char* ring = (char*)ring4;

    const int bid = xcd_swz(blockIdx.x, gridDim.x);
    const int tx = bid & 7, ty = bid >> 3;       // nx = 8
    const int y0 = ty * 8, x0 = tx * 32;

    const int tid = threadIdx.x;
    const int w = tid >> 6, lane = tid & 63;
    const int vx = lane & 31, h = lane >> 5;
    const int yr = w;

    // per-lane SOURCE offsets for the 3 staged chunks (dest pad for i>=1360)
    int soff[3];
#pragma unroll
    for (int k = 0; k < 3; ++k) {
        int i = tid + k * 512;
        int ii = i < 1360 ? i : 0;               // clamp SOURCE only
        int row = ii / 136, L = ii - row * 136;
        int ks = L / 68, r2 = L - ks * 68, v = r2 >> 1, hh = r2 & 1;
        int vs = v ^ ((v >> 2) & 3);             // slot v holds voxel swz(v)
        soff[k] = ((y0 + row) * XP0 + (x0 + vs)) * 32 + (2 * ks + hh) * 8;
    }
    auto stagefn = [&](int p, char* slab) {
        int zs = p < ZP0 ? p : ZP0 - 1;
        const bf16* pb = in + (size_t)zs * ((size_t)YP0 * XP0 * 32);
        // wave-uniform LDS bases; HW adds lane*16
        glds16(pb + soff[0], slab + w * 1024);
        glds16(pb + soff[1], slab + w * 1024 + 8192);
        glds16(pb + soff[2], slab + w * 1024 + 16384);
    };

    // B: 27 taps x 2 k-steps x 16B, pinned resident (216 VGPR)
    const u32x4* gw = (const u32x4*)wfrag;
    u32x4 breg[27][2];
#pragma unroll
    for (int t = 0; t < 27; ++t) {
        breg[t][0] = gw[(t * 2 + 0) * 64 + lane];
        breg[t][1] = gw[(t * 2 + 1) * 64 + lane];
    }
#pragma unroll
    for (int t = 0; t < 27; ++t)
        asm volatile("" : "+v"(breg[t][0]), "+v"(breg[t][1]));

    // swizzled A read offsets per dx (ks=0 half; ks=1 adds +1088)
    int asw[3];
#pragma unroll
    for (int dx = 0; dx < 3; ++dx) {
        int v = vx + dx;
        asw[dx] = (v ^ ((v >> 2) & 3)) * 32 + h * 16;
    }

    const float sc = scale[vx], sh = shift[vx];

    stagefn(0, ring);
    stagefn(1, ring + SLABB);
    stagefn(2, ring + 2 * SLABB);
    stagefn(3, ring + 3 * SLABB);
    stagefn(4, ring + 4 * SLABB);
    asm volatile("s_waitcnt vmcnt(0)" ::: "memory");
    __builtin_amdgcn_s_barrier();

    int s0 = 0;
    for (int z = 0; z < Z0; ++z) {
        const int s1 = s0 + 1 < 5 ? s0 + 1 : 0;
        const int s2 = s1 + 1 < 5 ? s1 + 1 : 0;
        const char* sl0 = ring + s0 * SLABB;
        const char* sl1 = ring + s1 * SLABB;
        const char* sl2 = ring + s2 * SLABB;

        f32x16 acc;
#pragma unroll
        for (int i = 0; i < 16; ++i) acc[i] = 0.f;

#pragma unroll
        for (int dz = 0; dz < 3; ++dz) {
            const char* slab = dz == 0 ? sl0 : (dz == 1 ? sl1 : sl2);
#pragma unroll
            for (int dy = 0; dy < 3; ++dy) {
                const char* rowp = slab + (yr + dy) * ROWB;
#pragma unroll
                for (int dx = 0; dx < 3; ++dx) {
                    const int tap = dz * 9 + dy * 3 + dx;
                    u32x4 a0 = *(const u32x4*)(rowp + asw[dx]);
                    u32x4 a1 = *(const u32x4*)(rowp + 1088 + asw[dx]);
                    acc = __builtin_amdgcn_mfma_f32_32x32x16_bf16(
                        __builtin_bit_cast(s16x8, a0),
                        __builtin_bit_cast(s16x8, breg[tap][0]), acc, 0, 0, 0);
                    acc = __builtin_amdgcn_mfma_f32_32x32x16_bf16(
                        __builtin_bit_cast(s16x8, a1),
                        __builtin_bit_cast(s16x8, breg[tap][1]), acc, 0, 0, 0);
                }
            }
        }

        // masks loaded in-loop (stage from last iter already covered by compute)
        const uint8_t* mrow = mask + ((size_t)z * Y0 + (y0 + yr)) * X0 + x0 + 4 * h;
        unsigned mq0 = *(const unsigned*)(mrow);
        unsigned mq1 = *(const unsigned*)(mrow + 8);
        unsigned mq2 = *(const unsigned*)(mrow + 16);
        unsigned mq3 = *(const unsigned*)(mrow + 24);

        // stores: C row(voxel-x) = (reg&3) + 8*(reg>>2) + 4*h, col = cout = vx
        const size_t obase = (size_t)vx * NV0 + ((size_t)z * Y0 + (y0 + yr)) * X0 + x0 + 4 * h;
#pragma unroll
        for (int q = 0; q < 4; ++q) {
            unsigned mq = q == 0 ? mq0 : (q == 1 ? mq1 : (q == 2 ? mq2 : mq3));
            f32x4 o;
#pragma unroll
            for (int r = 0; r < 4; ++r) {
                float m = (float)((mq >> (8 * r)) & 1);
                o[r] = fmaxf(fmaf(acc[q * 4 + r], sc, sh), 0.f) * m;
            }
            *(f32x4*)(outf + obase + 8 * q) = o;
        }

        __builtin_amdgcn_s_barrier();     // all waves done reading slot s0
        stagefn(z + 5, ring + s0 * SLABB);
        asm volatile("s_waitcnt vmcnt(11)" ::: "memory");  // keep this iter's ops in flight
        s0 = s1;
    }
}

// ---- rolling-z pipelined transposed conv 32->32 (L5a) via parity octants ----
__global__ __launch_bounds__(256, 3) void tconv_roll_k(
    const bf16* __restrict__ in, const bf16* __restrict__ wfrag,
    const float* __restrict__ scale, const float* __restrict__ shift,
    const uint8_t* __restrict__ mask, bf16* __restrict__ out,
    int Zo, int Yo, int Xo, int Zi, int Ypi, int Xpi, int Ypo, int Xpo, int nx) {
    constexpr int ROWB = 34 * 64;
    constexpr int SLABB = 3 * ROWB;
    __shared__ uint4 ring4[4 * SLABB / 16];
    char* ring = (char*)ring4;

    const int oct = blockIdx.y;
    const int pz = oct >> 2, py = (oct >> 1) & 1, px = oct & 1;
    const int Zq = (Zo - pz + 1) >> 1;

    const int bid = xcd_swz(blockIdx.x, gridDim.x);
    const int tx = bid % nx, ty = bid / nx;
    const int yq0 = ty * 2, xq0 = tx * 32;

    const int tid = threadIdx.x;
    const int w = tid >> 6, lane = tid & 63;
    const int lg = lane >> 4, lr = lane & 15;
    const int yr = w >> 1, xh = w & 1;

    const int kz0 = pz ? 0 : 1, dzo0 = pz ? 1 : 0;
    const int ky0 = py ? 0 : 1, dyo0 = py ? 1 : 0;
    const int kx0 = px ? 0 : 1, dxo0 = px ? 1 : 0;

    auto stagefn = [&](int p, int slot) {
        if (w < 3) {
            int zs = p < Zi ? p : Zi - 1;
            char* slab = ring + slot * SLABB + w * ROWB;
            const bf16* pb = in + ((size_t)(zs + 1) * Ypi + (yq0 + 1 + w)) * (size_t)Xpi * 32
                                + (size_t)(xq0 + 1) * 32;
            int u0 = lane;      glds16(pb + (u0 ^ ((u0 >> 3) & 7)) * 8, slab);
            int u1 = 64 + lane; glds16(pb + (u1 ^ ((u1 >> 3) & 7)) * 8, slab + 1024);
            if (lane < 8) { int u2 = 128 + lane; glds16(pb + u2 * 8, slab + 2048); }
        }
    };

    const uint4* gw = (const uint4*)wfrag;
    uint4 breg[2][2][2][2];
#pragma unroll
    for (int iz = 0; iz < 2; ++iz) {
        int kz = iz ? 2 : kz0;
#pragma unroll
        for (int iy = 0; iy < 2; ++iy) {
            int ky = iy ? 2 : ky0;
#pragma unroll
            for (int ix = 0; ix < 2; ++ix) {
                int kx = ix ? 2 : kx0;
                int tap = kz * 9 + ky * 3 + kx;
                breg[iz][iy][ix][0] = gw[(tap * 2 + 0) * 64 + lane];
                breg[iz][iy][ix][1] = gw[(tap * 2 + 1) * 64 + lane];
            }
        }
    }

    int b0 = (xh * 16 + lr + dxo0) * 64 + lg * 16;
    int b1 = (xh * 16 + lr) * 64 + lg * 16;
    const int aswA = b0 ^ (((b0 >> 7) & 7) << 4);
    const int aswB = b1 ^ (((b1 >> 7) & 7) << 4);
    const int rowA = (yr + dyo0) * ROWB;
    const int rowB = yr * ROWB;

    const float sc0 = scale[lr], sh0 = shift[lr];
    const float sc1 = scale[16 + lr], sh1 = shift[16 + lr];

    const int yout = 2 * (yq0 + yr) + py;
    const int xb = 2 * (xq0 + xh * 16 + lg * 4) + px;

    stagefn(0, 0); stagefn(1, 1); stagefn(2, 2);
    uint2 mv;
    mv = *(const uint2*)(mask + ((size_t)pz * Yo + yout) * Xo + (xb - px));
    asm volatile("s_waitcnt vmcnt(0)" ::: "memory");
    __builtin_amdgcn_s_barrier();

    int rs0 = 0, wslot = 3;
    for (int zq = 0; zq < Zq; ++zq) {
        uint2 nv;
        {
            int zqn = (zq + 1 < Zq) ? zq + 1 : Zq - 1;
            nv = *(const uint2*)(mask + ((size_t)(2 * zqn + pz) * Yo + yout) * Xo + (xb - px));
        }
        stagefn(zq + 3, wslot);

        int rs1 = rs0 + 1 < 4 ? rs0 + 1 : 0;
        const char* sl_0 = ring + rs0 * SLABB;
        const char* sl_1 = ring + rs1 * SLABB;
        const char* slz0 = pz ? sl_1 : sl_0;
        const char* slz1 = sl_0;

        f32x4 acc0 = (f32x4){0, 0, 0, 0}, acc1 = (f32x4){0, 0, 0, 0};
#pragma unroll
        for (int iz = 0; iz < 2; ++iz) {
            if (iz > pz) continue;
            const char* slab = iz ? slz1 : slz0;
#pragma unroll
            for (int iy = 0; iy < 2; ++iy) {
                if (iy > py) continue;
                const char* rowp = slab + (iy ? rowB : rowA);
#pragma unroll
                for (int ix = 0; ix < 2; ++ix) {
                    if (ix > px) continue;
                    uint4 a = *(const uint4*)(rowp + (ix ? aswB : aswA));
                    acc0 = __builtin_amdgcn_mfma_f32_16x16x32_bf16(
                        __builtin_bit_cast(s16x8, a),
                        __builtin_bit_cast(s16x8, breg[iz][iy][ix][0]), acc0, 0, 0, 0);
                    acc1 = __builtin_amdgcn_mfma_f32_16x16x32_bf16(
                        __builtin_bit_cast(s16x8, a),
                        __builtin_bit_cast(s16x8, breg[iz][iy][ix][1]), acc1, 0, 0, 0);
                }
            }
        }

        const int zout = 2 * zq + pz;
        const size_t opdbase = ((size_t)(zout + 1) * Ypo + (yout + 1)) * Xpo;
#pragma unroll
        for (int r = 0; r < 4; ++r) {
            unsigned word = (r < 2) ? mv.x : mv.y;
            float m = (float)((word >> (px * 8 + (r & 1) * 16)) & 1);
            float v0 = fmaxf(fmaf(acc0[r], sc0, sh0), 0.f) * m;
            float v1 = fmaxf(fmaf(acc1[r], sc1, sh1), 0.f) * m;
            size_t opd = opdbase + (size_t)(xb + 2 * r + 1);
            out[opd * 32 + lr]      = __float2bfloat16(v0);
            out[opd * 32 + 16 + lr] = __float2bfloat16(v1);
        }

        asm volatile("s_waitcnt vmcnt(20)" ::: "memory");
        __builtin_amdgcn_s_barrier();
        rs0 = rs1;
        wslot = wslot + 1 < 4 ? wslot + 1 : 0;
        mv = nv;
    }
}

// LDS-tiled MFMA stride-1 conv, CIN=COUT=32 (L2b, L4b)
template <bool FINAL>
__global__ __launch_bounds__(512, 4) void conv_lds_k(
    const bf16* __restrict__ in, const bf16* __restrict__ wfrag,
    const float* __restrict__ scale, const float* __restrict__ shift,
    const uint8_t* __restrict__ mask, bf16* __restrict__ out, float* __restrict__ outf,
    int Zo, int Yo, int Xo, int Ypi, int Xpi, int Ypo, int Xpo, int nx, int ny) {
    constexpr int ROWB = 34 * 64;
    __shared__ uint4 tile4[36 * ROWB / 16];
    char* tile = (char*)tile4;

    const int No = Zo * Yo * Xo;
    const int bid = xcd_swz(blockIdx.x, gridDim.x);
    int tx = bid % nx; int tt = bid / nx; int ty = tt % ny; int tz = tt / ny;
    const int z0 = tz * 4, y0 = ty * 4, x0 = tx * 32;

    const int tid = threadIdx.x;
    const int w = tid >> 6, lane = tid & 63, lg = lane >> 4, lr = lane & 15;

    int anywork;
    {
        int row = tid >> 5, xl = tid & 31;
        int zz = z0 + (row >> 2), yy = y0 + (row & 3), xx = x0 + xl;
        int ok = (zz < Zo) && (yy < Yo) && (xx < Xo) && mask[((size_t)zz * Yo + yy) * Xo + xx];
        anywork = __syncthreads_or(ok);
    }

    f32x4 acc[4][2];
#pragma unroll
    for (int s = 0; s < 4; ++s) { acc[s][0] = (f32x4){0,0,0,0}; acc[s][1] = (f32x4){0,0,0,0}; }

    if (anywork) {
        const int lsw = (lane ^ ((lane >> 3) & 7)) * 8;
        for (int rr = w; rr < 36; rr += 8) {
            int dz = rr / 6, dy = rr % 6;
            const bf16* g = in + ((size_t)(z0 + dz) * Ypi + (y0 + dy)) * Xpi * 32 + (size_t)x0 * 32;
            char* l = tile + rr * ROWB;
            glds16(g + lsw, l);
            glds16(g + 512 + lsw, l + 1024);
            if (lane < 8) glds16(g + 1024 + lane * 8, l + 2048);
        }
        asm volatile("s_waitcnt vmcnt(0)" ::: "memory");
        __syncthreads();

        int rbB[4], bsw[4][3];
#pragma unroll
        for (int s = 0; s < 4; ++s) {
            int lrow = 2 * w + (s >> 1);
            rbB[s] = ((lrow >> 2) * 6 + (lrow & 3)) * ROWB;
            int xpart = (s & 1) * 16 + lr;
#pragma unroll
            for (int dx = 0; dx < 3; ++dx) {
                int b = (xpart + dx) * 64 + lg * 16;
                bsw[s][dx] = b ^ (((b >> 7) & 7) << 4);
            }
        }

        const uint4* gw = (const uint4*)wfrag;
#pragma unroll 1
        for (int dz = 0; dz < 3; ++dz) {
#pragma unroll
            for (int dy = 0; dy < 3; ++dy) {
                const int rowoff = (dz * 6 + dy) * ROWB;
#pragma unroll
                for (int dx = 0; dx < 3; ++dx) {
                    const int tap = dz * 9 + dy * 3 + dx;
                    uint4 b0 = gw[(tap * 2 + 0) * 64 + lane];
                    uint4 b1 = gw[(tap * 2 + 1) * 64 + lane];
                    uint4 ua[4];
#pragma unroll
                    for (int s = 0; s < 4; ++s)
                        ua[s] = *(const uint4*)(tile + rbB[s] + rowoff + bsw[s][dx]);
#pragma unroll
                    for (int s = 0; s < 4; ++s) {
                        acc[s][0] = __builtin_amdgcn_mfma_f32_16x16x32_bf16(
                            __builtin_bit_cast(s16x8, ua[s]),
                            __builtin_bit_cast(s16x8, b0), acc[s][0], 0, 0, 0);
                        acc[s][1] = __builtin_amdgcn_mfma_f32_16x16x32_bf16(
                            __builtin_bit_cast(s16x8, ua[s]),
                            __builtin_bit_cast(s16x8, b1), acc[s][1], 0, 0, 0);
                    }
                }
            }
        }
    }

#pragma unroll
    for (int s = 0; s < 4; ++s) {
        int lrow = 2 * w + (s >> 1);
        int zz = z0 + (lrow >> 2), yy = y0 + (lrow & 3);
        int xv = x0 + (s & 1) * 16 + lg * 4;
        bool rowok = (zz < Zo) && (yy < Yo);
        if (!rowok) continue;
        size_t idx0 = ((size_t)zz * Yo + yy) * Xo + xv;
        float mm[4];
#pragma unroll
        for (int r = 0; r < 4; ++r)
            mm[r] = (xv + r < Xo && mask[idx0 + r]) ? 1.f : 0.f;
        if constexpr (FINAL) {
#pragma unroll
            for (int nt = 0; nt < 2; ++nt) {
                int co = nt * 16 + lr;
                float sc = scale[co], sh = shift[co];
                f32x4 o;
#pragma unroll
                for (int r = 0; r < 4; ++r)
                    o[r] = fmaxf(fmaf(acc[s][nt][r], sc, sh), 0.f) * mm[r];
                if (xv + 3 < Xo) {
                    *(f32x4*)(outf + (size_t)co * No + idx0) = o;
                } else {
#pragma unroll
                    for (int r = 0; r < 4; ++r)
                        if (xv + r < Xo) outf[(size_t)co * No + idx0 + r] = o[r];
                }
            }
        } else {
            int opd = ((zz + 1) * Ypo + (yy + 1)) * Xpo + (xv + 1);
#pragma unroll
            for (int nt = 0; nt < 2; ++nt) {
                int co = nt * 16 + lr;
                float sc = scale[co], sh = shift[co];
#pragma unroll
                for (int r = 0; r < 4; ++r) {
                    if (xv + r >= Xo) continue;
                    float yv = fmaxf(fmaf(acc[s][nt][r], sc, sh), 0.f) * mm[r];
                    out[(size_t)(opd + r) * 32 + co] = __float2bfloat16(yv);
                }
            }
        }
    }
}

// global-load MFMA conv, generic stride & block size (L3a, L3b)
template <int CIN, int COUT, int STRIDE, int BLK, bool FINAL>
__global__ __launch_bounds__(BLK, ((CIN <= 32 && COUT <= 32) ? 4 : 2)) void conv_mfma_k(
    const bf16* __restrict__ in, const bf16* __restrict__ wfrag,
    const float* __restrict__ scale, const float* __restrict__ shift,
    const uint8_t* __restrict__ mask, bf16* __restrict__ out, float* __restrict__ outf,
    int Zo, int Yo, int Xo, int Ypi, int Xpi, int Ypo, int Xpo) {
    constexpr int NT = COUT / 16;
    constexpr int KT = CIN / 32;
    const int No = Zo * Yo * Xo;
    const int bid = xcd_swz(blockIdx.x, gridDim.x);
    const int tid = threadIdx.x;
    const int wv = tid >> 6, lane = tid & 63;
    const int lg = lane >> 4, lr = lane & 15;
    const int v0 = bid * BLK + wv * 64;
    if (v0 >= No) return;

    int vm = v0 + lane;
    bool mw = (vm < No) && (mask[vm] != 0);
    const bool anywork = (__ballot(mw) != 0ull);

    f32x4 acc[4][NT];
#pragma unroll
    for (int s = 0; s < 4; ++s)
#pragma unroll
        for (int nt = 0; nt < NT; ++nt) acc[s][nt] = (f32x4){0.f, 0.f, 0.f, 0.f};

    const uint4* gw = (const uint4*)wfrag;

    if (anywork) {
        int pA[4];
#pragma unroll
        for (int s = 0; s < 4; ++s) {
            int vr = v0 + s * 16 + lr;
            if (vr >= No) vr = 0;
            int zz = vr / (Yo * Xo); int rr = vr - zz * (Yo * Xo);
            int yy = rr / Xo; int xx = rr - yy * Xo;
            pA[s] = (((zz * STRIDE + 1) * Ypi + (yy * STRIDE + 1)) * Xpi + (xx * STRIDE + 1)) * CIN + lg * 8;
        }
#pragma unroll
        for (int tap = 0; tap < 27; ++tap) {
            const int kz = tap / 9, r9 = tap - kz * 9, ky = r9 / 3, kx = r9 - ky * 3;
            const int toff = (((kz - 1) * Ypi + (ky - 1)) * Xpi + (kx - 1)) * CIN;
            uint4 ub[NT][KT];
#pragma unroll
            for (int nt = 0; nt < NT; ++nt)
#pragma unroll
                for (int kt = 0; kt < KT; ++kt)
                    ub[nt][kt] = gw[((tap * NT + nt) * KT + kt) * 64 + lane];
            uint4 ua[4][KT];
#pragma unroll
            for (int s = 0; s < 4; ++s)
#pragma unroll
                for (int kt = 0; kt < KT; ++kt)
                    ua[s][kt] = *(const uint4*)(in + pA[s] + toff + kt * 32);
#pragma unroll
            for (int s = 0; s < 4; ++s)
#pragma unroll
                for (int kt = 0; kt < KT; ++kt)
#pragma unroll
                    for (int nt = 0; nt < NT; ++nt)
                        acc[s][nt] = __builtin_amdgcn_mfma_f32_16x16x32_bf16(
                            __builtin_bit_cast(s16x8, ua[s][kt]),
                            __builtin_bit_cast(s16x8, ub[nt][kt]), acc[s][nt], 0, 0, 0);
        }
    }

#pragma unroll
    for (int s = 0; s < 4; ++s) {
        const int vb = v0 + s * 16 + lg * 4;
        int opd[4]; float mm[4]; bool ok[4];
#pragma unroll
        for (int r = 0; r < 4; ++r) {
            int v = vb + r;
            ok[r] = v < No;
            int vc = ok[r] ? v : 0;
            mm[r] = (ok[r] && mask[vc]) ? 1.f : 0.f;
            int zz = vc / (Yo * Xo); int rr = vc - zz * (Yo * Xo);
            int yy = rr / Xo; int xx = rr - yy * Xo;
            opd[r] = FINAL ? vc : ((zz + 1) * Ypo + (yy + 1)) * Xpo + (xx + 1);
        }
#pragma unroll
        for (int nt = 0; nt < NT; ++nt) {
            int co = nt * 16 + lr;
            float sc = scale[co], sh = shift[co];
#pragma unroll
            for (int r = 0; r < 4; ++r) {
                if (!ok[r]) continue;
                float yv = fmaxf(fmaf(acc[s][nt][r], sc, sh), 0.f) * mm[r];
                if constexpr (FINAL) outf[(size_t)co * No + opd[r]] = yv;
                else out[(size_t)opd[r] * COUT + co] = __float2bfloat16(yv);
            }
        }
    }
}

// stride-2 CIN=16 MFMA conv (L2a)
__global__ __launch_bounds__(256, 4) void conv_s2c16_k(
    const bf16* __restrict__ in, const bf16* __restrict__ wfrag,
    const float* __restrict__ scale, const float* __restrict__ shift,
    const uint8_t* __restrict__ mask, bf16* __restrict__ out,
    int Zo, int Yo, int Xo, int Ypi, int Xpi, int Ypo, int Xpo) {
    const int No = Zo * Yo * Xo;
    const int bid = xcd_swz(blockIdx.x, gridDim.x);
    const int tid = threadIdx.x;
    const int wv = tid >> 6, lane = tid & 63;
    const int lg = lane >> 4, lr = lane & 15;
    const int v0 = bid * 256 + wv * 64;
    if (v0 >= No) return;

    int vm = v0 + lane;
    bool mw = (vm < No) && (mask[vm] != 0);
    const bool anywork = (__ballot(mw) != 0ull);

    f32x4 acc[4][2];
#pragma unroll
    for (int s = 0; s < 4; ++s) { acc[s][0] = (f32x4){0,0,0,0}; acc[s][1] = (f32x4){0,0,0,0}; }

    if (anywork) {
        const uint4* gw = (const uint4*)wfrag;
        const int choff = (lg & 1) * 8;
        const int tb = lg >> 1;
        int toffl[14];
#pragma unroll
        for (int p = 0; p < 14; ++p) {
            int tp = 2 * p + tb;
            if (tp >= 27) tp = 0;
            int kz = tp / 9, r9 = tp - kz * 9, ky = r9 / 3, kx = r9 - ky * 3;
            toffl[p] = ((kz * Ypi + ky) * Xpi + kx) * 16;
        }
        int pA[4];
#pragma unroll
        for (int s = 0; s < 4; ++s) {
            int vr = v0 + s * 16 + lr;
            if (vr >= No) vr = 0;
            int zz = vr / (Yo * Xo); int rr = vr - zz * (Yo * Xo);
            int yy = rr / Xo; int xx = rr - yy * Xo;
            pA[s] = (((zz * 2) * Ypi + (yy * 2)) * Xpi + (xx * 2)) * 16 + choff;
        }
#pragma unroll
        for (int p = 0; p < 14; ++p) {
            uint4 b0 = gw[(p * 2 + 0) * 64 + lane];
            uint4 b1 = gw[(p * 2 + 1) * 64 + lane];
            uint4 ua[4];
#pragma unroll
            for (int s = 0; s < 4; ++s)
                ua[s] = *(const uint4*)(in + pA[s] + toffl[p]);
#pragma unroll
            for (int s = 0; s < 4; ++s) {
                acc[s][0] = __builtin_amdgcn_mfma_f32_16x16x32_bf16(
                    __builtin_bit_cast(s16x8, ua[s]),
                    __builtin_bit_cast(s16x8, b0), acc[s][0], 0, 0, 0);
                acc[s][1] = __builtin_amdgcn_mfma_f32_16x16x32_bf16(
                    __builtin_bit_cast(s16x8, ua[s]),
                    __builtin_bit_cast(s16x8, b1), acc[s][1], 0, 0, 0);
            }
        }
    }

#pragma unroll
    for (int s = 0; s < 4; ++s) {
        const int vb = v0 + s * 16 + lg * 4;
        int opd[4]; float mm[4]; bool ok[4];
#pragma unroll
        for (int r = 0; r < 4; ++r) {
            int v = vb + r;
            ok[r] = v < No;
            int vc = ok[r] ? v : 0;
            mm[r] = (ok[r] && mask[vc]) ? 1.f : 0.f;
            int zz = vc / (Yo * Xo); int rr = vc - zz * (Yo * Xo);
            int yy = rr / Xo; int xx = rr - yy * Xo;
            opd[r] = ((zz + 1) * Ypo + (yy + 1)) * Xpo + (xx + 1);
        }
#pragma unroll
        for (int nt = 0; nt < 2; ++nt) {
            int co = nt * 16 + lr;
            float sc = scale[co], sh = shift[co];
#pragma unroll
            for (int r = 0; r < 4; ++r) {
                if (!ok[r]) continue;
                float yv = fmaxf(fmaf(acc[s][nt][r], sc, sh), 0.f) * mm[r];
                out[(size_t)opd[r] * 32 + co] = __float2bfloat16(yv);
            }
        }
    }
}

// MFMA transposed conv (stride 2) via parity octants (L4a)
template <int CIN, int COUT>
__global__ __launch_bounds__(256, 4) void tconv_mfma_k(
    const bf16* __restrict__ in, const bf16* __restrict__ wfrag,
    const float* __restrict__ scale, const float* __restrict__ shift,
    const uint8_t* __restrict__ mask, bf16* __restrict__ out,
    int Zo, int Yo, int Xo, int Ypi, int Xpi, int Ypo, int Xpo) {
    constexpr int NT = COUT / 16;
    constexpr int KT = CIN / 32;
    const int oct = blockIdx.y;
    const int pz = oct >> 2, py = (oct >> 1) & 1, px = oct & 1;
    const int Zq = (Zo - pz + 1) >> 1, Yq = (Yo - py + 1) >> 1, Xq = (Xo - px + 1) >> 1;
    const int Nq = Zq * Yq * Xq;
    const int YXq = Yq * Xq;
    const int bid = xcd_swz(blockIdx.x, gridDim.x);
    const int tid = threadIdx.x;
    const int wv = tid >> 6, lane = tid & 63;
    const int lg = lane >> 4, lr = lane & 15;
    const int v0 = bid * 256 + wv * 64;
    if (v0 >= Nq) return;

    bool mw = false;
    {
        int q = v0 + lane;
        if (q < Nq) {
            int zq = q / YXq; int rr = q - zq * YXq; int yq = rr / Xq; int xq = rr - yq * Xq;
            int zz = 2 * zq + pz, yy = 2 * yq + py, xx = 2 * xq + px;
            mw = mask[(zz * Yo + yy) * Xo + xx] != 0;
        }
    }
    const bool anywork = (__ballot(mw) != 0ull);

    f32x4 acc[4][NT];
#pragma unroll
    for (int s = 0; s < 4; ++s)
#pragma unroll
        for (int nt = 0; nt < NT; ++nt) acc[s][nt] = (f32x4){0.f, 0.f, 0.f, 0.f};

    const uint4* gw = (const uint4*)wfrag;

    if (anywork) {
        int pA[4];
#pragma unroll
        for (int s = 0; s < 4; ++s) {
            int q = v0 + s * 16 + lr;
            if (q >= Nq) q = 0;
            int zq = q / YXq; int rr = q - zq * YXq; int yq = rr / Xq; int xq = rr - yq * Xq;
            pA[s] = (((zq + 1) * Ypi + (yq + 1)) * Xpi + (xq + 1)) * CIN + lg * 8;
        }
        const int nkz = 1 + pz, nky = 1 + py, nkx = 1 + px;
        for (int iz = 0; iz < nkz; ++iz) {
            const int kz = pz ? (iz ? 2 : 0) : 1;
            const int dz = (pz && !iz) ? 1 : 0;
            for (int iy = 0; iy < nky; ++iy) {
                const int ky = py ? (iy ? 2 : 0) : 1;
                const int dy = (py && !iy) ? 1 : 0;
                for (int ix = 0; ix < nkx; ++ix) {
                    const int kx = px ? (ix ? 2 : 0) : 1;
                    const int dx = (px && !ix) ? 1 : 0;
                    const int tap = kz * 9 + ky * 3 + kx;
                    const int toff = ((dz * Ypi + dy) * Xpi + dx) * CIN;
                    uint4 ub[NT][KT];
#pragma unroll
                    for (int nt = 0; nt < NT; ++nt)
#pragma unroll
                        for (int kt = 0; kt < KT; ++kt)
                            ub[nt][kt] = gw[((tap * NT + nt) * KT + kt) * 64 + lane];
                    uint4 ua[4][KT];
#pragma unroll
                    for (int s = 0; s < 4; ++s)
#pragma unroll
                        for (int kt = 0; kt < KT; ++kt)
                            ua[s][kt] = *(const uint4*)(in + pA[s] + toff + kt * 32);
#pragma unroll
                    for (int s = 0; s < 4; ++s)
#pragma unroll
                        for (int kt = 0; kt < KT; ++kt)
#pragma unroll
                            for (int nt = 0; nt < NT; ++nt)
                                acc[s][nt] = __builtin_amdgcn_mfma_f32_16x16x32_bf16(
                                    __builtin_bit_cast(s16x8, ua[s][kt]),
                                    __builtin_bit_cast(s16x8, ub[nt][kt]), acc[s][nt], 0, 0, 0);
                }
            }
        }
    }

#pragma unroll
    for (int s = 0; s < 4; ++s) {
        const int vb = v0 + s * 16 + lg * 4;
        int opd[4]; float mm[4]; bool ok[4];
#pragma unroll
        for (int r = 0; r < 4; ++r) {
            int q = vb + r;
            ok[r] = q < Nq;
            int qc = ok[r] ? q : 0;
            int zq = qc / YXq; int rr = qc - zq * YXq; int yq = rr / Xq; int xq = rr - yq * Xq;
            int zz = 2 * zq + pz, yy = 2 * yq + py, xx = 2 * xq + px;
            mm[r] = (ok[r] && mask[(zz * Yo + yy) * Xo + xx]) ? 1.f : 0.f;
            opd[r] = ((zz + 1) * Ypo + (yy + 1)) * Xpo + (xx + 1);
        }
#pragma unroll
        for (int nt = 0; nt < NT; ++nt) {
            int co = nt * 16 + lr;
            float sc = scale[co], sh = shift[co];
#pragma unroll
            for (int r = 0; r < 4; ++r) {
                if (!ok[r]) continue;
                float yv = fmaxf(fmaf(acc[s][nt][r], sc, sh), 0.f) * mm[r];
                out[(size_t)opd[r] * COUT + co] = __float2bfloat16(yv);
            }
        }
    }
}

__global__ __launch_bounds__(256, 4) void conv_l1_mfma_k(
    const bf16* __restrict__ in, const bf16* __restrict__ wfrag,
    const float* __restrict__ scale, const float* __restrict__ shift,
    const uint8_t* __restrict__ mask, bf16* __restrict__ out,
    int Zo, int Yo, int Xo, int Ypi, int Xpi, int Ypo, int Xpo) {
    const int No = Zo * Yo * Xo;
    const int bid = xcd_swz(blockIdx.x, gridDim.x);
    const int tid = threadIdx.x;
    const int wv = tid >> 6, lane = tid & 63;
    const int lg = lane >> 4, lr = lane & 15;
    const int v0 = bid * 256 + wv * 64;
    if (v0 >= No) return;

    int vm = v0 + lane;
    bool mw = (vm < No) && (mask[vm] != 0);
    const bool anywork = (__ballot(mw) != 0ull);

    f32x4 acc[4];
#pragma unroll
    for (int s = 0; s < 4; ++s) acc[s] = (f32x4){0.f, 0.f, 0.f, 0.f};

    if (anywork) {
        const uint4* gw = (const uint4*)wfrag;
        uint4 bu[4];
#pragma unroll
        for (int kb = 0; kb < 4; ++kb) bu[kb] = gw[kb * 64 + lane];

        int vtf[4][2];
#pragma unroll
        for (int kb = 0; kb < 4; ++kb)
#pragma unroll
            for (int u = 0; u < 2; ++u) {
                int tp = kb * 8 + lg * 2 + u;
                int kz = tp / 9, r9 = tp - kz * 9, ky = r9 / 3, kx = r9 - ky * 3;
                vtf[kb][u] = (tp < 27) ? (((kz - 1) * Ypi + (ky - 1)) * Xpi + (kx - 1)) : 0;
            }

        int pV[4];
#pragma unroll
        for (int s = 0; s < 4; ++s) {
            int vr = v0 + s * 16 + lr;
            if (vr >= No) vr = 0;
            int zz = vr / (Yo * Xo); int rr = vr - zz * (Yo * Xo);
            int yy = rr / Xo; int xx = rr - yy * Xo;
            pV[s] = ((zz + 1) * Ypi + (yy + 1)) * Xpi + (xx + 1);
        }

#pragma unroll
        for (int kb = 0; kb < 4; ++kb) {
#pragma unroll
            for (int s = 0; s < 4; ++s) {
                uint2 a0 = *(const uint2*)(in + (size_t)(pV[s] + vtf[kb][0]) * 4);
                uint2 a1 = *(const uint2*)(in + (size_t)(pV[s] + vtf[kb][1]) * 4);
                int4 ai; ai.x = a0.x; ai.y = a0.y; ai.z = a1.x; ai.w = a1.y;
                acc[s] = __builtin_amdgcn_mfma_f32_16x16x32_bf16(
                    __builtin_bit_cast(s16x8, ai),
                    __builtin_bit_cast(s16x8, bu[kb]), acc[s], 0, 0, 0);
            }
        }
    }

#pragma unroll
    for (int s = 0; s < 4; ++s) {
        const int vb = v0 + s * 16 + lg * 4;
        int co = lr;
        float sc = scale[co], sh = shift[co];
#pragma unroll
        for (int r = 0; r < 4; ++r) {
            int v = vb + r;
            if (v >= No) continue;
            float mm = mask[v] ? 1.f : 0.f;
            int zz = v / (Yo * Xo); int rr = v - zz * (Yo * Xo);
            int yy = rr / Xo; int xx = rr - yy * Xo;
            int opd = ((zz + 1) * Ypo + (yy + 1)) * Xpo + (xx + 1);
            float yv = fmaxf(fmaf(acc[s][r], sc, sh), 0.f) * mm;
            out[(size_t)opd * 16 + co] = __float2bfloat16(yv);
        }
    }
}

inline int nblk(int n) { return (n + 255) / 256; }
inline int cdiv(int a, int b) { return (a + b - 1) / b; }

}  // namespace

extern "C" void kernel_launch(void* const* d_in, const int* in_sizes, int n_in,
                              void* d_out, int out_size, void* d_ws, size_t ws_size,
                              hipStream_t stream) {
    const float* feats = (const float*)d_in[0];
    const int* coords = (const int*)d_in[1];
    const int NVOX = in_sizes[0] / 4;

    const float *w1 = (const float*)d_in[3], *s1 = (const float*)d_in[4], *b1 = (const float*)d_in[5];
    const float *w2a = (const float*)d_in[6], *s2a = (const float*)d_in[7], *b2a = (const float*)d_in[8];
    const float *w2b = (const float*)d_in[9], *s2b = (const float*)d_in[10], *b2b = (const float*)d_in[11];
    const float *w3a = (const float*)d_in[12], *s3a = (const float*)d_in[13], *b3a = (const float*)d_in[14];
    const float *w3b = (const float*)d_in[15], *s3b = (const float*)d_in[16], *b3b = (const float*)d_in[17];
    const float *w4a = (const float*)d_in[18], *s4a = (const float*)d_in[19], *b4a = (const float*)d_in[20];
    const float *w4b = (const float*)d_in[21], *s4b = (const float*)d_in[22], *b4b = (const float*)d_in[23];
    const float *w5a = (const float*)d_in[24], *s5a = (const float*)d_in[25], *b5a = (const float*)d_in[26];
    const float *w5b = (const float*)d_in[27], *s5b = (const float*)d_in[28], *b5b = (const float*)d_in[29];

    char* ws = (char*)d_ws;
    size_t off = 0;
    auto alloc = [&](size_t bytes) -> void* {
        void* p = ws + off;
        off = (off + bytes + 255) & ~(size_t)255;
        return p;
    };

    uint8_t* m0 = (uint8_t*)alloc(NV0);
    uint8_t* m1 = (uint8_t*)alloc(NV0);
    uint8_t* m2 = (uint8_t*)alloc(NV2);
    uint8_t* m3 = (uint8_t*)alloc(NV3);
    uint8_t* m4 = (uint8_t*)alloc(NV4);
    uint8_t* m5 = (uint8_t*)alloc(NV0);

    bf16* slot0 = (bf16*)alloc((size_t)NP0 * 32 * 2);
    bf16* slot1 = (bf16*)alloc((size_t)NP0 * 16 * 2);

    bf16* dense0 = slot0;  // 4ch  @P0
    bf16* x1     = slot1;  // 16ch @P0
    bf16* x2a    = slot0;  // 32ch @P2
    bf16* x2b    = slot1;  // 32ch @P2
    bf16* x3a    = slot0;  // 64ch @P3
    bf16* x3b    = slot1;  // 64ch @P3
    bf16* x4a    = slot0;  // 32ch @P4
    bf16* x4b    = slot1;  // 32ch @(23,130,130)
    bf16* x5a    = slot0;  // 32ch @P0

    bf16* wfL1 = (bf16*)alloc(4 * 64 * 8 * 2);
    bf16* wf2a = (bf16*)alloc((size_t)14 * 2 * 64 * 16);
    bf16* wf2b = (bf16*)alloc((size_t)27 * 2 * 1 * 64 * 16);
    bf16* wf3a = (bf16*)alloc((size_t)27 * 4 * 1 * 64 * 16);
    bf16* wf3b = (bf16*)alloc((size_t)27 * 4 * 2 * 64 * 16);
    bf16* wf4a = (bf16*)alloc((size_t)27 * 2 * 2 * 64 * 16);
    bf16* wf4b = (bf16*)alloc((size_t)27 * 2 * 1 * 64 * 16);
    bf16* wf5a = (bf16*)alloc((size_t)27 * 2 * 1 * 64 * 16);
    bf16* wf5b32 = (bf16*)alloc((size_t)27 * 2 * 64 * 16);   // 32x32 frag order
    alloc(20u << 20);

    if (off > ws_size) {
        sentinel_k<<<1, 256, 0, stream>>>((float*)d_out);
        return;
    }

    // stage 0
    hipMemsetAsync(dense0, 0, (size_t)NP0 * 4 * 2, stream);
    hipMemsetAsync(m0, 0, NV0, stream);
    repack_frag_l1_k<<<1, 256, 0, stream>>>(w1, wfL1);
    repack_frag_c16_k<<<nblk(14 * 2 * 64), 256, 0, stream>>>(w2a, wf2a);
    repack_frag_k<<<nblk(27 * 2 * 64), 256, 0, stream>>>(w2b, wf2b, 32, 32, 0);
    repack_frag_k<<<nblk(27 * 4 * 64), 256, 0, stream>>>(w3a, wf3a, 32, 64, 0);
    repack_frag_k<<<nblk(27 * 8 * 64), 256, 0, stream>>>(w3b, wf3b, 64, 64, 0);
    repack_frag_k<<<nblk(27 * 4 * 64), 256, 0, stream>>>(w4a, wf4a, 64, 32, 1);
    repack_frag_k<<<nblk(27 * 2 * 64), 256, 0, stream>>>(w4b, wf4b, 32, 32, 0);
    repack_frag_k<<<nblk(27 * 2 * 64), 256, 0, stream>>>(w5a, wf5a, 32, 32, 1);
    repack_frag32_k<<<nblk(27 * 2 * 64), 256, 0, stream>>>(w5b, wf5b32);

    scatter_k<<<nblk(NVOX), 256, 0, stream>>>(feats, coords, dense0, m0, NVOX);

    // level 1
    dilate4_k<<<nblk(NV0 / 4), 256, 0, stream>>>(m0, m1, Z0, Y0, X0);
    halo_zero_k<16><<<nblk(NP0), 256, 0, stream>>>(x1, Z0, Y0, X0, ZP0, YP0, XP0);
    conv_l1_mfma_k<<<nblk(NV0), 256, 0, stream>>>(
        dense0, wfL1, s1, b1, m1, x1, Z0, Y0, X0, YP0, XP0, YP0, XP0);

    // level 2
    dilate_k<<<nblk(NV2), 256, 0, stream>>>(m1, m2, Z0, Y0, X0, Z2, Y2, X2, 2);
    halo_zero_k<32><<<nblk(NP2), 256, 0, stream>>>(x2a, Z2, Y2, X2, ZP2, YP2, XP2);
    conv_s2c16_k<<<nblk(NV2), 256, 0, stream>>>(
        x1, wf2a, s2a, b2a, m2, x2a, Z2, Y2, X2, YP0, XP0, YP2, XP2);
    halo_zero_k<32><<<nblk(NP2), 256, 0, stream>>>(x2b, Z2, Y2, X2, ZP2, YP2, XP2);
    {
        int nx = cdiv(X2, 32), ny = cdiv(Y2, 4), nz = cdiv(Z2, 4);
        conv_lds_k<false><<<nx * ny * nz, 512, 0, stream>>>(
            x2a, wf2b, s2b, b2b, m2, x2b, nullptr, Z2, Y2, X2, YP2, XP2, YP2, XP2, nx, ny);
    }

    // level 3
    dilate_k<<<nblk(NV3), 256, 0, stream>>>(m2, m3, Z2, Y2, X2, Z3, Y3, X3, 2);
    halo_zero_k<64><<<nblk(NP3), 256, 0, stream>>>(x3a, Z3, Y3, X3, ZP3, YP3, XP3);
    conv_mfma_k<32, 64, 2, 64, false><<<cdiv(NV3, 64), 64, 0, stream>>>(
        x2b, wf3a, s3a, b3a, m3, x3a, nullptr, Z3, Y3, X3, YP2, XP2, YP3, XP3);
    halo_zero_k<64><<<nblk(NP3), 256, 0, stream>>>(x3b, Z3, Y3, X3, ZP3, YP3, XP3);
    conv_mfma_k<64, 64, 1, 64, false><<<cdiv(NV3, 64), 64, 0, stream>>>(
        x3a, wf3b, s3b, b3b, m3, x3b, nullptr, Z3, Y3, X3, YP3, XP3, YP3, XP3);

    // level 4 (tconv up via parity octants)
    tdilate_k<<<nblk(NV4), 256, 0, stream>>>(m3, m4, Z3, Y3, X3, Z4, Y4, X4);
    halo_zero_k<32><<<nblk(NP4), 256, 0, stream>>>(x4a, Z4, Y4, X4, ZP4, YP4, XP4);
    {
        int maxNq = ((Z4 + 1) >> 1) * ((Y4 + 1) >> 1) * ((X4 + 1) >> 1);
        dim3 g(nblk(maxNq), 8);
        tconv_mfma_k<64, 32><<<g, 256, 0, stream>>>(
            x3b, wf4a, s4a, b4a, m4, x4a, Z4, Y4, X4, YP3, XP3, YP4, XP4);
    }
    halo_zero_k<32><<<nblk(NP2), 256, 0, stream>>>(x4b, Z4, Y4, X4, ZP2, YP2, XP2);
    {
        int nx = cdiv(X4, 32), ny = cdiv(Y4, 4), nz = cdiv(Z4, 4);
        conv_lds_k<false><<<nx * ny * nz, 512, 0, stream>>>(
            x4a, wf4b, s4b, b4b, m4, x4b, nullptr, Z4, Y4, X4, YP4, XP4, YP2, XP2, nx, ny);
    }

    // level 5 (tconv up, outpad (0,3,3)) — both kernels rolling-z pipelined
    tdilate4_k<<<nblk(NV0 / 4), 256, 0, stream>>>(m4, m5, Z4, Y4, X4, Z0, Y0, X0);
    halo_zero_k<32><<<nblk(NP0), 256, 0, stream>>>(x5a, Z0, Y0, X0, ZP0, YP0, XP0);
    {
        dim3 g((Y0 / 2 / 2) * (X0 / 2 / 32), 8);
        tconv_roll_k<<<g, 256, 0, stream>>>(
            x4b, wf5a, s5a, b5a, m5, x5a, Z0, Y0, X0, Z4, YP2, XP2, YP0, XP0, X0 / 2 / 32);
    }
    {
        conv_roll_k<<<(X0 / 32) * (Y0 / 8), 512, 0, stream>>>(
            x5a, wf5b32, s5b, b5b, m5, (float*)d_out);
    }
}

// Round 11
// 851.900 us; speedup vs baseline: 1.1721x; 1.0150x over previous
//
#include <hip/hip_runtime.h>
#include <hip/hip_bf16.h>
#include <stdint.h>

namespace {

constexpr int Z0 = 41, Y0 = 256, X0 = 256;
constexpr int Z2 = 21, Y2 = 128, X2 = 128;
constexpr int Z3 = 11, Y3 = 64,  X3 = 64;
constexpr int Z4 = 21, Y4 = 127, X4 = 127;
constexpr int NV0 = Z0 * Y0 * X0;
constexpr int NV2 = Z2 * Y2 * X2;
constexpr int NV3 = Z3 * Y3 * X3;
constexpr int NV4 = Z4 * Y4 * X4;

constexpr int ZP0 = 43, YP0 = 258, XP0 = 258; constexpr int NP0 = ZP0 * YP0 * XP0;
constexpr int ZP2 = 23, YP2 = 130, XP2 = 130; constexpr int NP2 = ZP2 * YP2 * XP2;
constexpr int ZP3 = 13, YP3 = 66,  XP3 = 66;  constexpr int NP3 = ZP3 * YP3 * XP3;
constexpr int ZP4 = 23, YP4 = 129, XP4 = 129; constexpr int NP4 = ZP4 * YP4 * XP4;

using bf16 = __hip_bfloat16;
typedef __attribute__((ext_vector_type(8))) short s16x8;
typedef __attribute__((ext_vector_type(4))) float f32x4;
typedef __attribute__((ext_vector_type(16))) float f32x16;
typedef __attribute__((ext_vector_type(4))) unsigned u32x4;

__device__ inline unsigned f2b(float f) {
    return (unsigned)__builtin_bit_cast(unsigned short, __float2bfloat16(f));
}

__device__ inline int xcd_swz(int bid, int nwg) {
    int q = nwg >> 3, r = nwg & 7;
    int x = bid & 7, j = bid >> 3;
    return (x < r ? x * (q + 1) : r * (q + 1) + (x - r) * q) + j;
}

__device__ inline void glds16(const bf16* g, void* l) {
    __builtin_amdgcn_global_load_lds(
        (const __attribute__((address_space(1))) void*)g,
        (__attribute__((address_space(3))) void*)l, 16, 0, 0);
}

__global__ __launch_bounds__(256) void sentinel_k(float* out) { out[0] = 12345.0f; }

__global__ __launch_bounds__(256) void scatter_k(const float* __restrict__ feats,
                                                 const int* __restrict__ coords,
                                                 bf16* __restrict__ dense,
                                                 uint8_t* __restrict__ m0, int n) {
    int v = blockIdx.x * 256 + threadIdx.x;
    if (v >= n) return;
    int z = coords[v * 4 + 1], y = coords[v * 4 + 2], x = coords[v * 4 + 3];
    m0[(z * Y0 + y) * X0 + x] = 1;
    int pp = ((z + 1) * YP0 + (y + 1)) * XP0 + (x + 1);
    uint2 u;
    u.x = f2b(feats[v * 4 + 0]) | (f2b(feats[v * 4 + 1]) << 16);
    u.y = f2b(feats[v * 4 + 2]) | (f2b(feats[v * 4 + 3]) << 16);
    *(uint2*)(dense + (size_t)pp * 4) = u;
}

template <int C>
__global__ __launch_bounds__(256) void halo_zero_k(bf16* __restrict__ buf,
                                                   int Zi, int Yi, int Xi,
                                                   int Zp, int Yp, int Xp) {
    int i = blockIdx.x * 256 + threadIdx.x;
    int tot = Zp * Yp * Xp;
    if (i >= tot) return;
    int x = i % Xp; int t = i / Xp; int y = t % Yp; int z = t / Yp;
    bool halo = (z < 1) | (z > Zi) | (y < 1) | (y > Yi) | (x < 1) | (x > Xi);
    if (!halo) return;
    uint4 zz = make_uint4(0, 0, 0, 0);
    uint4* p = (uint4*)(buf + (size_t)i * C);
#pragma unroll
    for (int j = 0; j < C / 8; ++j) p[j] = zz;
}

__global__ __launch_bounds__(256) void repack_frag_k(const float* __restrict__ w,
                                                     bf16* __restrict__ wf,
                                                     int CIN, int COUT, int TRANS) {
    int NT = COUT / 16, KT = CIN / 32;
    int i = blockIdx.x * 256 + threadIdx.x;
    int total = 27 * NT * KT * 64;
    if (i >= total) return;
    int lane = i & 63; int t = i >> 6;
    int kt = t % KT; t /= KT; int nt = t % NT; int tap = t / NT;
    int co = nt * 16 + (lane & 15);
    int ci0 = kt * 32 + (lane >> 4) * 8;
    unsigned e[8];
#pragma unroll
    for (int j = 0; j < 8; ++j) {
        int ci = ci0 + j;
        int src = TRANS ? ((ci * COUT + co) * 27 + tap) : ((co * CIN + ci) * 27 + tap);
        e[j] = f2b(w[src]);
    }
    uint4 u;
    u.x = e[0] | (e[1] << 16); u.y = e[2] | (e[3] << 16);
    u.z = e[4] | (e[5] << 16); u.w = e[6] | (e[7] << 16);
    ((uint4*)wf)[i] = u;
}

// 32x32x16 B-frag repack: wf[(tap*2+ks)*64+lane], elem j: B[k=(lane>>5)*8+j][col=lane&31]
// with weight channel cin = ks*16 + k
__global__ __launch_bounds__(256) void repack_frag32_k(const float* __restrict__ w,
                                                       bf16* __restrict__ wf) {
    int i = blockIdx.x * 256 + threadIdx.x;
    if (i >= 27 * 2 * 64) return;
    int lane = i & 63; int t2 = i >> 6;
    int ks = t2 & 1; int tap = t2 >> 1;
    int co = lane & 31; int h = lane >> 5;
    unsigned e[8];
#pragma unroll
    for (int j = 0; j < 8; ++j) {
        int cin = ks * 16 + h * 8 + j;
        e[j] = f2b(w[(co * 32 + cin) * 27 + tap]);
    }
    uint4 u;
    u.x = e[0] | (e[1] << 16); u.y = e[2] | (e[3] << 16);
    u.z = e[4] | (e[5] << 16); u.w = e[6] | (e[7] << 16);
    ((uint4*)wf)[i] = u;
}

// CIN=16 stride-2 frag: K = 2 taps x 16ch, 14 pairs (tap 27 zero)
__global__ __launch_bounds__(256) void repack_frag_c16_k(const float* __restrict__ w,
                                                         bf16* __restrict__ wf) {
    int i = blockIdx.x * 256 + threadIdx.x;
    int total = 14 * 2 * 64;
    if (i >= total) return;
    int lane = i & 63; int t = i >> 6;
    int nt = t & 1; int p = t >> 1;
    int lg = lane >> 4, lr = lane & 15;
    int co = nt * 16 + lr;
    unsigned e[8];
#pragma unroll
    for (int j = 0; j < 8; ++j) {
        int tap = 2 * p + (lg >> 1);
        int ci = (lg & 1) * 8 + j;
        e[j] = (tap < 27) ? f2b(w[(co * 16 + ci) * 27 + tap]) : 0u;
    }
    uint4 u;
    u.x = e[0] | (e[1] << 16); u.y = e[2] | (e[3] << 16);
    u.z = e[4] | (e[5] << 16); u.w = e[6] | (e[7] << 16);
    ((uint4*)wf)[i] = u;
}

__global__ __launch_bounds__(256) void repack_frag_l1_k(const float* __restrict__ w,
                                                        bf16* __restrict__ wf) {
    int i = blockIdx.x * 256 + threadIdx.x;
    if (i >= 256) return;
    int lane = i & 63, kb = i >> 6;
    int lg = lane >> 4, lr = lane & 15;
    unsigned e[8];
#pragma unroll
    for (int j = 0; j < 8; ++j) {
        int tap = kb * 8 + lg * 2 + (j >> 2);
        int ci = j & 3;
        e[j] = (tap < 27) ? f2b(w[(lr * 4 + ci) * 27 + tap]) : 0u;
    }
    uint4 u;
    u.x = e[0] | (e[1] << 16); u.y = e[2] | (e[3] << 16);
    u.z = e[4] | (e[5] << 16); u.w = e[6] | (e[7] << 16);
    ((uint4*)wf)[i] = u;
}

__global__ __launch_bounds__(256) void dilate_k(const uint8_t* __restrict__ in,
                                                uint8_t* __restrict__ out,
                                                int Zi, int Yi, int Xi,
                                                int Zo, int Yo, int Xo, int stride) {
    int idx = blockIdx.x * 256 + threadIdx.x;
    int total = Zo * Yo * Xo;
    if (idx >= total) return;
    int x = idx % Xo; int t = idx / Xo; int y = t % Yo; int z = t / Yo;
    int YX = Yi * Xi;
    uint8_t r = 0;
    for (int kz = 0; kz < 3; ++kz) {
        int zi = z * stride + kz - 1;
        if ((unsigned)zi >= (unsigned)Zi) continue;
        for (int ky = 0; ky < 3; ++ky) {
            int yi = y * stride + ky - 1;
            if ((unsigned)yi >= (unsigned)Yi) continue;
            for (int kx = 0; kx < 3; ++kx) {
                int xi = x * stride + kx - 1;
                if ((unsigned)xi >= (unsigned)Xi) continue;
                r |= in[zi * YX + yi * Xi + xi];
            }
        }
    }
    out[idx] = r ? 1 : 0;
}

__global__ __launch_bounds__(256) void dilate4_k(const uint8_t* __restrict__ in,
                                                 uint8_t* __restrict__ out,
                                                 int Z, int Y, int X) {
    int ngx = X >> 2;
    int g = blockIdx.x * 256 + threadIdx.x;
    int total = Z * Y * ngx;
    if (g >= total) return;
    int gx = g % ngx; int t = g / ngx; int y = t % Y; int z = t / Y;
    const int YX = Y * X;
    unsigned r = 0;
    for (int kz = 0; kz < 3; ++kz) {
        int zi = z + kz - 1;
        if ((unsigned)zi >= (unsigned)Z) continue;
        for (int ky = 0; ky < 3; ++ky) {
            int yi = y + ky - 1;
            if ((unsigned)yi >= (unsigned)Y) continue;
            const unsigned* rw = (const unsigned*)(in + zi * YX + yi * X);
            unsigned u1 = rw[gx];
            unsigned u0 = gx ? rw[gx - 1] : 0u;
            unsigned u2 = (gx + 1 < ngx) ? rw[gx + 1] : 0u;
            r |= u1 | ((u1 << 8) | (u0 >> 24)) | ((u1 >> 8) | (u2 << 24));
        }
    }
    r |= r >> 4; r |= r >> 2; r |= r >> 1; r &= 0x01010101u;
    ((unsigned*)out)[g] = r;
}

__global__ __launch_bounds__(256) void tdilate_k(const uint8_t* __restrict__ in,
                                                 uint8_t* __restrict__ out,
                                                 int Zi, int Yi, int Xi,
                                                 int Zo, int Yo, int Xo) {
    int idx = blockIdx.x * 256 + threadIdx.x;
    int total = Zo * Yo * Xo;
    if (idx >= total) return;
    int x = idx % Xo; int t = idx / Xo; int y = t % Yo; int z = t / Yo;
    int YX = Yi * Xi;
    uint8_t r = 0;
    for (int kz = 0; kz < 3; ++kz) {
        int tz = z + 1 - kz;
        if (tz & 1) continue;
        int zi = tz >> 1;
        if ((unsigned)zi >= (unsigned)Zi) continue;
        for (int ky = 0; ky < 3; ++ky) {
            int ty = y + 1 - ky;
            if (ty & 1) continue;
            int yi = ty >> 1;
            if ((unsigned)yi >= (unsigned)Yi) continue;
            for (int kx = 0; kx < 3; ++kx) {
                int tx = x + 1 - kx;
                if (tx & 1) continue;
                int xi = tx >> 1;
                if ((unsigned)xi >= (unsigned)Xi) continue;
                r |= in[zi * YX + yi * Xi + xi];
            }
        }
    }
    out[idx] = r ? 1 : 0;
}

__global__ __launch_bounds__(256) void tdilate4_k(const uint8_t* __restrict__ in,
                                                  uint8_t* __restrict__ out,
                                                  int Zi, int Yi, int Xi,
                                                  int Zo, int Yo, int Xo) {
    int ngx = Xo >> 2;
    int g = blockIdx.x * 256 + threadIdx.x;
    int total = Zo * Yo * ngx;
    if (g >= total) return;
    int gx = g % ngx; int t = g / ngx; int y = t % Yo; int z = t / Yo;
    int YX = Yi * Xi;
    int j0 = gx * 2;
    unsigned r0 = 0, r1 = 0, r2 = 0, r3 = 0;
    for (int kz = 0; kz < 3; ++kz) {
        int tz = z + 1 - kz;
        if (tz & 1) continue;
        int zi = tz >> 1;
        if ((unsigned)zi >= (unsigned)Zi) continue;
        for (int ky = 0; ky < 3; ++ky) {
            int ty = y + 1 - ky;
            if (ty & 1) continue;
            int yi = ty >> 1;
            if ((unsigned)yi >= (unsigned)Yi) continue;
            const uint8_t* rp = in + zi * YX + yi * Xi;
            unsigned b0 = (j0 < Xi) ? rp[j0] : 0u;
            unsigned b1 = (j0 + 1 < Xi) ? rp[j0 + 1] : 0u;
            unsigned b2 = (j0 + 2 < Xi) ? rp[j0 + 2] : 0u;
            r0 |= b0; r1 |= b0 | b1; r2 |= b1; r3 |= b1 | b2;
        }
    }
    unsigned rr = (r0 ? 1u : 0u) | (r1 ? 0x100u : 0u) | (r2 ? 0x10000u : 0u) | (r3 ? 0x1000000u : 0u);
    ((unsigned*)out)[g] = rr;
}

// ---- rolling-z pipelined conv 32->32 (L5b) with 32x32x16 MFMA ----
// 512 thr = 8 waves, wave = 1 y-row of 32 x-voxels, FULL cout per wave.
// B loaded via LDS -> ds_read -> VGPRs (un-rematerializable; LDS reused by ring).
// Row layout [ks][h][voxel]: off = ks*1088 + h*544 + v*16 -> every 16-lane group of
// the ds_read_b128 is a contiguous 256B run => conflict-free. Ring slab padded to
// 24576B so staging-tail lands in pad (glds dest = wave-uniform base + lane*16).
__global__ __launch_bounds__(512, 2) void conv_roll_k(
    const bf16* __restrict__ in, const bf16* __restrict__ wfrag,
    const float* __restrict__ scale, const float* __restrict__ shift,
    const uint8_t* __restrict__ mask, float* __restrict__ outf) {
    constexpr int ROWB = 2176;           // 2 ks x 2 h x 34 voxels x 16B
    constexpr int SLABB = 24576;         // padded stride (1536 chunk slots; 1360 used)
    __shared__ uint4 ring4[5 * SLABB / 16];
    char* ring = (char*)ring4;

    const int bid = xcd_swz(blockIdx.x, gridDim.x);
    const int tx = bid & 7, ty = bid >> 3;       // nx = 8
    const int y0 = ty * 8, x0 = tx * 32;

    const int tid = threadIdx.x;
    const int w = tid >> 6, lane = tid & 63;
    const int vx = lane & 31, h = lane >> 5;
    const int yr = w;

    // ---- prologue A: stage B (3456 x 16B chunks) into ring[0..55296) ----
#pragma unroll
    for (int k = 0; k < 7; ++k) {
        int i = tid + k * 512;
        if (i < 27 * 2 * 64) {
            // wave-uniform dest chunk base = k*512 + w*64 ; per-lane source
            glds16(wfrag + (size_t)(k * 512 + w * 64 + lane) * 8,
                   ring + (k * 512 + w * 64) * 16);
        }
    }
    asm volatile("s_waitcnt vmcnt(0)" ::: "memory");
    __syncthreads();

    // ds_read B into registers (216 VGPR) — source LDS is clobbered below,
    // so these values CANNOT be rematerialized.
    u32x4 breg[27][2];
#pragma unroll
    for (int t = 0; t < 27; ++t) {
        breg[t][0] = *(const u32x4*)(ring + (t * 2 + 0) * 1024 + lane * 16);
        breg[t][1] = *(const u32x4*)(ring + (t * 2 + 1) * 1024 + lane * 16);
    }
    __syncthreads();

    // ---- per-lane SOURCE offsets for the 3 staged chunks (dest pad for i>=1360) ----
    int soff[3];
#pragma unroll
    for (int k = 0; k < 3; ++k) {
        int i = tid + k * 512;
        int ii = i < 1360 ? i : 0;               // clamp SOURCE only
        int row = ii / 136, c = ii - row * 136;
        int ks = c / 68, r2 = c - ks * 68, hh = r2 / 34, v = r2 - hh * 34;
        soff[k] = ((y0 + row) * XP0 + (x0 + v)) * 32 + (2 * ks + hh) * 8;
    }
    auto stagefn = [&](int p, char* slab) {
        int zs = p < ZP0 ? p : ZP0 - 1;
        const bf16* pb = in + (size_t)zs * ((size_t)YP0 * XP0 * 32);
        glds16(pb + soff[0], slab + w * 1024);
        glds16(pb + soff[1], slab + w * 1024 + 8192);
        glds16(pb + soff[2], slab + w * 1024 + 16384);
    };

    // A read offsets per dx (ks=0 half; ks=1 adds +1088)
    int asw[3];
#pragma unroll
    for (int dx = 0; dx < 3; ++dx) asw[dx] = h * 544 + (vx + dx) * 16;

    const float sc = scale[vx], sh = shift[vx];

    stagefn(0, ring);
    stagefn(1, ring + SLABB);
    stagefn(2, ring + 2 * SLABB);
    stagefn(3, ring + 3 * SLABB);
    stagefn(4, ring + 4 * SLABB);
    asm volatile("s_waitcnt vmcnt(0)" ::: "memory");
    __builtin_amdgcn_s_barrier();

    int s0 = 0;
    for (int z = 0; z < Z0; ++z) {
        const int s1 = s0 + 1 < 5 ? s0 + 1 : 0;
        const int s2 = s1 + 1 < 5 ? s1 + 1 : 0;
        const char* sl0 = ring + s0 * SLABB;
        const char* sl1 = ring + s1 * SLABB;
        const char* sl2 = ring + s2 * SLABB;

        f32x16 acc;
#pragma unroll
        for (int i = 0; i < 16; ++i) acc[i] = 0.f;

#pragma unroll
        for (int dz = 0; dz < 3; ++dz) {
            const char* slab = dz == 0 ? sl0 : (dz == 1 ? sl1 : sl2);
#pragma unroll
            for (int dy = 0; dy < 3; ++dy) {
                const char* rowp = slab + (yr + dy) * ROWB;
#pragma unroll
                for (int dx = 0; dx < 3; ++dx) {
                    const int tap = dz * 9 + dy * 3 + dx;
                    u32x4 a0 = *(const u32x4*)(rowp + asw[dx]);
                    u32x4 a1 = *(const u32x4*)(rowp + 1088 + asw[dx]);
                    acc = __builtin_amdgcn_mfma_f32_32x32x16_bf16(
                        __builtin_bit_cast(s16x8, a0),
                        __builtin_bit_cast(s16x8, breg[tap][0]), acc, 0, 0, 0);
                    acc = __builtin_amdgcn_mfma_f32_32x32x16_bf16(
                        __builtin_bit_cast(s16x8, a1),
                        __builtin_bit_cast(s16x8, breg[tap][1]), acc, 0, 0, 0);
                }
            }
        }

        // masks loaded in-loop (older stage loads already covered by compute)
        const uint8_t* mrow = mask + ((size_t)z * Y0 + (y0 + yr)) * X0 + x0 + 4 * h;
        unsigned mq0 = *(const unsigned*)(mrow);
        unsigned mq1 = *(const unsigned*)(mrow + 8);
        unsigned mq2 = *(const unsigned*)(mrow + 16);
        unsigned mq3 = *(const unsigned*)(mrow + 24);

        // stores: C row(voxel-x) = (reg&3) + 8*(reg>>2) + 4*h, col = cout = vx
        const size_t obase = (size_t)vx * NV0 + ((size_t)z * Y0 + (y0 + yr)) * X0 + x0 + 4 * h;
#pragma unroll
        for (int q = 0; q < 4; ++q) {
            unsigned mq = q == 0 ? mq0 : (q == 1 ? mq1 : (q == 2 ? mq2 : mq3));
            f32x4 o;
#pragma unroll
            for (int r = 0; r < 4; ++r) {
                float m = (float)((mq >> (8 * r)) & 1);
                o[r] = fmaxf(fmaf(acc[q * 4 + r], sc, sh), 0.f) * m;
            }
            *(f32x4*)(outf + obase + 8 * q) = o;
        }

        __builtin_amdgcn_s_barrier();     // all waves done reading slot s0
        stagefn(z + 5, ring + s0 * SLABB);
        asm volatile("s_waitcnt vmcnt(11)" ::: "memory");  // keep this iter's ops in flight
        s0 = s1;
    }
}

// ---- rolling-z pipelined transposed conv 32->32 (L5a) via parity octants ----
__global__ __launch_bounds__(256, 3) void tconv_roll_k(
    const bf16* __restrict__ in, const bf16* __restrict__ wfrag,
    const float* __restrict__ scale, const float* __restrict__ shift,
    const uint8_t* __restrict__ mask, bf16* __restrict__ out,
    int Zo, int Yo, int Xo, int Zi, int Ypi, int Xpi, int Ypo, int Xpo, int nx) {
    constexpr int ROWB = 34 * 64;
    constexpr int SLABB = 3 * ROWB;
    __shared__ uint4 ring4[4 * SLABB / 16];
    char* ring = (char*)ring4;

    const int oct = blockIdx.y;
    const int pz = oct >> 2, py = (oct >> 1) & 1, px = oct & 1;
    const int Zq = (Zo - pz + 1) >> 1;

    const int bid = xcd_swz(blockIdx.x, gridDim.x);
    const int tx = bid % nx, ty = bid / nx;
    const int yq0 = ty * 2, xq0 = tx * 32;

    const int tid = threadIdx.x;
    const int w = tid >> 6, lane = tid & 63;
    const int lg = lane >> 4, lr = lane & 15;
    const int yr = w >> 1, xh = w & 1;

    const int kz0 = pz ? 0 : 1, dzo0 = pz ? 1 : 0;
    const int ky0 = py ? 0 : 1, dyo0 = py ? 1 : 0;
    const int kx0 = px ? 0 : 1, dxo0 = px ? 1 : 0;

    auto stagefn = [&](int p, int slot) {
        if (w < 3) {
            int zs = p < Zi ? p : Zi - 1;
            char* slab = ring + slot * SLABB + w * ROWB;
            const bf16* pb = in + ((size_t)(zs + 1) * Ypi + (yq0 + 1 + w)) * (size_t)Xpi * 32
                                + (size_t)(xq0 + 1) * 32;
            int u0 = lane;      glds16(pb + (u0 ^ ((u0 >> 3) & 7)) * 8, slab);
            int u1 = 64 + lane; glds16(pb + (u1 ^ ((u1 >> 3) & 7)) * 8, slab + 1024);
            if (lane < 8) { int u2 = 128 + lane; glds16(pb + u2 * 8, slab + 2048); }
        }
    };

    const uint4* gw = (const uint4*)wfrag;
    uint4 breg[2][2][2][2];
#pragma unroll
    for (int iz = 0; iz < 2; ++iz) {
        int kz = iz ? 2 : kz0;
#pragma unroll
        for (int iy = 0; iy < 2; ++iy) {
            int ky = iy ? 2 : ky0;
#pragma unroll
            for (int ix = 0; ix < 2; ++ix) {
                int kx = ix ? 2 : kx0;
                int tap = kz * 9 + ky * 3 + kx;
                breg[iz][iy][ix][0] = gw[(tap * 2 + 0) * 64 + lane];
                breg[iz][iy][ix][1] = gw[(tap * 2 + 1) * 64 + lane];
            }
        }
    }

    int b0 = (xh * 16 + lr + dxo0) * 64 + lg * 16;
    int b1 = (xh * 16 + lr) * 64 + lg * 16;
    const int aswA = b0 ^ (((b0 >> 7) & 7) << 4);
    const int aswB = b1 ^ (((b1 >> 7) & 7) << 4);
    const int rowA = (yr + dyo0) * ROWB;
    const int rowB = yr * ROWB;

    const float sc0 = scale[lr], sh0 = shift[lr];
    const float sc1 = scale[16 + lr], sh1 = shift[16 + lr];

    const int yout = 2 * (yq0 + yr) + py;
    const int xb = 2 * (xq0 + xh * 16 + lg * 4) + px;

    stagefn(0, 0); stagefn(1, 1); stagefn(2, 2);
    uint2 mv;
    mv = *(const uint2*)(mask + ((size_t)pz * Yo + yout) * Xo + (xb - px));
    asm volatile("s_waitcnt vmcnt(0)" ::: "memory");
    __builtin_amdgcn_s_barrier();

    int rs0 = 0, wslot = 3;
    for (int zq = 0; zq < Zq; ++zq) {
        uint2 nv;
        {
            int zqn = (zq + 1 < Zq) ? zq + 1 : Zq - 1;
            nv = *(const uint2*)(mask + ((size_t)(2 * zqn + pz) * Yo + yout) * Xo + (xb - px));
        }
        stagefn(zq + 3, wslot);

        int rs1 = rs0 + 1 < 4 ? rs0 + 1 : 0;
        const char* sl_0 = ring + rs0 * SLABB;
        const char* sl_1 = ring + rs1 * SLABB;
        const char* slz0 = pz ? sl_1 : sl_0;
        const char* slz1 = sl_0;

        f32x4 acc0 = (f32x4){0, 0, 0, 0}, acc1 = (f32x4){0, 0, 0, 0};
#pragma unroll
        for (int iz = 0; iz < 2; ++iz) {
            if (iz > pz) continue;
            const char* slab = iz ? slz1 : slz0;
#pragma unroll
            for (int iy = 0; iy < 2; ++iy) {
                if (iy > py) continue;
                const char* rowp = slab + (iy ? rowB : rowA);
#pragma unroll
                for (int ix = 0; ix < 2; ++ix) {
                    if (ix > px) continue;
                    uint4 a = *(const uint4*)(rowp + (ix ? aswB : aswA));
                    acc0 = __builtin_amdgcn_mfma_f32_16x16x32_bf16(
                        __builtin_bit_cast(s16x8, a),
                        __builtin_bit_cast(s16x8, breg[iz][iy][ix][0]), acc0, 0, 0, 0);
                    acc1 = __builtin_amdgcn_mfma_f32_16x16x32_bf16(
                        __builtin_bit_cast(s16x8, a),
                        __builtin_bit_cast(s16x8, breg[iz][iy][ix][1]), acc1, 0, 0, 0);
                }
            }
        }

        const int zout = 2 * zq + pz;
        const size_t opdbase = ((size_t)(zout + 1) * Ypo + (yout + 1)) * Xpo;
#pragma unroll
        for (int r = 0; r < 4; ++r) {
            unsigned word = (r < 2) ? mv.x : mv.y;
            float m = (float)((word >> (px * 8 + (r & 1) * 16)) & 1);
            float v0 = fmaxf(fmaf(acc0[r], sc0, sh0), 0.f) * m;
            float v1 = fmaxf(fmaf(acc1[r], sc1, sh1), 0.f) * m;
            size_t opd = opdbase + (size_t)(xb + 2 * r + 1);
            out[opd * 32 + lr]      = __float2bfloat16(v0);
            out[opd * 32 + 16 + lr] = __float2bfloat16(v1);
        }

        asm volatile("s_waitcnt vmcnt(20)" ::: "memory");
        __builtin_amdgcn_s_barrier();
        rs0 = rs1;
        wslot = wslot + 1 < 4 ? wslot + 1 : 0;
        mv = nv;
    }
}

// LDS-tiled MFMA stride-1 conv, CIN=COUT=32 (L2b, L4b)
template <bool FINAL>
__global__ __launch_bounds__(512, 4) void conv_lds_k(
    const bf16* __restrict__ in, const bf16* __restrict__ wfrag,
    const float* __restrict__ scale, const float* __restrict__ shift,
    const uint8_t* __restrict__ mask, bf16* __restrict__ out, float* __restrict__ outf,
    int Zo, int Yo, int Xo, int Ypi, int Xpi, int Ypo, int Xpo, int nx, int ny) {
    constexpr int ROWB = 34 * 64;
    __shared__ uint4 tile4[36 * ROWB / 16];
    char* tile = (char*)tile4;

    const int No = Zo * Yo * Xo;
    const int bid = xcd_swz(blockIdx.x, gridDim.x);
    int tx = bid % nx; int tt = bid / nx; int ty = tt % ny; int tz = tt / ny;
    const int z0 = tz * 4, y0 = ty * 4, x0 = tx * 32;

    const int tid = threadIdx.x;
    const int w = tid >> 6, lane = tid & 63, lg = lane >> 4, lr = lane & 15;

    int anywork;
    {
        int row = tid >> 5, xl = tid & 31;
        int zz = z0 + (row >> 2), yy = y0 + (row & 3), xx = x0 + xl;
        int ok = (zz < Zo) && (yy < Yo) && (xx < Xo) && mask[((size_t)zz * Yo + yy) * Xo + xx];
        anywork = __syncthreads_or(ok);
    }

    f32x4 acc[4][2];
#pragma unroll
    for (int s = 0; s < 4; ++s) { acc[s][0] = (f32x4){0,0,0,0}; acc[s][1] = (f32x4){0,0,0,0}; }

    if (anywork) {
        const int lsw = (lane ^ ((lane >> 3) & 7)) * 8;
        for (int rr = w; rr < 36; rr += 8) {
            int dz = rr / 6, dy = rr % 6;
            const bf16* g = in + ((size_t)(z0 + dz) * Ypi + (y0 + dy)) * Xpi * 32 + (size_t)x0 * 32;
            char* l = tile + rr * ROWB;
            glds16(g + lsw, l);
            glds16(g + 512 + lsw, l + 1024);
            if (lane < 8) glds16(g + 1024 + lane * 8, l + 2048);
        }
        asm volatile("s_waitcnt vmcnt(0)" ::: "memory");
        __syncthreads();

        int rbB[4], bsw[4][3];
#pragma unroll
        for (int s = 0; s < 4; ++s) {
            int lrow = 2 * w + (s >> 1);
            rbB[s] = ((lrow >> 2) * 6 + (lrow & 3)) * ROWB;
            int xpart = (s & 1) * 16 + lr;
#pragma unroll
            for (int dx = 0; dx < 3; ++dx) {
                int b = (xpart + dx) * 64 + lg * 16;
                bsw[s][dx] = b ^ (((b >> 7) & 7) << 4);
            }
        }

        const uint4* gw = (const uint4*)wfrag;
#pragma unroll 1
        for (int dz = 0; dz < 3; ++dz) {
#pragma unroll
            for (int dy = 0; dy < 3; ++dy) {
                const int rowoff = (dz * 6 + dy) * ROWB;
#pragma unroll
                for (int dx = 0; dx < 3; ++dx) {
                    const int tap = dz * 9 + dy * 3 + dx;
                    uint4 b0 = gw[(tap * 2 + 0) * 64 + lane];
                    uint4 b1 = gw[(tap * 2 + 1) * 64 + lane];
                    uint4 ua[4];
#pragma unroll
                    for (int s = 0; s < 4; ++s)
                        ua[s] = *(const uint4*)(tile + rbB[s] + rowoff + bsw[s][dx]);
#pragma unroll
                    for (int s = 0; s < 4; ++s) {
                        acc[s][0] = __builtin_amdgcn_mfma_f32_16x16x32_bf16(
                            __builtin_bit_cast(s16x8, ua[s]),
                            __builtin_bit_cast(s16x8, b0), acc[s][0], 0, 0, 0);
                        acc[s][1] = __builtin_amdgcn_mfma_f32_16x16x32_bf16(
                            __builtin_bit_cast(s16x8, ua[s]),
                            __builtin_bit_cast(s16x8, b1), acc[s][1], 0, 0, 0);
                    }
                }
            }
        }
    }

#pragma unroll
    for (int s = 0; s < 4; ++s) {
        int lrow = 2 * w + (s >> 1);
        int zz = z0 + (lrow >> 2), yy = y0 + (lrow & 3);
        int xv = x0 + (s & 1) * 16 + lg * 4;
        bool rowok = (zz < Zo) && (yy < Yo);
        if (!rowok) continue;
        size_t idx0 = ((size_t)zz * Yo + yy) * Xo + xv;
        float mm[4];
#pragma unroll
        for (int r = 0; r < 4; ++r)
            mm[r] = (xv + r < Xo && mask[idx0 + r]) ? 1.f : 0.f;
        if constexpr (FINAL) {
#pragma unroll
            for (int nt = 0; nt < 2; ++nt) {
                int co = nt * 16 + lr;
                float sc = scale[co], sh = shift[co];
                f32x4 o;
#pragma unroll
                for (int r = 0; r < 4; ++r)
                    o[r] = fmaxf(fmaf(acc[s][nt][r], sc, sh), 0.f) * mm[r];
                if (xv + 3 < Xo) {
                    *(f32x4*)(outf + (size_t)co * No + idx0) = o;
                } else {
#pragma unroll
                    for (int r = 0; r < 4; ++r)
                        if (xv + r < Xo) outf[(size_t)co * No + idx0 + r] = o[r];
                }
            }
        } else {
            int opd = ((zz + 1) * Ypo + (yy + 1)) * Xpo + (xv + 1);
#pragma unroll
            for (int nt = 0; nt < 2; ++nt) {
                int co = nt * 16 + lr;
                float sc = scale[co], sh = shift[co];
#pragma unroll
                for (int r = 0; r < 4; ++r) {
                    if (xv + r >= Xo) continue;
                    float yv = fmaxf(fmaf(acc[s][nt][r], sc, sh), 0.f) * mm[r];
                    out[(size_t)(opd + r) * 32 + co] = __float2bfloat16(yv);
                }
            }
        }
    }
}

// global-load MFMA conv, generic stride & block size (L3a, L3b)
template <int CIN, int COUT, int STRIDE, int BLK, bool FINAL>
__global__ __launch_bounds__(BLK, ((CIN <= 32 && COUT <= 32) ? 4 : 2)) void conv_mfma_k(
    const bf16* __restrict__ in, const bf16* __restrict__ wfrag,
    const float* __restrict__ scale, const float* __restrict__ shift,
    const uint8_t* __restrict__ mask, bf16* __restrict__ out, float* __restrict__ outf,
    int Zo, int Yo, int Xo, int Ypi, int Xpi, int Ypo, int Xpo) {
    constexpr int NT = COUT / 16;
    constexpr int KT = CIN / 32;
    const int No = Zo * Yo * Xo;
    const int bid = xcd_swz(blockIdx.x, gridDim.x);
    const int tid = threadIdx.x;
    const int wv = tid >> 6, lane = tid & 63;
    const int lg = lane >> 4, lr = lane & 15;
    const int v0 = bid * BLK + wv * 64;
    if (v0 >= No) return;

    int vm = v0 + lane;
    bool mw = (vm < No) && (mask[vm] != 0);
    const bool anywork = (__ballot(mw) != 0ull);

    f32x4 acc[4][NT];
#pragma unroll
    for (int s = 0; s < 4; ++s)
#pragma unroll
        for (int nt = 0; nt < NT; ++nt) acc[s][nt] = (f32x4){0.f, 0.f, 0.f, 0.f};

    const uint4* gw = (const uint4*)wfrag;

    if (anywork) {
        int pA[4];
#pragma unroll
        for (int s = 0; s < 4; ++s) {
            int vr = v0 + s * 16 + lr;
            if (vr >= No) vr = 0;
            int zz = vr / (Yo * Xo); int rr = vr - zz * (Yo * Xo);
            int yy = rr / Xo; int xx = rr - yy * Xo;
            pA[s] = (((zz * STRIDE + 1) * Ypi + (yy * STRIDE + 1)) * Xpi + (xx * STRIDE + 1)) * CIN + lg * 8;
        }
#pragma unroll
        for (int tap = 0; tap < 27; ++tap) {
            const int kz = tap / 9, r9 = tap - kz * 9, ky = r9 / 3, kx = r9 - ky * 3;
            const int toff = (((kz - 1) * Ypi + (ky - 1)) * Xpi + (kx - 1)) * CIN;
            uint4 ub[NT][KT];
#pragma unroll
            for (int nt = 0; nt < NT; ++nt)
#pragma unroll
                for (int kt = 0; kt < KT; ++kt)
                    ub[nt][kt] = gw[((tap * NT + nt) * KT + kt) * 64 + lane];
            uint4 ua[4][KT];
#pragma unroll
            for (int s = 0; s < 4; ++s)
#pragma unroll
                for (int kt = 0; kt < KT; ++kt)
                    ua[s][kt] = *(const uint4*)(in + pA[s] + toff + kt * 32);
#pragma unroll
            for (int s = 0; s < 4; ++s)
#pragma unroll
                for (int kt = 0; kt < KT; ++kt)
#pragma unroll
                    for (int nt = 0; nt < NT; ++nt)
                        acc[s][nt] = __builtin_amdgcn_mfma_f32_16x16x32_bf16(
                            __builtin_bit_cast(s16x8, ua[s][kt]),
                            __builtin_bit_cast(s16x8, ub[nt][kt]), acc[s][nt], 0, 0, 0);
        }
    }

#pragma unroll
    for (int s = 0; s < 4; ++s) {
        const int vb = v0 + s * 16 + lg * 4;
        int opd[4]; float mm[4]; bool ok[4];
#pragma unroll
        for (int r = 0; r < 4; ++r) {
            int v = vb + r;
            ok[r] = v < No;
            int vc = ok[r] ? v : 0;
            mm[r] = (ok[r] && mask[vc]) ? 1.f : 0.f;
            int zz = vc / (Yo * Xo); int rr = vc - zz * (Yo * Xo);
            int yy = rr / Xo; int xx = rr - yy * Xo;
            opd[r] = FINAL ? vc : ((zz + 1) * Ypo + (yy + 1)) * Xpo + (xx + 1);
        }
#pragma unroll
        for (int nt = 0; nt < NT; ++nt) {
            int co = nt * 16 + lr;
            float sc = scale[co], sh = shift[co];
#pragma unroll
            for (int r = 0; r < 4; ++r) {
                if (!ok[r]) continue;
                float yv = fmaxf(fmaf(acc[s][nt][r], sc, sh), 0.f) * mm[r];
                if constexpr (FINAL) outf[(size_t)co * No + opd[r]] = yv;
                else out[(size_t)opd[r] * COUT + co] = __float2bfloat16(yv);
            }
        }
    }
}

// stride-2 CIN=16 MFMA conv (L2a)
__global__ __launch_bounds__(256, 4) void conv_s2c16_k(
    const bf16* __restrict__ in, const bf16* __restrict__ wfrag,
    const float* __restrict__ scale, const float* __restrict__ shift,
    const uint8_t* __restrict__ mask, bf16* __restrict__ out,
    int Zo, int Yo, int Xo, int Ypi, int Xpi, int Ypo, int Xpo) {
    const int No = Zo * Yo * Xo;
    const int bid = xcd_swz(blockIdx.x, gridDim.x);
    const int tid = threadIdx.x;
    const int wv = tid >> 6, lane = tid & 63;
    const int lg = lane >> 4, lr = lane & 15;
    const int v0 = bid * 256 + wv * 64;
    if (v0 >= No) return;

    int vm = v0 + lane;
    bool mw = (vm < No) && (mask[vm] != 0);
    const bool anywork = (__ballot(mw) != 0ull);

    f32x4 acc[4][2];
#pragma unroll
    for (int s = 0; s < 4; ++s) { acc[s][0] = (f32x4){0,0,0,0}; acc[s][1] = (f32x4){0,0,0,0}; }

    if (anywork) {
        const uint4* gw = (const uint4*)wfrag;
        const int choff = (lg & 1) * 8;
        const int tb = lg >> 1;
        int toffl[14];
#pragma unroll
        for (int p = 0; p < 14; ++p) {
            int tp = 2 * p + tb;
            if (tp >= 27) tp = 0;
            int kz = tp / 9, r9 = tp - kz * 9, ky = r9 / 3, kx = r9 - ky * 3;
            toffl[p] = ((kz * Ypi + ky) * Xpi + kx) * 16;
        }
        int pA[4];
#pragma unroll
        for (int s = 0; s < 4; ++s) {
            int vr = v0 + s * 16 + lr;
            if (vr >= No) vr = 0;
            int zz = vr / (Yo * Xo); int rr = vr - zz * (Yo * Xo);
            int yy = rr / Xo; int xx = rr - yy * Xo;
            pA[s] = (((zz * 2) * Ypi + (yy * 2)) * Xpi + (xx * 2)) * 16 + choff;
        }
#pragma unroll
        for (int p = 0; p < 14; ++p) {
            uint4 b0 = gw[(p * 2 + 0) * 64 + lane];
            uint4 b1 = gw[(p * 2 + 1) * 64 + lane];
            uint4 ua[4];
#pragma unroll
            for (int s = 0; s < 4; ++s)
                ua[s] = *(const uint4*)(in + pA[s] + toffl[p]);
#pragma unroll
            for (int s = 0; s < 4; ++s) {
                acc[s][0] = __builtin_amdgcn_mfma_f32_16x16x32_bf16(
                    __builtin_bit_cast(s16x8, ua[s]),
                    __builtin_bit_cast(s16x8, b0), acc[s][0], 0, 0, 0);
                acc[s][1] = __builtin_amdgcn_mfma_f32_16x16x32_bf16(
                    __builtin_bit_cast(s16x8, ua[s]),
                    __builtin_bit_cast(s16x8, b1), acc[s][1], 0, 0, 0);
            }
        }
    }

#pragma unroll
    for (int s = 0; s < 4; ++s) {
        const int vb = v0 + s * 16 + lg * 4;
        int opd[4]; float mm[4]; bool ok[4];
#pragma unroll
        for (int r = 0; r < 4; ++r) {
            int v = vb + r;
            ok[r] = v < No;
            int vc = ok[r] ? v : 0;
            mm[r] = (ok[r] && mask[vc]) ? 1.f : 0.f;
            int zz = vc / (Yo * Xo); int rr = vc - zz * (Yo * Xo);
            int yy = rr / Xo; int xx = rr - yy * Xo;
            opd[r] = ((zz + 1) * Ypo + (yy + 1)) * Xpo + (xx + 1);
        }
#pragma unroll
        for (int nt = 0; nt < 2; ++nt) {
            int co = nt * 16 + lr;
            float sc = scale[co], sh = shift[co];
#pragma unroll
            for (int r = 0; r < 4; ++r) {
                if (!ok[r]) continue;
                float yv = fmaxf(fmaf(acc[s][nt][r], sc, sh), 0.f) * mm[r];
                out[(size_t)opd[r] * 32 + co] = __float2bfloat16(yv);
            }
        }
    }
}

// MFMA transposed conv (stride 2) via parity octants (L4a)
template <int CIN, int COUT>
__global__ __launch_bounds__(256, 4) void tconv_mfma_k(
    const bf16* __restrict__ in, const bf16* __restrict__ wfrag,
    const float* __restrict__ scale, const float* __restrict__ shift,
    const uint8_t* __restrict__ mask, bf16* __restrict__ out,
    int Zo, int Yo, int Xo, int Ypi, int Xpi, int Ypo, int Xpo) {
    constexpr int NT = COUT / 16;
    constexpr int KT = CIN / 32;
    const int oct = blockIdx.y;
    const int pz = oct >> 2, py = (oct >> 1) & 1, px = oct & 1;
    const int Zq = (Zo - pz + 1) >> 1, Yq = (Yo - py + 1) >> 1, Xq = (Xo - px + 1) >> 1;
    const int Nq = Zq * Yq * Xq;
    const int YXq = Yq * Xq;
    const int bid = xcd_swz(blockIdx.x, gridDim.x);
    const int tid = threadIdx.x;
    const int wv = tid >> 6, lane = tid & 63;
    const int lg = lane >> 4, lr = lane & 15;
    const int v0 = bid * 256 + wv * 64;
    if (v0 >= Nq) return;

    bool mw = false;
    {
        int q = v0 + lane;
        if (q < Nq) {
            int zq = q / YXq; int rr = q - zq * YXq; int yq = rr / Xq; int xq = rr - yq * Xq;
            int zz = 2 * zq + pz, yy = 2 * yq + py, xx = 2 * xq + px;
            mw = mask[(zz * Yo + yy) * Xo + xx] != 0;
        }
    }
    const bool anywork = (__ballot(mw) != 0ull);

    f32x4 acc[4][NT];
#pragma unroll
    for (int s = 0; s < 4; ++s)
#pragma unroll
        for (int nt = 0; nt < NT; ++nt) acc[s][nt] = (f32x4){0.f, 0.f, 0.f, 0.f};

    const uint4* gw = (const uint4*)wfrag;

    if (anywork) {
        int pA[4];
#pragma unroll
        for (int s = 0; s < 4; ++s) {
            int q = v0 + s * 16 + lr;
            if (q >= Nq) q = 0;
            int zq = q / YXq; int rr = q - zq * YXq; int yq = rr / Xq; int xq = rr - yq * Xq;
            pA[s] = (((zq + 1) * Ypi + (yq + 1)) * Xpi + (xq + 1)) * CIN + lg * 8;
        }
        const int nkz = 1 + pz, nky = 1 + py, nkx = 1 + px;
        for (int iz = 0; iz < nkz; ++iz) {
            const int kz = pz ? (iz ? 2 : 0) : 1;
            const int dz = (pz && !iz) ? 1 : 0;
            for (int iy = 0; iy < nky; ++iy) {
                const int ky = py ? (iy ? 2 : 0) : 1;
                const int dy = (py && !iy) ? 1 : 0;
                for (int ix = 0; ix < nkx; ++ix) {
                    const int kx = px ? (ix ? 2 : 0) : 1;
                    const int dx = (px && !ix) ? 1 : 0;
                    const int tap = kz * 9 + ky * 3 + kx;
                    const int toff = ((dz * Ypi + dy) * Xpi + dx) * CIN;
                    uint4 ub[NT][KT];
#pragma unroll
                    for (int nt = 0; nt < NT; ++nt)
#pragma unroll
                        for (int kt = 0; kt < KT; ++kt)
                            ub[nt][kt] = gw[((tap * NT + nt) * KT + kt) * 64 + lane];
                    uint4 ua[4][KT];
#pragma unroll
                    for (int s = 0; s < 4; ++s)
#pragma unroll
                        for (int kt = 0; kt < KT; ++kt)
                            ua[s][kt] = *(const uint4*)(in + pA[s] + toff + kt * 32);
#pragma unroll
                    for (int s = 0; s < 4; ++s)
#pragma unroll
                        for (int kt = 0; kt < KT; ++kt)
#pragma unroll
                            for (int nt = 0; nt < NT; ++nt)
                                acc[s][nt] = __builtin_amdgcn_mfma_f32_16x16x32_bf16(
                                    __builtin_bit_cast(s16x8, ua[s][kt]),
                                    __builtin_bit_cast(s16x8, ub[nt][kt]), acc[s][nt], 0, 0, 0);
                }
            }
        }
    }

#pragma unroll
    for (int s = 0; s < 4; ++s) {
        const int vb = v0 + s * 16 + lg * 4;
        int opd[4]; float mm[4]; bool ok[4];
#pragma unroll
        for (int r = 0; r < 4; ++r) {
            int q = vb + r;
            ok[r] = q < Nq;
            int qc = ok[r] ? q : 0;
            int zq = qc / YXq; int rr = qc - zq * YXq; int yq = rr / Xq; int xq = rr - yq * Xq;
            int zz = 2 * zq + pz, yy = 2 * yq + py, xx = 2 * xq + px;
            mm[r] = (ok[r] && mask[(zz * Yo + yy) * Xo + xx]) ? 1.f : 0.f;
            opd[r] = ((zz + 1) * Ypo + (yy + 1)) * Xpo + (xx + 1);
        }
#pragma unroll
        for (int nt = 0; nt < NT; ++nt) {
            int co = nt * 16 + lr;
            float sc = scale[co], sh = shift[co];
#pragma unroll
            for (int r = 0; r < 4; ++r) {
                if (!ok[r]) continue;
                float yv = fmaxf(fmaf(acc[s][nt][r], sc, sh), 0.f) * mm[r];
                out[(size_t)opd[r] * COUT + co] = __float2bfloat16(yv);
            }
        }
    }
}

__global__ __launch_bounds__(256, 4) void conv_l1_mfma_k(
    const bf16* __restrict__ in, const bf16* __restrict__ wfrag,
    const float* __restrict__ scale, const float* __restrict__ shift,
    const uint8_t* __restrict__ mask, bf16* __restrict__ out,
    int Zo, int Yo, int Xo, int Ypi, int Xpi, int Ypo, int Xpo) {
    const int No = Zo * Yo * Xo;
    const int bid = xcd_swz(blockIdx.x, gridDim.x);
    const int tid = threadIdx.x;
    const int wv = tid >> 6, lane = tid & 63;
    const int lg = lane >> 4, lr = lane & 15;
    const int v0 = bid * 256 + wv * 64;
    if (v0 >= No) return;

    int vm = v0 + lane;
    bool mw = (vm < No) && (mask[vm] != 0);
    const bool anywork = (__ballot(mw) != 0ull);

    f32x4 acc[4];
#pragma unroll
    for (int s = 0; s < 4; ++s) acc[s] = (f32x4){0.f, 0.f, 0.f, 0.f};

    if (anywork) {
        const uint4* gw = (const uint4*)wfrag;
        uint4 bu[4];
#pragma unroll
        for (int kb = 0; kb < 4; ++kb) bu[kb] = gw[kb * 64 + lane];

        int vtf[4][2];
#pragma unroll
        for (int kb = 0; kb < 4; ++kb)
#pragma unroll
            for (int u = 0; u < 2; ++u) {
                int tp = kb * 8 + lg * 2 + u;
                int kz = tp / 9, r9 = tp - kz * 9, ky = r9 / 3, kx = r9 - ky * 3;
                vtf[kb][u] = (tp < 27) ? (((kz - 1) * Ypi + (ky - 1)) * Xpi + (kx - 1)) : 0;
            }

        int pV[4];
#pragma unroll
        for (int s = 0; s < 4; ++s) {
            int vr = v0 + s * 16 + lr;
            if (vr >= No) vr = 0;
            int zz = vr / (Yo * Xo); int rr = vr - zz * (Yo * Xo);
            int yy = rr / Xo; int xx = rr - yy * Xo;
            pV[s] = ((zz + 1) * Ypi + (yy + 1)) * Xpi + (xx + 1);
        }

#pragma unroll
        for (int kb = 0; kb < 4; ++kb) {
#pragma unroll
            for (int s = 0; s < 4; ++s) {
                uint2 a0 = *(const uint2*)(in + (size_t)(pV[s] + vtf[kb][0]) * 4);
                uint2 a1 = *(const uint2*)(in + (size_t)(pV[s] + vtf[kb][1]) * 4);
                int4 ai; ai.x = a0.x; ai.y = a0.y; ai.z = a1.x; ai.w = a1.y;
                acc[s] = __builtin_amdgcn_mfma_f32_16x16x32_bf16(
                    __builtin_bit_cast(s16x8, ai),
                    __builtin_bit_cast(s16x8, bu[kb]), acc[s], 0, 0, 0);
            }
        }
    }

#pragma unroll
    for (int s = 0; s < 4; ++s) {
        const int vb = v0 + s * 16 + lg * 4;
        int co = lr;
        float sc = scale[co], sh = shift[co];
#pragma unroll
        for (int r = 0; r < 4; ++r) {
            int v = vb + r;
            if (v >= No) continue;
            float mm = mask[v] ? 1.f : 0.f;
            int zz = v / (Yo * Xo); int rr = v - zz * (Yo * Xo);
            int yy = rr / Xo; int xx = rr - yy * Xo;
            int opd = ((zz + 1) * Ypo + (yy + 1)) * Xpo + (xx + 1);
            float yv = fmaxf(fmaf(acc[s][r], sc, sh), 0.f) * mm;
            out[(size_t)opd * 16 + co] = __float2bfloat16(yv);
        }
    }
}

inline int nblk(int n) { return (n + 255) / 256; }
inline int cdiv(int a, int b) { return (a + b - 1) / b; }

}  // namespace

extern "C" void kernel_launch(void* const* d_in, const int* in_sizes, int n_in,
                              void* d_out, int out_size, void* d_ws, size_t ws_size,
                              hipStream_t stream) {
    const float* feats = (const float*)d_in[0];
    const int* coords = (const int*)d_in[1];
    const int NVOX = in_sizes[0] / 4;

    const float *w1 = (const float*)d_in[3], *s1 = (const float*)d_in[4], *b1 = (const float*)d_in[5];
    const float *w2a = (const float*)d_in[6], *s2a = (const float*)d_in[7], *b2a = (const float*)d_in[8];
    const float *w2b = (const float*)d_in[9], *s2b = (const float*)d_in[10], *b2b = (const float*)d_in[11];
    const float *w3a = (const float*)d_in[12], *s3a = (const float*)d_in[13], *b3a = (const float*)d_in[14];
    const float *w3b = (const float*)d_in[15], *s3b = (const float*)d_in[16], *b3b = (const float*)d_in[17];
    const float *w4a = (const float*)d_in[18], *s4a = (const float*)d_in[19], *b4a = (const float*)d_in[20];
    const float *w4b = (const float*)d_in[21], *s4b = (const float*)d_in[22], *b4b = (const float*)d_in[23];
    const float *w5a = (const float*)d_in[24], *s5a = (const float*)d_in[25], *b5a = (const float*)d_in[26];
    const float *w5b = (const float*)d_in[27], *s5b = (const float*)d_in[28], *b5b = (const float*)d_in[29];

    char* ws = (char*)d_ws;
    size_t off = 0;
    auto alloc = [&](size_t bytes) -> void* {
        void* p = ws + off;
        off = (off + bytes + 255) & ~(size_t)255;
        return p;
    };

    uint8_t* m0 = (uint8_t*)alloc(NV0);
    uint8_t* m1 = (uint8_t*)alloc(NV0);
    uint8_t* m2 = (uint8_t*)alloc(NV2);
    uint8_t* m3 = (uint8_t*)alloc(NV3);
    uint8_t* m4 = (uint8_t*)alloc(NV4);
    uint8_t* m5 = (uint8_t*)alloc(NV0);

    bf16* slot0 = (bf16*)alloc((size_t)NP0 * 32 * 2);
    bf16* slot1 = (bf16*)alloc((size_t)NP0 * 16 * 2);

    bf16* dense0 = slot0;  // 4ch  @P0
    bf16* x1     = slot1;  // 16ch @P0
    bf16* x2a    = slot0;  // 32ch @P2
    bf16* x2b    = slot1;  // 32ch @P2
    bf16* x3a    = slot0;  // 64ch @P3
    bf16* x3b    = slot1;  // 64ch @P3
    bf16* x4a    = slot0;  // 32ch @P4
    bf16* x4b    = slot1;  // 32ch @(23,130,130)
    bf16* x5a    = slot0;  // 32ch @P0

    bf16* wfL1 = (bf16*)alloc(4 * 64 * 8 * 2);
    bf16* wf2a = (bf16*)alloc((size_t)14 * 2 * 64 * 16);
    bf16* wf2b = (bf16*)alloc((size_t)27 * 2 * 1 * 64 * 16);
    bf16* wf3a = (bf16*)alloc((size_t)27 * 4 * 1 * 64 * 16);
    bf16* wf3b = (bf16*)alloc((size_t)27 * 4 * 2 * 64 * 16);
    bf16* wf4a = (bf16*)alloc((size_t)27 * 2 * 2 * 64 * 16);
    bf16* wf4b = (bf16*)alloc((size_t)27 * 2 * 1 * 64 * 16);
    bf16* wf5a = (bf16*)alloc((size_t)27 * 2 * 1 * 64 * 16);
    bf16* wf5b32 = (bf16*)alloc((size_t)27 * 2 * 64 * 16);   // 32x32 frag order
    alloc(20u << 20);

    if (off > ws_size) {
        sentinel_k<<<1, 256, 0, stream>>>((float*)d_out);
        return;
    }

    // stage 0
    hipMemsetAsync(dense0, 0, (size_t)NP0 * 4 * 2, stream);
    hipMemsetAsync(m0, 0, NV0, stream);
    repack_frag_l1_k<<<1, 256, 0, stream>>>(w1, wfL1);
    repack_frag_c16_k<<<nblk(14 * 2 * 64), 256, 0, stream>>>(w2a, wf2a);
    repack_frag_k<<<nblk(27 * 2 * 64), 256, 0, stream>>>(w2b, wf2b, 32, 32, 0);
    repack_frag_k<<<nblk(27 * 4 * 64), 256, 0, stream>>>(w3a, wf3a, 32, 64, 0);
    repack_frag_k<<<nblk(27 * 8 * 64), 256, 0, stream>>>(w3b, wf3b, 64, 64, 0);
    repack_frag_k<<<nblk(27 * 4 * 64), 256, 0, stream>>>(w4a, wf4a, 64, 32, 1);
    repack_frag_k<<<nblk(27 * 2 * 64), 256, 0, stream>>>(w4b, wf4b, 32, 32, 0);
    repack_frag_k<<<nblk(27 * 2 * 64), 256, 0, stream>>>(w5a, wf5a, 32, 32, 1);
    repack_frag32_k<<<nblk(27 * 2 * 64), 256, 0, stream>>>(w5b, wf5b32);

    scatter_k<<<nblk(NVOX), 256, 0, stream>>>(feats, coords, dense0, m0, NVOX);

    // level 1
    dilate4_k<<<nblk(NV0 / 4), 256, 0, stream>>>(m0, m1, Z0, Y0, X0);
    halo_zero_k<16><<<nblk(NP0), 256, 0, stream>>>(x1, Z0, Y0, X0, ZP0, YP0, XP0);
    conv_l1_mfma_k<<<nblk(NV0), 256, 0, stream>>>(
        dense0, wfL1, s1, b1, m1, x1, Z0, Y0, X0, YP0, XP0, YP0, XP0);

    // level 2
    dilate_k<<<nblk(NV2), 256, 0, stream>>>(m1, m2, Z0, Y0, X0, Z2, Y2, X2, 2);
    halo_zero_k<32><<<nblk(NP2), 256, 0, stream>>>(x2a, Z2, Y2, X2, ZP2, YP2, XP2);
    conv_s2c16_k<<<nblk(NV2), 256, 0, stream>>>(
        x1, wf2a, s2a, b2a, m2, x2a, Z2, Y2, X2, YP0, XP0, YP2, XP2);
    halo_zero_k<32><<<nblk(NP2), 256, 0, stream>>>(x2b, Z2, Y2, X2, ZP2, YP2, XP2);
    {
        int nx = cdiv(X2, 32), ny = cdiv(Y2, 4), nz = cdiv(Z2, 4);
        conv_lds_k<false><<<nx * ny * nz, 512, 0, stream>>>(
            x2a, wf2b, s2b, b2b, m2, x2b, nullptr, Z2, Y2, X2, YP2, XP2, YP2, XP2, nx, ny);
    }

    // level 3
    dilate_k<<<nblk(NV3), 256, 0, stream>>>(m2, m3, Z2, Y2, X2, Z3, Y3, X3, 2);
    halo_zero_k<64><<<nblk(NP3), 256, 0, stream>>>(x3a, Z3, Y3, X3, ZP3, YP3, XP3);
    conv_mfma_k<32, 64, 2, 64, false><<<cdiv(NV3, 64), 64, 0, stream>>>(
        x2b, wf3a, s3a, b3a, m3, x3a, nullptr, Z3, Y3, X3, YP2, XP2, YP3, XP3);
    halo_zero_k<64><<<nblk(NP3), 256, 0, stream>>>(x3b, Z3, Y3, X3, ZP3, YP3, XP3);
    conv_mfma_k<64, 64, 1, 64, false><<<cdiv(NV3, 64), 64, 0, stream>>>(
        x3a, wf3b, s3b, b3b, m3, x3b, nullptr, Z3, Y3, X3, YP3, XP3, YP3, XP3);

    // level 4 (tconv up via parity octants)
    tdilate_k<<<nblk(NV4), 256, 0, stream>>>(m3, m4, Z3, Y3, X3, Z4, Y4, X4);
    halo_zero_k<32><<<nblk(NP4), 256, 0, stream>>>(x4a, Z4, Y4, X4, ZP4, YP4, XP4);
    {
        int maxNq = ((Z4 + 1) >> 1) * ((Y4 + 1) >> 1) * ((X4 + 1) >> 1);
        dim3 g(nblk(maxNq), 8);
        tconv_mfma_k<64, 32><<<g, 256, 0, stream>>>(
            x3b, wf4a, s4a, b4a, m4, x4a, Z4, Y4, X4, YP3, XP3, YP4, XP4);
    }
    halo_zero_k<32><<<nblk(NP2), 256, 0, stream>>>(x4b, Z4, Y4, X4, ZP2, YP2, XP2);
    {
        int nx = cdiv(X4, 32), ny = cdiv(Y4, 4), nz = cdiv(Z4, 4);
        conv_lds_k<false><<<nx * ny * nz, 512, 0, stream>>>(
            x4a, wf4b, s4b, b4b, m4, x4b, nullptr, Z4, Y4, X4, YP4, XP4, YP2, XP2, nx, ny);
    }

    // level 5 (tconv up, outpad (0,3,3)) — both kernels rolling-z pipelined
    tdilate4_k<<<nblk(NV0 / 4), 256, 0, stream>>>(m4, m5, Z4, Y4, X4, Z0, Y0, X0);
    halo_zero_k<32><<<nblk(NP0), 256, 0, stream>>>(x5a, Z0, Y0, X0, ZP0, YP0, XP0);
    {
        dim3 g((Y0 / 2 / 2) * (X0 / 2 / 32), 8);
        tconv_roll_k<<<g, 256, 0, stream>>>(
            x4b, wf5a, s5a, b5a, m5, x5a, Z0, Y0, X0, Z4, YP2, XP2, YP0, XP0, X0 / 2 / 32);
    }
    {
        conv_roll_k<<<(X0 / 32) * (Y0 / 8), 512, 0, stream>>>(
            x5a, wf5b32, s5b, b5b, m5, (float*)d_out);
    }
}

// Round 12
// 797.889 us; speedup vs baseline: 1.2514x; 1.0677x over previous
//
#include <hip/hip_runtime.h>
#include <hip/hip_bf16.h>
#include <stdint.h>

namespace {

constexpr int Z0 = 41, Y0 = 256, X0 = 256;
constexpr int Z2 = 21, Y2 = 128, X2 = 128;
constexpr int Z3 = 11, Y3 = 64,  X3 = 64;
constexpr int Z4 = 21, Y4 = 127, X4 = 127;
constexpr int NV0 = Z0 * Y0 * X0;
constexpr int NV2 = Z2 * Y2 * X2;
constexpr int NV3 = Z3 * Y3 * X3;
constexpr int NV4 = Z4 * Y4 * X4;

constexpr int ZP0 = 43, YP0 = 258, XP0 = 258; constexpr int NP0 = ZP0 * YP0 * XP0;
constexpr int ZP2 = 23, YP2 = 130, XP2 = 130; constexpr int NP2 = ZP2 * YP2 * XP2;
constexpr int ZP3 = 13, YP3 = 66,  XP3 = 66;  constexpr int NP3 = ZP3 * YP3 * XP3;
constexpr int ZP4 = 23, YP4 = 129, XP4 = 129; constexpr int NP4 = ZP4 * YP4 * XP4;

using bf16 = __hip_bfloat16;
typedef __attribute__((ext_vector_type(8))) short s16x8;
typedef __attribute__((ext_vector_type(4))) float f32x4;
typedef __attribute__((ext_vector_type(16))) float f32x16;
typedef __attribute__((ext_vector_type(4))) unsigned u32x4;

__device__ inline unsigned f2b(float f) {
    return (unsigned)__builtin_bit_cast(unsigned short, __float2bfloat16(f));
}

__device__ inline int xcd_swz(int bid, int nwg) {
    int q = nwg >> 3, r = nwg & 7;
    int x = bid & 7, j = bid >> 3;
    return (x < r ? x * (q + 1) : r * (q + 1) + (x - r) * q) + j;
}

__device__ inline void glds16(const bf16* g, void* l) {
    __builtin_amdgcn_global_load_lds(
        (const __attribute__((address_space(1))) void*)g,
        (__attribute__((address_space(3))) void*)l, 16, 0, 0);
}

__global__ __launch_bounds__(256) void sentinel_k(float* out) { out[0] = 12345.0f; }

__global__ __launch_bounds__(256) void scatter_k(const float* __restrict__ feats,
                                                 const int* __restrict__ coords,
                                                 bf16* __restrict__ dense,
                                                 uint8_t* __restrict__ m0, int n) {
    int v = blockIdx.x * 256 + threadIdx.x;
    if (v >= n) return;
    int z = coords[v * 4 + 1], y = coords[v * 4 + 2], x = coords[v * 4 + 3];
    m0[(z * Y0 + y) * X0 + x] = 1;
    int pp = ((z + 1) * YP0 + (y + 1)) * XP0 + (x + 1);
    uint2 u;
    u.x = f2b(feats[v * 4 + 0]) | (f2b(feats[v * 4 + 1]) << 16);
    u.y = f2b(feats[v * 4 + 2]) | (f2b(feats[v * 4 + 3]) << 16);
    *(uint2*)(dense + (size_t)pp * 4) = u;
}

template <int C>
__global__ __launch_bounds__(256) void halo_zero_k(bf16* __restrict__ buf,
                                                   int Zi, int Yi, int Xi,
                                                   int Zp, int Yp, int Xp) {
    int i = blockIdx.x * 256 + threadIdx.x;
    int tot = Zp * Yp * Xp;
    if (i >= tot) return;
    int x = i % Xp; int t = i / Xp; int y = t % Yp; int z = t / Yp;
    bool halo = (z < 1) | (z > Zi) | (y < 1) | (y > Yi) | (x < 1) | (x > Xi);
    if (!halo) return;
    uint4 zz = make_uint4(0, 0, 0, 0);
    uint4* p = (uint4*)(buf + (size_t)i * C);
#pragma unroll
    for (int j = 0; j < C / 8; ++j) p[j] = zz;
}

__global__ __launch_bounds__(256) void repack_frag_k(const float* __restrict__ w,
                                                     bf16* __restrict__ wf,
                                                     int CIN, int COUT, int TRANS) {
    int NT = COUT / 16, KT = CIN / 32;
    int i = blockIdx.x * 256 + threadIdx.x;
    int total = 27 * NT * KT * 64;
    if (i >= total) return;
    int lane = i & 63; int t = i >> 6;
    int kt = t % KT; t /= KT; int nt = t % NT; int tap = t / NT;
    int co = nt * 16 + (lane & 15);
    int ci0 = kt * 32 + (lane >> 4) * 8;
    unsigned e[8];
#pragma unroll
    for (int j = 0; j < 8; ++j) {
        int ci = ci0 + j;
        int src = TRANS ? ((ci * COUT + co) * 27 + tap) : ((co * CIN + ci) * 27 + tap);
        e[j] = f2b(w[src]);
    }
    uint4 u;
    u.x = e[0] | (e[1] << 16); u.y = e[2] | (e[3] << 16);
    u.z = e[4] | (e[5] << 16); u.w = e[6] | (e[7] << 16);
    ((uint4*)wf)[i] = u;
}

// 32x32x16 B-frag repack: wf[(tap*2+ks)*64+lane], elem j: B[k=(lane>>5)*8+j][col=lane&31]
__global__ __launch_bounds__(256) void repack_frag32_k(const float* __restrict__ w,
                                                       bf16* __restrict__ wf) {
    int i = blockIdx.x * 256 + threadIdx.x;
    if (i >= 27 * 2 * 64) return;
    int lane = i & 63; int t2 = i >> 6;
    int ks = t2 & 1; int tap = t2 >> 1;
    int co = lane & 31; int h = lane >> 5;
    unsigned e[8];
#pragma unroll
    for (int j = 0; j < 8; ++j) {
        int cin = ks * 16 + h * 8 + j;
        e[j] = f2b(w[(co * 32 + cin) * 27 + tap]);
    }
    uint4 u;
    u.x = e[0] | (e[1] << 16); u.y = e[2] | (e[3] << 16);
    u.z = e[4] | (e[5] << 16); u.w = e[6] | (e[7] << 16);
    ((uint4*)wf)[i] = u;
}

// CIN=16 stride-2 frag: K = 2 taps x 16ch, 14 pairs (tap 27 zero)
__global__ __launch_bounds__(256) void repack_frag_c16_k(const float* __restrict__ w,
                                                         bf16* __restrict__ wf) {
    int i = blockIdx.x * 256 + threadIdx.x;
    int total = 14 * 2 * 64;
    if (i >= total) return;
    int lane = i & 63; int t = i >> 6;
    int nt = t & 1; int p = t >> 1;
    int lg = lane >> 4, lr = lane & 15;
    int co = nt * 16 + lr;
    unsigned e[8];
#pragma unroll
    for (int j = 0; j < 8; ++j) {
        int tap = 2 * p + (lg >> 1);
        int ci = (lg & 1) * 8 + j;
        e[j] = (tap < 27) ? f2b(w[(co * 16 + ci) * 27 + tap]) : 0u;
    }
    uint4 u;
    u.x = e[0] | (e[1] << 16); u.y = e[2] | (e[3] << 16);
    u.z = e[4] | (e[5] << 16); u.w = e[6] | (e[7] << 16);
    ((uint4*)wf)[i] = u;
}

__global__ __launch_bounds__(256) void repack_frag_l1_k(const float* __restrict__ w,
                                                        bf16* __restrict__ wf) {
    int i = blockIdx.x * 256 + threadIdx.x;
    if (i >= 256) return;
    int lane = i & 63, kb = i >> 6;
    int lg = lane >> 4, lr = lane & 15;
    unsigned e[8];
#pragma unroll
    for (int j = 0; j < 8; ++j) {
        int tap = kb * 8 + lg * 2 + (j >> 2);
        int ci = j & 3;
        e[j] = (tap < 27) ? f2b(w[(lr * 4 + ci) * 27 + tap]) : 0u;
    }
    uint4 u;
    u.x = e[0] | (e[1] << 16); u.y = e[2] | (e[3] << 16);
    u.z = e[4] | (e[5] << 16); u.w = e[6] | (e[7] << 16);
    ((uint4*)wf)[i] = u;
}

__global__ __launch_bounds__(256) void dilate_k(const uint8_t* __restrict__ in,
                                                uint8_t* __restrict__ out,
                                                int Zi, int Yi, int Xi,
                                                int Zo, int Yo, int Xo, int stride) {
    int idx = blockIdx.x * 256 + threadIdx.x;
    int total = Zo * Yo * Xo;
    if (idx >= total) return;
    int x = idx % Xo; int t = idx / Xo; int y = t % Yo; int z = t / Yo;
    int YX = Yi * Xi;
    uint8_t r = 0;
    for (int kz = 0; kz < 3; ++kz) {
        int zi = z * stride + kz - 1;
        if ((unsigned)zi >= (unsigned)Zi) continue;
        for (int ky = 0; ky < 3; ++ky) {
            int yi = y * stride + ky - 1;
            if ((unsigned)yi >= (unsigned)Yi) continue;
            for (int kx = 0; kx < 3; ++kx) {
                int xi = x * stride + kx - 1;
                if ((unsigned)xi >= (unsigned)Xi) continue;
                r |= in[zi * YX + yi * Xi + xi];
            }
        }
    }
    out[idx] = r ? 1 : 0;
}

__global__ __launch_bounds__(256) void dilate4_k(const uint8_t* __restrict__ in,
                                                 uint8_t* __restrict__ out,
                                                 int Z, int Y, int X) {
    int ngx = X >> 2;
    int g = blockIdx.x * 256 + threadIdx.x;
    int total = Z * Y * ngx;
    if (g >= total) return;
    int gx = g % ngx; int t = g / ngx; int y = t % Y; int z = t / Y;
    const int YX = Y * X;
    unsigned r = 0;
    for (int kz = 0; kz < 3; ++kz) {
        int zi = z + kz - 1;
        if ((unsigned)zi >= (unsigned)Z) continue;
        for (int ky = 0; ky < 3; ++ky) {
            int yi = y + ky - 1;
            if ((unsigned)yi >= (unsigned)Y) continue;
            const unsigned* rw = (const unsigned*)(in + zi * YX + yi * X);
            unsigned u1 = rw[gx];
            unsigned u0 = gx ? rw[gx - 1] : 0u;
            unsigned u2 = (gx + 1 < ngx) ? rw[gx + 1] : 0u;
            r |= u1 | ((u1 << 8) | (u0 >> 24)) | ((u1 >> 8) | (u2 << 24));
        }
    }
    r |= r >> 4; r |= r >> 2; r |= r >> 1; r &= 0x01010101u;
    ((unsigned*)out)[g] = r;
}

__global__ __launch_bounds__(256) void tdilate_k(const uint8_t* __restrict__ in,
                                                 uint8_t* __restrict__ out,
                                                 int Zi, int Yi, int Xi,
                                                 int Zo, int Yo, int Xo) {
    int idx = blockIdx.x * 256 + threadIdx.x;
    int total = Zo * Yo * Xo;
    if (idx >= total) return;
    int x = idx % Xo; int t = idx / Xo; int y = t % Yo; int z = t / Yo;
    int YX = Yi * Xi;
    uint8_t r = 0;
    for (int kz = 0; kz < 3; ++kz) {
        int tz = z + 1 - kz;
        if (tz & 1) continue;
        int zi = tz >> 1;
        if ((unsigned)zi >= (unsigned)Zi) continue;
        for (int ky = 0; ky < 3; ++ky) {
            int ty = y + 1 - ky;
            if (ty & 1) continue;
            int yi = ty >> 1;
            if ((unsigned)yi >= (unsigned)Yi) continue;
            for (int kx = 0; kx < 3; ++kx) {
                int tx = x + 1 - kx;
                if (tx & 1) continue;
                int xi = tx >> 1;
                if ((unsigned)xi >= (unsigned)Xi) continue;
                r |= in[zi * YX + yi * Xi + xi];
            }
        }
    }
    out[idx] = r ? 1 : 0;
}

__global__ __launch_bounds__(256) void tdilate4_k(const uint8_t* __restrict__ in,
                                                  uint8_t* __restrict__ out,
                                                  int Zi, int Yi, int Xi,
                                                  int Zo, int Yo, int Xo) {
    int ngx = Xo >> 2;
    int g = blockIdx.x * 256 + threadIdx.x;
    int total = Zo * Yo * ngx;
    if (g >= total) return;
    int gx = g % ngx; int t = g / ngx; int y = t % Yo; int z = t / Yo;
    int YX = Yi * Xi;
    int j0 = gx * 2;
    unsigned r0 = 0, r1 = 0, r2 = 0, r3 = 0;
    for (int kz = 0; kz < 3; ++kz) {
        int tz = z + 1 - kz;
        if (tz & 1) continue;
        int zi = tz >> 1;
        if ((unsigned)zi >= (unsigned)Zi) continue;
        for (int ky = 0; ky < 3; ++ky) {
            int ty = y + 1 - ky;
            if (ty & 1) continue;
            int yi = ty >> 1;
            if ((unsigned)yi >= (unsigned)Yi) continue;
            const uint8_t* rp = in + zi * YX + yi * Xi;
            unsigned b0 = (j0 < Xi) ? rp[j0] : 0u;
            unsigned b1 = (j0 + 1 < Xi) ? rp[j0 + 1] : 0u;
            unsigned b2 = (j0 + 2 < Xi) ? rp[j0 + 2] : 0u;
            r0 |= b0; r1 |= b0 | b1; r2 |= b1; r3 |= b1 | b2;
        }
    }
    unsigned rr = (r0 ? 1u : 0u) | (r1 ? 0x100u : 0u) | (r2 ? 0x10000u : 0u) | (r3 ? 0x1000000u : 0u);
    ((unsigned*)out)[g] = rr;
}

// ---- rolling-z pipelined conv 32->32 (L5b), W=2 rows/wave, 1 wave/SIMD ----
// 256 thr = 4 waves; wave w owns output rows y0+2w, y0+2w+1 (full cout).
// Per (dz,dx,ks): 4 row-fragment ds_reads feed 6 MFMAs (1.5x less LDS traffic).
// B via LDS->ds_read->VGPR (un-remat'able); 512-reg budget at 1 wave/SIMD.
// 4-slab ring (10 rows each); stage(z+3) at iter TOP, drained after compute.
// Grid: 8(x) x 32(y) x 2(z-segments) = 512 blocks.
__global__ __launch_bounds__(256, 1) void conv_roll_k(
    const bf16* __restrict__ in, const bf16* __restrict__ wfrag,
    const float* __restrict__ scale, const float* __restrict__ shift,
    const uint8_t* __restrict__ mask, float* __restrict__ outf) {
    constexpr int ROWB = 2176;           // 2 ks x 2 h x 34 voxels x 16B
    constexpr int SLABB = 24576;         // 10 rows = 21760 used + pad (1536 chunk slots)
    __shared__ uint4 ring4[4 * SLABB / 16];
    char* ring = (char*)ring4;

    const int bid = xcd_swz(blockIdx.x, gridDim.x);
    const int tx = bid & 7;
    const int t2 = bid >> 3;
    const int ty = t2 & 31;
    const int zs = t2 >> 5;
    const int y0 = ty * 8, x0 = tx * 32;
    const int zlo = zs ? 21 : 0;
    const int zcnt = zs ? 20 : 21;

    const int tid = threadIdx.x;
    const int w = tid >> 6, lane = tid & 63;
    const int vx = lane & 31, h = lane >> 5;

    // ---- prologue A: stage B (3456 x 16B chunks) into ring[0..55296) ----
#pragma unroll
    for (int k = 0; k < 14; ++k) {
        int base = k * 256 + w * 64;
        if (base < 27 * 2 * 64)
            glds16(wfrag + (size_t)(base + lane) * 8, ring + base * 16);
    }
    asm volatile("s_waitcnt vmcnt(0)" ::: "memory");
    __syncthreads();

    u32x4 breg[27][2];
#pragma unroll
    for (int t = 0; t < 27; ++t) {
        breg[t][0] = *(const u32x4*)(ring + (t * 2 + 0) * 1024 + lane * 16);
        breg[t][1] = *(const u32x4*)(ring + (t * 2 + 1) * 1024 + lane * 16);
    }
    __syncthreads();

    // per-lane SOURCE offsets for the 6 staged chunks (dest pad for i>=1360)
    int soff[6];
#pragma unroll
    for (int k = 0; k < 6; ++k) {
        int i = tid + k * 256;
        int ii = i < 1360 ? i : 0;               // clamp SOURCE only
        int row = ii / 136, c = ii - row * 136;
        int ks = c / 68, r2 = c - ks * 68, hh = r2 / 34, v = r2 - hh * 34;
        soff[k] = ((y0 + row) * XP0 + (x0 + v)) * 32 + (2 * ks + hh) * 8;
    }
    auto stagefn = [&](int p, char* slab) {
        int zp = p < ZP0 ? p : ZP0 - 1;
        const bf16* pb = in + (size_t)zp * ((size_t)YP0 * XP0 * 32);
#pragma unroll
        for (int k = 0; k < 6; ++k)
            glds16(pb + soff[k], slab + (k * 256 + w * 64) * 16);
    };

    // A read row bases: local rows 2w+fr (fr=0..3)
    int rb[4];
#pragma unroll
    for (int fr = 0; fr < 4; ++fr)
        rb[fr] = (2 * w + fr) * ROWB + h * 544 + vx * 16;

    const float sc = scale[vx], sh = shift[vx];

    stagefn(zlo + 0, ring);
    stagefn(zlo + 1, ring + SLABB);
    stagefn(zlo + 2, ring + 2 * SLABB);
    asm volatile("s_waitcnt vmcnt(0)" ::: "memory");
    __builtin_amdgcn_s_barrier();

    int s0 = 0;
    for (int zi = 0; zi < zcnt; ++zi) {
        const int z = zlo + zi;
        // stage plane z+3 into the slot freed last iter
        stagefn(z + 3, ring + ((s0 + 3) & 3) * SLABB);

        // masks for this wave's two rows
        unsigned mk0[4], mk1[4];
        {
            const uint8_t* mr0 = mask + ((size_t)z * Y0 + (y0 + 2 * w)) * X0 + x0 + 4 * h;
            const uint8_t* mr1 = mr0 + X0;
            mk0[0] = *(const unsigned*)(mr0);      mk0[1] = *(const unsigned*)(mr0 + 8);
            mk0[2] = *(const unsigned*)(mr0 + 16); mk0[3] = *(const unsigned*)(mr0 + 24);
            mk1[0] = *(const unsigned*)(mr1);      mk1[1] = *(const unsigned*)(mr1 + 8);
            mk1[2] = *(const unsigned*)(mr1 + 16); mk1[3] = *(const unsigned*)(mr1 + 24);
        }

        const char* slp0 = ring + s0 * SLABB;
        const char* slp1 = ring + ((s0 + 1) & 3) * SLABB;
        const char* slp2 = ring + ((s0 + 2) & 3) * SLABB;

        f32x16 acc0, acc1;
#pragma unroll
        for (int i = 0; i < 16; ++i) { acc0[i] = 0.f; acc1[i] = 0.f; }

#pragma unroll
        for (int dz = 0; dz < 3; ++dz) {
            const char* slab = dz == 0 ? slp0 : (dz == 1 ? slp1 : slp2);
#pragma unroll
            for (int dx = 0; dx < 3; ++dx) {
#pragma unroll
                for (int ks = 0; ks < 2; ++ks) {
                    const int ko = ks * 1088 + dx * 16;
                    u32x4 a0 = *(const u32x4*)(slab + rb[0] + ko);
                    u32x4 a1 = *(const u32x4*)(slab + rb[1] + ko);
                    u32x4 a2 = *(const u32x4*)(slab + rb[2] + ko);
                    u32x4 a3 = *(const u32x4*)(slab + rb[3] + ko);
                    const int t0 = dz * 9 + 0 * 3 + dx;
                    const int t1 = dz * 9 + 1 * 3 + dx;
                    const int t2_ = dz * 9 + 2 * 3 + dx;
                    acc0 = __builtin_amdgcn_mfma_f32_32x32x16_bf16(
                        __builtin_bit_cast(s16x8, a0), __builtin_bit_cast(s16x8, breg[t0][ks]), acc0, 0, 0, 0);
                    acc1 = __builtin_amdgcn_mfma_f32_32x32x16_bf16(
                        __builtin_bit_cast(s16x8, a1), __builtin_bit_cast(s16x8, breg[t0][ks]), acc1, 0, 0, 0);
                    acc0 = __builtin_amdgcn_mfma_f32_32x32x16_bf16(
                        __builtin_bit_cast(s16x8, a1), __builtin_bit_cast(s16x8, breg[t1][ks]), acc0, 0, 0, 0);
                    acc1 = __builtin_amdgcn_mfma_f32_32x32x16_bf16(
                        __builtin_bit_cast(s16x8, a2), __builtin_bit_cast(s16x8, breg[t1][ks]), acc1, 0, 0, 0);
                    acc0 = __builtin_amdgcn_mfma_f32_32x32x16_bf16(
                        __builtin_bit_cast(s16x8, a2), __builtin_bit_cast(s16x8, breg[t2_][ks]), acc0, 0, 0, 0);
                    acc1 = __builtin_amdgcn_mfma_f32_32x32x16_bf16(
                        __builtin_bit_cast(s16x8, a3), __builtin_bit_cast(s16x8, breg[t2_][ks]), acc1, 0, 0, 0);
                }
            }
        }

        // epilogue: 2 rows; C row(voxel-x) = (reg&3)+8*(reg>>2)+4*h, col = vx
        const size_t ob0 = (size_t)vx * NV0 + ((size_t)z * Y0 + (y0 + 2 * w)) * X0 + x0 + 4 * h;
        const size_t ob1 = ob0 + X0;
#pragma unroll
        for (int q = 0; q < 4; ++q) {
            f32x4 o0, o1;
#pragma unroll
            for (int r = 0; r < 4; ++r) {
                float m0 = (float)((mk0[q] >> (8 * r)) & 1);
                float m1 = (float)((mk1[q] >> (8 * r)) & 1);
                o0[r] = fmaxf(fmaf(acc0[q * 4 + r], sc, sh), 0.f) * m0;
                o1[r] = fmaxf(fmaf(acc1[q * 4 + r], sc, sh), 0.f) * m1;
            }
            *(f32x4*)(outf + ob0 + 8 * q) = o0;
            *(f32x4*)(outf + ob1 + 8 * q) = o1;
        }

        // drain stage (older than the 8 stores); keep stores in flight
        asm volatile("s_waitcnt vmcnt(8)" ::: "memory");
        __builtin_amdgcn_s_barrier();
        s0 = (s0 + 1) & 3;
    }
}

// ---- rolling-z pipelined transposed conv 32->32 (L5a) via parity octants ----
__global__ __launch_bounds__(256, 3) void tconv_roll_k(
    const bf16* __restrict__ in, const bf16* __restrict__ wfrag,
    const float* __restrict__ scale, const float* __restrict__ shift,
    const uint8_t* __restrict__ mask, bf16* __restrict__ out,
    int Zo, int Yo, int Xo, int Zi, int Ypi, int Xpi, int Ypo, int Xpo, int nx) {
    constexpr int ROWB = 34 * 64;
    constexpr int SLABB = 3 * ROWB;
    __shared__ uint4 ring4[4 * SLABB / 16];
    char* ring = (char*)ring4;

    const int oct = blockIdx.y;
    const int pz = oct >> 2, py = (oct >> 1) & 1, px = oct & 1;
    const int Zq = (Zo - pz + 1) >> 1;

    const int bid = xcd_swz(blockIdx.x, gridDim.x);
    const int tx = bid % nx, ty = bid / nx;
    const int yq0 = ty * 2, xq0 = tx * 32;

    const int tid = threadIdx.x;
    const int w = tid >> 6, lane = tid & 63;
    const int lg = lane >> 4, lr = lane & 15;
    const int yr = w >> 1, xh = w & 1;

    const int kz0 = pz ? 0 : 1, dzo0 = pz ? 1 : 0;
    const int ky0 = py ? 0 : 1, dyo0 = py ? 1 : 0;
    const int kx0 = px ? 0 : 1, dxo0 = px ? 1 : 0;

    auto stagefn = [&](int p, int slot) {
        if (w < 3) {
            int zs = p < Zi ? p : Zi - 1;
            char* slab = ring + slot * SLABB + w * ROWB;
            const bf16* pb = in + ((size_t)(zs + 1) * Ypi + (yq0 + 1 + w)) * (size_t)Xpi * 32
                                + (size_t)(xq0 + 1) * 32;
            int u0 = lane;      glds16(pb + (u0 ^ ((u0 >> 3) & 7)) * 8, slab);
            int u1 = 64 + lane; glds16(pb + (u1 ^ ((u1 >> 3) & 7)) * 8, slab + 1024);
            if (lane < 8) { int u2 = 128 + lane; glds16(pb + u2 * 8, slab + 2048); }
        }
    };

    const uint4* gw = (const uint4*)wfrag;
    uint4 breg[2][2][2][2];
#pragma unroll
    for (int iz = 0; iz < 2; ++iz) {
        int kz = iz ? 2 : kz0;
#pragma unroll
        for (int iy = 0; iy < 2; ++iy) {
            int ky = iy ? 2 : ky0;
#pragma unroll
            for (int ix = 0; ix < 2; ++ix) {
                int kx = ix ? 2 : kx0;
                int tap = kz * 9 + ky * 3 + kx;
                breg[iz][iy][ix][0] = gw[(tap * 2 + 0) * 64 + lane];
                breg[iz][iy][ix][1] = gw[(tap * 2 + 1) * 64 + lane];
            }
        }
    }

    int b0 = (xh * 16 + lr + dxo0) * 64 + lg * 16;
    int b1 = (xh * 16 + lr) * 64 + lg * 16;
    const int aswA = b0 ^ (((b0 >> 7) & 7) << 4);
    const int aswB = b1 ^ (((b1 >> 7) & 7) << 4);
    const int rowA = (yr + dyo0) * ROWB;
    const int rowB = yr * ROWB;

    const float sc0 = scale[lr], sh0 = shift[lr];
    const float sc1 = scale[16 + lr], sh1 = shift[16 + lr];

    const int yout = 2 * (yq0 + yr) + py;
    const int xb = 2 * (xq0 + xh * 16 + lg * 4) + px;

    stagefn(0, 0); stagefn(1, 1); stagefn(2, 2);
    uint2 mv;
    mv = *(const uint2*)(mask + ((size_t)pz * Yo + yout) * Xo + (xb - px));
    asm volatile("s_waitcnt vmcnt(0)" ::: "memory");
    __builtin_amdgcn_s_barrier();

    int rs0 = 0, wslot = 3;
    for (int zq = 0; zq < Zq; ++zq) {
        uint2 nv;
        {
            int zqn = (zq + 1 < Zq) ? zq + 1 : Zq - 1;
            nv = *(const uint2*)(mask + ((size_t)(2 * zqn + pz) * Yo + yout) * Xo + (xb - px));
        }
        stagefn(zq + 3, wslot);

        int rs1 = rs0 + 1 < 4 ? rs0 + 1 : 0;
        const char* sl_0 = ring + rs0 * SLABB;
        const char* sl_1 = ring + rs1 * SLABB;
        const char* slz0 = pz ? sl_1 : sl_0;
        const char* slz1 = sl_0;

        f32x4 acc0 = (f32x4){0, 0, 0, 0}, acc1 = (f32x4){0, 0, 0, 0};
#pragma unroll
        for (int iz = 0; iz < 2; ++iz) {
            if (iz > pz) continue;
            const char* slab = iz ? slz1 : slz0;
#pragma unroll
            for (int iy = 0; iy < 2; ++iy) {
                if (iy > py) continue;
                const char* rowp = slab + (iy ? rowB : rowA);
#pragma unroll
                for (int ix = 0; ix < 2; ++ix) {
                    if (ix > px) continue;
                    uint4 a = *(const uint4*)(rowp + (ix ? aswB : aswA));
                    acc0 = __builtin_amdgcn_mfma_f32_16x16x32_bf16(
                        __builtin_bit_cast(s16x8, a),
                        __builtin_bit_cast(s16x8, breg[iz][iy][ix][0]), acc0, 0, 0, 0);
                    acc1 = __builtin_amdgcn_mfma_f32_16x16x32_bf16(
                        __builtin_bit_cast(s16x8, a),
                        __builtin_bit_cast(s16x8, breg[iz][iy][ix][1]), acc1, 0, 0, 0);
                }
            }
        }

        const int zout = 2 * zq + pz;
        const size_t opdbase = ((size_t)(zout + 1) * Ypo + (yout + 1)) * Xpo;
#pragma unroll
        for (int r = 0; r < 4; ++r) {
            unsigned word = (r < 2) ? mv.x : mv.y;
            float m = (float)((word >> (px * 8 + (r & 1) * 16)) & 1);
            float v0 = fmaxf(fmaf(acc0[r], sc0, sh0), 0.f) * m;
            float v1 = fmaxf(fmaf(acc1[r], sc1, sh1), 0.f) * m;
            size_t opd = opdbase + (size_t)(xb + 2 * r + 1);
            out[opd * 32 + lr]      = __float2bfloat16(v0);
            out[opd * 32 + 16 + lr] = __float2bfloat16(v1);
        }

        asm volatile("s_waitcnt vmcnt(20)" ::: "memory");
        __builtin_amdgcn_s_barrier();
        rs0 = rs1;
        wslot = wslot + 1 < 4 ? wslot + 1 : 0;
        mv = nv;
    }
}

// LDS-tiled MFMA stride-1 conv, CIN=COUT=32 (L2b, L4b)
template <bool FINAL>
__global__ __launch_bounds__(512, 4) void conv_lds_k(
    const bf16* __restrict__ in, const bf16* __restrict__ wfrag,
    const float* __restrict__ scale, const float* __restrict__ shift,
    const uint8_t* __restrict__ mask, bf16* __restrict__ out, float* __restrict__ outf,
    int Zo, int Yo, int Xo, int Ypi, int Xpi, int Ypo, int Xpo, int nx, int ny) {
    constexpr int ROWB = 34 * 64;
    __shared__ uint4 tile4[36 * ROWB / 16];
    char* tile = (char*)tile4;

    const int No = Zo * Yo * Xo;
    const int bid = xcd_swz(blockIdx.x, gridDim.x);
    int tx = bid % nx; int tt = bid / nx; int ty = tt % ny; int tz = tt / ny;
    const int z0 = tz * 4, y0 = ty * 4, x0 = tx * 32;

    const int tid = threadIdx.x;
    const int w = tid >> 6, lane = tid & 63, lg = lane >> 4, lr = lane & 15;

    int anywork;
    {
        int row = tid >> 5, xl = tid & 31;
        int zz = z0 + (row >> 2), yy = y0 + (row & 3), xx = x0 + xl;
        int ok = (zz < Zo) && (yy < Yo) && (xx < Xo) && mask[((size_t)zz * Yo + yy) * Xo + xx];
        anywork = __syncthreads_or(ok);
    }

    f32x4 acc[4][2];
#pragma unroll
    for (int s = 0; s < 4; ++s) { acc[s][0] = (f32x4){0,0,0,0}; acc[s][1] = (f32x4){0,0,0,0}; }

    if (anywork) {
        const int lsw = (lane ^ ((lane >> 3) & 7)) * 8;
        for (int rr = w; rr < 36; rr += 8) {
            int dz = rr / 6, dy = rr % 6;
            const bf16* g = in + ((size_t)(z0 + dz) * Ypi + (y0 + dy)) * Xpi * 32 + (size_t)x0 * 32;
            char* l = tile + rr * ROWB;
            glds16(g + lsw, l);
            glds16(g + 512 + lsw, l + 1024);
            if (lane < 8) glds16(g + 1024 + lane * 8, l + 2048);
        }
        asm volatile("s_waitcnt vmcnt(0)" ::: "memory");
        __syncthreads();

        int rbB[4], bsw[4][3];
#pragma unroll
        for (int s = 0; s < 4; ++s) {
            int lrow = 2 * w + (s >> 1);
            rbB[s] = ((lrow >> 2) * 6 + (lrow & 3)) * ROWB;
            int xpart = (s & 1) * 16 + lr;
#pragma unroll
            for (int dx = 0; dx < 3; ++dx) {
                int b = (xpart + dx) * 64 + lg * 16;
                bsw[s][dx] = b ^ (((b >> 7) & 7) << 4);
            }
        }

        const uint4* gw = (const uint4*)wfrag;
#pragma unroll 1
        for (int dz = 0; dz < 3; ++dz) {
#pragma unroll
            for (int dy = 0; dy < 3; ++dy) {
                const int rowoff = (dz * 6 + dy) * ROWB;
#pragma unroll
                for (int dx = 0; dx < 3; ++dx) {
                    const int tap = dz * 9 + dy * 3 + dx;
                    uint4 b0 = gw[(tap * 2 + 0) * 64 + lane];
                    uint4 b1 = gw[(tap * 2 + 1) * 64 + lane];
                    uint4 ua[4];
#pragma unroll
                    for (int s = 0; s < 4; ++s)
                        ua[s] = *(const uint4*)(tile + rbB[s] + rowoff + bsw[s][dx]);
#pragma unroll
                    for (int s = 0; s < 4; ++s) {
                        acc[s][0] = __builtin_amdgcn_mfma_f32_16x16x32_bf16(
                            __builtin_bit_cast(s16x8, ua[s]),
                            __builtin_bit_cast(s16x8, b0), acc[s][0], 0, 0, 0);
                        acc[s][1] = __builtin_amdgcn_mfma_f32_16x16x32_bf16(
                            __builtin_bit_cast(s16x8, ua[s]),
                            __builtin_bit_cast(s16x8, b1), acc[s][1], 0, 0, 0);
                    }
                }
            }
        }
    }

#pragma unroll
    for (int s = 0; s < 4; ++s) {
        int lrow = 2 * w + (s >> 1);
        int zz = z0 + (lrow >> 2), yy = y0 + (lrow & 3);
        int xv = x0 + (s & 1) * 16 + lg * 4;
        bool rowok = (zz < Zo) && (yy < Yo);
        if (!rowok) continue;
        size_t idx0 = ((size_t)zz * Yo + yy) * Xo + xv;
        float mm[4];
#pragma unroll
        for (int r = 0; r < 4; ++r)
            mm[r] = (xv + r < Xo && mask[idx0 + r]) ? 1.f : 0.f;
        if constexpr (FINAL) {
#pragma unroll
            for (int nt = 0; nt < 2; ++nt) {
                int co = nt * 16 + lr;
                float sc = scale[co], sh = shift[co];
                f32x4 o;
#pragma unroll
                for (int r = 0; r < 4; ++r)
                    o[r] = fmaxf(fmaf(acc[s][nt][r], sc, sh), 0.f) * mm[r];
                if (xv + 3 < Xo) {
                    *(f32x4*)(outf + (size_t)co * No + idx0) = o;
                } else {
#pragma unroll
                    for (int r = 0; r < 4; ++r)
                        if (xv + r < Xo) outf[(size_t)co * No + idx0 + r] = o[r];
                }
            }
        } else {
            int opd = ((zz + 1) * Ypo + (yy + 1)) * Xpo + (xv + 1);
#pragma unroll
            for (int nt = 0; nt < 2; ++nt) {
                int co = nt * 16 + lr;
                float sc = scale[co], sh = shift[co];
#pragma unroll
                for (int r = 0; r < 4; ++r) {
                    if (xv + r >= Xo) continue;
                    float yv = fmaxf(fmaf(acc[s][nt][r], sc, sh), 0.f) * mm[r];
                    out[(size_t)(opd + r) * 32 + co] = __float2bfloat16(yv);
                }
            }
        }
    }
}

// global-load MFMA conv, generic stride & block size (L3a, L3b)
template <int CIN, int COUT, int STRIDE, int BLK, bool FINAL>
__global__ __launch_bounds__(BLK, ((CIN <= 32 && COUT <= 32) ? 4 : 2)) void conv_mfma_k(
    const bf16* __restrict__ in, const bf16* __restrict__ wfrag,
    const float* __restrict__ scale, const float* __restrict__ shift,
    const uint8_t* __restrict__ mask, bf16* __restrict__ out, float* __restrict__ outf,
    int Zo, int Yo, int Xo, int Ypi, int Xpi, int Ypo, int Xpo) {
    constexpr int NT = COUT / 16;
    constexpr int KT = CIN / 32;
    const int No = Zo * Yo * Xo;
    const int bid = xcd_swz(blockIdx.x, gridDim.x);
    const int tid = threadIdx.x;
    const int wv = tid >> 6, lane = tid & 63;
    const int lg = lane >> 4, lr = lane & 15;
    const int v0 = bid * BLK + wv * 64;
    if (v0 >= No) return;

    int vm = v0 + lane;
    bool mw = (vm < No) && (mask[vm] != 0);
    const bool anywork = (__ballot(mw) != 0ull);

    f32x4 acc[4][NT];
#pragma unroll
    for (int s = 0; s < 4; ++s)
#pragma unroll
        for (int nt = 0; nt < NT; ++nt) acc[s][nt] = (f32x4){0.f, 0.f, 0.f, 0.f};

    const uint4* gw = (const uint4*)wfrag;

    if (anywork) {
        int pA[4];
#pragma unroll
        for (int s = 0; s < 4; ++s) {
            int vr = v0 + s * 16 + lr;
            if (vr >= No) vr = 0;
            int zz = vr / (Yo * Xo); int rr = vr - zz * (Yo * Xo);
            int yy = rr / Xo; int xx = rr - yy * Xo;
            pA[s] = (((zz * STRIDE + 1) * Ypi + (yy * STRIDE + 1)) * Xpi + (xx * STRIDE + 1)) * CIN + lg * 8;
        }
#pragma unroll
        for (int tap = 0; tap < 27; ++tap) {
            const int kz = tap / 9, r9 = tap - kz * 9, ky = r9 / 3, kx = r9 - ky * 3;
            const int toff = (((kz - 1) * Ypi + (ky - 1)) * Xpi + (kx - 1)) * CIN;
            uint4 ub[NT][KT];
#pragma unroll
            for (int nt = 0; nt < NT; ++nt)
#pragma unroll
                for (int kt = 0; kt < KT; ++kt)
                    ub[nt][kt] = gw[((tap * NT + nt) * KT + kt) * 64 + lane];
            uint4 ua[4][KT];
#pragma unroll
            for (int s = 0; s < 4; ++s)
#pragma unroll
                for (int kt = 0; kt < KT; ++kt)
                    ua[s][kt] = *(const uint4*)(in + pA[s] + toff + kt * 32);
#pragma unroll
            for (int s = 0; s < 4; ++s)
#pragma unroll
                for (int kt = 0; kt < KT; ++kt)
#pragma unroll
                    for (int nt = 0; nt < NT; ++nt)
                        acc[s][nt] = __builtin_amdgcn_mfma_f32_16x16x32_bf16(
                            __builtin_bit_cast(s16x8, ua[s][kt]),
                            __builtin_bit_cast(s16x8, ub[nt][kt]), acc[s][nt], 0, 0, 0);
        }
    }

#pragma unroll
    for (int s = 0; s < 4; ++s) {
        const int vb = v0 + s * 16 + lg * 4;
        int opd[4]; float mm[4]; bool ok[4];
#pragma unroll
        for (int r = 0; r < 4; ++r) {
            int v = vb + r;
            ok[r] = v < No;
            int vc = ok[r] ? v : 0;
            mm[r] = (ok[r] && mask[vc]) ? 1.f : 0.f;
            int zz = vc / (Yo * Xo); int rr = vc - zz * (Yo * Xo);
            int yy = rr / Xo; int xx = rr - yy * Xo;
            opd[r] = FINAL ? vc : ((zz + 1) * Ypo + (yy + 1)) * Xpo + (xx + 1);
        }
#pragma unroll
        for (int nt = 0; nt < NT; ++nt) {
            int co = nt * 16 + lr;
            float sc = scale[co], sh = shift[co];
#pragma unroll
            for (int r = 0; r < 4; ++r) {
                if (!ok[r]) continue;
                float yv = fmaxf(fmaf(acc[s][nt][r], sc, sh), 0.f) * mm[r];
                if constexpr (FINAL) outf[(size_t)co * No + opd[r]] = yv;
                else out[(size_t)opd[r] * COUT + co] = __float2bfloat16(yv);
            }
        }
    }
}

// stride-2 CIN=16 MFMA conv (L2a)
__global__ __launch_bounds__(256, 4) void conv_s2c16_k(
    const bf16* __restrict__ in, const bf16* __restrict__ wfrag,
    const float* __restrict__ scale, const float* __restrict__ shift,
    const uint8_t* __restrict__ mask, bf16* __restrict__ out,
    int Zo, int Yo, int Xo, int Ypi, int Xpi, int Ypo, int Xpo) {
    const int No = Zo * Yo * Xo;
    const int bid = xcd_swz(blockIdx.x, gridDim.x);
    const int tid = threadIdx.x;
    const int wv = tid >> 6, lane = tid & 63;
    const int lg = lane >> 4, lr = lane & 15;
    const int v0 = bid * 256 + wv * 64;
    if (v0 >= No) return;

    int vm = v0 + lane;
    bool mw = (vm < No) && (mask[vm] != 0);
    const bool anywork = (__ballot(mw) != 0ull);

    f32x4 acc[4][2];
#pragma unroll
    for (int s = 0; s < 4; ++s) { acc[s][0] = (f32x4){0,0,0,0}; acc[s][1] = (f32x4){0,0,0,0}; }

    if (anywork) {
        const uint4* gw = (const uint4*)wfrag;
        const int choff = (lg & 1) * 8;
        const int tb = lg >> 1;
        int toffl[14];
#pragma unroll
        for (int p = 0; p < 14; ++p) {
            int tp = 2 * p + tb;
            if (tp >= 27) tp = 0;
            int kz = tp / 9, r9 = tp - kz * 9, ky = r9 / 3, kx = r9 - ky * 3;
            toffl[p] = ((kz * Ypi + ky) * Xpi + kx) * 16;
        }
        int pA[4];
#pragma unroll
        for (int s = 0; s < 4; ++s) {
            int vr = v0 + s * 16 + lr;
            if (vr >= No) vr = 0;
            int zz = vr / (Yo * Xo); int rr = vr - zz * (Yo * Xo);
            int yy = rr / Xo; int xx = rr - yy * Xo;
            pA[s] = (((zz * 2) * Ypi + (yy * 2)) * Xpi + (xx * 2)) * 16 + choff;
        }
#pragma unroll
        for (int p = 0; p < 14; ++p) {
            uint4 b0 = gw[(p * 2 + 0) * 64 + lane];
            uint4 b1 = gw[(p * 2 + 1) * 64 + lane];
            uint4 ua[4];
#pragma unroll
            for (int s = 0; s < 4; ++s)
                ua[s] = *(const uint4*)(in + pA[s] + toffl[p]);
#pragma unroll
            for (int s = 0; s < 4; ++s) {
                acc[s][0] = __builtin_amdgcn_mfma_f32_16x16x32_bf16(
                    __builtin_bit_cast(s16x8, ua[s]),
                    __builtin_bit_cast(s16x8, b0), acc[s][0], 0, 0, 0);
                acc[s][1] = __builtin_amdgcn_mfma_f32_16x16x32_bf16(
                    __builtin_bit_cast(s16x8, ua[s]),
                    __builtin_bit_cast(s16x8, b1), acc[s][1], 0, 0, 0);
            }
        }
    }

#pragma unroll
    for (int s = 0; s < 4; ++s) {
        const int vb = v0 + s * 16 + lg * 4;
        int opd[4]; float mm[4]; bool ok[4];
#pragma unroll
        for (int r = 0; r < 4; ++r) {
            int v = vb + r;
            ok[r] = v < No;
            int vc = ok[r] ? v : 0;
            mm[r] = (ok[r] && mask[vc]) ? 1.f : 0.f;
            int zz = vc / (Yo * Xo); int rr = vc - zz * (Yo * Xo);
            int yy = rr / Xo; int xx = rr - yy * Xo;
            opd[r] = ((zz + 1) * Ypo + (yy + 1)) * Xpo + (xx + 1);
        }
#pragma unroll
        for (int nt = 0; nt < 2; ++nt) {
            int co = nt * 16 + lr;
            float sc = scale[co], sh = shift[co];
#pragma unroll
            for (int r = 0; r < 4; ++r) {
                if (!ok[r]) continue;
                float yv = fmaxf(fmaf(acc[s][nt][r], sc, sh), 0.f) * mm[r];
                out[(size_t)opd[r] * 32 + co] = __float2bfloat16(yv);
            }
        }
    }
}

// MFMA transposed conv (stride 2) via parity octants (L4a)
template <int CIN, int COUT>
__global__ __launch_bounds__(256, 4) void tconv_mfma_k(
    const bf16* __restrict__ in, const bf16* __restrict__ wfrag,
    const float* __restrict__ scale, const float* __restrict__ shift,
    const uint8_t* __restrict__ mask, bf16* __restrict__ out,
    int Zo, int Yo, int Xo, int Ypi, int Xpi, int Ypo, int Xpo) {
    constexpr int NT = COUT / 16;
    constexpr int KT = CIN / 32;
    const int oct = blockIdx.y;
    const int pz = oct >> 2, py = (oct >> 1) & 1, px = oct & 1;
    const int Zq = (Zo - pz + 1) >> 1, Yq = (Yo - py + 1) >> 1, Xq = (Xo - px + 1) >> 1;
    const int Nq = Zq * Yq * Xq;
    const int YXq = Yq * Xq;
    const int bid = xcd_swz(blockIdx.x, gridDim.x);
    const int tid = threadIdx.x;
    const int wv = tid >> 6, lane = tid & 63;
    const int lg = lane >> 4, lr = lane & 15;
    const int v0 = bid * 256 + wv * 64;
    if (v0 >= Nq) return;

    bool mw = false;
    {
        int q = v0 + lane;
        if (q < Nq) {
            int zq = q / YXq; int rr = q - zq * YXq; int yq = rr / Xq; int xq = rr - yq * Xq;
            int zz = 2 * zq + pz, yy = 2 * yq + py, xx = 2 * xq + px;
            mw = mask[(zz * Yo + yy) * Xo + xx] != 0;
        }
    }
    const bool anywork = (__ballot(mw) != 0ull);

    f32x4 acc[4][NT];
#pragma unroll
    for (int s = 0; s < 4; ++s)
#pragma unroll
        for (int nt = 0; nt < NT; ++nt) acc[s][nt] = (f32x4){0.f, 0.f, 0.f, 0.f};

    const uint4* gw = (const uint4*)wfrag;

    if (anywork) {
        int pA[4];
#pragma unroll
        for (int s = 0; s < 4; ++s) {
            int q = v0 + s * 16 + lr;
            if (q >= Nq) q = 0;
            int zq = q / YXq; int rr = q - zq * YXq; int yq = rr / Xq; int xq = rr - yq * Xq;
            pA[s] = (((zq + 1) * Ypi + (yq + 1)) * Xpi + (xq + 1)) * CIN + lg * 8;
        }
        const int nkz = 1 + pz, nky = 1 + py, nkx = 1 + px;
        for (int iz = 0; iz < nkz; ++iz) {
            const int kz = pz ? (iz ? 2 : 0) : 1;
            const int dz = (pz && !iz) ? 1 : 0;
            for (int iy = 0; iy < nky; ++iy) {
                const int ky = py ? (iy ? 2 : 0) : 1;
                const int dy = (py && !iy) ? 1 : 0;
                for (int ix = 0; ix < nkx; ++ix) {
                    const int kx = px ? (ix ? 2 : 0) : 1;
                    const int dx = (px && !ix) ? 1 : 0;
                    const int tap = kz * 9 + ky * 3 + kx;
                    const int toff = ((dz * Ypi + dy) * Xpi + dx) * CIN;
                    uint4 ub[NT][KT];
#pragma unroll
                    for (int nt = 0; nt < NT; ++nt)
#pragma unroll
                        for (int kt = 0; kt < KT; ++kt)
                            ub[nt][kt] = gw[((tap * NT + nt) * KT + kt) * 64 + lane];
                    uint4 ua[4][KT];
#pragma unroll
                    for (int s = 0; s < 4; ++s)
#pragma unroll
                        for (int kt = 0; kt < KT; ++kt)
                            ua[s][kt] = *(const uint4*)(in + pA[s] + toff + kt * 32);
#pragma unroll
                    for (int s = 0; s < 4; ++s)
#pragma unroll
                        for (int kt = 0; kt < KT; ++kt)
#pragma unroll
                            for (int nt = 0; nt < NT; ++nt)
                                acc[s][nt] = __builtin_amdgcn_mfma_f32_16x16x32_bf16(
                                    __builtin_bit_cast(s16x8, ua[s][kt]),
                                    __builtin_bit_cast(s16x8, ub[nt][kt]), acc[s][nt], 0, 0, 0);
                }
            }
        }
    }

#pragma unroll
    for (int s = 0; s < 4; ++s) {
        const int vb = v0 + s * 16 + lg * 4;
        int opd[4]; float mm[4]; bool ok[4];
#pragma unroll
        for (int r = 0; r < 4; ++r) {
            int q = vb + r;
            ok[r] = q < Nq;
            int qc = ok[r] ? q : 0;
            int zq = qc / YXq; int rr = qc - zq * YXq; int yq = rr / Xq; int xq = rr - yq * Xq;
            int zz = 2 * zq + pz, yy = 2 * yq + py, xx = 2 * xq + px;
            mm[r] = (ok[r] && mask[(zz * Yo + yy) * Xo + xx]) ? 1.f : 0.f;
            opd[r] = ((zz + 1) * Ypo + (yy + 1)) * Xpo + (xx + 1);
        }
#pragma unroll
        for (int nt = 0; nt < NT; ++nt) {
            int co = nt * 16 + lr;
            float sc = scale[co], sh = shift[co];
#pragma unroll
            for (int r = 0; r < 4; ++r) {
                if (!ok[r]) continue;
                float yv = fmaxf(fmaf(acc[s][nt][r], sc, sh), 0.f) * mm[r];
                out[(size_t)opd[r] * COUT + co] = __float2bfloat16(yv);
            }
        }
    }
}

__global__ __launch_bounds__(256, 4) void conv_l1_mfma_k(
    const bf16* __restrict__ in, const bf16* __restrict__ wfrag,
    const float* __restrict__ scale, const float* __restrict__ shift,
    const uint8_t* __restrict__ mask, bf16* __restrict__ out,
    int Zo, int Yo, int Xo, int Ypi, int Xpi, int Ypo, int Xpo) {
    const int No = Zo * Yo * Xo;
    const int bid = xcd_swz(blockIdx.x, gridDim.x);
    const int tid = threadIdx.x;
    const int wv = tid >> 6, lane = tid & 63;
    const int lg = lane >> 4, lr = lane & 15;
    const int v0 = bid * 256 + wv * 64;
    if (v0 >= No) return;

    int vm = v0 + lane;
    bool mw = (vm < No) && (mask[vm] != 0);
    const bool anywork = (__ballot(mw) != 0ull);

    f32x4 acc[4];
#pragma unroll
    for (int s = 0; s < 4; ++s) acc[s] = (f32x4){0.f, 0.f, 0.f, 0.f};

    if (anywork) {
        const uint4* gw = (const uint4*)wfrag;
        uint4 bu[4];
#pragma unroll
        for (int kb = 0; kb < 4; ++kb) bu[kb] = gw[kb * 64 + lane];

        int vtf[4][2];
#pragma unroll
        for (int kb = 0; kb < 4; ++kb)
#pragma unroll
            for (int u = 0; u < 2; ++u) {
                int tp = kb * 8 + lg * 2 + u;
                int kz = tp / 9, r9 = tp - kz * 9, ky = r9 / 3, kx = r9 - ky * 3;
                vtf[kb][u] = (tp < 27) ? (((kz - 1) * Ypi + (ky - 1)) * Xpi + (kx - 1)) : 0;
            }

        int pV[4];
#pragma unroll
        for (int s = 0; s < 4; ++s) {
            int vr = v0 + s * 16 + lr;
            if (vr >= No) vr = 0;
            int zz = vr / (Yo * Xo); int rr = vr - zz * (Yo * Xo);
            int yy = rr / Xo; int xx = rr - yy * Xo;
            pV[s] = ((zz + 1) * Ypi + (yy + 1)) * Xpi + (xx + 1);
        }

#pragma unroll
        for (int kb = 0; kb < 4; ++kb) {
#pragma unroll
            for (int s = 0; s < 4; ++s) {
                uint2 a0 = *(const uint2*)(in + (size_t)(pV[s] + vtf[kb][0]) * 4);
                uint2 a1 = *(const uint2*)(in + (size_t)(pV[s] + vtf[kb][1]) * 4);
                int4 ai; ai.x = a0.x; ai.y = a0.y; ai.z = a1.x; ai.w = a1.y;
                acc[s] = __builtin_amdgcn_mfma_f32_16x16x32_bf16(
                    __builtin_bit_cast(s16x8, ai),
                    __builtin_bit_cast(s16x8, bu[kb]), acc[s], 0, 0, 0);
            }
        }
    }

#pragma unroll
    for (int s = 0; s < 4; ++s) {
        const int vb = v0 + s * 16 + lg * 4;
        int co = lr;
        float sc = scale[co], sh = shift[co];
#pragma unroll
        for (int r = 0; r < 4; ++r) {
            int v = vb + r;
            if (v >= No) continue;
            float mm = mask[v] ? 1.f : 0.f;
            int zz = v / (Yo * Xo); int rr = v - zz * (Yo * Xo);
            int yy = rr / Xo; int xx = rr - yy * Xo;
            int opd = ((zz + 1) * Ypo + (yy + 1)) * Xpo + (xx + 1);
            float yv = fmaxf(fmaf(acc[s][r], sc, sh), 0.f) * mm;
            out[(size_t)opd * 16 + co] = __float2bfloat16(yv);
        }
    }
}

inline int nblk(int n) { return (n + 255) / 256; }
inline int cdiv(int a, int b) { return (a + b - 1) / b; }

}  // namespace

extern "C" void kernel_launch(void* const* d_in, const int* in_sizes, int n_in,
                              void* d_out, int out_size, void* d_ws, size_t ws_size,
                              hipStream_t stream) {
    const float* feats = (const float*)d_in[0];
    const int* coords = (const int*)d_in[1];
    const int NVOX = in_sizes[0] / 4;

    const float *w1 = (const float*)d_in[3], *s1 = (const float*)d_in[4], *b1 = (const float*)d_in[5];
    const float *w2a = (const float*)d_in[6], *s2a = (const float*)d_in[7], *b2a = (const float*)d_in[8];
    const float *w2b = (const float*)d_in[9], *s2b = (const float*)d_in[10], *b2b = (const float*)d_in[11];
    const float *w3a = (const float*)d_in[12], *s3a = (const float*)d_in[13], *b3a = (const float*)d_in[14];
    const float *w3b = (const float*)d_in[15], *s3b = (const float*)d_in[16], *b3b = (const float*)d_in[17];
    const float *w4a = (const float*)d_in[18], *s4a = (const float*)d_in[19], *b4a = (const float*)d_in[20];
    const float *w4b = (const float*)d_in[21], *s4b = (const float*)d_in[22], *b4b = (const float*)d_in[23];
    const float *w5a = (const float*)d_in[24], *s5a = (const float*)d_in[25], *b5a = (const float*)d_in[26];
    const float *w5b = (const float*)d_in[27], *s5b = (const float*)d_in[28], *b5b = (const float*)d_in[29];

    char* ws = (char*)d_ws;
    size_t off = 0;
    auto alloc = [&](size_t bytes) -> void* {
        void* p = ws + off;
        off = (off + bytes + 255) & ~(size_t)255;
        return p;
    };

    uint8_t* m0 = (uint8_t*)alloc(NV0);
    uint8_t* m1 = (uint8_t*)alloc(NV0);
    uint8_t* m2 = (uint8_t*)alloc(NV2);
    uint8_t* m3 = (uint8_t*)alloc(NV3);
    uint8_t* m4 = (uint8_t*)alloc(NV4);
    uint8_t* m5 = (uint8_t*)alloc(NV0);

    bf16* slot0 = (bf16*)alloc((size_t)NP0 * 32 * 2);
    bf16* slot1 = (bf16*)alloc((size_t)NP0 * 16 * 2);

    bf16* dense0 = slot0;  // 4ch  @P0
    bf16* x1     = slot1;  // 16ch @P0
    bf16* x2a    = slot0;  // 32ch @P2
    bf16* x2b    = slot1;  // 32ch @P2
    bf16* x3a    = slot0;  // 64ch @P3
    bf16* x3b    = slot1;  // 64ch @P3
    bf16* x4a    = slot0;  // 32ch @P4
    bf16* x4b    = slot1;  // 32ch @(23,130,130)
    bf16* x5a    = slot0;  // 32ch @P0

    bf16* wfL1 = (bf16*)alloc(4 * 64 * 8 * 2);
    bf16* wf2a = (bf16*)alloc((size_t)14 * 2 * 64 * 16);
    bf16* wf2b = (bf16*)alloc((size_t)27 * 2 * 1 * 64 * 16);
    bf16* wf3a = (bf16*)alloc((size_t)27 * 4 * 1 * 64 * 16);
    bf16* wf3b = (bf16*)alloc((size_t)27 * 4 * 2 * 64 * 16);
    bf16* wf4a = (bf16*)alloc((size_t)27 * 2 * 2 * 64 * 16);
    bf16* wf4b = (bf16*)alloc((size_t)27 * 2 * 1 * 64 * 16);
    bf16* wf5a = (bf16*)alloc((size_t)27 * 2 * 1 * 64 * 16);
    bf16* wf5b32 = (bf16*)alloc((size_t)27 * 2 * 64 * 16);   // 32x32 frag order
    alloc(20u << 20);

    if (off > ws_size) {
        sentinel_k<<<1, 256, 0, stream>>>((float*)d_out);
        return;
    }

    // stage 0
    hipMemsetAsync(dense0, 0, (size_t)NP0 * 4 * 2, stream);
    hipMemsetAsync(m0, 0, NV0, stream);
    repack_frag_l1_k<<<1, 256, 0, stream>>>(w1, wfL1);
    repack_frag_c16_k<<<nblk(14 * 2 * 64), 256, 0, stream>>>(w2a, wf2a);
    repack_frag_k<<<nblk(27 * 2 * 64), 256, 0, stream>>>(w2b, wf2b, 32, 32, 0);
    repack_frag_k<<<nblk(27 * 4 * 64), 256, 0, stream>>>(w3a, wf3a, 32, 64, 0);
    repack_frag_k<<<nblk(27 * 8 * 64), 256, 0, stream>>>(w3b, wf3b, 64, 64, 0);
    repack_frag_k<<<nblk(27 * 4 * 64), 256, 0, stream>>>(w4a, wf4a, 64, 32, 1);
    repack_frag_k<<<nblk(27 * 2 * 64), 256, 0, stream>>>(w4b, wf4b, 32, 32, 0);
    repack_frag_k<<<nblk(27 * 2 * 64), 256, 0, stream>>>(w5a, wf5a, 32, 32, 1);
    repack_frag32_k<<<nblk(27 * 2 * 64), 256, 0, stream>>>(w5b, wf5b32);

    scatter_k<<<nblk(NVOX), 256, 0, stream>>>(feats, coords, dense0, m0, NVOX);

    // level 1
    dilate4_k<<<nblk(NV0 / 4), 256, 0, stream>>>(m0, m1, Z0, Y0, X0);
    halo_zero_k<16><<<nblk(NP0), 256, 0, stream>>>(x1, Z0, Y0, X0, ZP0, YP0, XP0);
    conv_l1_mfma_k<<<nblk(NV0), 256, 0, stream>>>(
        dense0, wfL1, s1, b1, m1, x1, Z0, Y0, X0, YP0, XP0, YP0, XP0);

    // level 2
    dilate_k<<<nblk(NV2), 256, 0, stream>>>(m1, m2, Z0, Y0, X0, Z2, Y2, X2, 2);
    halo_zero_k<32><<<nblk(NP2), 256, 0, stream>>>(x2a, Z2, Y2, X2, ZP2, YP2, XP2);
    conv_s2c16_k<<<nblk(NV2), 256, 0, stream>>>(
        x1, wf2a, s2a, b2a, m2, x2a, Z2, Y2, X2, YP0, XP0, YP2, XP2);
    halo_zero_k<32><<<nblk(NP2), 256, 0, stream>>>(x2b, Z2, Y2, X2, ZP2, YP2, XP2);
    {
        int nx = cdiv(X2, 32), ny = cdiv(Y2, 4), nz = cdiv(Z2, 4);
        conv_lds_k<false><<<nx * ny * nz, 512, 0, stream>>>(
            x2a, wf2b, s2b, b2b, m2, x2b, nullptr, Z2, Y2, X2, YP2, XP2, YP2, XP2, nx, ny);
    }

    // level 3
    dilate_k<<<nblk(NV3), 256, 0, stream>>>(m2, m3, Z2, Y2, X2, Z3, Y3, X3, 2);
    halo_zero_k<64><<<nblk(NP3), 256, 0, stream>>>(x3a, Z3, Y3, X3, ZP3, YP3, XP3);
    conv_mfma_k<32, 64, 2, 64, false><<<cdiv(NV3, 64), 64, 0, stream>>>(
        x2b, wf3a, s3a, b3a, m3, x3a, nullptr, Z3, Y3, X3, YP2, XP2, YP3, XP3);
    halo_zero_k<64><<<nblk(NP3), 256, 0, stream>>>(x3b, Z3, Y3, X3, ZP3, YP3, XP3);
    conv_mfma_k<64, 64, 1, 64, false><<<cdiv(NV3, 64), 64, 0, stream>>>(
        x3a, wf3b, s3b, b3b, m3, x3b, nullptr, Z3, Y3, X3, YP3, XP3, YP3, XP3);

    // level 4 (tconv up via parity octants)
    tdilate_k<<<nblk(NV4), 256, 0, stream>>>(m3, m4, Z3, Y3, X3, Z4, Y4, X4);
    halo_zero_k<32><<<nblk(NP4), 256, 0, stream>>>(x4a, Z4, Y4, X4, ZP4, YP4, XP4);
    {
        int maxNq = ((Z4 + 1) >> 1) * ((Y4 + 1) >> 1) * ((X4 + 1) >> 1);
        dim3 g(nblk(maxNq), 8);
        tconv_mfma_k<64, 32><<<g, 256, 0, stream>>>(
            x3b, wf4a, s4a, b4a, m4, x4a, Z4, Y4, X4, YP3, XP3, YP4, XP4);
    }
    halo_zero_k<32><<<nblk(NP2), 256, 0, stream>>>(x4b, Z4, Y4, X4, ZP2, YP2, XP2);
    {
        int nx = cdiv(X4, 32), ny = cdiv(Y4, 4), nz = cdiv(Z4, 4);
        conv_lds_k<false><<<nx * ny * nz, 512, 0, stream>>>(
            x4a, wf4b, s4b, b4b, m4, x4b, nullptr, Z4, Y4, X4, YP4, XP4, YP2, XP2, nx, ny);
    }

    // level 5 (tconv up, outpad (0,3,3)) — both kernels rolling-z pipelined
    tdilate4_k<<<nblk(NV0 / 4), 256, 0, stream>>>(m4, m5, Z4, Y4, X4, Z0, Y0, X0);
    halo_zero_k<32><<<nblk(NP0), 256, 0, stream>>>(x5a, Z0, Y0, X0, ZP0, YP0, XP0);
    {
        dim3 g((Y0 / 2 / 2) * (X0 / 2 / 32), 8);
        tconv_roll_k<<<g, 256, 0, stream>>>(
            x4b, wf5a, s5a, b5a, m5, x5a, Z0, Y0, X0, Z4, YP2, XP2, YP0, XP0, X0 / 2 / 32);
    }
    {
        // 8(x) x 32(y) x 2(z-seg) = 512 blocks, 256 thr
        conv_roll_k<<<512, 256, 0, stream>>>(
            x5a, wf5b32, s5b, b5b, m5, (float*)d_out);
    }
}

// Round 13
// 789.726 us; speedup vs baseline: 1.2644x; 1.0103x over previous
//
#include <hip/hip_runtime.h>
#include <hip/hip_bf16.h>
#include <stdint.h>

namespace {

constexpr int Z0 = 41, Y0 = 256, X0 = 256;
constexpr int Z2 = 21, Y2 = 128, X2 = 128;
constexpr int Z3 = 11, Y3 = 64,  X3 = 64;
constexpr int Z4 = 21, Y4 = 127, X4 = 127;
constexpr int NV0 = Z0 * Y0 * X0;
constexpr int NV2 = Z2 * Y2 * X2;
constexpr int NV3 = Z3 * Y3 * X3;
constexpr int NV4 = Z4 * Y4 * X4;

constexpr int ZP0 = 43, YP0 = 258, XP0 = 258; constexpr int NP0 = ZP0 * YP0 * XP0;
constexpr int ZP2 = 23, YP2 = 130, XP2 = 130; constexpr int NP2 = ZP2 * YP2 * XP2;
constexpr int ZP3 = 13, YP3 = 66,  XP3 = 66;  constexpr int NP3 = ZP3 * YP3 * XP3;
constexpr int ZP4 = 23, YP4 = 129, XP4 = 129; constexpr int NP4 = ZP4 * YP4 * XP4;

using bf16 = __hip_bfloat16;
typedef __attribute__((ext_vector_type(8))) short s16x8;
typedef __attribute__((ext_vector_type(4))) float f32x4;
typedef __attribute__((ext_vector_type(16))) float f32x16;
typedef __attribute__((ext_vector_type(4))) unsigned u32x4;

__device__ inline unsigned f2b(float f) {
    return (unsigned)__builtin_bit_cast(unsigned short, __float2bfloat16(f));
}

__device__ inline int xcd_swz(int bid, int nwg) {
    int q = nwg >> 3, r = nwg & 7;
    int x = bid & 7, j = bid >> 3;
    return (x < r ? x * (q + 1) : r * (q + 1) + (x - r) * q) + j;
}

__device__ inline void glds16(const bf16* g, void* l) {
    __builtin_amdgcn_global_load_lds(
        (const __attribute__((address_space(1))) void*)g,
        (__attribute__((address_space(3))) void*)l, 16, 0, 0);
}

__global__ __launch_bounds__(256) void sentinel_k(float* out) { out[0] = 12345.0f; }

__global__ __launch_bounds__(256) void scatter_k(const float* __restrict__ feats,
                                                 const int* __restrict__ coords,
                                                 bf16* __restrict__ dense,
                                                 uint8_t* __restrict__ m0, int n) {
    int v = blockIdx.x * 256 + threadIdx.x;
    if (v >= n) return;
    int z = coords[v * 4 + 1], y = coords[v * 4 + 2], x = coords[v * 4 + 3];
    m0[(z * Y0 + y) * X0 + x] = 1;
    int pp = ((z + 1) * YP0 + (y + 1)) * XP0 + (x + 1);
    uint2 u;
    u.x = f2b(feats[v * 4 + 0]) | (f2b(feats[v * 4 + 1]) << 16);
    u.y = f2b(feats[v * 4 + 2]) | (f2b(feats[v * 4 + 3]) << 16);
    *(uint2*)(dense + (size_t)pp * 4) = u;
}

template <int C>
__global__ __launch_bounds__(256) void halo_zero_k(bf16* __restrict__ buf,
                                                   int Zi, int Yi, int Xi,
                                                   int Zp, int Yp, int Xp) {
    int i = blockIdx.x * 256 + threadIdx.x;
    int tot = Zp * Yp * Xp;
    if (i >= tot) return;
    int x = i % Xp; int t = i / Xp; int y = t % Yp; int z = t / Yp;
    bool halo = (z < 1) | (z > Zi) | (y < 1) | (y > Yi) | (x < 1) | (x > Xi);
    if (!halo) return;
    uint4 zz = make_uint4(0, 0, 0, 0);
    uint4* p = (uint4*)(buf + (size_t)i * C);
#pragma unroll
    for (int j = 0; j < C / 8; ++j) p[j] = zz;
}

// MFMA B-frag repack. TRANS: weight layout (CIN,COUT,taps) vs (COUT,CIN,taps).
// PAIR: col c + slice nt -> cout = 2c+nt (paired-channel stores) else nt*16+c.
__global__ __launch_bounds__(256) void repack_frag_k(const float* __restrict__ w,
                                                     bf16* __restrict__ wf,
                                                     int CIN, int COUT, int TRANS, int PAIR) {
    int NT = COUT / 16, KT = CIN / 32;
    int i = blockIdx.x * 256 + threadIdx.x;
    int total = 27 * NT * KT * 64;
    if (i >= total) return;
    int lane = i & 63; int t = i >> 6;
    int kt = t % KT; t /= KT; int nt = t % NT; int tap = t / NT;
    int c = lane & 15;
    int co = PAIR ? (2 * c + nt) : (nt * 16 + c);
    int ci0 = kt * 32 + (lane >> 4) * 8;
    unsigned e[8];
#pragma unroll
    for (int j = 0; j < 8; ++j) {
        int ci = ci0 + j;
        int src = TRANS ? ((ci * COUT + co) * 27 + tap) : ((co * CIN + ci) * 27 + tap);
        e[j] = f2b(w[src]);
    }
    uint4 u;
    u.x = e[0] | (e[1] << 16); u.y = e[2] | (e[3] << 16);
    u.z = e[4] | (e[5] << 16); u.w = e[6] | (e[7] << 16);
    ((uint4*)wf)[i] = u;
}

// 32x32x16 B-frag repack: wf[(tap*2+ks)*64+lane], elem j: B[k=(lane>>5)*8+j][col=lane&31]
__global__ __launch_bounds__(256) void repack_frag32_k(const float* __restrict__ w,
                                                       bf16* __restrict__ wf) {
    int i = blockIdx.x * 256 + threadIdx.x;
    if (i >= 27 * 2 * 64) return;
    int lane = i & 63; int t2 = i >> 6;
    int ks = t2 & 1; int tap = t2 >> 1;
    int co = lane & 31; int h = lane >> 5;
    unsigned e[8];
#pragma unroll
    for (int j = 0; j < 8; ++j) {
        int cin = ks * 16 + h * 8 + j;
        e[j] = f2b(w[(co * 32 + cin) * 27 + tap]);
    }
    uint4 u;
    u.x = e[0] | (e[1] << 16); u.y = e[2] | (e[3] << 16);
    u.z = e[4] | (e[5] << 16); u.w = e[6] | (e[7] << 16);
    ((uint4*)wf)[i] = u;
}

// CIN=16 stride-2 frag: K = 2 taps x 16ch, 14 pairs (tap 27 zero)
__global__ __launch_bounds__(256) void repack_frag_c16_k(const float* __restrict__ w,
                                                         bf16* __restrict__ wf) {
    int i = blockIdx.x * 256 + threadIdx.x;
    int total = 14 * 2 * 64;
    if (i >= total) return;
    int lane = i & 63; int t = i >> 6;
    int nt = t & 1; int p = t >> 1;
    int lg = lane >> 4, lr = lane & 15;
    int co = nt * 16 + lr;
    unsigned e[8];
#pragma unroll
    for (int j = 0; j < 8; ++j) {
        int tap = 2 * p + (lg >> 1);
        int ci = (lg & 1) * 8 + j;
        e[j] = (tap < 27) ? f2b(w[(co * 16 + ci) * 27 + tap]) : 0u;
    }
    uint4 u;
    u.x = e[0] | (e[1] << 16); u.y = e[2] | (e[3] << 16);
    u.z = e[4] | (e[5] << 16); u.w = e[6] | (e[7] << 16);
    ((uint4*)wf)[i] = u;
}

__global__ __launch_bounds__(256) void repack_frag_l1_k(const float* __restrict__ w,
                                                        bf16* __restrict__ wf) {
    int i = blockIdx.x * 256 + threadIdx.x;
    if (i >= 256) return;
    int lane = i & 63, kb = i >> 6;
    int lg = lane >> 4, lr = lane & 15;
    unsigned e[8];
#pragma unroll
    for (int j = 0; j < 8; ++j) {
        int tap = kb * 8 + lg * 2 + (j >> 2);
        int ci = j & 3;
        e[j] = (tap < 27) ? f2b(w[(lr * 4 + ci) * 27 + tap]) : 0u;
    }
    uint4 u;
    u.x = e[0] | (e[1] << 16); u.y = e[2] | (e[3] << 16);
    u.z = e[4] | (e[5] << 16); u.w = e[6] | (e[7] << 16);
    ((uint4*)wf)[i] = u;
}

__global__ __launch_bounds__(256) void dilate_k(const uint8_t* __restrict__ in,
                                                uint8_t* __restrict__ out,
                                                int Zi, int Yi, int Xi,
                                                int Zo, int Yo, int Xo, int stride) {
    int idx = blockIdx.x * 256 + threadIdx.x;
    int total = Zo * Yo * Xo;
    if (idx >= total) return;
    int x = idx % Xo; int t = idx / Xo; int y = t % Yo; int z = t / Yo;
    int YX = Yi * Xi;
    uint8_t r = 0;
    for (int kz = 0; kz < 3; ++kz) {
        int zi = z * stride + kz - 1;
        if ((unsigned)zi >= (unsigned)Zi) continue;
        for (int ky = 0; ky < 3; ++ky) {
            int yi = y * stride + ky - 1;
            if ((unsigned)yi >= (unsigned)Yi) continue;
            for (int kx = 0; kx < 3; ++kx) {
                int xi = x * stride + kx - 1;
                if ((unsigned)xi >= (unsigned)Xi) continue;
                r |= in[zi * YX + yi * Xi + xi];
            }
        }
    }
    out[idx] = r ? 1 : 0;
}

__global__ __launch_bounds__(256) void dilate4_k(const uint8_t* __restrict__ in,
                                                 uint8_t* __restrict__ out,
                                                 int Z, int Y, int X) {
    int ngx = X >> 2;
    int g = blockIdx.x * 256 + threadIdx.x;
    int total = Z * Y * ngx;
    if (g >= total) return;
    int gx = g % ngx; int t = g / ngx; int y = t % Y; int z = t / Y;
    const int YX = Y * X;
    unsigned r = 0;
    for (int kz = 0; kz < 3; ++kz) {
        int zi = z + kz - 1;
        if ((unsigned)zi >= (unsigned)Z) continue;
        for (int ky = 0; ky < 3; ++ky) {
            int yi = y + ky - 1;
            if ((unsigned)yi >= (unsigned)Y) continue;
            const unsigned* rw = (const unsigned*)(in + zi * YX + yi * X);
            unsigned u1 = rw[gx];
            unsigned u0 = gx ? rw[gx - 1] : 0u;
            unsigned u2 = (gx + 1 < ngx) ? rw[gx + 1] : 0u;
            r |= u1 | ((u1 << 8) | (u0 >> 24)) | ((u1 >> 8) | (u2 << 24));
        }
    }
    r |= r >> 4; r |= r >> 2; r |= r >> 1; r &= 0x01010101u;
    ((unsigned*)out)[g] = r;
}

__global__ __launch_bounds__(256) void tdilate_k(const uint8_t* __restrict__ in,
                                                 uint8_t* __restrict__ out,
                                                 int Zi, int Yi, int Xi,
                                                 int Zo, int Yo, int Xo) {
    int idx = blockIdx.x * 256 + threadIdx.x;
    int total = Zo * Yo * Xo;
    if (idx >= total) return;
    int x = idx % Xo; int t = idx / Xo; int y = t % Yo; int z = t / Yo;
    int YX = Yi * Xi;
    uint8_t r = 0;
    for (int kz = 0; kz < 3; ++kz) {
        int tz = z + 1 - kz;
        if (tz & 1) continue;
        int zi = tz >> 1;
        if ((unsigned)zi >= (unsigned)Zi) continue;
        for (int ky = 0; ky < 3; ++ky) {
            int ty = y + 1 - ky;
            if (ty & 1) continue;
            int yi = ty >> 1;
            if ((unsigned)yi >= (unsigned)Yi) continue;
            for (int kx = 0; kx < 3; ++kx) {
                int tx = x + 1 - kx;
                if (tx & 1) continue;
                int xi = tx >> 1;
                if ((unsigned)xi >= (unsigned)Xi) continue;
                r |= in[zi * YX + yi * Xi + xi];
            }
        }
    }
    out[idx] = r ? 1 : 0;
}

__global__ __launch_bounds__(256) void tdilate4_k(const uint8_t* __restrict__ in,
                                                  uint8_t* __restrict__ out,
                                                  int Zi, int Yi, int Xi,
                                                  int Zo, int Yo, int Xo) {
    int ngx = Xo >> 2;
    int g = blockIdx.x * 256 + threadIdx.x;
    int total = Zo * Yo * ngx;
    if (g >= total) return;
    int gx = g % ngx; int t = g / ngx; int y = t % Yo; int z = t / Yo;
    int YX = Yi * Xi;
    int j0 = gx * 2;
    unsigned r0 = 0, r1 = 0, r2 = 0, r3 = 0;
    for (int kz = 0; kz < 3; ++kz) {
        int tz = z + 1 - kz;
        if (tz & 1) continue;
        int zi = tz >> 1;
        if ((unsigned)zi >= (unsigned)Zi) continue;
        for (int ky = 0; ky < 3; ++ky) {
            int ty = y + 1 - ky;
            if (ty & 1) continue;
            int yi = ty >> 1;
            if ((unsigned)yi >= (unsigned)Yi) continue;
            const uint8_t* rp = in + zi * YX + yi * Xi;
            unsigned b0 = (j0 < Xi) ? rp[j0] : 0u;
            unsigned b1 = (j0 + 1 < Xi) ? rp[j0 + 1] : 0u;
            unsigned b2 = (j0 + 2 < Xi) ? rp[j0 + 2] : 0u;
            r0 |= b0; r1 |= b0 | b1; r2 |= b1; r3 |= b1 | b2;
        }
    }
    unsigned rr = (r0 ? 1u : 0u) | (r1 ? 0x100u : 0u) | (r2 ? 0x10000u : 0u) | (r3 ? 0x1000000u : 0u);
    ((unsigned*)out)[g] = rr;
}

// ---- rolling-z pipelined conv 32->32 (L5b), W=2 rows/wave, 1 wave/SIMD ----
// 256 blocks (1/CU), 41 z-iters; wave w owns rows y0+2w..y0+2w+1 (full cout).
__global__ __launch_bounds__(256, 1) void conv_roll_k(
    const bf16* __restrict__ in, const bf16* __restrict__ wfrag,
    const float* __restrict__ scale, const float* __restrict__ shift,
    const uint8_t* __restrict__ mask, float* __restrict__ outf) {
    constexpr int ROWB = 2176;           // 2 ks x 2 h x 34 voxels x 16B
    constexpr int SLABB = 24576;         // 10 rows = 21760 used + pad
    __shared__ uint4 ring4[4 * SLABB / 16];
    char* ring = (char*)ring4;

    const int bid = xcd_swz(blockIdx.x, gridDim.x);
    const int tx = bid & 7, ty = bid >> 3;   // 8 x 32
    const int y0 = ty * 8, x0 = tx * 32;

    const int tid = threadIdx.x;
    const int w = tid >> 6, lane = tid & 63;
    const int vx = lane & 31, h = lane >> 5;

    // ---- prologue A: stage B (3456 x 16B chunks) into ring[0..55296) ----
#pragma unroll
    for (int k = 0; k < 14; ++k) {
        int base = k * 256 + w * 64;
        if (base < 27 * 2 * 64)
            glds16(wfrag + (size_t)(base + lane) * 8, ring + base * 16);
    }
    asm volatile("s_waitcnt vmcnt(0)" ::: "memory");
    __syncthreads();

    u32x4 breg[27][2];
#pragma unroll
    for (int t = 0; t < 27; ++t) {
        breg[t][0] = *(const u32x4*)(ring + (t * 2 + 0) * 1024 + lane * 16);
        breg[t][1] = *(const u32x4*)(ring + (t * 2 + 1) * 1024 + lane * 16);
    }
    __syncthreads();

    // per-lane SOURCE offsets for the 6 staged chunks (dest pad for i>=1360)
    int soff[6];
#pragma unroll
    for (int k = 0; k < 6; ++k) {
        int i = tid + k * 256;
        int ii = i < 1360 ? i : 0;
        int row = ii / 136, c = ii - row * 136;
        int ks = c / 68, r2 = c - ks * 68, hh = r2 / 34, v = r2 - hh * 34;
        soff[k] = ((y0 + row) * XP0 + (x0 + v)) * 32 + (2 * ks + hh) * 8;
    }
    auto stagefn = [&](int p, char* slab) {
        int zp = p < ZP0 ? p : ZP0 - 1;
        const bf16* pb = in + (size_t)zp * ((size_t)YP0 * XP0 * 32);
#pragma unroll
        for (int k = 0; k < 6; ++k)
            glds16(pb + soff[k], slab + (k * 256 + w * 64) * 16);
    };

    int rb[4];
#pragma unroll
    for (int fr = 0; fr < 4; ++fr)
        rb[fr] = (2 * w + fr) * ROWB + h * 544 + vx * 16;

    const float sc = scale[vx], sh = shift[vx];

    stagefn(0, ring);
    stagefn(1, ring + SLABB);
    stagefn(2, ring + 2 * SLABB);
    asm volatile("s_waitcnt vmcnt(0)" ::: "memory");
    __builtin_amdgcn_s_barrier();

    int s0 = 0;
    for (int z = 0; z < Z0; ++z) {
        stagefn(z + 3, ring + ((s0 + 3) & 3) * SLABB);

        unsigned mk0[4], mk1[4];
        {
            const uint8_t* mr0 = mask + ((size_t)z * Y0 + (y0 + 2 * w)) * X0 + x0 + 4 * h;
            const uint8_t* mr1 = mr0 + X0;
            mk0[0] = *(const unsigned*)(mr0);      mk0[1] = *(const unsigned*)(mr0 + 8);
            mk0[2] = *(const unsigned*)(mr0 + 16); mk0[3] = *(const unsigned*)(mr0 + 24);
            mk1[0] = *(const unsigned*)(mr1);      mk1[1] = *(const unsigned*)(mr1 + 8);
            mk1[2] = *(const unsigned*)(mr1 + 16); mk1[3] = *(const unsigned*)(mr1 + 24);
        }

        const char* slp0 = ring + s0 * SLABB;
        const char* slp1 = ring + ((s0 + 1) & 3) * SLABB;
        const char* slp2 = ring + ((s0 + 2) & 3) * SLABB;

        f32x16 acc0, acc1;
#pragma unroll
        for (int i = 0; i < 16; ++i) { acc0[i] = 0.f; acc1[i] = 0.f; }

#pragma unroll
        for (int dz = 0; dz < 3; ++dz) {
            const char* slab = dz == 0 ? slp0 : (dz == 1 ? slp1 : slp2);
#pragma unroll
            for (int dx = 0; dx < 3; ++dx) {
#pragma unroll
                for (int ks = 0; ks < 2; ++ks) {
                    const int ko = ks * 1088 + dx * 16;
                    u32x4 a0 = *(const u32x4*)(slab + rb[0] + ko);
                    u32x4 a1 = *(const u32x4*)(slab + rb[1] + ko);
                    u32x4 a2 = *(const u32x4*)(slab + rb[2] + ko);
                    u32x4 a3 = *(const u32x4*)(slab + rb[3] + ko);
                    const int t0 = dz * 9 + 0 * 3 + dx;
                    const int t1 = dz * 9 + 1 * 3 + dx;
                    const int t2_ = dz * 9 + 2 * 3 + dx;
                    acc0 = __builtin_amdgcn_mfma_f32_32x32x16_bf16(
                        __builtin_bit_cast(s16x8, a0), __builtin_bit_cast(s16x8, breg[t0][ks]), acc0, 0, 0, 0);
                    acc1 = __builtin_amdgcn_mfma_f32_32x32x16_bf16(
                        __builtin_bit_cast(s16x8, a1), __builtin_bit_cast(s16x8, breg[t0][ks]), acc1, 0, 0, 0);
                    acc0 = __builtin_amdgcn_mfma_f32_32x32x16_bf16(
                        __builtin_bit_cast(s16x8, a1), __builtin_bit_cast(s16x8, breg[t1][ks]), acc0, 0, 0, 0);
                    acc1 = __builtin_amdgcn_mfma_f32_32x32x16_bf16(
                        __builtin_bit_cast(s16x8, a2), __builtin_bit_cast(s16x8, breg[t1][ks]), acc1, 0, 0, 0);
                    acc0 = __builtin_amdgcn_mfma_f32_32x32x16_bf16(
                        __builtin_bit_cast(s16x8, a2), __builtin_bit_cast(s16x8, breg[t2_][ks]), acc0, 0, 0, 0);
                    acc1 = __builtin_amdgcn_mfma_f32_32x32x16_bf16(
                        __builtin_bit_cast(s16x8, a3), __builtin_bit_cast(s16x8, breg[t2_][ks]), acc1, 0, 0, 0);
                }
            }
        }

        const size_t ob0 = (size_t)vx * NV0 + ((size_t)z * Y0 + (y0 + 2 * w)) * X0 + x0 + 4 * h;
        const size_t ob1 = ob0 + X0;
#pragma unroll
        for (int q = 0; q < 4; ++q) {
            f32x4 o0, o1;
#pragma unroll
            for (int r = 0; r < 4; ++r) {
                float m0 = (float)((mk0[q] >> (8 * r)) & 1);
                float m1 = (float)((mk1[q] >> (8 * r)) & 1);
                o0[r] = fmaxf(fmaf(acc0[q * 4 + r], sc, sh), 0.f) * m0;
                o1[r] = fmaxf(fmaf(acc1[q * 4 + r], sc, sh), 0.f) * m1;
            }
            *(f32x4*)(outf + ob0 + 8 * q) = o0;
            *(f32x4*)(outf + ob1 + 8 * q) = o1;
        }

        asm volatile("s_waitcnt vmcnt(8)" ::: "memory");
        __builtin_amdgcn_s_barrier();
        s0 = (s0 + 1) & 3;
    }
}

// ---- rolling-z pipelined transposed conv 32->32 (L5a), paired-channel stores ----
__global__ __launch_bounds__(256, 3) void tconv_roll_k(
    const bf16* __restrict__ in, const bf16* __restrict__ wfrag,
    const float* __restrict__ scale, const float* __restrict__ shift,
    const uint8_t* __restrict__ mask, bf16* __restrict__ out,
    int Zo, int Yo, int Xo, int Zi, int Ypi, int Xpi, int Ypo, int Xpo, int nx) {
    constexpr int ROWB = 34 * 64;
    constexpr int SLABB = 3 * ROWB;
    __shared__ uint4 ring4[4 * SLABB / 16];
    char* ring = (char*)ring4;

    const int oct = blockIdx.y;
    const int pz = oct >> 2, py = (oct >> 1) & 1, px = oct & 1;
    const int Zq = (Zo - pz + 1) >> 1;

    const int bid = xcd_swz(blockIdx.x, gridDim.x);
    const int tx = bid % nx, ty = bid / nx;
    const int yq0 = ty * 2, xq0 = tx * 32;

    const int tid = threadIdx.x;
    const int w = tid >> 6, lane = tid & 63;
    const int lg = lane >> 4, lr = lane & 15;
    const int yr = w >> 1, xh = w & 1;

    const int kz0 = pz ? 0 : 1, dzo0 = pz ? 1 : 0;
    const int ky0 = py ? 0 : 1, dyo0 = py ? 1 : 0;
    const int kx0 = px ? 0 : 1, dxo0 = px ? 1 : 0;

    auto stagefn = [&](int p, int slot) {
        if (w < 3) {
            int zs = p < Zi ? p : Zi - 1;
            char* slab = ring + slot * SLABB + w * ROWB;
            const bf16* pb = in + ((size_t)(zs + 1) * Ypi + (yq0 + 1 + w)) * (size_t)Xpi * 32
                                + (size_t)(xq0 + 1) * 32;
            int u0 = lane;      glds16(pb + (u0 ^ ((u0 >> 3) & 7)) * 8, slab);
            int u1 = 64 + lane; glds16(pb + (u1 ^ ((u1 >> 3) & 7)) * 8, slab + 1024);
            if (lane < 8) { int u2 = 128 + lane; glds16(pb + u2 * 8, slab + 2048); }
        }
    };

    const uint4* gw = (const uint4*)wfrag;
    uint4 breg[2][2][2][2];
#pragma unroll
    for (int iz = 0; iz < 2; ++iz) {
        int kz = iz ? 2 : kz0;
#pragma unroll
        for (int iy = 0; iy < 2; ++iy) {
            int ky = iy ? 2 : ky0;
#pragma unroll
            for (int ix = 0; ix < 2; ++ix) {
                int kx = ix ? 2 : kx0;
                int tap = kz * 9 + ky * 3 + kx;
                breg[iz][iy][ix][0] = gw[(tap * 2 + 0) * 64 + lane];
                breg[iz][iy][ix][1] = gw[(tap * 2 + 1) * 64 + lane];
            }
        }
    }

    int b0 = (xh * 16 + lr + dxo0) * 64 + lg * 16;
    int b1 = (xh * 16 + lr) * 64 + lg * 16;
    const int aswA = b0 ^ (((b0 >> 7) & 7) << 4);
    const int aswB = b1 ^ (((b1 >> 7) & 7) << 4);
    const int rowA = (yr + dyo0) * ROWB;
    const int rowB = yr * ROWB;

    // paired channels: acc0 -> cout 2lr, acc1 -> cout 2lr+1
    const float sc0 = scale[2 * lr], sh0 = shift[2 * lr];
    const float sc1 = scale[2 * lr + 1], sh1 = shift[2 * lr + 1];

    const int yout = 2 * (yq0 + yr) + py;
    const int xb = 2 * (xq0 + xh * 16 + lg * 4) + px;

    stagefn(0, 0); stagefn(1, 1); stagefn(2, 2);
    uint2 mv;
    mv = *(const uint2*)(mask + ((size_t)pz * Yo + yout) * Xo + (xb - px));
    asm volatile("s_waitcnt vmcnt(0)" ::: "memory");
    __builtin_amdgcn_s_barrier();

    int rs0 = 0, wslot = 3;
    for (int zq = 0; zq < Zq; ++zq) {
        uint2 nv;
        {
            int zqn = (zq + 1 < Zq) ? zq + 1 : Zq - 1;
            nv = *(const uint2*)(mask + ((size_t)(2 * zqn + pz) * Yo + yout) * Xo + (xb - px));
        }
        stagefn(zq + 3, wslot);

        int rs1 = rs0 + 1 < 4 ? rs0 + 1 : 0;
        const char* sl_0 = ring + rs0 * SLABB;
        const char* sl_1 = ring + rs1 * SLABB;
        const char* slz0 = pz ? sl_1 : sl_0;
        const char* slz1 = sl_0;

        f32x4 acc0 = (f32x4){0, 0, 0, 0}, acc1 = (f32x4){0, 0, 0, 0};
#pragma unroll
        for (int iz = 0; iz < 2; ++iz) {
            if (iz > pz) continue;
            const char* slab = iz ? slz1 : slz0;
#pragma unroll
            for (int iy = 0; iy < 2; ++iy) {
                if (iy > py) continue;
                const char* rowp = slab + (iy ? rowB : rowA);
#pragma unroll
                for (int ix = 0; ix < 2; ++ix) {
                    if (ix > px) continue;
                    uint4 a = *(const uint4*)(rowp + (ix ? aswB : aswA));
                    acc0 = __builtin_amdgcn_mfma_f32_16x16x32_bf16(
                        __builtin_bit_cast(s16x8, a),
                        __builtin_bit_cast(s16x8, breg[iz][iy][ix][0]), acc0, 0, 0, 0);
                    acc1 = __builtin_amdgcn_mfma_f32_16x16x32_bf16(
                        __builtin_bit_cast(s16x8, a),
                        __builtin_bit_cast(s16x8, breg[iz][iy][ix][1]), acc1, 0, 0, 0);
                }
            }
        }

        const int zout = 2 * zq + pz;
        const size_t opdbase = ((size_t)(zout + 1) * Ypo + (yout + 1)) * Xpo;
#pragma unroll
        for (int r = 0; r < 4; ++r) {
            unsigned word = (r < 2) ? mv.x : mv.y;
            float m = (float)((word >> (px * 8 + (r & 1) * 16)) & 1);
            float v0 = fmaxf(fmaf(acc0[r], sc0, sh0), 0.f) * m;
            float v1 = fmaxf(fmaf(acc1[r], sc1, sh1), 0.f) * m;
            size_t opd = opdbase + (size_t)(xb + 2 * r + 1);
            unsigned pk = f2b(v0) | (f2b(v1) << 16);
            *(unsigned*)(out + opd * 32 + 2 * lr) = pk;
        }

        asm volatile("s_waitcnt vmcnt(12)" ::: "memory");
        __builtin_amdgcn_s_barrier();
        rs0 = rs1;
        wslot = wslot + 1 < 4 ? wslot + 1 : 0;
        mv = nv;
    }
}

// LDS-tiled MFMA stride-1 conv, CIN=COUT=32 (L2b, L4b)
template <bool FINAL>
__global__ __launch_bounds__(512, 4) void conv_lds_k(
    const bf16* __restrict__ in, const bf16* __restrict__ wfrag,
    const float* __restrict__ scale, const float* __restrict__ shift,
    const uint8_t* __restrict__ mask, bf16* __restrict__ out, float* __restrict__ outf,
    int Zo, int Yo, int Xo, int Ypi, int Xpi, int Ypo, int Xpo, int nx, int ny) {
    constexpr int ROWB = 34 * 64;
    __shared__ uint4 tile4[36 * ROWB / 16];
    char* tile = (char*)tile4;

    const int No = Zo * Yo * Xo;
    const int bid = xcd_swz(blockIdx.x, gridDim.x);
    int tx = bid % nx; int tt = bid / nx; int ty = tt % ny; int tz = tt / ny;
    const int z0 = tz * 4, y0 = ty * 4, x0 = tx * 32;

    const int tid = threadIdx.x;
    const int w = tid >> 6, lane = tid & 63, lg = lane >> 4, lr = lane & 15;

    int anywork;
    {
        int row = tid >> 5, xl = tid & 31;
        int zz = z0 + (row >> 2), yy = y0 + (row & 3), xx = x0 + xl;
        int ok = (zz < Zo) && (yy < Yo) && (xx < Xo) && mask[((size_t)zz * Yo + yy) * Xo + xx];
        anywork = __syncthreads_or(ok);
    }

    f32x4 acc[4][2];
#pragma unroll
    for (int s = 0; s < 4; ++s) { acc[s][0] = (f32x4){0,0,0,0}; acc[s][1] = (f32x4){0,0,0,0}; }

    if (anywork) {
        const int lsw = (lane ^ ((lane >> 3) & 7)) * 8;
        for (int rr = w; rr < 36; rr += 8) {
            int dz = rr / 6, dy = rr % 6;
            const bf16* g = in + ((size_t)(z0 + dz) * Ypi + (y0 + dy)) * Xpi * 32 + (size_t)x0 * 32;
            char* l = tile + rr * ROWB;
            glds16(g + lsw, l);
            glds16(g + 512 + lsw, l + 1024);
            if (lane < 8) glds16(g + 1024 + lane * 8, l + 2048);
        }
        asm volatile("s_waitcnt vmcnt(0)" ::: "memory");
        __syncthreads();

        int rbB[4], bsw[4][3];
#pragma unroll
        for (int s = 0; s < 4; ++s) {
            int lrow = 2 * w + (s >> 1);
            rbB[s] = ((lrow >> 2) * 6 + (lrow & 3)) * ROWB;
            int xpart = (s & 1) * 16 + lr;
#pragma unroll
            for (int dx = 0; dx < 3; ++dx) {
                int b = (xpart + dx) * 64 + lg * 16;
                bsw[s][dx] = b ^ (((b >> 7) & 7) << 4);
            }
        }

        const uint4* gw = (const uint4*)wfrag;
#pragma unroll 1
        for (int dz = 0; dz < 3; ++dz) {
#pragma unroll
            for (int dy = 0; dy < 3; ++dy) {
                const int rowoff = (dz * 6 + dy) * ROWB;
#pragma unroll
                for (int dx = 0; dx < 3; ++dx) {
                    const int tap = dz * 9 + dy * 3 + dx;
                    uint4 b0 = gw[(tap * 2 + 0) * 64 + lane];
                    uint4 b1 = gw[(tap * 2 + 1) * 64 + lane];
                    uint4 ua[4];
#pragma unroll
                    for (int s = 0; s < 4; ++s)
                        ua[s] = *(const uint4*)(tile + rbB[s] + rowoff + bsw[s][dx]);
#pragma unroll
                    for (int s = 0; s < 4; ++s) {
                        acc[s][0] = __builtin_amdgcn_mfma_f32_16x16x32_bf16(
                            __builtin_bit_cast(s16x8, ua[s]),
                            __builtin_bit_cast(s16x8, b0), acc[s][0], 0, 0, 0);
                        acc[s][1] = __builtin_amdgcn_mfma_f32_16x16x32_bf16(
                            __builtin_bit_cast(s16x8, ua[s]),
                            __builtin_bit_cast(s16x8, b1), acc[s][1], 0, 0, 0);
                    }
                }
            }
        }
    }

#pragma unroll
    for (int s = 0; s < 4; ++s) {
        int lrow = 2 * w + (s >> 1);
        int zz = z0 + (lrow >> 2), yy = y0 + (lrow & 3);
        int xv = x0 + (s & 1) * 16 + lg * 4;
        bool rowok = (zz < Zo) && (yy < Yo);
        if (!rowok) continue;
        size_t idx0 = ((size_t)zz * Yo + yy) * Xo + xv;
        float mm[4];
#pragma unroll
        for (int r = 0; r < 4; ++r)
            mm[r] = (xv + r < Xo && mask[idx0 + r]) ? 1.f : 0.f;
        if constexpr (FINAL) {
#pragma unroll
            for (int nt = 0; nt < 2; ++nt) {
                int co = nt * 16 + lr;
                float sc = scale[co], sh = shift[co];
                f32x4 o;
#pragma unroll
                for (int r = 0; r < 4; ++r)
                    o[r] = fmaxf(fmaf(acc[s][nt][r], sc, sh), 0.f) * mm[r];
                if (xv + 3 < Xo) {
                    *(f32x4*)(outf + (size_t)co * No + idx0) = o;
                } else {
#pragma unroll
                    for (int r = 0; r < 4; ++r)
                        if (xv + r < Xo) outf[(size_t)co * No + idx0 + r] = o[r];
                }
            }
        } else {
            int opd = ((zz + 1) * Ypo + (yy + 1)) * Xpo + (xv + 1);
#pragma unroll
            for (int nt = 0; nt < 2; ++nt) {
                int co = nt * 16 + lr;
                float sc = scale[co], sh = shift[co];
#pragma unroll
                for (int r = 0; r < 4; ++r) {
                    if (xv + r >= Xo) continue;
                    float yv = fmaxf(fmaf(acc[s][nt][r], sc, sh), 0.f) * mm[r];
                    out[(size_t)(opd + r) * 32 + co] = __float2bfloat16(yv);
                }
            }
        }
    }
}

// global-load MFMA conv, generic stride & block size (L3a, L3b)
template <int CIN, int COUT, int STRIDE, int BLK, bool FINAL>
__global__ __launch_bounds__(BLK, ((CIN <= 32 && COUT <= 32) ? 4 : 2)) void conv_mfma_k(
    const bf16* __restrict__ in, const bf16* __restrict__ wfrag,
    const float* __restrict__ scale, const float* __restrict__ shift,
    const uint8_t* __restrict__ mask, bf16* __restrict__ out, float* __restrict__ outf,
    int Zo, int Yo, int Xo, int Ypi, int Xpi, int Ypo, int Xpo) {
    constexpr int NT = COUT / 16;
    constexpr int KT = CIN / 32;
    const int No = Zo * Yo * Xo;
    const int bid = xcd_swz(blockIdx.x, gridDim.x);
    const int tid = threadIdx.x;
    const int wv = tid >> 6, lane = tid & 63;
    const int lg = lane >> 4, lr = lane & 15;
    const int v0 = bid * BLK + wv * 64;
    if (v0 >= No) return;

    int vm = v0 + lane;
    bool mw = (vm < No) && (mask[vm] != 0);
    const bool anywork = (__ballot(mw) != 0ull);

    f32x4 acc[4][NT];
#pragma unroll
    for (int s = 0; s < 4; ++s)
#pragma unroll
        for (int nt = 0; nt < NT; ++nt) acc[s][nt] = (f32x4){0.f, 0.f, 0.f, 0.f};

    const uint4* gw = (const uint4*)wfrag;

    if (anywork) {
        int pA[4];
#pragma unroll
        for (int s = 0; s < 4; ++s) {
            int vr = v0 + s * 16 + lr;
            if (vr >= No) vr = 0;
            int zz = vr / (Yo * Xo); int rr = vr - zz * (Yo * Xo);
            int yy = rr / Xo; int xx = rr - yy * Xo;
            pA[s] = (((zz * STRIDE + 1) * Ypi + (yy * STRIDE + 1)) * Xpi + (xx * STRIDE + 1)) * CIN + lg * 8;
        }
#pragma unroll
        for (int tap = 0; tap < 27; ++tap) {
            const int kz = tap / 9, r9 = tap - kz * 9, ky = r9 / 3, kx = r9 - ky * 3;
            const int toff = (((kz - 1) * Ypi + (ky - 1)) * Xpi + (kx - 1)) * CIN;
            uint4 ub[NT][KT];
#pragma unroll
            for (int nt = 0; nt < NT; ++nt)
#pragma unroll
                for (int kt = 0; kt < KT; ++kt)
                    ub[nt][kt] = gw[((tap * NT + nt) * KT + kt) * 64 + lane];
            uint4 ua[4][KT];
#pragma unroll
            for (int s = 0; s < 4; ++s)
#pragma unroll
                for (int kt = 0; kt < KT; ++kt)
                    ua[s][kt] = *(const uint4*)(in + pA[s] + toff + kt * 32);
#pragma unroll
            for (int s = 0; s < 4; ++s)
#pragma unroll
                for (int kt = 0; kt < KT; ++kt)
#pragma unroll
                    for (int nt = 0; nt < NT; ++nt)
                        acc[s][nt] = __builtin_amdgcn_mfma_f32_16x16x32_bf16(
                            __builtin_bit_cast(s16x8, ua[s][kt]),
                            __builtin_bit_cast(s16x8, ub[nt][kt]), acc[s][nt], 0, 0, 0);
        }
    }

#pragma unroll
    for (int s = 0; s < 4; ++s) {
        const int vb = v0 + s * 16 + lg * 4;
        int opd[4]; float mm[4]; bool ok[4];
#pragma unroll
        for (int r = 0; r < 4; ++r) {
            int v = vb + r;
            ok[r] = v < No;
            int vc = ok[r] ? v : 0;
            mm[r] = (ok[r] && mask[vc]) ? 1.f : 0.f;
            int zz = vc / (Yo * Xo); int rr = vc - zz * (Yo * Xo);
            int yy = rr / Xo; int xx = rr - yy * Xo;
            opd[r] = FINAL ? vc : ((zz + 1) * Ypo + (yy + 1)) * Xpo + (xx + 1);
        }
#pragma unroll
        for (int nt = 0; nt < NT; ++nt) {
            int co = nt * 16 + lr;
            float sc = scale[co], sh = shift[co];
#pragma unroll
            for (int r = 0; r < 4; ++r) {
                if (!ok[r]) continue;
                float yv = fmaxf(fmaf(acc[s][nt][r], sc, sh), 0.f) * mm[r];
                if constexpr (FINAL) outf[(size_t)co * No + opd[r]] = yv;
                else out[(size_t)opd[r] * COUT + co] = __float2bfloat16(yv);
            }
        }
    }
}

// stride-2 CIN=16 MFMA conv (L2a)
__global__ __launch_bounds__(256, 4) void conv_s2c16_k(
    const bf16* __restrict__ in, const bf16* __restrict__ wfrag,
    const float* __restrict__ scale, const float* __restrict__ shift,
    const uint8_t* __restrict__ mask, bf16* __restrict__ out,
    int Zo, int Yo, int Xo, int Ypi, int Xpi, int Ypo, int Xpo) {
    const int No = Zo * Yo * Xo;
    const int bid = xcd_swz(blockIdx.x, gridDim.x);
    const int tid = threadIdx.x;
    const int wv = tid >> 6, lane = tid & 63;
    const int lg = lane >> 4, lr = lane & 15;
    const int v0 = bid * 256 + wv * 64;
    if (v0 >= No) return;

    int vm = v0 + lane;
    bool mw = (vm < No) && (mask[vm] != 0);
    const bool anywork = (__ballot(mw) != 0ull);

    f32x4 acc[4][2];
#pragma unroll
    for (int s = 0; s < 4; ++s) { acc[s][0] = (f32x4){0,0,0,0}; acc[s][1] = (f32x4){0,0,0,0}; }

    if (anywork) {
        const uint4* gw = (const uint4*)wfrag;
        const int choff = (lg & 1) * 8;
        const int tb = lg >> 1;
        int toffl[14];
#pragma unroll
        for (int p = 0; p < 14; ++p) {
            int tp = 2 * p + tb;
            if (tp >= 27) tp = 0;
            int kz = tp / 9, r9 = tp - kz * 9, ky = r9 / 3, kx = r9 - ky * 3;
            toffl[p] = ((kz * Ypi + ky) * Xpi + kx) * 16;
        }
        int pA[4];
#pragma unroll
        for (int s = 0; s < 4; ++s) {
            int vr = v0 + s * 16 + lr;
            if (vr >= No) vr = 0;
            int zz = vr / (Yo * Xo); int rr = vr - zz * (Yo * Xo);
            int yy = rr / Xo; int xx = rr - yy * Xo;
            pA[s] = (((zz * 2) * Ypi + (yy * 2)) * Xpi + (xx * 2)) * 16 + choff;
        }
#pragma unroll
        for (int p = 0; p < 14; ++p) {
            uint4 b0 = gw[(p * 2 + 0) * 64 + lane];
            uint4 b1 = gw[(p * 2 + 1) * 64 + lane];
            uint4 ua[4];
#pragma unroll
            for (int s = 0; s < 4; ++s)
                ua[s] = *(const uint4*)(in + pA[s] + toffl[p]);
#pragma unroll
            for (int s = 0; s < 4; ++s) {
                acc[s][0] = __builtin_amdgcn_mfma_f32_16x16x32_bf16(
                    __builtin_bit_cast(s16x8, ua[s]),
                    __builtin_bit_cast(s16x8, b0), acc[s][0], 0, 0, 0);
                acc[s][1] = __builtin_amdgcn_mfma_f32_16x16x32_bf16(
                    __builtin_bit_cast(s16x8, ua[s]),
                    __builtin_bit_cast(s16x8, b1), acc[s][1], 0, 0, 0);
            }
        }
    }

#pragma unroll
    for (int s = 0; s < 4; ++s) {
        const int vb = v0 + s * 16 + lg * 4;
        int opd[4]; float mm[4]; bool ok[4];
#pragma unroll
        for (int r = 0; r < 4; ++r) {
            int v = vb + r;
            ok[r] = v < No;
            int vc = ok[r] ? v : 0;
            mm[r] = (ok[r] && mask[vc]) ? 1.f : 0.f;
            int zz = vc / (Yo * Xo); int rr = vc - zz * (Yo * Xo);
            int yy = rr / Xo; int xx = rr - yy * Xo;
            opd[r] = ((zz + 1) * Ypo + (yy + 1)) * Xpo + (xx + 1);
        }
#pragma unroll
        for (int nt = 0; nt < 2; ++nt) {
            int co = nt * 16 + lr;
            float sc = scale[co], sh = shift[co];
#pragma unroll
            for (int r = 0; r < 4; ++r) {
                if (!ok[r]) continue;
                float yv = fmaxf(fmaf(acc[s][nt][r], sc, sh), 0.f) * mm[r];
                out[(size_t)opd[r] * 32 + co] = __float2bfloat16(yv);
            }
        }
    }
}

// MFMA transposed conv (stride 2) via parity octants (L4a)
template <int CIN, int COUT>
__global__ __launch_bounds__(256, 4) void tconv_mfma_k(
    const bf16* __restrict__ in, const bf16* __restrict__ wfrag,
    const float* __restrict__ scale, const float* __restrict__ shift,
    const uint8_t* __restrict__ mask, bf16* __restrict__ out,
    int Zo, int Yo, int Xo, int Ypi, int Xpi, int Ypo, int Xpo) {
    constexpr int NT = COUT / 16;
    constexpr int KT = CIN / 32;
    const int oct = blockIdx.y;
    const int pz = oct >> 2, py = (oct >> 1) & 1, px = oct & 1;
    const int Zq = (Zo - pz + 1) >> 1, Yq = (Yo - py + 1) >> 1, Xq = (Xo - px + 1) >> 1;
    const int Nq = Zq * Yq * Xq;
    const int YXq = Yq * Xq;
    const int bid = xcd_swz(blockIdx.x, gridDim.x);
    const int tid = threadIdx.x;
    const int wv = tid >> 6, lane = tid & 63;
    const int lg = lane >> 4, lr = lane & 15;
    const int v0 = bid * 256 + wv * 64;
    if (v0 >= Nq) return;

    bool mw = false;
    {
        int q = v0 + lane;
        if (q < Nq) {
            int zq = q / YXq; int rr = q - zq * YXq; int yq = rr / Xq; int xq = rr - yq * Xq;
            int zz = 2 * zq + pz, yy = 2 * yq + py, xx = 2 * xq + px;
            mw = mask[(zz * Yo + yy) * Xo + xx] != 0;
        }
    }
    const bool anywork = (__ballot(mw) != 0ull);

    f32x4 acc[4][NT];
#pragma unroll
    for (int s = 0; s < 4; ++s)
#pragma unroll
        for (int nt = 0; nt < NT; ++nt) acc[s][nt] = (f32x4){0.f, 0.f, 0.f, 0.f};

    const uint4* gw = (const uint4*)wfrag;

    if (anywork) {
        int pA[4];
#pragma unroll
        for (int s = 0; s < 4; ++s) {
            int q = v0 + s * 16 + lr;
            if (q >= Nq) q = 0;
            int zq = q / YXq; int rr = q - zq * YXq; int yq = rr / Xq; int xq = rr - yq * Xq;
            pA[s] = (((zq + 1) * Ypi + (yq + 1)) * Xpi + (xq + 1)) * CIN + lg * 8;
        }
        const int nkz = 1 + pz, nky = 1 + py, nkx = 1 + px;
        for (int iz = 0; iz < nkz; ++iz) {
            const int kz = pz ? (iz ? 2 : 0) : 1;
            const int dz = (pz && !iz) ? 1 : 0;
            for (int iy = 0; iy < nky; ++iy) {
                const int ky = py ? (iy ? 2 : 0) : 1;
                const int dy = (py && !iy) ? 1 : 0;
                for (int ix = 0; ix < nkx; ++ix) {
                    const int kx = px ? (ix ? 2 : 0) : 1;
                    const int dx = (px && !ix) ? 1 : 0;
                    const int tap = kz * 9 + ky * 3 + kx;
                    const int toff = ((dz * Ypi + dy) * Xpi + dx) * CIN;
                    uint4 ub[NT][KT];
#pragma unroll
                    for (int nt = 0; nt < NT; ++nt)
#pragma unroll
                        for (int kt = 0; kt < KT; ++kt)
                            ub[nt][kt] = gw[((tap * NT + nt) * KT + kt) * 64 + lane];
                    uint4 ua[4][KT];
#pragma unroll
                    for (int s = 0; s < 4; ++s)
#pragma unroll
                        for (int kt = 0; kt < KT; ++kt)
                            ua[s][kt] = *(const uint4*)(in + pA[s] + toff + kt * 32);
#pragma unroll
                    for (int s = 0; s < 4; ++s)
#pragma unroll
                        for (int kt = 0; kt < KT; ++kt)
#pragma unroll
                            for (int nt = 0; nt < NT; ++nt)
                                acc[s][nt] = __builtin_amdgcn_mfma_f32_16x16x32_bf16(
                                    __builtin_bit_cast(s16x8, ua[s][kt]),
                                    __builtin_bit_cast(s16x8, ub[nt][kt]), acc[s][nt], 0, 0, 0);
                }
            }
        }
    }

#pragma unroll
    for (int s = 0; s < 4; ++s) {
        const int vb = v0 + s * 16 + lg * 4;
        int opd[4]; float mm[4]; bool ok[4];
#pragma unroll
        for (int r = 0; r < 4; ++r) {
            int q = vb + r;
            ok[r] = q < Nq;
            int qc = ok[r] ? q : 0;
            int zq = qc / YXq; int rr = qc - zq * YXq; int yq = rr / Xq; int xq = rr - yq * Xq;
            int zz = 2 * zq + pz, yy = 2 * yq + py, xx = 2 * xq + px;
            mm[r] = (ok[r] && mask[(zz * Yo + yy) * Xo + xx]) ? 1.f : 0.f;
            opd[r] = ((zz + 1) * Ypo + (yy + 1)) * Xpo + (xx + 1);
        }
#pragma unroll
        for (int nt = 0; nt < NT; ++nt) {
            int co = nt * 16 + lr;
            float sc = scale[co], sh = shift[co];
#pragma unroll
            for (int r = 0; r < 4; ++r) {
                if (!ok[r]) continue;
                float yv = fmaxf(fmaf(acc[s][nt][r], sc, sh), 0.f) * mm[r];
                out[(size_t)opd[r] * COUT + co] = __float2bfloat16(yv);
            }
        }
    }
}

__global__ __launch_bounds__(256, 4) void conv_l1_mfma_k(
    const bf16* __restrict__ in, const bf16* __restrict__ wfrag,
    const float* __restrict__ scale, const float* __restrict__ shift,
    const uint8_t* __restrict__ mask, bf16* __restrict__ out,
    int Zo, int Yo, int Xo, int Ypi, int Xpi, int Ypo, int Xpo) {
    const int No = Zo * Yo * Xo;
    const int bid = xcd_swz(blockIdx.x, gridDim.x);
    const int tid = threadIdx.x;
    const int wv = tid >> 6, lane = tid & 63;
    const int lg = lane >> 4, lr = lane & 15;
    const int v0 = bid * 256 + wv * 64;
    if (v0 >= No) return;

    int vm = v0 + lane;
    bool mw = (vm < No) && (mask[vm] != 0);
    const bool anywork = (__ballot(mw) != 0ull);

    f32x4 acc[4];
#pragma unroll
    for (int s = 0; s < 4; ++s) acc[s] = (f32x4){0.f, 0.f, 0.f, 0.f};

    if (anywork) {
        const uint4* gw = (const uint4*)wfrag;
        uint4 bu[4];
#pragma unroll
        for (int kb = 0; kb < 4; ++kb) bu[kb] = gw[kb * 64 + lane];

        int vtf[4][2];
#pragma unroll
        for (int kb = 0; kb < 4; ++kb)
#pragma unroll
            for (int u = 0; u < 2; ++u) {
                int tp = kb * 8 + lg * 2 + u;
                int kz = tp / 9, r9 = tp - kz * 9, ky = r9 / 3, kx = r9 - ky * 3;
                vtf[kb][u] = (tp < 27) ? (((kz - 1) * Ypi + (ky - 1)) * Xpi + (kx - 1)) : 0;
            }

        int pV[4];
#pragma unroll
        for (int s = 0; s < 4; ++s) {
            int vr = v0 + s * 16 + lr;
            if (vr >= No) vr = 0;
            int zz = vr / (Yo * Xo); int rr = vr - zz * (Yo * Xo);
            int yy = rr / Xo; int xx = rr - yy * Xo;
            pV[s] = ((zz + 1) * Ypi + (yy + 1)) * Xpi + (xx + 1);
        }

#pragma unroll
        for (int kb = 0; kb < 4; ++kb) {
#pragma unroll
            for (int s = 0; s < 4; ++s) {
                uint2 a0 = *(const uint2*)(in + (size_t)(pV[s] + vtf[kb][0]) * 4);
                uint2 a1 = *(const uint2*)(in + (size_t)(pV[s] + vtf[kb][1]) * 4);
                int4 ai; ai.x = a0.x; ai.y = a0.y; ai.z = a1.x; ai.w = a1.y;
                acc[s] = __builtin_amdgcn_mfma_f32_16x16x32_bf16(
                    __builtin_bit_cast(s16x8, ai),
                    __builtin_bit_cast(s16x8, bu[kb]), acc[s], 0, 0, 0);
            }
        }
    }

#pragma unroll
    for (int s = 0; s < 4; ++s) {
        const int vb = v0 + s * 16 + lg * 4;
        int co = lr;
        float sc = scale[co], sh = shift[co];
#pragma unroll
        for (int r = 0; r < 4; ++r) {
            int v = vb + r;
            if (v >= No) continue;
            float mm = mask[v] ? 1.f : 0.f;
            int zz = v / (Yo * Xo); int rr = v - zz * (Yo * Xo);
            int yy = rr / Xo; int xx = rr - yy * Xo;
            int opd = ((zz + 1) * Ypo + (yy + 1)) * Xpo + (xx + 1);
            float yv = fmaxf(fmaf(acc[s][r], sc, sh), 0.f) * mm;
            out[(size_t)opd * 16 + co] = __float2bfloat16(yv);
        }
    }
}

inline int nblk(int n) { return (n + 255) / 256; }
inline int cdiv(int a, int b) { return (a + b - 1) / b; }

}  // namespace

extern "C" void kernel_launch(void* const* d_in, const int* in_sizes, int n_in,
                              void* d_out, int out_size, void* d_ws, size_t ws_size,
                              hipStream_t stream) {
    const float* feats = (const float*)d_in[0];
    const int* coords = (const int*)d_in[1];
    const int NVOX = in_sizes[0] / 4;

    const float *w1 = (const float*)d_in[3], *s1 = (const float*)d_in[4], *b1 = (const float*)d_in[5];
    const float *w2a = (const float*)d_in[6], *s2a = (const float*)d_in[7], *b2a = (const float*)d_in[8];
    const float *w2b = (const float*)d_in[9], *s2b = (const float*)d_in[10], *b2b = (const float*)d_in[11];
    const float *w3a = (const float*)d_in[12], *s3a = (const float*)d_in[13], *b3a = (const float*)d_in[14];
    const float *w3b = (const float*)d_in[15], *s3b = (const float*)d_in[16], *b3b = (const float*)d_in[17];
    const float *w4a = (const float*)d_in[18], *s4a = (const float*)d_in[19], *b4a = (const float*)d_in[20];
    const float *w4b = (const float*)d_in[21], *s4b = (const float*)d_in[22], *b4b = (const float*)d_in[23];
    const float *w5a = (const float*)d_in[24], *s5a = (const float*)d_in[25], *b5a = (const float*)d_in[26];
    const float *w5b = (const float*)d_in[27], *s5b = (const float*)d_in[28], *b5b = (const float*)d_in[29];

    char* ws = (char*)d_ws;
    size_t off = 0;
    auto alloc = [&](size_t bytes) -> void* {
        void* p = ws + off;
        off = (off + bytes + 255) & ~(size_t)255;
        return p;
    };

    uint8_t* m0 = (uint8_t*)alloc(NV0);
    uint8_t* m1 = (uint8_t*)alloc(NV0);
    uint8_t* m2 = (uint8_t*)alloc(NV2);
    uint8_t* m3 = (uint8_t*)alloc(NV3);
    uint8_t* m4 = (uint8_t*)alloc(NV4);
    uint8_t* m5 = (uint8_t*)alloc(NV0);

    bf16* slot0 = (bf16*)alloc((size_t)NP0 * 32 * 2);
    bf16* slot1 = (bf16*)alloc((size_t)NP0 * 16 * 2);

    bf16* dense0 = slot0;  // 4ch  @P0
    bf16* x1     = slot1;  // 16ch @P0
    bf16* x2a    = slot0;  // 32ch @P2
    bf16* x2b    = slot1;  // 32ch @P2
    bf16* x3a    = slot0;  // 64ch @P3
    bf16* x3b    = slot1;  // 64ch @P3
    bf16* x4a    = slot0;  // 32ch @P4
    bf16* x4b    = slot1;  // 32ch @(23,130,130)
    bf16* x5a    = slot0;  // 32ch @P0

    bf16* wfL1 = (bf16*)alloc(4 * 64 * 8 * 2);
    bf16* wf2a = (bf16*)alloc((size_t)14 * 2 * 64 * 16);
    bf16* wf2b = (bf16*)alloc((size_t)27 * 2 * 1 * 64 * 16);
    bf16* wf3a = (bf16*)alloc((size_t)27 * 4 * 1 * 64 * 16);
    bf16* wf3b = (bf16*)alloc((size_t)27 * 4 * 2 * 64 * 16);
    bf16* wf4a = (bf16*)alloc((size_t)27 * 2 * 2 * 64 * 16);
    bf16* wf4b = (bf16*)alloc((size_t)27 * 2 * 1 * 64 * 16);
    bf16* wf5a = (bf16*)alloc((size_t)27 * 2 * 1 * 64 * 16);
    bf16* wf5b32 = (bf16*)alloc((size_t)27 * 2 * 64 * 16);   // 32x32 frag order
    alloc(20u << 20);

    if (off > ws_size) {
        sentinel_k<<<1, 256, 0, stream>>>((float*)d_out);
        return;
    }

    // stage 0
    hipMemsetAsync(dense0, 0, (size_t)NP0 * 4 * 2, stream);
    hipMemsetAsync(m0, 0, NV0, stream);
    repack_frag_l1_k<<<1, 256, 0, stream>>>(w1, wfL1);
    repack_frag_c16_k<<<nblk(14 * 2 * 64), 256, 0, stream>>>(w2a, wf2a);
    repack_frag_k<<<nblk(27 * 2 * 64), 256, 0, stream>>>(w2b, wf2b, 32, 32, 0, 0);
    repack_frag_k<<<nblk(27 * 4 * 64), 256, 0, stream>>>(w3a, wf3a, 32, 64, 0, 0);
    repack_frag_k<<<nblk(27 * 8 * 64), 256, 0, stream>>>(w3b, wf3b, 64, 64, 0, 0);
    repack_frag_k<<<nblk(27 * 4 * 64), 256, 0, stream>>>(w4a, wf4a, 64, 32, 1, 0);
    repack_frag_k<<<nblk(27 * 2 * 64), 256, 0, stream>>>(w4b, wf4b, 32, 32, 0, 0);
    repack_frag_k<<<nblk(27 * 2 * 64), 256, 0, stream>>>(w5a, wf5a, 32, 32, 1, 1);  // paired
    repack_frag32_k<<<nblk(27 * 2 * 64), 256, 0, stream>>>(w5b, wf5b32);

    scatter_k<<<nblk(NVOX), 256, 0, stream>>>(feats, coords, dense0, m0, NVOX);

    // level 1
    dilate4_k<<<nblk(NV0 / 4), 256, 0, stream>>>(m0, m1, Z0, Y0, X0);
    halo_zero_k<16><<<nblk(NP0), 256, 0, stream>>>(x1, Z0, Y0, X0, ZP0, YP0, XP0);
    conv_l1_mfma_k<<<nblk(NV0), 256, 0, stream>>>(
        dense0, wfL1, s1, b1, m1, x1, Z0, Y0, X0, YP0, XP0, YP0, XP0);

    // level 2
    dilate_k<<<nblk(NV2), 256, 0, stream>>>(m1, m2, Z0, Y0, X0, Z2, Y2, X2, 2);
    halo_zero_k<32><<<nblk(NP2), 256, 0, stream>>>(x2a, Z2, Y2, X2, ZP2, YP2, XP2);
    conv_s2c16_k<<<nblk(NV2), 256, 0, stream>>>(
        x1, wf2a, s2a, b2a, m2, x2a, Z2, Y2, X2, YP0, XP0, YP2, XP2);
    halo_zero_k<32><<<nblk(NP2), 256, 0, stream>>>(x2b, Z2, Y2, X2, ZP2, YP2, XP2);
    {
        int nx = cdiv(X2, 32), ny = cdiv(Y2, 4), nz = cdiv(Z2, 4);
        conv_lds_k<false><<<nx * ny * nz, 512, 0, stream>>>(
            x2a, wf2b, s2b, b2b, m2, x2b, nullptr, Z2, Y2, X2, YP2, XP2, YP2, XP2, nx, ny);
    }

    // level 3
    dilate_k<<<nblk(NV3), 256, 0, stream>>>(m2, m3, Z2, Y2, X2, Z3, Y3, X3, 2);
    halo_zero_k<64><<<nblk(NP3), 256, 0, stream>>>(x3a, Z3, Y3, X3, ZP3, YP3, XP3);
    conv_mfma_k<32, 64, 2, 64, false><<<cdiv(NV3, 64), 64, 0, stream>>>(
        x2b, wf3a, s3a, b3a, m3, x3a, nullptr, Z3, Y3, X3, YP2, XP2, YP3, XP3);
    halo_zero_k<64><<<nblk(NP3), 256, 0, stream>>>(x3b, Z3, Y3, X3, ZP3, YP3, XP3);
    conv_mfma_k<64, 64, 1, 64, false><<<cdiv(NV3, 64), 64, 0, stream>>>(
        x3a, wf3b, s3b, b3b, m3, x3b, nullptr, Z3, Y3, X3, YP3, XP3, YP3, XP3);

    // level 4 (tconv up via parity octants)
    tdilate_k<<<nblk(NV4), 256, 0, stream>>>(m3, m4, Z3, Y3, X3, Z4, Y4, X4);
    halo_zero_k<32><<<nblk(NP4), 256, 0, stream>>>(x4a, Z4, Y4, X4, ZP4, YP4, XP4);
    {
        int maxNq = ((Z4 + 1) >> 1) * ((Y4 + 1) >> 1) * ((X4 + 1) >> 1);
        dim3 g(nblk(maxNq), 8);
        tconv_mfma_k<64, 32><<<g, 256, 0, stream>>>(
            x3b, wf4a, s4a, b4a, m4, x4a, Z4, Y4, X4, YP3, XP3, YP4, XP4);
    }
    halo_zero_k<32><<<nblk(NP2), 256, 0, stream>>>(x4b, Z4, Y4, X4, ZP2, YP2, XP2);
    {
        int nx = cdiv(X4, 32), ny = cdiv(Y4, 4), nz = cdiv(Z4, 4);
        conv_lds_k<false><<<nx * ny * nz, 512, 0, stream>>>(
            x4a, wf4b, s4b, b4b, m4, x4b, nullptr, Z4, Y4, X4, YP4, XP4, YP2, XP2, nx, ny);
    }

    // level 5 (tconv up, outpad (0,3,3)) — both kernels rolling-z pipelined
    tdilate4_k<<<nblk(NV0 / 4), 256, 0, stream>>>(m4, m5, Z4, Y4, X4, Z0, Y0, X0);
    halo_zero_k<32><<<nblk(NP0), 256, 0, stream>>>(x5a, Z0, Y0, X0, ZP0, YP0, XP0);
    {
        dim3 g((Y0 / 2 / 2) * (X0 / 2 / 32), 8);
        tconv_roll_k<<<g, 256, 0, stream>>>(
            x4b, wf5a, s5a, b5a, m5, x5a, Z0, Y0, X0, Z4, YP2, XP2, YP0, XP0, X0 / 2 / 32);
    }
    {
        conv_roll_k<<<256, 256, 0, stream>>>(
            x5a, wf5b32, s5b, b5b, m5, (float*)d_out);
    }
}